// Round 2
// baseline (8368.964 us; speedup 1.0000x reference)
//
#include <hip/hip_runtime.h>
#include <math.h>

#define N0    4096
#define CIN   128
#define HID   256
#define COUTC 128
#define K1P   3277   // ceil(0.8*4096)
#define K2P   1967   // ceil(0.6*3277)
#define SORT_N 4096

// ---------------- kernels ----------------

__global__ void k_zero32(float* __restrict__ p, size_t n) {
  size_t i = (size_t)blockIdx.x * blockDim.x + threadIdx.x;
  size_t st = (size_t)gridDim.x * blockDim.x;
  for (; i < n; i += st) p[i] = 0.0f;
}

__global__ void k_widen_f32_f64(const float* __restrict__ in, double* __restrict__ out, int n) {
  int i = blockIdx.x * blockDim.x + threadIdx.x;
  int st = gridDim.x * blockDim.x;
  for (; i < n; i += st) out[i] = (double)in[i];
}

__global__ void k_build_adj(const int* __restrict__ ei, float* __restrict__ A, int E, int n) {
  int e = blockIdx.x * blockDim.x + threadIdx.x;
  if (e < E) {
    int src = ei[e];
    int dst = ei[E + e];
    atomicAdd(&A[(size_t)dst * n + src], 1.0f);  // small integer counts: exact in f32
  }
}

// C = offdiag((A+I)@(A+I)) = offdiag(A@A + 2A), all f32, square n x n.
// Exact for integer A with entries/partial sums < 2^24 (true for A0->A1, A1->A2).
// A2p->A3 is inexact (~1e-6 rel) but A3 only affects post-pooling values (2% tol).
__global__ __launch_bounds__(256) void k_aug_f32(
    const float* __restrict__ A, float* __restrict__ C, int n) {
  __shared__ float As[16][64];
  __shared__ float Bs[16][64];
  const int tx = threadIdx.x, ty = threadIdx.y;
  const int tid = ty * 16 + tx;
  const int brow = blockIdx.y * 64, bcol = blockIdx.x * 64;
  float acc[4][4];
#pragma unroll
  for (int i = 0; i < 4; ++i)
#pragma unroll
    for (int j = 0; j < 4; ++j) acc[i][j] = 0.0f;

  const int lac = tid & 15, lar = tid >> 4;
  const int lbc = tid & 63, lbr = tid >> 6;

  for (int kt = 0; kt < n; kt += 16) {
#pragma unroll
    for (int rr = 0; rr < 4; ++rr) {
      int r = lar + rr * 16;
      int gr = brow + r, gk = kt + lac;
      As[lac][r] = (gr < n && gk < n) ? A[(size_t)gr * n + gk] : 0.0f;
    }
#pragma unroll
    for (int rr = 0; rr < 4; ++rr) {
      int br = lbr + rr * 4;
      int gk = kt + br, gc = bcol + lbc;
      Bs[br][lbc] = (gk < n && gc < n) ? A[(size_t)gk * n + gc] : 0.0f;
    }
    __syncthreads();
#pragma unroll
    for (int kk = 0; kk < 16; ++kk) {
      float a[4], b[4];
#pragma unroll
      for (int i = 0; i < 4; ++i) a[i] = As[kk][ty * 4 + i];
#pragma unroll
      for (int j = 0; j < 4; ++j) b[j] = Bs[kk][tx * 4 + j];
#pragma unroll
      for (int i = 0; i < 4; ++i)
#pragma unroll
        for (int j = 0; j < 4; ++j) acc[i][j] = fmaf(a[i], b[j], acc[i][j]);
    }
    __syncthreads();
  }
#pragma unroll
  for (int i = 0; i < 4; ++i) {
    int gr = brow + ty * 4 + i;
    if (gr >= n) continue;
#pragma unroll
    for (int j = 0; j < 4; ++j) {
      int gc = bcol + tx * 4 + j;
      if (gc >= n) continue;
      float v = acc[i][j];
      v = (gr == gc) ? 0.0f : v + 2.0f * A[(size_t)gr * n + gc];
      C[(size_t)gr * n + gc] = v;
    }
  }
}

// C f64[M,N] = X f64[M,K] @ W f32[K,N]   (t = x @ W, ordering-critical -> f64)
__global__ __launch_bounds__(256) void k_gemm_xw(
    const double* __restrict__ X, const float* __restrict__ W, double* __restrict__ C,
    int M, int N, int K) {
  __shared__ double As[16][64];
  __shared__ double Bs[16][64];
  const int tx = threadIdx.x, ty = threadIdx.y;
  const int tid = ty * 16 + tx;
  const int brow = blockIdx.y * 64, bcol = blockIdx.x * 64;
  double acc[4][4];
#pragma unroll
  for (int i = 0; i < 4; ++i)
#pragma unroll
    for (int j = 0; j < 4; ++j) acc[i][j] = 0.0;
  const int lac = tid & 15, lar = tid >> 4;
  const int lbc = tid & 63, lbr = tid >> 6;
  for (int kt = 0; kt < K; kt += 16) {
#pragma unroll
    for (int rr = 0; rr < 4; ++rr) {
      int r = lar + rr * 16;
      int gr = brow + r, gk = kt + lac;
      As[lac][r] = (gr < M && gk < K) ? X[(size_t)gr * K + gk] : 0.0;
    }
#pragma unroll
    for (int rr = 0; rr < 4; ++rr) {
      int br = lbr + rr * 4;
      int gk = kt + br, gc = bcol + lbc;
      Bs[br][lbc] = (gk < K && gc < N) ? (double)W[(size_t)gk * N + gc] : 0.0;
    }
    __syncthreads();
#pragma unroll
    for (int kk = 0; kk < 16; ++kk) {
      double a[4], b[4];
#pragma unroll
      for (int i = 0; i < 4; ++i) a[i] = As[kk][ty * 4 + i];
#pragma unroll
      for (int j = 0; j < 4; ++j) b[j] = Bs[kk][tx * 4 + j];
#pragma unroll
      for (int i = 0; i < 4; ++i)
#pragma unroll
        for (int j = 0; j < 4; ++j) acc[i][j] = fma(a[i], b[j], acc[i][j]);
    }
    __syncthreads();
  }
#pragma unroll
  for (int i = 0; i < 4; ++i) {
    int gr = brow + ty * 4 + i;
    if (gr >= M) continue;
#pragma unroll
    for (int j = 0; j < 4; ++j) {
      int gc = bcol + tx * 4 + j;
      if (gc >= N) continue;
      C[(size_t)gr * N + gc] = acc[i][j];
    }
  }
}

// Y f64[M,N] = A f32[M,K] @ diag(dinv) @ T f64[K,N]
__global__ __launch_bounds__(256) void k_gemm_ax(
    const float* __restrict__ A, const double* __restrict__ T,
    const double* __restrict__ dinv, double* __restrict__ Y,
    int M, int N, int K) {
  __shared__ float  As[16][64];
  __shared__ double Bs[16][64];
  const int tx = threadIdx.x, ty = threadIdx.y;
  const int tid = ty * 16 + tx;
  const int brow = blockIdx.y * 64, bcol = blockIdx.x * 64;
  double acc[4][4];
#pragma unroll
  for (int i = 0; i < 4; ++i)
#pragma unroll
    for (int j = 0; j < 4; ++j) acc[i][j] = 0.0;
  const int lac = tid & 15, lar = tid >> 4;
  const int lbc = tid & 63, lbr = tid >> 6;
  for (int kt = 0; kt < K; kt += 16) {
#pragma unroll
    for (int rr = 0; rr < 4; ++rr) {
      int r = lar + rr * 16;
      int gr = brow + r, gk = kt + lac;
      As[lac][r] = (gr < M && gk < K) ? A[(size_t)gr * K + gk] : 0.0f;
    }
#pragma unroll
    for (int rr = 0; rr < 4; ++rr) {
      int br = lbr + rr * 4;
      int gk = kt + br, gc = bcol + lbc;
      Bs[br][lbc] = (gk < K && gc < N) ? dinv[gk] * T[(size_t)gk * N + gc] : 0.0;
    }
    __syncthreads();
#pragma unroll
    for (int kk = 0; kk < 16; ++kk) {
      double a[4], b[4];
#pragma unroll
      for (int i = 0; i < 4; ++i) a[i] = (double)As[kk][ty * 4 + i];
#pragma unroll
      for (int j = 0; j < 4; ++j) b[j] = Bs[kk][tx * 4 + j];
#pragma unroll
      for (int i = 0; i < 4; ++i)
#pragma unroll
        for (int j = 0; j < 4; ++j) acc[i][j] = fma(a[i], b[j], acc[i][j]);
    }
    __syncthreads();
  }
#pragma unroll
  for (int i = 0; i < 4; ++i) {
    int gr = brow + ty * 4 + i;
    if (gr >= M) continue;
#pragma unroll
    for (int j = 0; j < 4; ++j) {
      int gc = bcol + tx * 4 + j;
      if (gc >= N) continue;
      Y[(size_t)gr * N + gc] = acc[i][j];
    }
  }
}

__global__ void k_degdinv(const float* __restrict__ A, double* __restrict__ dinv, int n) {
  __shared__ double red[256];
  int row = blockIdx.x;
  double s = 0.0;
  for (int j = threadIdx.x; j < n; j += 256) s += (double)A[(size_t)row * n + j];
  red[threadIdx.x] = s;
  __syncthreads();
  for (int st = 128; st > 0; st >>= 1) {
    if (threadIdx.x < st) red[threadIdx.x] += red[threadIdx.x + st];
    __syncthreads();
  }
  if (threadIdx.x == 0) {
    double deg = red[0] + 2.0;
    dinv[row] = (deg > 0.0) ? 1.0 / sqrt(deg) : 0.0;
  }
}

__global__ void k_gcn_fin(const double* __restrict__ y, const double* __restrict__ t,
                          const double* __restrict__ dinv, const float* __restrict__ b,
                          double* __restrict__ out, int C, int relu) {
  int row = blockIdx.x;
  double d = dinv[row];
  for (int c = threadIdx.x; c < C; c += blockDim.x) {
    double v = d * (y[(size_t)row * C + c] + 2.0 * d * t[(size_t)row * C + c]) + (double)b[c];
    if (relu) v = v > 0.0 ? v : 0.0;
    out[(size_t)row * C + c] = v;
  }
}

__global__ void k_pnorm(const float* __restrict__ p, double* __restrict__ pn, int C) {
  __shared__ double red[256];
  double s = 0.0;
  for (int j = threadIdx.x; j < C; j += 256) { double v = (double)p[j]; s += v * v; }
  red[threadIdx.x] = s;
  __syncthreads();
  for (int st = 128; st > 0; st >>= 1) {
    if (threadIdx.x < st) red[threadIdx.x] += red[threadIdx.x + st];
    __syncthreads();
  }
  if (threadIdx.x == 0) pn[0] = sqrt(red[0]);
}

__global__ void k_scores(const double* __restrict__ x, const float* __restrict__ p,
                         const double* __restrict__ pn, double* __restrict__ sc, int C) {
  __shared__ double red[256];
  int row = blockIdx.x;
  double s = 0.0;
  for (int j = threadIdx.x; j < C; j += 256) s += x[(size_t)row * C + j] * (double)p[j];
  red[threadIdx.x] = s;
  __syncthreads();
  for (int st = 128; st > 0; st >>= 1) {
    if (threadIdx.x < st) red[threadIdx.x] += red[threadIdx.x + st];
    __syncthreads();
  }
  if (threadIdx.x == 0) sc[row] = tanh(red[0] / pn[0]);
}

__global__ __launch_bounds__(1024) void k_topk(const double* __restrict__ sc, int n,
                                               int* __restrict__ perm, double* __restrict__ vals) {
  __shared__ double s[SORT_N];
  __shared__ int id[SORT_N];
  const int t = threadIdx.x;
  for (int i = t; i < SORT_N; i += 1024) {
    s[i] = (i < n) ? sc[i] : -INFINITY;
    id[i] = i;
  }
  __syncthreads();
  for (int size = 2; size <= SORT_N; size <<= 1) {
    for (int stride = size >> 1; stride > 0; stride >>= 1) {
      for (int i = t; i < SORT_N; i += 1024) {
        int l = i ^ stride;
        if (l > i) {
          double si = s[i], sl = s[l];
          int ii = id[i], il = id[l];
          bool iAfterL = (sl > si) || (sl == si && il < ii);
          bool up = ((i & size) == 0);
          if (iAfterL == up) { s[i] = sl; s[l] = si; id[i] = il; id[l] = ii; }
        }
      }
      __syncthreads();
    }
  }
  for (int i = t; i < n; i += 1024) { perm[i] = id[i]; vals[i] = s[i]; }
}

__global__ void k_gather_x(const double* __restrict__ x, const int* __restrict__ perm,
                           const double* __restrict__ vals, double* __restrict__ xo, int C) {
  int row = blockIdx.x;
  int src = perm[row];
  double v = vals[row];
  for (int c = threadIdx.x; c < C; c += blockDim.x)
    xo[(size_t)row * C + c] = x[(size_t)src * C + c] * v;
}

__global__ void k_gather_A(const float* __restrict__ A, const int* __restrict__ perm,
                           float* __restrict__ Ao, int k, int lda) {
  int j = blockIdx.x * 16 + threadIdx.x;
  int i = blockIdx.y * 16 + threadIdx.y;
  if (i < k && j < k)
    Ao[(size_t)i * k + j] = A[(size_t)perm[i] * lda + perm[j]];
}

__global__ void k_write_out(const double* __restrict__ x, float* __restrict__ out,
                            int nvals, int total) {
  int i = blockIdx.x * blockDim.x + threadIdx.x;
  int st = gridDim.x * blockDim.x;
  for (; i < total; i += st) out[i] = (i < nvals) ? (float)x[i] : 0.0f;
}

__global__ void k_sentinel(float* __restrict__ out, int total) {
  int i = blockIdx.x * blockDim.x + threadIdx.x;
  int st = gridDim.x * blockDim.x;
  for (; i < total; i += st) out[i] = 1e30f;
}

// ---------------- driver ----------------

extern "C" void kernel_launch(void* const* d_in, const int* in_sizes, int n_in,
                              void* d_out, int out_size, void* d_ws, size_t ws_size,
                              hipStream_t stream) {
  const float* x0f  = (const float*)d_in[0];
  const int*   ei   = (const int*)d_in[1];
  const float* W0   = (const float*)d_in[2];
  const float* b0   = (const float*)d_in[3];
  const float* W1   = (const float*)d_in[4];
  const float* b1   = (const float*)d_in[5];
  const float* W2   = (const float*)d_in[6];
  const float* b2   = (const float*)d_in[7];
  const float* p1   = (const float*)d_in[8];
  const float* p2   = (const float*)d_in[9];
  const float* Wout = (const float*)d_in[10];
  const float* bout = (const float*)d_in[11];
  const int E = in_sizes[1] / 2;

  size_t off = 0;
  auto take = [&](size_t bytes) -> void* {
    void* p = (char*)d_ws + off;
    off += (bytes + 255) & ~(size_t)255;
    return p;
  };
  float*  A_a  = (float*)take((size_t)N0 * N0 * 4);
  float*  A_b  = (float*)take((size_t)N0 * N0 * 4);
  double* tb   = (double*)take((size_t)N0 * HID * 8);
  double* yb   = (double*)take((size_t)N0 * HID * 8);
  double* xA   = (double*)take((size_t)N0 * HID * 8);
  double* xB   = (double*)take((size_t)N0 * HID * 8);
  double* dinv = (double*)take((size_t)N0 * 8);
  double* sc   = (double*)take((size_t)N0 * 8);
  double* vals = (double*)take((size_t)N0 * 8);
  double* pn   = (double*)take(256);
  int*    perm = (int*)take((size_t)N0 * 4);
  // total ~168.3 MB

  if (off > ws_size) {
    k_sentinel<<<dim3(256), dim3(256), 0, stream>>>((float*)d_out, out_size);
    return;
  }

  auto aug = [&](const float* A, float* C, int n) {
    dim3 g((n + 63) / 64, (n + 63) / 64), b(16, 16);
    k_aug_f32<<<g, b, 0, stream>>>(A, C, n);
  };

  auto gcn = [&](const float* Amat, int n, const double* xin, int cin,
                 const float* Wf, const float* bf, int cout, int relu,
                 double* xout, bool newdinv) {
    dim3 b(16, 16);
    dim3 g1((cout + 63) / 64, (n + 63) / 64);
    k_gemm_xw<<<g1, b, 0, stream>>>(xin, Wf, tb, n, cout, cin);
    if (newdinv) k_degdinv<<<dim3(n), dim3(256), 0, stream>>>(Amat, dinv, n);
    k_gemm_ax<<<g1, b, 0, stream>>>(Amat, tb, dinv, yb, n, cout, n);
    k_gcn_fin<<<dim3(n), dim3(256), 0, stream>>>(yb, tb, dinv, bf, xout, cout, relu);
  };

  auto pool = [&](const double* x, int n, const float* pw, int k,
                  const float* Ain, int lda, float* Aout, double* xout) {
    k_pnorm<<<dim3(1), dim3(256), 0, stream>>>(pw, pn, HID);
    k_scores<<<dim3(n), dim3(256), 0, stream>>>(x, pw, pn, sc, HID);
    k_topk<<<dim3(1), dim3(1024), 0, stream>>>(sc, n, perm, vals);
    k_gather_x<<<dim3(k), dim3(256), 0, stream>>>(x, perm, vals, xout, HID);
    dim3 g((k + 15) / 16, (k + 15) / 16);
    k_gather_A<<<g, dim3(16, 16), 0, stream>>>(Ain, perm, Aout, k, lda);
  };

  // ---- pipeline ----
  k_zero32<<<dim3(2048), dim3(256), 0, stream>>>(A_b, (size_t)N0 * N0);
  k_build_adj<<<dim3((E + 255) / 256), dim3(256), 0, stream>>>(ei, A_b, E, N0);

  // A1 = augment(A0) -> A_a
  aug(A_b, A_a, N0);

  // x1 = relu(gcn(x0, A1)) -> xA (4096x256)
  k_widen_f32_f64<<<dim3(512), dim3(256), 0, stream>>>(x0f, xB, N0 * CIN);
  gcn(A_a, N0, xB, CIN, W0, b0, HID, 1, xA, true);

  // A2 = augment(A1) -> A_b
  aug(A_a, A_b, N0);

  // pool1 -> xB (3277x256), A2p -> A_a
  pool(xA, N0, p1, K1P, A_b, N0, A_a, xB);

  // x2 -> xA
  gcn(A_a, K1P, xB, HID, W1, b1, HID, 1, xA, true);

  // A3 = augment(A2p) -> A_b
  aug(A_a, A_b, K1P);

  // pool2 -> xB (1967x256), A3p -> A_a
  pool(xA, K1P, p2, K2P, A_b, K1P, A_a, xB);

  // x3 -> xA
  gcn(A_a, K2P, xB, HID, W2, b2, HID, 1, xA, true);

  // out -> xB (1967x128), reuse dinv
  gcn(A_a, K2P, xA, HID, Wout, bout, COUTC, 0, xB, false);

  k_write_out<<<dim3(1024), dim3(256), 0, stream>>>(xB, (float*)d_out, K2P * COUTC, out_size);
}

// Round 3
// 4432.006 us; speedup vs baseline: 1.8883x; 1.8883x over previous
//
#include <hip/hip_runtime.h>
#include <math.h>

#define N0    4096
#define CIN   128
#define HID   256
#define COUTC 128
#define K1P   3277   // ceil(0.8*4096)
#define K2P   1967   // ceil(0.6*3277)
#define K1PAD 3328   // K1P padded to 128
#define K2PAD 2048   // K2P padded to 128
#define SORT_N 4096

typedef __attribute__((ext_vector_type(8))) short bf16x8;
typedef __attribute__((ext_vector_type(4))) float f32x4;

__device__ __forceinline__ float b2f(short s) {
  unsigned u = ((unsigned)(unsigned short)s) << 16;
  return __builtin_bit_cast(float, u);
}
__device__ __forceinline__ short f2b(float f) {  // round-to-nearest-even bf16
  unsigned u = __builtin_bit_cast(unsigned, f);
  u = (u + 0x7fffu + ((u >> 16) & 1u)) >> 16;
  return (short)u;
}

// ---------------- elementwise / build ----------------

__global__ void k_zero32(float* __restrict__ p, size_t n) {
  size_t i = (size_t)blockIdx.x * blockDim.x + threadIdx.x;
  size_t st = (size_t)gridDim.x * blockDim.x;
  for (; i < n; i += st) p[i] = 0.0f;
}

__global__ void k_widen_f32_f64(const float* __restrict__ in, double* __restrict__ out, int n) {
  int i = blockIdx.x * blockDim.x + threadIdx.x;
  int st = gridDim.x * blockDim.x;
  for (; i < n; i += st) out[i] = (double)in[i];
}

__global__ void k_build_adj(const int* __restrict__ ei, float* __restrict__ A, int E, int n) {
  int e = blockIdx.x * blockDim.x + threadIdx.x;
  if (e < E) {
    int src = ei[e];
    int dst = ei[E + e];
    atomicAdd(&A[(size_t)dst * n + src], 1.0f);  // small integer counts: exact in f32
  }
}

// f32 (exact small ints) -> bf16 (exact for |v| <= 256)
__global__ void k_split_bf16(const float* __restrict__ in, short* __restrict__ out, size_t n) {
  size_t i = (size_t)blockIdx.x * blockDim.x + threadIdx.x;
  size_t st = (size_t)gridDim.x * blockDim.x;
  for (; i < n; i += st) out[i] = f2b(in[i]);
}

// out[j*dstld + k] = (j<M) ? in[k*srcld + (perm?perm[j]:j)] : 0, for j in [0,Mp), k in [0,K)
__global__ void k_gatherT_bf16(const short* __restrict__ in, const int* __restrict__ perm,
                               short* __restrict__ out, int M, int K, int srcld, int dstld) {
  int j = blockIdx.x;
  int pj = (j < M) ? (perm ? perm[j] : j) : 0;
  for (int k = threadIdx.x; k < K; k += blockDim.x) {
    short v = (j < M) ? in[(size_t)k * srcld + pj] : (short)0;
    out[(size_t)j * dstld + k] = v;
  }
}

// out[i*dstld + k] = (i<M) ? in[perm[i]*srcld + k] : 0   (bf16 rows, vectorized)
__global__ void k_gather_rows_bf16(const short* __restrict__ in, const int* __restrict__ perm,
                                   short* __restrict__ out, int M, int K, int srcld, int dstld) {
  int i = blockIdx.x;
  if (i < M) {
    const short* src = in + (size_t)perm[i] * srcld;
    short* dst = out + (size_t)i * dstld;
    for (int k = threadIdx.x * 8; k < K; k += blockDim.x * 8)
      *(int4*)(dst + k) = *(const int4*)(src + k);
  } else {
    short* dst = out + (size_t)i * dstld;
    for (int k = threadIdx.x * 8; k < K; k += blockDim.x * 8)
      *(int4*)(dst + k) = make_int4(0, 0, 0, 0);
  }
}

// row-gather + bf16 split: b = rn(v), r = v - b (both exact); pads -> 0
__global__ void k_gatherR_split_f32(const float* __restrict__ in, const int* __restrict__ perm,
                                    short* __restrict__ ob, short* __restrict__ orr,
                                    int M, int K, int Kp, int srcld) {
  int i = blockIdx.x;
  const float* src = (i < M) ? in + (size_t)perm[i] * srcld : nullptr;
  for (int k = threadIdx.x; k < Kp; k += blockDim.x) {
    float v = (i < M && k < K) ? src[k] : 0.0f;
    short b = f2b(v);
    float r = v - b2f(b);
    ob[(size_t)i * Kp + k] = b;
    orr[(size_t)i * Kp + k] = f2b(r);
  }
}

// transposed gather + split: v = in[k*srcld + perm[j]]
__global__ void k_gatherT_split_f32(const float* __restrict__ in, const int* __restrict__ perm,
                                    short* __restrict__ ob, short* __restrict__ orr,
                                    int M, int K, int Kp, int srcld) {
  int j = blockIdx.x;
  int pj = (j < M) ? perm[j] : 0;
  for (int k = threadIdx.x; k < Kp; k += blockDim.x) {
    float v = (j < M && k < K) ? in[(size_t)k * srcld + pj] : 0.0f;
    short b = f2b(v);
    float r = v - b2f(b);
    ob[(size_t)j * Kp + k] = b;
    orr[(size_t)j * Kp + k] = f2b(r);
  }
}

// ---------------- MFMA augment GEMM ----------------
// C = L @ Rt^T (+ TERMS=3 cross terms) with augment epilogue.
// L row-major [Mp][K] pitch ldk; Rt row-major [Np][K] pitch ldk (Rt[j][k] = R[k][j]).
// EP=0: v += 2*bf16(EpB[grow][gcol]); out bf16 Cb.   (aug1: full square)
// EP=1: v += 2*bf16(EpB[perm[grow]][perm[gcol]]); out f32.  (aug2: pre-gathered)
// EP=2: v += 2*EpF[perm[grow]][perm[gcol]]; out f32.        (aug3: pre-gathered, 3-term)
// diag (grow==gcol) -> 0.
template <int TERMS, int EP>
__global__ __launch_bounds__(256) void k_aug_mfma(
    const short* __restrict__ La, const short* __restrict__ Lr,
    const short* __restrict__ Rta, const short* __restrict__ Rtr,
    int K, int ldk,
    const int* __restrict__ perm,
    const short* __restrict__ EpB, int epldB,
    const float* __restrict__ EpF, int epldF,
    float* __restrict__ Cf, short* __restrict__ Cb,
    int M, int N, int ldc)
{
  constexpr int NT = (TERMS == 3) ? 4 : 2;
  __shared__ __align__(16) short Ls[NT][128 * 32];
  const int tid = threadIdx.x;
  const int wave = tid >> 6, lane = tid & 63;
  const int wr = wave >> 1, wc = wave & 1;
  const int brow = blockIdx.y * 128, bcol = blockIdx.x * 128;
  const int lr = lane & 15, ko = (lane >> 4) * 8;

  const short* gsrc[NT];
  int rbase[NT];
  gsrc[0] = La;  rbase[0] = brow;
  gsrc[1] = Rta; rbase[1] = bcol;
  if (TERMS == 3) { gsrc[2] = Lr; rbase[2] = brow; gsrc[3] = Rtr; rbase[3] = bcol; }

  f32x4 acc[4][4];
#pragma unroll
  for (int m = 0; m < 4; ++m)
#pragma unroll
    for (int n = 0; n < 4; ++n) acc[m][n] = (f32x4){0.f, 0.f, 0.f, 0.f};

  const int srow0 = (wave << 4) + (lane >> 2);  // + it*64
  const int scol = (lane & 3) * 8;
  const int lds_off = wave * 512 + lane * 8;    // + it*2048 (shorts)

  for (int kt = 0; kt < K; kt += 32) {
    int4 st[NT][2];
#pragma unroll
    for (int t = 0; t < NT; ++t)
#pragma unroll
      for (int it = 0; it < 2; ++it)
        st[t][it] = *(const int4*)(gsrc[t] + (size_t)(rbase[t] + it * 64 + srow0) * ldk + kt + scol);
    __syncthreads();
#pragma unroll
    for (int t = 0; t < NT; ++t)
#pragma unroll
      for (int it = 0; it < 2; ++it)
        *(int4*)&Ls[t][it * 2048 + lds_off] = st[t][it];
    __syncthreads();

    bf16x8 a0[4], b0[4];
#pragma unroll
    for (int m = 0; m < 4; ++m) a0[m] = *(const bf16x8*)&Ls[0][(wr * 64 + m * 16 + lr) * 32 + ko];
#pragma unroll
    for (int n = 0; n < 4; ++n) b0[n] = *(const bf16x8*)&Ls[1][(wc * 64 + n * 16 + lr) * 32 + ko];
    if (TERMS == 3) {
      bf16x8 a1[4], b1[4];
#pragma unroll
      for (int m = 0; m < 4; ++m) a1[m] = *(const bf16x8*)&Ls[2][(wr * 64 + m * 16 + lr) * 32 + ko];
#pragma unroll
      for (int n = 0; n < 4; ++n) b1[n] = *(const bf16x8*)&Ls[3][(wc * 64 + n * 16 + lr) * 32 + ko];
#pragma unroll
      for (int m = 0; m < 4; ++m)
#pragma unroll
        for (int n = 0; n < 4; ++n) {
          acc[m][n] = __builtin_amdgcn_mfma_f32_16x16x32_bf16(a0[m], b0[n], acc[m][n], 0, 0, 0);
          acc[m][n] = __builtin_amdgcn_mfma_f32_16x16x32_bf16(a0[m], b1[n], acc[m][n], 0, 0, 0);
          acc[m][n] = __builtin_amdgcn_mfma_f32_16x16x32_bf16(a1[m], b0[n], acc[m][n], 0, 0, 0);
        }
    } else {
#pragma unroll
      for (int m = 0; m < 4; ++m)
#pragma unroll
        for (int n = 0; n < 4; ++n)
          acc[m][n] = __builtin_amdgcn_mfma_f32_16x16x32_bf16(a0[m], b0[n], acc[m][n], 0, 0, 0);
    }
  }

#pragma unroll
  for (int m = 0; m < 4; ++m)
#pragma unroll
    for (int n = 0; n < 4; ++n)
#pragma unroll
      for (int q = 0; q < 4; ++q) {
        int grow = brow + wr * 64 + m * 16 + (lane >> 4) * 4 + q;
        int gcol = bcol + wc * 64 + n * 16 + lr;
        if (grow < M && gcol < N) {
          float v = acc[m][n][q];
          if (EP == 0)      v += 2.0f * b2f(EpB[(size_t)grow * epldB + gcol]);
          else if (EP == 1) v += 2.0f * b2f(EpB[(size_t)perm[grow] * epldB + perm[gcol]]);
          else              v += 2.0f * EpF[(size_t)perm[grow] * epldF + perm[gcol]];
          if (grow == gcol) v = 0.0f;
          if (EP == 0) Cb[(size_t)grow * ldc + gcol] = f2b(v);
          else         Cf[(size_t)grow * ldc + gcol] = v;
        }
      }
}

// ---------------- f64 feature path (ordering-critical) ----------------

// C f64[M,N] = X f64[M,K] @ W f32[K,N]
__global__ __launch_bounds__(256) void k_gemm_xw(
    const double* __restrict__ X, const float* __restrict__ W, double* __restrict__ C,
    int M, int N, int K) {
  __shared__ double As[16][64];
  __shared__ double Bs[16][64];
  const int tx = threadIdx.x, ty = threadIdx.y;
  const int tid = ty * 16 + tx;
  const int brow = blockIdx.y * 64, bcol = blockIdx.x * 64;
  double acc[4][4];
#pragma unroll
  for (int i = 0; i < 4; ++i)
#pragma unroll
    for (int j = 0; j < 4; ++j) acc[i][j] = 0.0;
  const int lac = tid & 15, lar = tid >> 4;
  const int lbc = tid & 63, lbr = tid >> 6;
  for (int kt = 0; kt < K; kt += 16) {
#pragma unroll
    for (int rr = 0; rr < 4; ++rr) {
      int r = lar + rr * 16;
      int gr = brow + r, gk = kt + lac;
      As[lac][r] = (gr < M && gk < K) ? X[(size_t)gr * K + gk] : 0.0;
    }
#pragma unroll
    for (int rr = 0; rr < 4; ++rr) {
      int br = lbr + rr * 4;
      int gk = kt + br, gc = bcol + lbc;
      Bs[br][lbc] = (gk < K && gc < N) ? (double)W[(size_t)gk * N + gc] : 0.0;
    }
    __syncthreads();
#pragma unroll
    for (int kk = 0; kk < 16; ++kk) {
      double a[4], b[4];
#pragma unroll
      for (int i = 0; i < 4; ++i) a[i] = As[kk][ty * 4 + i];
#pragma unroll
      for (int j = 0; j < 4; ++j) b[j] = Bs[kk][tx * 4 + j];
#pragma unroll
      for (int i = 0; i < 4; ++i)
#pragma unroll
        for (int j = 0; j < 4; ++j) acc[i][j] = fma(a[i], b[j], acc[i][j]);
    }
    __syncthreads();
  }
#pragma unroll
  for (int i = 0; i < 4; ++i) {
    int gr = brow + ty * 4 + i;
    if (gr >= M) continue;
#pragma unroll
    for (int j = 0; j < 4; ++j) {
      int gc = bcol + tx * 4 + j;
      if (gc >= N) continue;
      C[(size_t)gr * N + gc] = acc[i][j];
    }
  }
}

template <typename TA>
__device__ __forceinline__ float a_as_f32(TA v);
template <> __device__ __forceinline__ float a_as_f32<short>(short v) { return b2f(v); }
template <> __device__ __forceinline__ float a_as_f32<float>(float v) { return v; }

// Y f64[M,N] = A[M,K] @ diag(dinv) @ T f64[K,N]; A is bf16(short) or f32
template <typename TA>
__global__ __launch_bounds__(256) void k_gemm_ax(
    const TA* __restrict__ A, int lda, const double* __restrict__ T,
    const double* __restrict__ dinv, double* __restrict__ Y,
    int M, int N, int K) {
  __shared__ float  As[16][64];
  __shared__ double Bs[16][64];
  const int tx = threadIdx.x, ty = threadIdx.y;
  const int tid = ty * 16 + tx;
  const int brow = blockIdx.y * 64, bcol = blockIdx.x * 64;
  double acc[4][4];
#pragma unroll
  for (int i = 0; i < 4; ++i)
#pragma unroll
    for (int j = 0; j < 4; ++j) acc[i][j] = 0.0;
  const int lac = tid & 15, lar = tid >> 4;
  const int lbc = tid & 63, lbr = tid >> 6;
  for (int kt = 0; kt < K; kt += 16) {
#pragma unroll
    for (int rr = 0; rr < 4; ++rr) {
      int r = lar + rr * 16;
      int gr = brow + r, gk = kt + lac;
      As[lac][r] = (gr < M && gk < K) ? a_as_f32<TA>(A[(size_t)gr * lda + gk]) : 0.0f;
    }
#pragma unroll
    for (int rr = 0; rr < 4; ++rr) {
      int br = lbr + rr * 4;
      int gk = kt + br, gc = bcol + lbc;
      Bs[br][lbc] = (gk < K && gc < N) ? dinv[gk] * T[(size_t)gk * N + gc] : 0.0;
    }
    __syncthreads();
#pragma unroll
    for (int kk = 0; kk < 16; ++kk) {
      double a[4], b[4];
#pragma unroll
      for (int i = 0; i < 4; ++i) a[i] = (double)As[kk][ty * 4 + i];
#pragma unroll
      for (int j = 0; j < 4; ++j) b[j] = Bs[kk][tx * 4 + j];
#pragma unroll
      for (int i = 0; i < 4; ++i)
#pragma unroll
        for (int j = 0; j < 4; ++j) acc[i][j] = fma(a[i], b[j], acc[i][j]);
    }
    __syncthreads();
  }
#pragma unroll
  for (int i = 0; i < 4; ++i) {
    int gr = brow + ty * 4 + i;
    if (gr >= M) continue;
#pragma unroll
    for (int j = 0; j < 4; ++j) {
      int gc = bcol + tx * 4 + j;
      if (gc >= N) continue;
      Y[(size_t)gr * N + gc] = acc[i][j];
    }
  }
}

template <typename TA>
__global__ void k_degdinv(const TA* __restrict__ A, int lda, double* __restrict__ dinv, int n) {
  __shared__ double red[256];
  int row = blockIdx.x;
  double s = 0.0;
  for (int j = threadIdx.x; j < n; j += 256) s += (double)a_as_f32<TA>(A[(size_t)row * lda + j]);
  red[threadIdx.x] = s;
  __syncthreads();
  for (int st = 128; st > 0; st >>= 1) {
    if (threadIdx.x < st) red[threadIdx.x] += red[threadIdx.x + st];
    __syncthreads();
  }
  if (threadIdx.x == 0) {
    double deg = red[0] + 2.0;
    dinv[row] = (deg > 0.0) ? 1.0 / sqrt(deg) : 0.0;
  }
}

__global__ void k_gcn_fin(const double* __restrict__ y, const double* __restrict__ t,
                          const double* __restrict__ dinv, const float* __restrict__ b,
                          double* __restrict__ out, int C, int relu) {
  int row = blockIdx.x;
  double d = dinv[row];
  for (int c = threadIdx.x; c < C; c += blockDim.x) {
    double v = d * (y[(size_t)row * C + c] + 2.0 * d * t[(size_t)row * C + c]) + (double)b[c];
    if (relu) v = v > 0.0 ? v : 0.0;
    out[(size_t)row * C + c] = v;
  }
}

__global__ void k_pnorm(const float* __restrict__ p, double* __restrict__ pn, int C) {
  __shared__ double red[256];
  double s = 0.0;
  for (int j = threadIdx.x; j < C; j += 256) { double v = (double)p[j]; s += v * v; }
  red[threadIdx.x] = s;
  __syncthreads();
  for (int st = 128; st > 0; st >>= 1) {
    if (threadIdx.x < st) red[threadIdx.x] += red[threadIdx.x + st];
    __syncthreads();
  }
  if (threadIdx.x == 0) pn[0] = sqrt(red[0]);
}

__global__ void k_scores(const double* __restrict__ x, const float* __restrict__ p,
                         const double* __restrict__ pn, double* __restrict__ sc, int C) {
  __shared__ double red[256];
  int row = blockIdx.x;
  double s = 0.0;
  for (int j = threadIdx.x; j < C; j += 256) s += x[(size_t)row * C + j] * (double)p[j];
  red[threadIdx.x] = s;
  __syncthreads();
  for (int st = 128; st > 0; st >>= 1) {
    if (threadIdx.x < st) red[threadIdx.x] += red[threadIdx.x + st];
    __syncthreads();
  }
  if (threadIdx.x == 0) sc[row] = tanh(red[0] / pn[0]);
}

__global__ __launch_bounds__(1024) void k_topk(const double* __restrict__ sc, int n,
                                               int* __restrict__ perm, double* __restrict__ vals) {
  __shared__ double s[SORT_N];
  __shared__ int id[SORT_N];
  const int t = threadIdx.x;
  for (int i = t; i < SORT_N; i += 1024) {
    s[i] = (i < n) ? sc[i] : -INFINITY;
    id[i] = i;
  }
  __syncthreads();
  for (int size = 2; size <= SORT_N; size <<= 1) {
    for (int stride = size >> 1; stride > 0; stride >>= 1) {
      for (int i = t; i < SORT_N; i += 1024) {
        int l = i ^ stride;
        if (l > i) {
          double si = s[i], sl = s[l];
          int ii = id[i], il = id[l];
          bool iAfterL = (sl > si) || (sl == si && il < ii);
          bool up = ((i & size) == 0);
          if (iAfterL == up) { s[i] = sl; s[l] = si; id[i] = il; id[l] = ii; }
        }
      }
      __syncthreads();
    }
  }
  for (int i = t; i < n; i += 1024) { perm[i] = id[i]; vals[i] = s[i]; }
}

__global__ void k_gather_x(const double* __restrict__ x, const int* __restrict__ perm,
                           const double* __restrict__ vals, double* __restrict__ xo, int C) {
  int row = blockIdx.x;
  int src = perm[row];
  double v = vals[row];
  for (int c = threadIdx.x; c < C; c += blockDim.x)
    xo[(size_t)row * C + c] = x[(size_t)src * C + c] * v;
}

__global__ void k_write_out(const double* __restrict__ x, float* __restrict__ out,
                            int nvals, int total) {
  int i = blockIdx.x * blockDim.x + threadIdx.x;
  int st = gridDim.x * blockDim.x;
  for (; i < total; i += st) out[i] = (i < nvals) ? (float)x[i] : 0.0f;
}

__global__ void k_sentinel(float* __restrict__ out, int total) {
  int i = blockIdx.x * blockDim.x + threadIdx.x;
  int st = gridDim.x * blockDim.x;
  for (; i < total; i += st) out[i] = 1e30f;
}

// ---------------- driver ----------------

extern "C" void kernel_launch(void* const* d_in, const int* in_sizes, int n_in,
                              void* d_out, int out_size, void* d_ws, size_t ws_size,
                              hipStream_t stream) {
  const float* x0f  = (const float*)d_in[0];
  const int*   ei   = (const int*)d_in[1];
  const float* W0   = (const float*)d_in[2];
  const float* b0   = (const float*)d_in[3];
  const float* W1   = (const float*)d_in[4];
  const float* b1   = (const float*)d_in[5];
  const float* W2   = (const float*)d_in[6];
  const float* b2   = (const float*)d_in[7];
  const float* p1   = (const float*)d_in[8];
  const float* p2   = (const float*)d_in[9];
  const float* Wout = (const float*)d_in[10];
  const float* bout = (const float*)d_in[11];
  const int E = in_sizes[1] / 2;

  const size_t MiB = 1ull << 20;
  if (ws_size < 160 * MiB) {
    k_sentinel<<<dim3(256), dim3(256), 0, stream>>>((float*)d_out, out_size);
    return;
  }
  char* W = (char*)d_ws;
  // epoch A
  short* A1  = (short*)(W + 0);          // 32 MiB, live steps 5..12
  float* A0  = (float*)(W + 32 * MiB);   // 64 MiB, dead after split
  short* Ab  = (short*)(W + 96 * MiB);   // 32 MiB, dead after aug1
  short* Abt = (short*)(W + 128 * MiB);  // 32 MiB, dead after aug1 (region later = features)
  // epoch B (over dead A0/Ab)
  short* L2  = (short*)(W + 32 * MiB);   // 26 MiB
  short* Rt2 = (short*)(W + 58 * MiB);   // 26 MiB
  float* A2p = (float*)(W + 84 * MiB);   // 41 MiB, ends < 125 MiB
  // epoch C (over dead A1/L2/Rt2)
  short* Lb  = (short*)(W + 0);          // 13 MiB each
  short* Lr  = (short*)(W + 13 * MiB);
  short* Rtb = (short*)(W + 26 * MiB);
  short* Rtr = (short*)(W + 39 * MiB);
  float* A3p = (float*)(W + 52 * MiB);   // 14.8 MiB
  // features (region shared temporally with Abt; first use after aug1)
  double* tb = (double*)(W + 128 * MiB);
  double* yb = (double*)(W + 136 * MiB);
  double* xA = (double*)(W + 144 * MiB);
  double* xB = (double*)(W + 152 * MiB);  // max content 6.41 MiB
  char* SM = W + 159 * MiB;               // smalls, inside xB tail
  double* dinv = (double*)(SM);
  double* sc   = (double*)(SM + 32768);
  double* vals = (double*)(SM + 65536);
  double* pn   = (double*)(SM + 98304);
  int* perm    = (int*)(SM + 98304 + 256);
  int* perm2   = (int*)(SM + 98304 + 256 + 16384);

  // ---- build A0 ----
  k_zero32<<<dim3(2048), dim3(256), 0, stream>>>(A0, (size_t)N0 * N0);
  k_build_adj<<<dim3((E + 255) / 256), dim3(256), 0, stream>>>(ei, A0, E, N0);

  // ---- aug1: A1 = offdiag(A0@A0 + 2*A0), exact in bf16-MFMA ----
  k_split_bf16<<<dim3(2048), dim3(256), 0, stream>>>(A0, Ab, (size_t)N0 * N0);
  k_gatherT_bf16<<<dim3(N0), dim3(256), 0, stream>>>(Ab, nullptr, Abt, N0, N0, N0, N0);
  k_aug_mfma<1, 0><<<dim3(32, 32), dim3(256), 0, stream>>>(
      Ab, nullptr, Abt, nullptr, N0, N0, nullptr, Ab, N0, nullptr, 0, nullptr, A1, N0, N0, N0);

  // ---- gcn1 (f64 features) ----
  k_widen_f32_f64<<<dim3(512), dim3(256), 0, stream>>>(x0f, xB, N0 * CIN);
  {
    dim3 b(16, 16), g((HID + 63) / 64, (N0 + 63) / 64);
    k_gemm_xw<<<g, b, 0, stream>>>(xB, W0, tb, N0, HID, CIN);
    k_degdinv<short><<<dim3(N0), dim3(256), 0, stream>>>(A1, N0, dinv, N0);
    k_gemm_ax<short><<<g, b, 0, stream>>>(A1, N0, tb, dinv, yb, N0, HID, N0);
    k_gcn_fin<<<dim3(N0), dim3(256), 0, stream>>>(yb, tb, dinv, b0, xA, HID, 1);
  }

  // ---- pool1 scores/perm ----
  k_pnorm<<<dim3(1), dim3(256), 0, stream>>>(p1, pn, HID);
  k_scores<<<dim3(N0), dim3(256), 0, stream>>>(xA, p1, pn, sc, HID);
  k_topk<<<dim3(1), dim3(1024), 0, stream>>>(sc, N0, perm, vals);
  k_gather_x<<<dim3(K1P), dim3(256), 0, stream>>>(xA, perm, vals, xB, HID);

  // ---- aug2 (pre-gathered): A2p = offdiag'(A1@A1 + 2*A1)[perm x perm] ----
  k_gather_rows_bf16<<<dim3(K1PAD), dim3(256), 0, stream>>>(A1, perm, L2, K1P, N0, N0, N0);
  k_gatherT_bf16<<<dim3(K1PAD), dim3(256), 0, stream>>>(A1, perm, Rt2, K1P, N0, N0, N0);
  k_aug_mfma<1, 1><<<dim3(26, 26), dim3(256), 0, stream>>>(
      L2, nullptr, Rt2, nullptr, N0, N0, perm, A1, N0, nullptr, 0, A2p, nullptr, K1P, K1P, K1P);

  // ---- gcn2 ----
  {
    dim3 b(16, 16), g((HID + 63) / 64, (K1P + 63) / 64);
    k_gemm_xw<<<g, b, 0, stream>>>(xB, W1, tb, K1P, HID, HID);
    k_degdinv<float><<<dim3(K1P), dim3(256), 0, stream>>>(A2p, K1P, dinv, K1P);
    k_gemm_ax<float><<<g, b, 0, stream>>>(A2p, K1P, tb, dinv, yb, K1P, HID, K1P);
    k_gcn_fin<<<dim3(K1P), dim3(256), 0, stream>>>(yb, tb, dinv, b1, xA, HID, 1);
  }

  // ---- pool2 scores/perm ----
  k_pnorm<<<dim3(1), dim3(256), 0, stream>>>(p2, pn, HID);
  k_scores<<<dim3(K1P), dim3(256), 0, stream>>>(xA, p2, pn, sc, HID);
  k_topk<<<dim3(1), dim3(1024), 0, stream>>>(sc, K1P, perm2, vals);
  k_gather_x<<<dim3(K2P), dim3(256), 0, stream>>>(xA, perm2, vals, xB, HID);

  // ---- aug3 (pre-gathered, 3-term bf16 split; values-only path) ----
  k_gatherR_split_f32<<<dim3(K2PAD), dim3(256), 0, stream>>>(A2p, perm2, Lb, Lr, K2P, K1P, K1PAD, K1P);
  k_gatherT_split_f32<<<dim3(K2PAD), dim3(256), 0, stream>>>(A2p, perm2, Rtb, Rtr, K2P, K1P, K1PAD, K1P);
  k_aug_mfma<3, 2><<<dim3(16, 16), dim3(256), 0, stream>>>(
      Lb, Lr, Rtb, Rtr, K1PAD, K1PAD, perm2, nullptr, 0, A2p, K1P, A3p, nullptr, K2P, K2P, K2P);

  // ---- gcn3 ----
  {
    dim3 b(16, 16), g((HID + 63) / 64, (K2P + 63) / 64);
    k_gemm_xw<<<g, b, 0, stream>>>(xB, W2, tb, K2P, HID, HID);
    k_degdinv<float><<<dim3(K2P), dim3(256), 0, stream>>>(A3p, K2P, dinv, K2P);
    k_gemm_ax<float><<<g, b, 0, stream>>>(A3p, K2P, tb, dinv, yb, K2P, HID, K2P);
    k_gcn_fin<<<dim3(K2P), dim3(256), 0, stream>>>(yb, tb, dinv, b2, xA, HID, 1);
  }

  // ---- gcn_out (reuse dinv of A3p) ----
  {
    dim3 b(16, 16), g((COUTC + 63) / 64, (K2P + 63) / 64);
    k_gemm_xw<<<g, b, 0, stream>>>(xA, Wout, tb, K2P, COUTC, HID);
    k_gemm_ax<float><<<g, b, 0, stream>>>(A3p, K2P, tb, dinv, yb, K2P, COUTC, K2P);
    k_gcn_fin<<<dim3(K2P), dim3(256), 0, stream>>>(yb, tb, dinv, bout, xB, COUTC, 0);
  }

  k_write_out<<<dim3(1024), dim3(256), 0, stream>>>(xB, (float*)d_out, K2P * COUTC, out_size);
}

// Round 5
// 2618.574 us; speedup vs baseline: 3.1960x; 1.6925x over previous
//
#include <hip/hip_runtime.h>
#include <math.h>

#define N0    4096
#define CIN   128
#define HID   256
#define COUTC 128
#define K1P   3277   // ceil(0.8*4096)
#define K2P   1967   // ceil(0.6*3277)
#define LD2   3280   // K1P padded to mult of 4 floats (16B rows)
#define LD3   1968   // K2P padded likewise
#define KI2   3328   // K1P padded to mult of 64 (MFMA K-loop + digitize tiles)
#define KI3   1984   // K2P padded to mult of 64
#define SORT_N 4096

typedef __attribute__((ext_vector_type(8))) short bf16x8;
typedef __attribute__((ext_vector_type(4))) short s16x4;
typedef __attribute__((ext_vector_type(4))) float f32x4;

__device__ __forceinline__ float b2f(short s) {
  unsigned u = ((unsigned)(unsigned short)s) << 16;
  return __builtin_bit_cast(float, u);
}
__device__ __forceinline__ short f2b(float f) {  // RNE bf16
  unsigned u = __builtin_bit_cast(unsigned, f);
  u = (u + 0x7fffu + ((u >> 16) & 1u)) >> 16;
  return (short)u;
}

// ---------------- build / elementwise ----------------

__global__ void k_zero32(float* __restrict__ p, size_t n) {
  size_t i = (size_t)blockIdx.x * blockDim.x + threadIdx.x;
  size_t st = (size_t)gridDim.x * blockDim.x;
  for (; i < n; i += st) p[i] = 0.0f;
}

__global__ void k_widen_f32_f64(const float* __restrict__ in, double* __restrict__ out, int n) {
  int i = blockIdx.x * blockDim.x + threadIdx.x;
  int st = gridDim.x * blockDim.x;
  for (; i < n; i += st) out[i] = (double)in[i];
}

__global__ void k_build_adj(const int* __restrict__ ei, float* __restrict__ A, int E, int n) {
  int e = blockIdx.x * blockDim.x + threadIdx.x;
  if (e < E) atomicAdd(&A[(size_t)ei[E + e] * n + ei[e]], 1.0f);
}

// A0 f32 [4096][4096] -> A0b bf16 (straight) + A0bt bf16 (transposed). Coalesced LDS tiles.
__global__ __launch_bounds__(256) void k_transpose_split_f32(
    const float* __restrict__ A, short* __restrict__ B, short* __restrict__ BT) {
  __shared__ short sm[64][68];
  const int t = threadIdx.x;
  const int r0 = blockIdx.y * 64, c0 = blockIdx.x * 64;
  const int rr = t >> 2, cs = (t & 3) * 16;
  short tmp[16];
#pragma unroll
  for (int j = 0; j < 16; ++j) {
    short v = f2b(A[(size_t)(r0 + rr) * N0 + c0 + cs + j]);
    tmp[j] = v;
    sm[cs + j][rr] = v;
  }
#pragma unroll
  for (int j = 0; j < 16; j += 8)
    *(int4*)&B[(size_t)(r0 + rr) * N0 + c0 + cs + j] = *(int4*)&tmp[j];
  __syncthreads();
  const int cc = t >> 2, rs = (t & 3) * 16;
#pragma unroll
  for (int j = 0; j < 16; j += 8) {
    short o[8];
#pragma unroll
    for (int q = 0; q < 8; ++q) o[q] = sm[cc][rs + j + q];
    *(int4*)&BT[(size_t)(c0 + cc) * N0 + r0 + rs + j] = *(int4*)&o[0];
  }
}

// bf16 [4096][4096] transpose
__global__ __launch_bounds__(256) void k_transpose_bf16(
    const short* __restrict__ A, short* __restrict__ BT) {
  __shared__ short sm[64][68];
  const int t = threadIdx.x;
  const int r0 = blockIdx.y * 64, c0 = blockIdx.x * 64;
  const int rr = t >> 2, cs = (t & 3) * 16;
#pragma unroll
  for (int j = 0; j < 16; ++j) sm[cs + j][rr] = A[(size_t)(r0 + rr) * N0 + c0 + cs + j];
  __syncthreads();
  const int cc = t >> 2, rs = (t & 3) * 16;
#pragma unroll
  for (int j = 0; j < 16; j += 8) {
    short o[8];
#pragma unroll
    for (int q = 0; q < 8; ++q) o[q] = sm[cc][rs + j + q];
    *(int4*)&BT[(size_t)(c0 + cc) * N0 + r0 + rs + j] = *(int4*)&o[0];
  }
}

// f32 transpose with guards: in rows<M valid (pitch LD), out [LD][LD]
__global__ __launch_bounds__(256) void k_transpose_f32g(
    const float* __restrict__ A, float* __restrict__ BT, int M, int LD) {
  __shared__ float sm[64][65];
  const int t = threadIdx.x;
  const int r0 = blockIdx.y * 64, c0 = blockIdx.x * 64;
  const int rr = t >> 2, cs = (t & 3) * 16;
  int gr = r0 + rr;
#pragma unroll
  for (int j = 0; j < 16; ++j) {
    int gc = c0 + cs + j;
    sm[cs + j][rr] = (gr < M && gc < LD) ? A[(size_t)gr * LD + gc] : 0.0f;
  }
  __syncthreads();
  const int cc = t >> 2, rs = (t & 3) * 16;
  int oc = c0 + cc;
  if (oc < LD)
#pragma unroll
    for (int j = 0; j < 16; ++j) {
      int orr = r0 + rs + j;
      if (orr < LD) BT[(size_t)oc * LD + orr] = sm[cc][rs + j];
    }
}

// ---------------- unified MFMA augment: C = rows(A) @ (B' = B + 2I) , diag->0 ----------------
// MODE 0: aug1. A=A0b bf16 ld N0, Bt=A0bt bf16 ld N0, no perm, out bf16 Cb [N0][N0].
// MODE 1: aug2. A=A1 bf16, Bt=A1T bf16, rows via perm, out f32 Cf pitch ldcp, cols<N real.
// MODE 2: aug3. A=A2p f32 ld LD2, Bt=A2pT f32 ld LD2, perm2, in-staging b/r split, 3-term.
template <int MODE>
__global__ __launch_bounds__(256) void k_aug_mfma2(
    const void* __restrict__ Asrc, const void* __restrict__ Btsrc,
    const int* __restrict__ perm, int K, int Kiter, int lds_src,
    float* __restrict__ Cf, short* __restrict__ Cb,
    int M, int N, int ldcp)
{
  constexpr int NT = (MODE == 2) ? 4 : 2;
  __shared__ __align__(16) short Ls[NT][128 * 32];
  __shared__ int rowsA[128], rowsB[128];
  const int tid = threadIdx.x;
  const int wave = tid >> 6, lane = tid & 63;
  const int wr = wave >> 1, wc = wave & 1;
  const int brow = blockIdx.y * 128, bcol = blockIdx.x * 128;
  const int lr = lane & 15, ko = (lane >> 4) * 8;

  if (tid < 128) {
    int ra = brow + tid, rb = bcol + tid;
    if (MODE == 0) { rowsA[tid] = ra; rowsB[tid] = rb; }
    else {
      rowsA[tid] = (ra < M) ? perm[ra] : -1;
      rowsB[tid] = (rb < N) ? perm[rb] : -1;
    }
  }
  __syncthreads();

  f32x4 acc[4][4];
#pragma unroll
  for (int m = 0; m < 4; ++m)
#pragma unroll
    for (int n = 0; n < 4; ++n) acc[m][n] = (f32x4){0.f, 0.f, 0.f, 0.f};

  for (int kt = 0; kt < Kiter; kt += 32) {
    __syncthreads();
    if (MODE != 2) {
      const short* A = (const short*)Asrc;
      const short* Bt = (const short*)Btsrc;
      const int row = tid >> 2, scol = (tid & 3) * 8;
#pragma unroll
      for (int it = 0; it < 2; ++it) {
        int r = it * 64 + row;
        // A side
        int ridx = rowsA[r];
        int4 v = make_int4(0, 0, 0, 0);
        if (ridx >= 0) v = *(const int4*)(A + (size_t)ridx * lds_src + kt + scol);
        *(int4*)&Ls[0][r * 32 + scol] = v;
        // B side (+2I at k == pcol)
        int pcol = rowsB[r];
        int4 w = make_int4(0, 0, 0, 0);
        if (pcol >= 0) {
          w = *(const int4*)(Bt + (size_t)pcol * lds_src + kt + scol);
          int k0 = kt + scol;
          if (pcol >= k0 && pcol < k0 + 8) {
            short* ws = (short*)&w;
            ws[pcol - k0] = f2b(b2f(ws[pcol - k0]) + 2.0f);
          }
        }
        *(int4*)&Ls[1][r * 32 + scol] = w;
      }
    } else {
      const float* A = (const float*)Asrc;
      const float* Bt = (const float*)Btsrc;
      const int row = tid >> 3, sc4 = (tid & 7) * 4;
#pragma unroll
      for (int it = 0; it < 4; ++it) {
        int r = it * 32 + row;
        int k0 = kt + sc4;
        // A side
        {
          int ridx = rowsA[r];
          float v[4] = {0.f, 0.f, 0.f, 0.f};
          if (ridx >= 0 && k0 < lds_src) *(float4*)v = *(const float4*)(A + (size_t)ridx * lds_src + k0);
          short b[4], rr_[4];
#pragma unroll
          for (int q = 0; q < 4; ++q) { b[q] = f2b(v[q]); rr_[q] = f2b(v[q] - b2f(b[q])); }
          *(s16x4*)&Ls[0][r * 32 + sc4] = *(s16x4*)&b[0];
          *(s16x4*)&Ls[2][r * 32 + sc4] = *(s16x4*)&rr_[0];
        }
        // B side
        {
          int pcol = rowsB[r];
          float v[4] = {0.f, 0.f, 0.f, 0.f};
          if (pcol >= 0 && k0 < lds_src) {
            *(float4*)v = *(const float4*)(Bt + (size_t)pcol * lds_src + k0);
            if (pcol >= k0 && pcol < k0 + 4) v[pcol - k0] += 2.0f;
          }
          short b[4], rr_[4];
#pragma unroll
          for (int q = 0; q < 4; ++q) { b[q] = f2b(v[q]); rr_[q] = f2b(v[q] - b2f(b[q])); }
          *(s16x4*)&Ls[1][r * 32 + sc4] = *(s16x4*)&b[0];
          *(s16x4*)&Ls[3][r * 32 + sc4] = *(s16x4*)&rr_[0];
        }
      }
    }
    __syncthreads();

    bf16x8 a0[4], b0[4];
#pragma unroll
    for (int m = 0; m < 4; ++m) a0[m] = *(const bf16x8*)&Ls[0][(wr * 64 + m * 16 + lr) * 32 + ko];
#pragma unroll
    for (int n = 0; n < 4; ++n) b0[n] = *(const bf16x8*)&Ls[1][(wc * 64 + n * 16 + lr) * 32 + ko];
    if (MODE == 2) {
      bf16x8 a1[4], b1[4];
#pragma unroll
      for (int m = 0; m < 4; ++m) a1[m] = *(const bf16x8*)&Ls[2][(wr * 64 + m * 16 + lr) * 32 + ko];
#pragma unroll
      for (int n = 0; n < 4; ++n) b1[n] = *(const bf16x8*)&Ls[3][(wc * 64 + n * 16 + lr) * 32 + ko];
#pragma unroll
      for (int m = 0; m < 4; ++m)
#pragma unroll
        for (int n = 0; n < 4; ++n) {
          acc[m][n] = __builtin_amdgcn_mfma_f32_16x16x32_bf16(a0[m], b0[n], acc[m][n], 0, 0, 0);
          acc[m][n] = __builtin_amdgcn_mfma_f32_16x16x32_bf16(a0[m], b1[n], acc[m][n], 0, 0, 0);
          acc[m][n] = __builtin_amdgcn_mfma_f32_16x16x32_bf16(a1[m], b0[n], acc[m][n], 0, 0, 0);
        }
    } else {
#pragma unroll
      for (int m = 0; m < 4; ++m)
#pragma unroll
        for (int n = 0; n < 4; ++n)
          acc[m][n] = __builtin_amdgcn_mfma_f32_16x16x32_bf16(a0[m], b0[n], acc[m][n], 0, 0, 0);
    }
  }

#pragma unroll
  for (int m = 0; m < 4; ++m)
#pragma unroll
    for (int n = 0; n < 4; ++n)
#pragma unroll
      for (int q = 0; q < 4; ++q) {
        int grow = brow + wr * 64 + m * 16 + (lane >> 4) * 4 + q;
        int gcol = bcol + wc * 64 + n * 16 + lr;
        float v = acc[m][n][q];
        if (MODE == 0) {
          if (grow == gcol) v = 0.0f;
          Cb[(size_t)grow * N0 + gcol] = f2b(v);
        } else {
          if (grow < M && gcol < ldcp) {
            if (gcol >= N || grow == gcol) v = 0.0f;
            Cf[(size_t)grow * ldcp + gcol] = v;
          }
        }
      }
}

// ---------------- f64 x@W (small, ordering-critical) ----------------

__global__ __launch_bounds__(256) void k_gemm_xw(
    const double* __restrict__ X, const float* __restrict__ W, double* __restrict__ C,
    int M, int N, int K) {
  __shared__ double As[16][64];
  __shared__ double Bs[16][64];
  const int tx = threadIdx.x, ty = threadIdx.y;
  const int tid = ty * 16 + tx;
  const int brow = blockIdx.y * 64, bcol = blockIdx.x * 64;
  double acc[4][4];
#pragma unroll
  for (int i = 0; i < 4; ++i)
#pragma unroll
    for (int j = 0; j < 4; ++j) acc[i][j] = 0.0;
  const int lac = tid & 15, lar = tid >> 4;
  const int lbc = tid & 63, lbr = tid >> 6;
  for (int kt = 0; kt < K; kt += 16) {
#pragma unroll
    for (int rr = 0; rr < 4; ++rr) {
      int r = lar + rr * 16;
      int gr = brow + r, gk = kt + lac;
      As[lac][r] = (gr < M && gk < K) ? X[(size_t)gr * K + gk] : 0.0;
    }
#pragma unroll
    for (int rr = 0; rr < 4; ++rr) {
      int br = lbr + rr * 4;
      int gk = kt + br, gc = bcol + lbc;
      Bs[br][lbc] = (gk < K && gc < N) ? (double)W[(size_t)gk * N + gc] : 0.0;
    }
    __syncthreads();
#pragma unroll
    for (int kk = 0; kk < 16; ++kk) {
      double a[4], b[4];
#pragma unroll
      for (int i = 0; i < 4; ++i) a[i] = As[kk][ty * 4 + i];
#pragma unroll
      for (int j = 0; j < 4; ++j) b[j] = Bs[kk][tx * 4 + j];
#pragma unroll
      for (int i = 0; i < 4; ++i)
#pragma unroll
        for (int j = 0; j < 4; ++j) acc[i][j] = fma(a[i], b[j], acc[i][j]);
    }
    __syncthreads();
  }
#pragma unroll
  for (int i = 0; i < 4; ++i) {
    int gr = brow + ty * 4 + i;
    if (gr >= M) continue;
#pragma unroll
    for (int j = 0; j < 4; ++j) {
      int gc = bcol + tx * 4 + j;
      if (gc >= N) continue;
      C[(size_t)gr * N + gc] = acc[i][j];
    }
  }
}

// ---------------- digit machinery ----------------

__global__ void k_reset_u32(unsigned* p) { if (threadIdx.x == 0 && blockIdx.x == 0) *p = 0u; }

__global__ void k_wmax(const double* __restrict__ t, const double* __restrict__ dinv,
                       unsigned* __restrict__ wmax, int K, int N) {
  __shared__ float red[256];
  float mx = 0.0f;
  int tot = K * N;
  for (int i = blockIdx.x * 256 + threadIdx.x; i < tot; i += gridDim.x * 256) {
    double w = dinv[i / N] * t[i];
    float a = (float)fabs(w);
    mx = fmaxf(mx, a);
  }
  red[threadIdx.x] = mx;
  __syncthreads();
  for (int st = 128; st > 0; st >>= 1) {
    if (threadIdx.x < st) red[threadIdx.x] = fmaxf(red[threadIdx.x], red[threadIdx.x + st]);
    __syncthreads();
  }
  if (threadIdx.x == 0) atomicMax(wmax, __builtin_bit_cast(unsigned, red[0]));
}

// w[k][n] = dinv[k]*t[k][n] -> D bf16 digit planes wdT[d][n][Kpad] (transposed), base-32 balanced.
// Kpad MUST be a multiple of 64 (grid = Kpad/64 tiles); pads k>=K write 0.
template <int D>
__global__ __launch_bounds__(256) void k_digitize(
    const double* __restrict__ t, const double* __restrict__ dinv,
    const unsigned* __restrict__ wmax, short* __restrict__ wdT,
    int K, int Kpad, int N) {
  __shared__ char sm[D][64][66];
  const int tid = threadIdx.x;
  const int k0 = blockIdx.x * 64, n0 = blockIdx.y * 64;
  float wm = __builtin_bit_cast(float, *wmax);
  double sc = (wm > 0.0f) ? scalbn(1.0, -(ilogbf(wm) + 1)) : 0.0;
  const int kk = tid >> 2, ns = (tid & 3) * 16;
  int k = k0 + kk;
  double dv = (k < K) ? dinv[k] : 0.0;
#pragma unroll
  for (int j = 0; j < 16; ++j) {
    int n = n0 + ns + j;
    double w = (k < K) ? dv * t[(size_t)k * N + n] : 0.0;
    double r = w * sc;
#pragma unroll
    for (int d = 0; d < D; ++d) {
      double rm = r * 32.0;
      double m = rint(rm);
      sm[d][kk][ns + j] = (char)(int)m;
      r = rm - m;
    }
  }
  __syncthreads();
  const int nn = tid >> 2, ks = (tid & 3) * 16;
  const size_t PS = (size_t)N * Kpad;
#pragma unroll
  for (int d = 0; d < D; ++d) {
    short o[16];
#pragma unroll
    for (int j = 0; j < 16; ++j) o[j] = f2b((float)sm[d][ks + j][nn]);
    short* dst = wdT + d * PS + (size_t)(n0 + nn) * Kpad + k0 + ks;
    *(int4*)&dst[0] = *(int4*)&o[0];
    *(int4*)&dst[8] = *(int4*)&o[8];
  }
}

// y-partials[z][M][N] f64 = digit-MFMA of A @ w. AMODE 0: A bf16 direct (1 plane);
// 1: A f32, exact hi/lo base-64; 2: A f32, approx b/r. Exact f32 accumulation per digit.
template <int AMODE, int D, int NF>
__global__ __launch_bounds__(256) void k_axw_digit(
    const void* __restrict__ Asrc, int lda,
    const short* __restrict__ wdT, int Kpad,
    const unsigned* __restrict__ wmax,
    double* __restrict__ P, int M, int N, int Z) {
  constexpr int PL = (AMODE == 0) ? 1 : 2;
  __shared__ __align__(16) short Als[PL][32 * 32];
  __shared__ __align__(16) short Bls[256 * 32];
  const int tid = threadIdx.x;
  const int wave = tid >> 6, lane = tid & 63;
  const int lr = lane & 15, ko = (lane >> 4) * 8;
  const int brow = blockIdx.y * 32;
  const int z = blockIdx.x;
  constexpr int WN = NF * 16;
  const size_t PS = (size_t)N * Kpad;

  float wm = __builtin_bit_cast(float, *wmax);
  int E = (wm > 0.0f) ? (ilogbf(wm) + 1) : -3000;

  const int KT = Kpad / 32;
  const int base = KT / Z, rem = KT % Z;
  const int t0 = z * base + min(z, rem);
  const int t1 = t0 + base + (z < rem ? 1 : 0);

  double master[2][NF][4];
#pragma unroll
  for (int m = 0; m < 2; ++m)
#pragma unroll
    for (int n = 0; n < NF; ++n)
#pragma unroll
      for (int q = 0; q < 4; ++q) master[m][n][q] = 0.0;

  for (int d = 0; d < D; ++d) {
    double sd = (E > -3000) ? scalbn(1.0, E - 5 * (d + 1)) : 0.0;
    f32x4 acc[PL][2][NF];
#pragma unroll
    for (int p = 0; p < PL; ++p)
#pragma unroll
      for (int m = 0; m < 2; ++m)
#pragma unroll
        for (int n = 0; n < NF; ++n) acc[p][m][n] = (f32x4){0.f, 0.f, 0.f, 0.f};

    for (int kt = t0 * 32; kt < t1 * 32; kt += 32) {
      __syncthreads();
      // stage A
      if (AMODE == 0) {
        if (tid < 128) {
          const short* A = (const short*)Asrc;
          int row = tid >> 2, scol = (tid & 3) * 8;
          int gr = brow + row;
          int4 v = make_int4(0, 0, 0, 0);
          if (gr < M) v = *(const int4*)(A + (size_t)gr * lda + kt + scol);
          *(int4*)&Als[0][row * 32 + scol] = v;
        }
      } else {
        const float* A = (const float*)Asrc;
        int row = tid >> 3, sc4 = (tid & 7) * 4;
        int gr = brow + row, k0 = kt + sc4;
        float v[4] = {0.f, 0.f, 0.f, 0.f};
        if (gr < M && k0 < lda) *(float4*)v = *(const float4*)(A + (size_t)gr * lda + k0);
        short p0[4], p1[4];
#pragma unroll
        for (int q = 0; q < 4; ++q) {
          if (AMODE == 1) {
            float hi = floorf(v[q] * (1.0f / 64.0f));
            p0[q] = f2b(hi);
            p1[q] = f2b(v[q] - 64.0f * hi);
          } else {
            p0[q] = f2b(v[q]);
            p1[q] = f2b(v[q] - b2f(p0[q]));
          }
        }
        *(s16x4*)&Als[0][row * 32 + sc4] = *(s16x4*)&p0[0];
        *(s16x4*)&Als[1][row * 32 + sc4] = *(s16x4*)&p1[0];
      }
      // stage B (digit plane d, rows n, transposed layout [n][Kpad])
      {
        const short* src = wdT + d * PS;
        int row = tid >> 2, scol = (tid & 3) * 8;
#pragma unroll
        for (int it = 0; it < NF; ++it) {  // NF*64 = N rows
          int n = it * 64 + row;
          int4 v = *(const int4*)(src + (size_t)n * Kpad + kt + scol);
          *(int4*)&Bls[n * 32 + scol] = v;
        }
      }
      __syncthreads();
      bf16x8 a[PL][2], b[NF];
#pragma unroll
      for (int p = 0; p < PL; ++p)
#pragma unroll
        for (int m = 0; m < 2; ++m) a[p][m] = *(const bf16x8*)&Als[p][(m * 16 + lr) * 32 + ko];
#pragma unroll
      for (int n = 0; n < NF; ++n) b[n] = *(const bf16x8*)&Bls[(wave * WN + n * 16 + lr) * 32 + ko];
#pragma unroll
      for (int p = 0; p < PL; ++p)
#pragma unroll
        for (int m = 0; m < 2; ++m)
#pragma unroll
          for (int n = 0; n < NF; ++n)
            acc[p][m][n] = __builtin_amdgcn_mfma_f32_16x16x32_bf16(a[p][m], b[n], acc[p][m][n], 0, 0, 0);
    }
#pragma unroll
    for (int m = 0; m < 2; ++m)
#pragma unroll
      for (int n = 0; n < NF; ++n)
#pragma unroll
        for (int q = 0; q < 4; ++q) {
          double contrib;
          if (AMODE == 0) contrib = (double)acc[0][m][n][q];
          else if (AMODE == 1) contrib = 64.0 * (double)acc[0][m][n][q] + (double)acc[1][m][n][q];
          else contrib = (double)acc[0][m][n][q] + (double)acc[1][m][n][q];
          master[m][n][q] += sd * contrib;
        }
  }
#pragma unroll
  for (int m = 0; m < 2; ++m)
#pragma unroll
    for (int n = 0; n < NF; ++n)
#pragma unroll
      for (int q = 0; q < 4; ++q) {
        int grow = brow + m * 16 + (lane >> 4) * 4 + q;
        int gcol = wave * WN + n * 16 + lr;
        if (grow < M) P[((size_t)z * M + grow) * N + gcol] = master[m][n][q];
      }
}

__global__ void k_reduce4(const double* __restrict__ P, double* __restrict__ y, int MN) {
  int i = blockIdx.x * blockDim.x + threadIdx.x;
  int st = gridDim.x * blockDim.x;
  size_t s = (size_t)MN;
  for (; i < MN; i += st)
    y[i] = ((P[i] + P[s + i]) + P[2 * s + i]) + P[3 * s + i];
}

// ---------------- GCN tail / pooling ----------------

template <typename TA>
__device__ __forceinline__ float a_as_f32(TA v);
template <> __device__ __forceinline__ float a_as_f32<short>(short v) { return b2f(v); }
template <> __device__ __forceinline__ float a_as_f32<float>(float v) { return v; }

template <typename TA>
__global__ void k_degdinv(const TA* __restrict__ A, int lda, double* __restrict__ dinv, int n) {
  __shared__ double red[256];
  int row = blockIdx.x;
  double s = 0.0;
  for (int j = threadIdx.x; j < n; j += 256) s += (double)a_as_f32<TA>(A[(size_t)row * lda + j]);
  red[threadIdx.x] = s;
  __syncthreads();
  for (int st = 128; st > 0; st >>= 1) {
    if (threadIdx.x < st) red[threadIdx.x] += red[threadIdx.x + st];
    __syncthreads();
  }
  if (threadIdx.x == 0) {
    double deg = red[0] + 2.0;
    dinv[row] = (deg > 0.0) ? 1.0 / sqrt(deg) : 0.0;
  }
}

__global__ void k_gcn_fin(const double* __restrict__ y, const double* __restrict__ t,
                          const double* __restrict__ dinv, const float* __restrict__ b,
                          double* __restrict__ out, int C, int relu) {
  int row = blockIdx.x;
  double d = dinv[row];
  for (int c = threadIdx.x; c < C; c += blockDim.x) {
    double v = d * (y[(size_t)row * C + c] + 2.0 * d * t[(size_t)row * C + c]) + (double)b[c];
    if (relu) v = v > 0.0 ? v : 0.0;
    out[(size_t)row * C + c] = v;
  }
}

__global__ void k_pnorm(const float* __restrict__ p, double* __restrict__ pn, int C) {
  __shared__ double red[256];
  double s = 0.0;
  for (int j = threadIdx.x; j < C; j += 256) { double v = (double)p[j]; s += v * v; }
  red[threadIdx.x] = s;
  __syncthreads();
  for (int st = 128; st > 0; st >>= 1) {
    if (threadIdx.x < st) red[threadIdx.x] += red[threadIdx.x + st];
    __syncthreads();
  }
  if (threadIdx.x == 0) pn[0] = sqrt(red[0]);
}

__global__ void k_scores(const double* __restrict__ x, const float* __restrict__ p,
                         const double* __restrict__ pn, double* __restrict__ sc, int C) {
  __shared__ double red[256];
  int row = blockIdx.x;
  double s = 0.0;
  for (int j = threadIdx.x; j < C; j += 256) s += x[(size_t)row * C + j] * (double)p[j];
  red[threadIdx.x] = s;
  __syncthreads();
  for (int st = 128; st > 0; st >>= 1) {
    if (threadIdx.x < st) red[threadIdx.x] += red[threadIdx.x + st];
    __syncthreads();
  }
  if (threadIdx.x == 0) sc[row] = tanh(red[0] / pn[0]);
}

__global__ __launch_bounds__(1024) void k_topk(const double* __restrict__ sc, int n,
                                               int* __restrict__ perm, double* __restrict__ vals) {
  __shared__ double s[SORT_N];
  __shared__ int id[SORT_N];
  const int t = threadIdx.x;
  for (int i = t; i < SORT_N; i += 1024) {
    s[i] = (i < n) ? sc[i] : -INFINITY;
    id[i] = i;
  }
  __syncthreads();
  for (int size = 2; size <= SORT_N; size <<= 1) {
    for (int stride = size >> 1; stride > 0; stride >>= 1) {
      for (int i = t; i < SORT_N; i += 1024) {
        int l = i ^ stride;
        if (l > i) {
          double si = s[i], sl = s[l];
          int ii = id[i], il = id[l];
          bool iAfterL = (sl > si) || (sl == si && il < ii);
          bool up = ((i & size) == 0);
          if (iAfterL == up) { s[i] = sl; s[l] = si; id[i] = il; id[l] = ii; }
        }
      }
      __syncthreads();
    }
  }
  for (int i = t; i < n; i += 1024) { perm[i] = id[i]; vals[i] = s[i]; }
}

__global__ void k_gather_x(const double* __restrict__ x, const int* __restrict__ perm,
                           const double* __restrict__ vals, double* __restrict__ xo, int C) {
  int row = blockIdx.x;
  int src = perm[row];
  double v = vals[row];
  for (int c = threadIdx.x; c < C; c += blockDim.x)
    xo[(size_t)row * C + c] = x[(size_t)src * C + c] * v;
}

__global__ void k_write_out(const double* __restrict__ x, float* __restrict__ out,
                            int nvals, int total) {
  int i = blockIdx.x * blockDim.x + threadIdx.x;
  int st = gridDim.x * blockDim.x;
  for (; i < total; i += st) out[i] = (i < nvals) ? (float)x[i] : 0.0f;
}

__global__ void k_sentinel(float* __restrict__ out, int total) {
  int i = blockIdx.x * blockDim.x + threadIdx.x;
  int st = gridDim.x * blockDim.x;
  for (; i < total; i += st) out[i] = 1e30f;
}

// ---------------- driver ----------------

extern "C" void kernel_launch(void* const* d_in, const int* in_sizes, int n_in,
                              void* d_out, int out_size, void* d_ws, size_t ws_size,
                              hipStream_t stream) {
  const float* x0f  = (const float*)d_in[0];
  const int*   ei   = (const int*)d_in[1];
  const float* W0   = (const float*)d_in[2];
  const float* b0   = (const float*)d_in[3];
  const float* W1   = (const float*)d_in[4];
  const float* b1   = (const float*)d_in[5];
  const float* W2   = (const float*)d_in[6];
  const float* b2   = (const float*)d_in[7];
  const float* p1   = (const float*)d_in[8];
  const float* p2   = (const float*)d_in[9];
  const float* Wout = (const float*)d_in[10];
  const float* bout = (const float*)d_in[11];
  const int E = in_sizes[1] / 2;

  const size_t MiB = 1ull << 20;
  if (ws_size < 160 * MiB) {
    k_sentinel<<<dim3(256), dim3(256), 0, stream>>>((float*)d_out, out_size);
    return;
  }
  char* W = (char*)d_ws;
  float*  A0   = (float*)(W + 0);            // 64 MiB (build phase)
  short*  A0b  = (short*)(W + 64 * MiB);     // 32
  short*  A0bt = (short*)(W + 96 * MiB);     // 32
  short*  A1   = (short*)(W + 0);            // 32 (after A0 dead)
  short*  A1T  = (short*)(W + 32 * MiB);     // 32
  short*  wdT1 = (short*)(W + 64 * MiB);     // 20 (gcn1)
  double* P1   = (double*)(W + 85 * MiB);    // 32 (gcn1 partials z4)
  float*  A2p  = (float*)(W + 64 * MiB);     // 41.0 (after gcn1)
  short*  wdT2 = (short*)(W + 106 * MiB);    // 16.25 (10*256*3328*2)
  double* P2   = (double*)(W + 0);           // 25.6 (A1 dead after aug2)
  float*  A2pT = (float*)(W + 0);            // 41.04 (after gcn2)
  float*  A3p  = (float*)(W + 42 * MiB);     // 14.8
  short*  wdT3 = (short*)(W + 57 * MiB);     // 2.9
  double* P3   = (double*)(W + 60 * MiB);    // 15.4
  double* tb   = (double*)(W + 128 * MiB);   // 8
  double* yb   = (double*)(W + 136 * MiB);   // 8
  double* xA   = (double*)(W + 144 * MiB);   // 8
  double* xB   = (double*)(W + 152 * MiB);   // ~6.5
  char* SM = W + (159 * MiB + 256 * 1024);
  double* dinv = (double*)(SM);
  double* sc   = (double*)(SM + 32768);
  double* vals = (double*)(SM + 65536);
  double* pn   = (double*)(SM + 98304);
  unsigned* wmax = (unsigned*)(SM + 98304 + 128);
  int* perm    = (int*)(SM + 98304 + 256);
  int* permB   = (int*)(SM + 98304 + 256 + 16384);

  // ---- build A0, split+transpose to bf16 ----
  k_zero32<<<dim3(2048), dim3(256), 0, stream>>>(A0, (size_t)N0 * N0);
  k_build_adj<<<dim3((E + 255) / 256), dim3(256), 0, stream>>>(ei, A0, E, N0);
  k_transpose_split_f32<<<dim3(64, 64), dim3(256), 0, stream>>>(A0, A0b, A0bt);

  // ---- aug1: A1 = offdiag(A0 @ (A0+2I)) (bf16-exact) ----
  k_aug_mfma2<0><<<dim3(32, 32), dim3(256), 0, stream>>>(
      A0b, A0bt, nullptr, N0, N0, N0, nullptr, A1, N0, N0, N0);
  k_transpose_bf16<<<dim3(64, 64), dim3(256), 0, stream>>>(A1, A1T);

  // ---- gcn1 ----
  k_widen_f32_f64<<<dim3(512), dim3(256), 0, stream>>>(x0f, xB, N0 * CIN);
  {
    dim3 b(16, 16), g((HID + 63) / 64, (N0 + 63) / 64);
    k_gemm_xw<<<g, b, 0, stream>>>(xB, W0, tb, N0, HID, CIN);
    k_degdinv<short><<<dim3(N0), dim3(256), 0, stream>>>(A1, N0, dinv, N0);
    k_reset_u32<<<dim3(1), dim3(64), 0, stream>>>(wmax);
    k_wmax<<<dim3(256), dim3(256), 0, stream>>>(tb, dinv, wmax, N0, HID);
    k_digitize<10><<<dim3((N0 + 63) / 64, HID / 64), dim3(256), 0, stream>>>(tb, dinv, wmax, wdT1, N0, N0, HID);
    k_axw_digit<0, 10, 4><<<dim3(4, N0 / 32), dim3(256), 0, stream>>>(
        A1, N0, wdT1, N0, wmax, P1, N0, HID, 4);
    k_reduce4<<<dim3(1024), dim3(256), 0, stream>>>(P1, yb, N0 * HID);
    k_gcn_fin<<<dim3(N0), dim3(256), 0, stream>>>(yb, tb, dinv, b0, xA, HID, 1);
  }

  // ---- pool1 ----
  k_pnorm<<<dim3(1), dim3(256), 0, stream>>>(p1, pn, HID);
  k_scores<<<dim3(N0), dim3(256), 0, stream>>>(xA, p1, pn, sc, HID);
  k_topk<<<dim3(1), dim3(1024), 0, stream>>>(sc, N0, perm, vals);
  k_gather_x<<<dim3(K1P), dim3(256), 0, stream>>>(xA, perm, vals, xB, HID);

  // ---- aug2: A2p[i][j] = offdiag(A1 @ (A1+2I))[perm x perm], f32 pitch LD2 ----
  k_aug_mfma2<1><<<dim3(26, 26), dim3(256), 0, stream>>>(
      A1, A1T, perm, N0, N0, N0, A2p, nullptr, K1P, K1P, LD2);

  // ---- gcn2 (ordering-critical: exact hi/lo A-split + digit planes) ----
  {
    dim3 b(16, 16), g((HID + 63) / 64, (K1P + 63) / 64);
    k_gemm_xw<<<g, b, 0, stream>>>(xB, W1, tb, K1P, HID, HID);
    k_degdinv<float><<<dim3(K1P), dim3(256), 0, stream>>>(A2p, LD2, dinv, K1P);
    k_reset_u32<<<dim3(1), dim3(64), 0, stream>>>(wmax);
    k_wmax<<<dim3(256), dim3(256), 0, stream>>>(tb, dinv, wmax, K1P, HID);
    k_digitize<10><<<dim3((KI2 + 63) / 64, HID / 64), dim3(256), 0, stream>>>(tb, dinv, wmax, wdT2, K1P, KI2, HID);
    k_axw_digit<1, 10, 4><<<dim3(4, (K1P + 31) / 32), dim3(256), 0, stream>>>(
        A2p, LD2, wdT2, KI2, wmax, P2, K1P, HID, 4);
    k_reduce4<<<dim3(1024), dim3(256), 0, stream>>>(P2, yb, K1P * HID);
    k_gcn_fin<<<dim3(K1P), dim3(256), 0, stream>>>(yb, tb, dinv, b1, xA, HID, 1);
  }

  // ---- pool2 ----
  k_pnorm<<<dim3(1), dim3(256), 0, stream>>>(p2, pn, HID);
  k_scores<<<dim3(K1P), dim3(256), 0, stream>>>(xA, p2, pn, sc, HID);
  k_topk<<<dim3(1), dim3(1024), 0, stream>>>(sc, K1P, permB, vals);
  k_gather_x<<<dim3(K2P), dim3(256), 0, stream>>>(xA, permB, vals, xB, HID);

  // ---- aug3: A3p = offdiag(A2p @ (A2p+2I))[perm2 x perm2], 3-term b/r ----
  k_transpose_f32g<<<dim3(52, 52), dim3(256), 0, stream>>>(A2p, A2pT, K1P, LD2);
  k_aug_mfma2<2><<<dim3(16, 16), dim3(256), 0, stream>>>(
      A2p, A2pT, permB, K1P, KI2, LD2, A3p, nullptr, K2P, K2P, LD3);

  // ---- gcn3 ----
  {
    dim3 b(16, 16), g((HID + 63) / 64, (K2P + 63) / 64);
    k_gemm_xw<<<g, b, 0, stream>>>(xB, W2, tb, K2P, HID, HID);
    k_degdinv<float><<<dim3(K2P), dim3(256), 0, stream>>>(A3p, LD3, dinv, K2P);
    k_reset_u32<<<dim3(1), dim3(64), 0, stream>>>(wmax);
    k_wmax<<<dim3(256), dim3(256), 0, stream>>>(tb, dinv, wmax, K2P, HID);
    k_digitize<3><<<dim3((KI3 + 63) / 64, HID / 64), dim3(256), 0, stream>>>(tb, dinv, wmax, wdT3, K2P, KI3, HID);
    k_axw_digit<2, 3, 4><<<dim3(4, (K2P + 31) / 32), dim3(256), 0, stream>>>(
        A3p, LD3, wdT3, KI3, wmax, P3, K2P, HID, 4);
    k_reduce4<<<dim3(1024), dim3(256), 0, stream>>>(P3, yb, K2P * HID);
    k_gcn_fin<<<dim3(K2P), dim3(256), 0, stream>>>(yb, tb, dinv, b2, xA, HID, 1);
  }

  // ---- gcn_out (reuse dinv of A3p) ----
  {
    dim3 b(16, 16), g((COUTC + 63) / 64, (K2P + 63) / 64);
    k_gemm_xw<<<g, b, 0, stream>>>(xA, Wout, tb, K2P, COUTC, HID);
    k_reset_u32<<<dim3(1), dim3(64), 0, stream>>>(wmax);
    k_wmax<<<dim3(256), dim3(256), 0, stream>>>(tb, dinv, wmax, K2P, COUTC);
    k_digitize<3><<<dim3((KI3 + 63) / 64, COUTC / 64), dim3(256), 0, stream>>>(tb, dinv, wmax, wdT3, K2P, KI3, COUTC);
    k_axw_digit<2, 3, 2><<<dim3(4, (K2P + 31) / 32), dim3(256), 0, stream>>>(
        A3p, LD3, wdT3, KI3, wmax, P3, K2P, COUTC, 4);
    k_reduce4<<<dim3(1024), dim3(256), 0, stream>>>(P3, yb, K2P * COUTC);
    k_gcn_fin<<<dim3(K2P), dim3(256), 0, stream>>>(yb, tb, dinv, bout, xB, COUTC, 0);
  }

  k_write_out<<<dim3(1024), dim3(256), 0, stream>>>(xB, (float*)d_out, K2P * COUTC, out_size);
}

// Round 6
// 1792.982 us; speedup vs baseline: 4.6676x; 1.4605x over previous
//
#include <hip/hip_runtime.h>
#include <math.h>

#define N0    4096
#define CIN   128
#define HID   256
#define COUTC 128
#define K1P   3277   // ceil(0.8*4096)
#define K2P   1967   // ceil(0.6*3277)
#define LD2   3280   // K1P padded to mult of 4 floats (16B rows)
#define LD3   1968   // K2P padded likewise
#define KI2   3328   // K1P padded to mult of 64 (MFMA K-loop + digitize tiles)
#define KI3   1984   // K2P padded to mult of 64
#define SORT_N 4096

typedef __attribute__((ext_vector_type(8))) short bf16x8;
typedef __attribute__((ext_vector_type(4))) short s16x4;
typedef __attribute__((ext_vector_type(4))) float f32x4;

__device__ __forceinline__ float b2f(short s) {
  unsigned u = ((unsigned)(unsigned short)s) << 16;
  return __builtin_bit_cast(float, u);
}
__device__ __forceinline__ short f2b(float f) {  // RNE bf16
  unsigned u = __builtin_bit_cast(unsigned, f);
  u = (u + 0x7fffu + ((u >> 16) & 1u)) >> 16;
  return (short)u;
}

// async global->LDS, 16B per lane; LDS base must be wave-uniform (HW adds lane*16)
__device__ __forceinline__ void gl2lds16(const void* g, void* l) {
  __builtin_amdgcn_global_load_lds((const __attribute__((address_space(1))) void*)g,
                                   (__attribute__((address_space(3))) void*)l, 16, 0, 0);
}

// ---------------- build / elementwise ----------------

__global__ void k_zero32(float* __restrict__ p, size_t n) {
  size_t i = (size_t)blockIdx.x * blockDim.x + threadIdx.x;
  size_t st = (size_t)gridDim.x * blockDim.x;
  for (; i < n; i += st) p[i] = 0.0f;
}

__global__ void k_widen_f32_f64(const float* __restrict__ in, double* __restrict__ out, int n) {
  int i = blockIdx.x * blockDim.x + threadIdx.x;
  int st = gridDim.x * blockDim.x;
  for (; i < n; i += st) out[i] = (double)in[i];
}

__global__ void k_build_adj(const int* __restrict__ ei, float* __restrict__ A, int E, int n) {
  int e = blockIdx.x * blockDim.x + threadIdx.x;
  if (e < E) atomicAdd(&A[(size_t)ei[E + e] * n + ei[e]], 1.0f);
}

// A0 f32 -> A0b bf16 (straight) + A0bt bf16 (transposed, +2 on diag: holds (A0+2I)^T cols).
__global__ __launch_bounds__(256) void k_transpose_split_f32(
    const float* __restrict__ A, short* __restrict__ B, short* __restrict__ BT) {
  __shared__ short sm[64][68];
  const int t = threadIdx.x;
  const int r0 = blockIdx.y * 64, c0 = blockIdx.x * 64;
  const int rr = t >> 2, cs = (t & 3) * 16;
  short tmp[16];
#pragma unroll
  for (int j = 0; j < 16; ++j) {
    short v = f2b(A[(size_t)(r0 + rr) * N0 + c0 + cs + j]);
    tmp[j] = v;
    sm[cs + j][rr] = v;
  }
#pragma unroll
  for (int j = 0; j < 16; j += 8)
    *(int4*)&B[(size_t)(r0 + rr) * N0 + c0 + cs + j] = *(int4*)&tmp[j];
  __syncthreads();
  const int cc = t >> 2, rs = (t & 3) * 16;
  const int orow = c0 + cc;
#pragma unroll
  for (int j = 0; j < 16; j += 8) {
    short o[8];
#pragma unroll
    for (int q = 0; q < 8; ++q) {
      short v = sm[cc][rs + j + q];
      if (r0 + rs + j + q == orow) v = f2b(b2f(v) + 2.0f);  // fold +2I
      o[q] = v;
    }
    *(int4*)&BT[(size_t)orow * N0 + r0 + rs + j] = *(int4*)&o[0];
  }
}

// bf16 transpose with +2I fold on output diag (A1T holds (A1+2I)^T cols)
__global__ __launch_bounds__(256) void k_transpose_bf16(
    const short* __restrict__ A, short* __restrict__ BT) {
  __shared__ short sm[64][68];
  const int t = threadIdx.x;
  const int r0 = blockIdx.y * 64, c0 = blockIdx.x * 64;
  const int rr = t >> 2, cs = (t & 3) * 16;
#pragma unroll
  for (int j = 0; j < 16; ++j) sm[cs + j][rr] = A[(size_t)(r0 + rr) * N0 + c0 + cs + j];
  __syncthreads();
  const int cc = t >> 2, rs = (t & 3) * 16;
  const int orow = c0 + cc;
#pragma unroll
  for (int j = 0; j < 16; j += 8) {
    short o[8];
#pragma unroll
    for (int q = 0; q < 8; ++q) {
      short v = sm[cc][rs + j + q];
      if (r0 + rs + j + q == orow) v = f2b(b2f(v) + 2.0f);  // fold +2I
      o[q] = v;
    }
    *(int4*)&BT[(size_t)orow * N0 + r0 + rs + j] = *(int4*)&o[0];
  }
}

// f32 transpose with guards: in rows<M valid (pitch LD), out [LD][LD] (no +2I; aug3 patches)
__global__ __launch_bounds__(256) void k_transpose_f32g(
    const float* __restrict__ A, float* __restrict__ BT, int M, int LD) {
  __shared__ float sm[64][65];
  const int t = threadIdx.x;
  const int r0 = blockIdx.y * 64, c0 = blockIdx.x * 64;
  const int rr = t >> 2, cs = (t & 3) * 16;
  int gr = r0 + rr;
#pragma unroll
  for (int j = 0; j < 16; ++j) {
    int gc = c0 + cs + j;
    sm[cs + j][rr] = (gr < M && gc < LD) ? A[(size_t)gr * LD + gc] : 0.0f;
  }
  __syncthreads();
  const int cc = t >> 2, rs = (t & 3) * 16;
  int oc = c0 + cc;
  if (oc < LD)
#pragma unroll
    for (int j = 0; j < 16; ++j) {
      int orr = r0 + rs + j;
      if (orr < LD) BT[(size_t)oc * LD + orr] = sm[cc][rs + j];
    }
}

// ---------------- pipelined MFMA augment (MODE 0: aug1 bf16-out; MODE 1: aug2 f32-out) ----------
// C = rows(A) @ rows(Bt)^T with +2I pre-folded into Bt's diag; diag(C)->0.
// global_load_lds double-buffered: stage tile kt+32 while MFMA-ing tile kt.
template <int MODE>
__global__ __launch_bounds__(256) void k_aug_pipe(
    const short* __restrict__ Asrc, const short* __restrict__ Btsrc,
    const int* __restrict__ perm, const short* __restrict__ zrow,
    int K, int ldk,
    float* __restrict__ Cf, short* __restrict__ Cb,
    int M, int N, int ldcp)
{
  __shared__ __align__(16) short Ls[2][2][4096];  // [buf][A/B][128*32]
  const int tid = threadIdx.x;
  const int wave = tid >> 6, lane = tid & 63;
  const int wr = wave >> 1, wc = wave & 1;
  const int brow = blockIdx.y * 128, bcol = blockIdx.x * 128;
  const int lr = lane & 15, ko = (lane >> 4) * 8;
  const int koff = (lane & 3) * 8;

  // per-thread constant row base pointers (chunk c covers rows [ (c*4+wave)*16, +16) )
  const short* pA[2];
  const short* pB[2];
#pragma unroll
  for (int c = 0; c < 2; ++c) {
    int r = (c * 4 + wave) * 16 + (lane >> 2);
    int ra = brow + r, rb = bcol + r;
    int ia, ib;
    if (MODE == 0) { ia = ra; ib = rb; }
    else {
      ia = (ra < M) ? perm[ra] : -1;
      ib = (rb < N) ? perm[rb] : -1;
    }
    pA[c] = (ia >= 0) ? Asrc + (size_t)ia * ldk : zrow;
    pB[c] = (ib >= 0) ? Btsrc + (size_t)ib * ldk : zrow;
  }

  f32x4 acc[4][4];
#pragma unroll
  for (int m = 0; m < 4; ++m)
#pragma unroll
    for (int n = 0; n < 4; ++n) acc[m][n] = (f32x4){0.f, 0.f, 0.f, 0.f};

  auto STAGE = [&](int buf, int kt) {
#pragma unroll
    for (int c = 0; c < 2; ++c) {
      int f = c * 4 + wave;
      gl2lds16(pA[c] + kt + koff, &Ls[buf][0][f * 512]);
      gl2lds16(pB[c] + kt + koff, &Ls[buf][1][f * 512]);
    }
  };

  STAGE(0, 0);
  __syncthreads();  // drains vmcnt before first use
  int cur = 0;
  for (int kt = 0; kt < K; kt += 32) {
    if (kt + 32 < K) STAGE(cur ^ 1, kt + 32);  // async, in flight during MFMA
    bf16x8 a0[4], b0[4];
#pragma unroll
    for (int m = 0; m < 4; ++m) a0[m] = *(const bf16x8*)&Ls[cur][0][(wr * 64 + m * 16 + lr) * 32 + ko];
#pragma unroll
    for (int n = 0; n < 4; ++n) b0[n] = *(const bf16x8*)&Ls[cur][1][(wc * 64 + n * 16 + lr) * 32 + ko];
#pragma unroll
    for (int m = 0; m < 4; ++m)
#pragma unroll
      for (int n = 0; n < 4; ++n)
        acc[m][n] = __builtin_amdgcn_mfma_f32_16x16x32_bf16(a0[m], b0[n], acc[m][n], 0, 0, 0);
    __syncthreads();  // drains prefetch vmcnt + lgkm, next buffer ready
    cur ^= 1;
  }

#pragma unroll
  for (int m = 0; m < 4; ++m)
#pragma unroll
    for (int n = 0; n < 4; ++n)
#pragma unroll
      for (int q = 0; q < 4; ++q) {
        int grow = brow + wr * 64 + m * 16 + (lane >> 4) * 4 + q;
        int gcol = bcol + wc * 64 + n * 16 + lr;
        float v = acc[m][n][q];
        if (MODE == 0) {
          if (grow == gcol) v = 0.0f;
          Cb[(size_t)grow * N0 + gcol] = f2b(v);
        } else {
          if (grow < M && gcol < ldcp) {
            if (gcol >= N || grow == gcol) v = 0.0f;
            Cf[(size_t)grow * ldcp + gcol] = v;
          }
        }
      }
}

// aug3: C = rows(A2p) @ (rows(A2pT)+2I)^T, 3-term b/r split, reg-staged T14 pipeline.
__global__ __launch_bounds__(256) void k_aug3_pipe(
    const float* __restrict__ A2p, const float* __restrict__ A2pT,
    const int* __restrict__ perm, const float* __restrict__ zrowF,
    int Kiter, int lda,
    float* __restrict__ Cf, int M, int N, int ldcp)
{
  __shared__ __align__(16) short Ls[2][4][4096];  // [buf][Ab,Bb,Ar,Br]
  const int tid = threadIdx.x;
  const int wave = tid >> 6, lane = tid & 63;
  const int wr = wave >> 1, wc = wave & 1;
  const int brow = blockIdx.y * 128, bcol = blockIdx.x * 128;
  const int lr = lane & 15, ko = (lane >> 4) * 8;
  const int srow = tid >> 3;        // 0..31
  const int sc4 = (tid & 7) * 4;    // float col within tile

  const float* pA[4];
  const float* pB[4];
  int pcolB[4];
#pragma unroll
  for (int it = 0; it < 4; ++it) {
    int r = it * 32 + srow;
    int ra = brow + r, rb = bcol + r;
    int ia = (ra < M) ? perm[ra] : -1;
    int ib = (rb < N) ? perm[rb] : -1;
    pA[it] = (ia >= 0) ? A2p + (size_t)ia * lda : zrowF;
    pB[it] = (ib >= 0) ? A2pT + (size_t)ib * lda : zrowF;
    pcolB[it] = ib;
  }

  f32x4 acc[4][4];
#pragma unroll
  for (int m = 0; m < 4; ++m)
#pragma unroll
    for (int n = 0; n < 4; ++n) acc[m][n] = (f32x4){0.f, 0.f, 0.f, 0.f};

  float rA[4][4], rB[4][4];
  auto LOADT = [&](int kt) {
    int k0 = kt + sc4;
#pragma unroll
    for (int it = 0; it < 4; ++it) {
      const float* gA = (k0 < lda) ? pA[it] : zrowF;
      const float* gB = (k0 < lda) ? pB[it] : zrowF;
      *(float4*)rA[it] = *(const float4*)(gA + k0);
      *(float4*)rB[it] = *(const float4*)(gB + k0);
    }
  };
  auto CVTW = [&](int buf, int kt) {
    int k0 = kt + sc4;
#pragma unroll
    for (int it = 0; it < 4; ++it) {
      int r = it * 32 + srow;
      float va[4], vb[4];
      *(float4*)va = *(float4*)rA[it];
      *(float4*)vb = *(float4*)rB[it];
      if (pcolB[it] >= k0 && pcolB[it] < k0 + 4) vb[pcolB[it] - k0] += 2.0f;  // +2I
      short ab[4], ar[4], bb[4], br[4];
#pragma unroll
      for (int q = 0; q < 4; ++q) {
        ab[q] = f2b(va[q]); ar[q] = f2b(va[q] - b2f(ab[q]));
        bb[q] = f2b(vb[q]); br[q] = f2b(vb[q] - b2f(bb[q]));
      }
      *(s16x4*)&Ls[buf][0][r * 32 + sc4] = *(s16x4*)&ab[0];
      *(s16x4*)&Ls[buf][1][r * 32 + sc4] = *(s16x4*)&bb[0];
      *(s16x4*)&Ls[buf][2][r * 32 + sc4] = *(s16x4*)&ar[0];
      *(s16x4*)&Ls[buf][3][r * 32 + sc4] = *(s16x4*)&br[0];
    }
  };

  LOADT(0);
  CVTW(0, 0);
  __syncthreads();
  int cur = 0;
  for (int kt = 0; kt < Kiter; kt += 32) {
    bool hasNext = (kt + 32 < Kiter);
    if (hasNext) LOADT(kt + 32);  // loads fly during MFMA cluster
    bf16x8 a0[4], b0[4], a1[4], b1[4];
#pragma unroll
    for (int m = 0; m < 4; ++m) {
      a0[m] = *(const bf16x8*)&Ls[cur][0][(wr * 64 + m * 16 + lr) * 32 + ko];
      a1[m] = *(const bf16x8*)&Ls[cur][2][(wr * 64 + m * 16 + lr) * 32 + ko];
    }
#pragma unroll
    for (int n = 0; n < 4; ++n) {
      b0[n] = *(const bf16x8*)&Ls[cur][1][(wc * 64 + n * 16 + lr) * 32 + ko];
      b1[n] = *(const bf16x8*)&Ls[cur][3][(wc * 64 + n * 16 + lr) * 32 + ko];
    }
#pragma unroll
    for (int m = 0; m < 4; ++m)
#pragma unroll
      for (int n = 0; n < 4; ++n) {
        acc[m][n] = __builtin_amdgcn_mfma_f32_16x16x32_bf16(a0[m], b0[n], acc[m][n], 0, 0, 0);
        acc[m][n] = __builtin_amdgcn_mfma_f32_16x16x32_bf16(a0[m], b1[n], acc[m][n], 0, 0, 0);
        acc[m][n] = __builtin_amdgcn_mfma_f32_16x16x32_bf16(a1[m], b0[n], acc[m][n], 0, 0, 0);
      }
    __syncthreads();
    if (hasNext) CVTW(cur ^ 1, kt + 32);
    __syncthreads();
    cur ^= 1;
  }

#pragma unroll
  for (int m = 0; m < 4; ++m)
#pragma unroll
    for (int n = 0; n < 4; ++n)
#pragma unroll
      for (int q = 0; q < 4; ++q) {
        int grow = brow + wr * 64 + m * 16 + (lane >> 4) * 4 + q;
        int gcol = bcol + wc * 64 + n * 16 + lr;
        if (grow < M && gcol < ldcp) {
          float v = acc[m][n][q];
          if (gcol >= N || grow == gcol) v = 0.0f;
          Cf[(size_t)grow * ldcp + gcol] = v;
        }
      }
}

// ---------------- f64 x@W (small, ordering-critical) ----------------

__global__ __launch_bounds__(256) void k_gemm_xw(
    const double* __restrict__ X, const float* __restrict__ W, double* __restrict__ C,
    int M, int N, int K) {
  __shared__ double As[16][64];
  __shared__ double Bs[16][64];
  const int tx = threadIdx.x, ty = threadIdx.y;
  const int tid = ty * 16 + tx;
  const int brow = blockIdx.y * 64, bcol = blockIdx.x * 64;
  double acc[4][4];
#pragma unroll
  for (int i = 0; i < 4; ++i)
#pragma unroll
    for (int j = 0; j < 4; ++j) acc[i][j] = 0.0;
  const int lac = tid & 15, lar = tid >> 4;
  const int lbc = tid & 63, lbr = tid >> 6;
  for (int kt = 0; kt < K; kt += 16) {
#pragma unroll
    for (int rr = 0; rr < 4; ++rr) {
      int r = lar + rr * 16;
      int gr = brow + r, gk = kt + lac;
      As[lac][r] = (gr < M && gk < K) ? X[(size_t)gr * K + gk] : 0.0;
    }
#pragma unroll
    for (int rr = 0; rr < 4; ++rr) {
      int br = lbr + rr * 4;
      int gk = kt + br, gc = bcol + lbc;
      Bs[br][lbc] = (gk < K && gc < N) ? (double)W[(size_t)gk * N + gc] : 0.0;
    }
    __syncthreads();
#pragma unroll
    for (int kk = 0; kk < 16; ++kk) {
      double a[4], b[4];
#pragma unroll
      for (int i = 0; i < 4; ++i) a[i] = As[kk][ty * 4 + i];
#pragma unroll
      for (int j = 0; j < 4; ++j) b[j] = Bs[kk][tx * 4 + j];
#pragma unroll
      for (int i = 0; i < 4; ++i)
#pragma unroll
        for (int j = 0; j < 4; ++j) acc[i][j] = fma(a[i], b[j], acc[i][j]);
    }
    __syncthreads();
  }
#pragma unroll
  for (int i = 0; i < 4; ++i) {
    int gr = brow + ty * 4 + i;
    if (gr >= M) continue;
#pragma unroll
    for (int j = 0; j < 4; ++j) {
      int gc = bcol + tx * 4 + j;
      if (gc >= N) continue;
      C[(size_t)gr * N + gc] = acc[i][j];
    }
  }
}

// ---------------- digit machinery (unchanged, verified round 5) ----------------

__global__ void k_reset_u32(unsigned* p) { if (threadIdx.x == 0 && blockIdx.x == 0) *p = 0u; }

__global__ void k_wmax(const double* __restrict__ t, const double* __restrict__ dinv,
                       unsigned* __restrict__ wmax, int K, int N) {
  __shared__ float red[256];
  float mx = 0.0f;
  int tot = K * N;
  for (int i = blockIdx.x * 256 + threadIdx.x; i < tot; i += gridDim.x * 256) {
    double w = dinv[i / N] * t[i];
    float a = (float)fabs(w);
    mx = fmaxf(mx, a);
  }
  red[threadIdx.x] = mx;
  __syncthreads();
  for (int st = 128; st > 0; st >>= 1) {
    if (threadIdx.x < st) red[threadIdx.x] = fmaxf(red[threadIdx.x], red[threadIdx.x + st]);
    __syncthreads();
  }
  if (threadIdx.x == 0) atomicMax(wmax, __builtin_bit_cast(unsigned, red[0]));
}

template <int D>
__global__ __launch_bounds__(256) void k_digitize(
    const double* __restrict__ t, const double* __restrict__ dinv,
    const unsigned* __restrict__ wmax, short* __restrict__ wdT,
    int K, int Kpad, int N) {
  __shared__ char sm[D][64][66];
  const int tid = threadIdx.x;
  const int k0 = blockIdx.x * 64, n0 = blockIdx.y * 64;
  float wm = __builtin_bit_cast(float, *wmax);
  double sc = (wm > 0.0f) ? scalbn(1.0, -(ilogbf(wm) + 1)) : 0.0;
  const int kk = tid >> 2, ns = (tid & 3) * 16;
  int k = k0 + kk;
  double dv = (k < K) ? dinv[k] : 0.0;
#pragma unroll
  for (int j = 0; j < 16; ++j) {
    int n = n0 + ns + j;
    double w = (k < K) ? dv * t[(size_t)k * N + n] : 0.0;
    double r = w * sc;
#pragma unroll
    for (int d = 0; d < D; ++d) {
      double rm = r * 32.0;
      double m = rint(rm);
      sm[d][kk][ns + j] = (char)(int)m;
      r = rm - m;
    }
  }
  __syncthreads();
  const int nn = tid >> 2, ks = (tid & 3) * 16;
  const size_t PS = (size_t)N * Kpad;
#pragma unroll
  for (int d = 0; d < D; ++d) {
    short o[16];
#pragma unroll
    for (int j = 0; j < 16; ++j) o[j] = f2b((float)sm[d][ks + j][nn]);
    short* dst = wdT + d * PS + (size_t)(n0 + nn) * Kpad + k0 + ks;
    *(int4*)&dst[0] = *(int4*)&o[0];
    *(int4*)&dst[8] = *(int4*)&o[8];
  }
}

template <int AMODE, int D, int NF>
__global__ __launch_bounds__(256) void k_axw_digit(
    const void* __restrict__ Asrc, int lda,
    const short* __restrict__ wdT, int Kpad,
    const unsigned* __restrict__ wmax,
    double* __restrict__ P, int M, int N, int Z) {
  constexpr int PL = (AMODE == 0) ? 1 : 2;
  __shared__ __align__(16) short Als[PL][32 * 32];
  __shared__ __align__(16) short Bls[256 * 32];
  const int tid = threadIdx.x;
  const int wave = tid >> 6, lane = tid & 63;
  const int lr = lane & 15, ko = (lane >> 4) * 8;
  const int brow = blockIdx.y * 32;
  const int z = blockIdx.x;
  constexpr int WN = NF * 16;
  const size_t PS = (size_t)N * Kpad;

  float wm = __builtin_bit_cast(float, *wmax);
  int E = (wm > 0.0f) ? (ilogbf(wm) + 1) : -3000;

  const int KT = Kpad / 32;
  const int base = KT / Z, rem = KT % Z;
  const int t0 = z * base + min(z, rem);
  const int t1 = t0 + base + (z < rem ? 1 : 0);

  double master[2][NF][4];
#pragma unroll
  for (int m = 0; m < 2; ++m)
#pragma unroll
    for (int n = 0; n < NF; ++n)
#pragma unroll
      for (int q = 0; q < 4; ++q) master[m][n][q] = 0.0;

  for (int d = 0; d < D; ++d) {
    double sd = (E > -3000) ? scalbn(1.0, E - 5 * (d + 1)) : 0.0;
    f32x4 acc[PL][2][NF];
#pragma unroll
    for (int p = 0; p < PL; ++p)
#pragma unroll
      for (int m = 0; m < 2; ++m)
#pragma unroll
        for (int n = 0; n < NF; ++n) acc[p][m][n] = (f32x4){0.f, 0.f, 0.f, 0.f};

    for (int kt = t0 * 32; kt < t1 * 32; kt += 32) {
      __syncthreads();
      if (AMODE == 0) {
        if (tid < 128) {
          const short* A = (const short*)Asrc;
          int row = tid >> 2, scol = (tid & 3) * 8;
          int gr = brow + row;
          int4 v = make_int4(0, 0, 0, 0);
          if (gr < M) v = *(const int4*)(A + (size_t)gr * lda + kt + scol);
          *(int4*)&Als[0][row * 32 + scol] = v;
        }
      } else {
        const float* A = (const float*)Asrc;
        int row = tid >> 3, sc4 = (tid & 7) * 4;
        int gr = brow + row, k0 = kt + sc4;
        float v[4] = {0.f, 0.f, 0.f, 0.f};
        if (gr < M && k0 < lda) *(float4*)v = *(const float4*)(A + (size_t)gr * lda + k0);
        short p0[4], p1[4];
#pragma unroll
        for (int q = 0; q < 4; ++q) {
          if (AMODE == 1) {
            float hi = floorf(v[q] * (1.0f / 64.0f));
            p0[q] = f2b(hi);
            p1[q] = f2b(v[q] - 64.0f * hi);
          } else {
            p0[q] = f2b(v[q]);
            p1[q] = f2b(v[q] - b2f(p0[q]));
          }
        }
        *(s16x4*)&Als[0][row * 32 + sc4] = *(s16x4*)&p0[0];
        *(s16x4*)&Als[1][row * 32 + sc4] = *(s16x4*)&p1[0];
      }
      {
        const short* src = wdT + d * PS;
        int row = tid >> 2, scol = (tid & 3) * 8;
#pragma unroll
        for (int it = 0; it < NF; ++it) {
          int n = it * 64 + row;
          int4 v = *(const int4*)(src + (size_t)n * Kpad + kt + scol);
          *(int4*)&Bls[n * 32 + scol] = v;
        }
      }
      __syncthreads();
      bf16x8 a[PL][2], b[NF];
#pragma unroll
      for (int p = 0; p < PL; ++p)
#pragma unroll
        for (int m = 0; m < 2; ++m) a[p][m] = *(const bf16x8*)&Als[p][(m * 16 + lr) * 32 + ko];
#pragma unroll
      for (int n = 0; n < NF; ++n) b[n] = *(const bf16x8*)&Bls[(wave * WN + n * 16 + lr) * 32 + ko];
#pragma unroll
      for (int p = 0; p < PL; ++p)
#pragma unroll
        for (int m = 0; m < 2; ++m)
#pragma unroll
          for (int n = 0; n < NF; ++n)
            acc[p][m][n] = __builtin_amdgcn_mfma_f32_16x16x32_bf16(a[p][m], b[n], acc[p][m][n], 0, 0, 0);
    }
#pragma unroll
    for (int m = 0; m < 2; ++m)
#pragma unroll
      for (int n = 0; n < NF; ++n)
#pragma unroll
        for (int q = 0; q < 4; ++q) {
          double contrib;
          if (AMODE == 0) contrib = (double)acc[0][m][n][q];
          else if (AMODE == 1) contrib = 64.0 * (double)acc[0][m][n][q] + (double)acc[1][m][n][q];
          else contrib = (double)acc[0][m][n][q] + (double)acc[1][m][n][q];
          master[m][n][q] += sd * contrib;
        }
  }
#pragma unroll
  for (int m = 0; m < 2; ++m)
#pragma unroll
    for (int n = 0; n < NF; ++n)
#pragma unroll
      for (int q = 0; q < 4; ++q) {
        int grow = brow + m * 16 + (lane >> 4) * 4 + q;
        int gcol = wave * WN + n * 16 + lr;
        if (grow < M) P[((size_t)z * M + grow) * N + gcol] = master[m][n][q];
      }
}

__global__ void k_reduce4(const double* __restrict__ P, double* __restrict__ y, int MN) {
  int i = blockIdx.x * blockDim.x + threadIdx.x;
  int st = gridDim.x * blockDim.x;
  size_t s = (size_t)MN;
  for (; i < MN; i += st)
    y[i] = ((P[i] + P[s + i]) + P[2 * s + i]) + P[3 * s + i];
}

// ---------------- GCN tail / pooling ----------------

template <typename TA>
__device__ __forceinline__ float a_as_f32(TA v);
template <> __device__ __forceinline__ float a_as_f32<short>(short v) { return b2f(v); }
template <> __device__ __forceinline__ float a_as_f32<float>(float v) { return v; }

template <typename TA>
__global__ void k_degdinv(const TA* __restrict__ A, int lda, double* __restrict__ dinv, int n) {
  __shared__ double red[256];
  int row = blockIdx.x;
  double s = 0.0;
  for (int j = threadIdx.x; j < n; j += 256) s += (double)a_as_f32<TA>(A[(size_t)row * lda + j]);
  red[threadIdx.x] = s;
  __syncthreads();
  for (int st = 128; st > 0; st >>= 1) {
    if (threadIdx.x < st) red[threadIdx.x] += red[threadIdx.x + st];
    __syncthreads();
  }
  if (threadIdx.x == 0) {
    double deg = red[0] + 2.0;
    dinv[row] = (deg > 0.0) ? 1.0 / sqrt(deg) : 0.0;
  }
}

__global__ void k_gcn_fin(const double* __restrict__ y, const double* __restrict__ t,
                          const double* __restrict__ dinv, const float* __restrict__ b,
                          double* __restrict__ out, int C, int relu) {
  int row = blockIdx.x;
  double d = dinv[row];
  for (int c = threadIdx.x; c < C; c += blockDim.x) {
    double v = d * (y[(size_t)row * C + c] + 2.0 * d * t[(size_t)row * C + c]) + (double)b[c];
    if (relu) v = v > 0.0 ? v : 0.0;
    out[(size_t)row * C + c] = v;
  }
}

__global__ void k_pnorm(const float* __restrict__ p, double* __restrict__ pn, int C) {
  __shared__ double red[256];
  double s = 0.0;
  for (int j = threadIdx.x; j < C; j += 256) { double v = (double)p[j]; s += v * v; }
  red[threadIdx.x] = s;
  __syncthreads();
  for (int st = 128; st > 0; st >>= 1) {
    if (threadIdx.x < st) red[threadIdx.x] += red[threadIdx.x + st];
    __syncthreads();
  }
  if (threadIdx.x == 0) pn[0] = sqrt(red[0]);
}

__global__ void k_scores(const double* __restrict__ x, const float* __restrict__ p,
                         const double* __restrict__ pn, double* __restrict__ sc, int C) {
  __shared__ double red[256];
  int row = blockIdx.x;
  double s = 0.0;
  for (int j = threadIdx.x; j < C; j += 256) s += x[(size_t)row * C + j] * (double)p[j];
  red[threadIdx.x] = s;
  __syncthreads();
  for (int st = 128; st > 0; st >>= 1) {
    if (threadIdx.x < st) red[threadIdx.x] += red[threadIdx.x + st];
    __syncthreads();
  }
  if (threadIdx.x == 0) sc[row] = tanh(red[0] / pn[0]);
}

__global__ __launch_bounds__(1024) void k_topk(const double* __restrict__ sc, int n,
                                               int* __restrict__ perm, double* __restrict__ vals) {
  __shared__ double s[SORT_N];
  __shared__ int id[SORT_N];
  const int t = threadIdx.x;
  for (int i = t; i < SORT_N; i += 1024) {
    s[i] = (i < n) ? sc[i] : -INFINITY;
    id[i] = i;
  }
  __syncthreads();
  for (int size = 2; size <= SORT_N; size <<= 1) {
    for (int stride = size >> 1; stride > 0; stride >>= 1) {
      for (int i = t; i < SORT_N; i += 1024) {
        int l = i ^ stride;
        if (l > i) {
          double si = s[i], sl = s[l];
          int ii = id[i], il = id[l];
          bool iAfterL = (sl > si) || (sl == si && il < ii);
          bool up = ((i & size) == 0);
          if (iAfterL == up) { s[i] = sl; s[l] = si; id[i] = il; id[l] = ii; }
        }
      }
      __syncthreads();
    }
  }
  for (int i = t; i < n; i += 1024) { perm[i] = id[i]; vals[i] = s[i]; }
}

__global__ void k_gather_x(const double* __restrict__ x, const int* __restrict__ perm,
                           const double* __restrict__ vals, double* __restrict__ xo, int C) {
  int row = blockIdx.x;
  int src = perm[row];
  double v = vals[row];
  for (int c = threadIdx.x; c < C; c += blockDim.x)
    xo[(size_t)row * C + c] = x[(size_t)src * C + c] * v;
}

__global__ void k_write_out(const double* __restrict__ x, float* __restrict__ out,
                            int nvals, int total) {
  int i = blockIdx.x * blockDim.x + threadIdx.x;
  int st = gridDim.x * blockDim.x;
  for (; i < total; i += st) out[i] = (i < nvals) ? (float)x[i] : 0.0f;
}

__global__ void k_sentinel(float* __restrict__ out, int total) {
  int i = blockIdx.x * blockDim.x + threadIdx.x;
  int st = gridDim.x * blockDim.x;
  for (; i < total; i += st) out[i] = 1e30f;
}

// ---------------- driver ----------------

extern "C" void kernel_launch(void* const* d_in, const int* in_sizes, int n_in,
                              void* d_out, int out_size, void* d_ws, size_t ws_size,
                              hipStream_t stream) {
  const float* x0f  = (const float*)d_in[0];
  const int*   ei   = (const int*)d_in[1];
  const float* W0   = (const float*)d_in[2];
  const float* b0   = (const float*)d_in[3];
  const float* W1   = (const float*)d_in[4];
  const float* b1   = (const float*)d_in[5];
  const float* W2   = (const float*)d_in[6];
  const float* b2   = (const float*)d_in[7];
  const float* p1   = (const float*)d_in[8];
  const float* p2   = (const float*)d_in[9];
  const float* Wout = (const float*)d_in[10];
  const float* bout = (const float*)d_in[11];
  const int E = in_sizes[1] / 2;

  const size_t MiB = 1ull << 20;
  if (ws_size < 160 * MiB) {
    k_sentinel<<<dim3(256), dim3(256), 0, stream>>>((float*)d_out, out_size);
    return;
  }
  char* W = (char*)d_ws;
  float*  A0   = (float*)(W + 0);            // 64 MiB (build phase)
  short*  A0b  = (short*)(W + 64 * MiB);     // 32
  short*  A0bt = (short*)(W + 96 * MiB);     // 32 (+2I folded)
  short*  A1   = (short*)(W + 0);            // 32 (after A0 dead)
  short*  A1T  = (short*)(W + 32 * MiB);     // 32 (+2I folded)
  short*  wdT1 = (short*)(W + 64 * MiB);     // 20 (gcn1)
  double* P1   = (double*)(W + 85 * MiB);    // 32 (gcn1 partials z4)
  float*  A2p  = (float*)(W + 64 * MiB);     // 41.0 (after gcn1)
  short*  wdT2 = (short*)(W + 106 * MiB);    // 16.25
  double* P2   = (double*)(W + 0);           // 25.6 (A1 dead after aug2)
  float*  A2pT = (float*)(W + 0);            // 41.04 (after gcn2)
  float*  A3p  = (float*)(W + 42 * MiB);     // 14.8
  short*  wdT3 = (short*)(W + 57 * MiB);     // 2.9
  double* P3   = (double*)(W + 60 * MiB);    // 15.4
  double* tb   = (double*)(W + 128 * MiB);   // 8
  double* yb   = (double*)(W + 136 * MiB);   // 8
  double* xA   = (double*)(W + 144 * MiB);   // 8
  double* xB   = (double*)(W + 152 * MiB);   // ~6.7
  char* SM = W + (159 * MiB + 256 * 1024);
  double* dinv = (double*)(SM);
  double* sc   = (double*)(SM + 32768);
  double* vals = (double*)(SM + 65536);
  double* pn   = (double*)(SM + 98304);
  unsigned* wmax = (unsigned*)(SM + 98304 + 128);
  int* perm    = (int*)(SM + 98304 + 256);
  int* permB   = (int*)(SM + 98304 + 256 + 16384);
  float* zpage = (float*)(W + 159 * MiB + 512 * 1024);  // 32 KiB zeros

  // ---- zero page + build A0, split+transpose to bf16 ----
  k_zero32<<<dim3(8), dim3(256), 0, stream>>>(zpage, 8192);
  k_zero32<<<dim3(2048), dim3(256), 0, stream>>>(A0, (size_t)N0 * N0);
  k_build_adj<<<dim3((E + 255) / 256), dim3(256), 0, stream>>>(ei, A0, E, N0);
  k_transpose_split_f32<<<dim3(64, 64), dim3(256), 0, stream>>>(A0, A0b, A0bt);

  // ---- aug1: A1 = offdiag(A0 @ (A0+2I)) (bf16-exact, pipelined) ----
  k_aug_pipe<0><<<dim3(32, 32), dim3(256), 0, stream>>>(
      A0b, A0bt, nullptr, (const short*)zpage, N0, N0, nullptr, A1, N0, N0, N0);
  k_transpose_bf16<<<dim3(64, 64), dim3(256), 0, stream>>>(A1, A1T);

  // ---- gcn1 ----
  k_widen_f32_f64<<<dim3(512), dim3(256), 0, stream>>>(x0f, xB, N0 * CIN);
  {
    dim3 b(16, 16), g((HID + 63) / 64, (N0 + 63) / 64);
    k_gemm_xw<<<g, b, 0, stream>>>(xB, W0, tb, N0, HID, CIN);
    k_degdinv<short><<<dim3(N0), dim3(256), 0, stream>>>(A1, N0, dinv, N0);
    k_reset_u32<<<dim3(1), dim3(64), 0, stream>>>(wmax);
    k_wmax<<<dim3(256), dim3(256), 0, stream>>>(tb, dinv, wmax, N0, HID);
    k_digitize<10><<<dim3((N0 + 63) / 64, HID / 64), dim3(256), 0, stream>>>(tb, dinv, wmax, wdT1, N0, N0, HID);
    k_axw_digit<0, 10, 4><<<dim3(4, N0 / 32), dim3(256), 0, stream>>>(
        A1, N0, wdT1, N0, wmax, P1, N0, HID, 4);
    k_reduce4<<<dim3(1024), dim3(256), 0, stream>>>(P1, yb, N0 * HID);
    k_gcn_fin<<<dim3(N0), dim3(256), 0, stream>>>(yb, tb, dinv, b0, xA, HID, 1);
  }

  // ---- pool1 ----
  k_pnorm<<<dim3(1), dim3(256), 0, stream>>>(p1, pn, HID);
  k_scores<<<dim3(N0), dim3(256), 0, stream>>>(xA, p1, pn, sc, HID);
  k_topk<<<dim3(1), dim3(1024), 0, stream>>>(sc, N0, perm, vals);
  k_gather_x<<<dim3(K1P), dim3(256), 0, stream>>>(xA, perm, vals, xB, HID);

  // ---- aug2: A2p = offdiag(A1 @ (A1+2I))[perm x perm], pipelined ----
  k_aug_pipe<1><<<dim3(26, 26), dim3(256), 0, stream>>>(
      A1, A1T, perm, (const short*)zpage, N0, N0, A2p, nullptr, K1P, K1P, LD2);

  // ---- gcn2 (ordering-critical: exact hi/lo A-split + digit planes) ----
  {
    dim3 b(16, 16), g((HID + 63) / 64, (K1P + 63) / 64);
    k_gemm_xw<<<g, b, 0, stream>>>(xB, W1, tb, K1P, HID, HID);
    k_degdinv<float><<<dim3(K1P), dim3(256), 0, stream>>>(A2p, LD2, dinv, K1P);
    k_reset_u32<<<dim3(1), dim3(64), 0, stream>>>(wmax);
    k_wmax<<<dim3(256), dim3(256), 0, stream>>>(tb, dinv, wmax, K1P, HID);
    k_digitize<10><<<dim3((KI2 + 63) / 64, HID / 64), dim3(256), 0, stream>>>(tb, dinv, wmax, wdT2, K1P, KI2, HID);
    k_axw_digit<1, 10, 4><<<dim3(4, (K1P + 31) / 32), dim3(256), 0, stream>>>(
        A2p, LD2, wdT2, KI2, wmax, P2, K1P, HID, 4);
    k_reduce4<<<dim3(1024), dim3(256), 0, stream>>>(P2, yb, K1P * HID);
    k_gcn_fin<<<dim3(K1P), dim3(256), 0, stream>>>(yb, tb, dinv, b1, xA, HID, 1);
  }

  // ---- pool2 ----
  k_pnorm<<<dim3(1), dim3(256), 0, stream>>>(p2, pn, HID);
  k_scores<<<dim3(K1P), dim3(256), 0, stream>>>(xA, p2, pn, sc, HID);
  k_topk<<<dim3(1), dim3(1024), 0, stream>>>(sc, K1P, permB, vals);
  k_gather_x<<<dim3(K2P), dim3(256), 0, stream>>>(xA, permB, vals, xB, HID);

  // ---- aug3: A3p = offdiag(A2p @ (A2p+2I))[perm2 x perm2], 3-term b/r, pipelined ----
  k_transpose_f32g<<<dim3(52, 52), dim3(256), 0, stream>>>(A2p, A2pT, K1P, LD2);
  k_aug3_pipe<<<dim3(16, 16), dim3(256), 0, stream>>>(
      A2p, A2pT, permB, zpage, KI2, LD2, A3p, K2P, K2P, LD3);

  // ---- gcn3 ----
  {
    dim3 b(16, 16), g((HID + 63) / 64, (K2P + 63) / 64);
    k_gemm_xw<<<g, b, 0, stream>>>(xB, W2, tb, K2P, HID, HID);
    k_degdinv<float><<<dim3(K2P), dim3(256), 0, stream>>>(A3p, LD3, dinv, K2P);
    k_reset_u32<<<dim3(1), dim3(64), 0, stream>>>(wmax);
    k_wmax<<<dim3(256), dim3(256), 0, stream>>>(tb, dinv, wmax, K2P, HID);
    k_digitize<3><<<dim3((KI3 + 63) / 64, HID / 64), dim3(256), 0, stream>>>(tb, dinv, wmax, wdT3, K2P, KI3, HID);
    k_axw_digit<2, 3, 4><<<dim3(4, (K2P + 31) / 32), dim3(256), 0, stream>>>(
        A3p, LD3, wdT3, KI3, wmax, P3, K2P, HID, 4);
    k_reduce4<<<dim3(1024), dim3(256), 0, stream>>>(P3, yb, K2P * HID);
    k_gcn_fin<<<dim3(K2P), dim3(256), 0, stream>>>(yb, tb, dinv, b2, xA, HID, 1);
  }

  // ---- gcn_out (reuse dinv of A3p) ----
  {
    dim3 b(16, 16), g((COUTC + 63) / 64, (K2P + 63) / 64);
    k_gemm_xw<<<g, b, 0, stream>>>(xA, Wout, tb, K2P, COUTC, HID);
    k_reset_u32<<<dim3(1), dim3(64), 0, stream>>>(wmax);
    k_wmax<<<dim3(256), dim3(256), 0, stream>>>(tb, dinv, wmax, K2P, COUTC);
    k_digitize<3><<<dim3((KI3 + 63) / 64, COUTC / 64), dim3(256), 0, stream>>>(tb, dinv, wmax, wdT3, K2P, KI3, COUTC);
    k_axw_digit<2, 3, 2><<<dim3(4, (K2P + 31) / 32), dim3(256), 0, stream>>>(
        A3p, LD3, wdT3, KI3, wmax, P3, K2P, COUTC, 4);
    k_reduce4<<<dim3(1024), dim3(256), 0, stream>>>(P3, yb, K2P * COUTC);
    k_gcn_fin<<<dim3(K2P), dim3(256), 0, stream>>>(yb, tb, dinv, bout, xB, COUTC, 0);
  }

  k_write_out<<<dim3(1024), dim3(256), 0, stream>>>(xB, (float*)d_out, K2P * COUTC, out_size);
}

// Round 7
// 1347.154 us; speedup vs baseline: 6.2123x; 1.3309x over previous
//
#include <hip/hip_runtime.h>
#include <math.h>

#define N0    4096
#define CIN   128
#define HID   256
#define COUTC 128
#define K1P   3277   // ceil(0.8*4096)
#define K2P   1967   // ceil(0.6*3277)
#define LD2   3280   // K1P padded to mult of 4 floats (16B rows)
#define LD3   1968   // K2P padded likewise
#define KI2   3328   // K1P padded to mult of 64
#define KI3   1984   // K2P padded to mult of 64
#define SORT_N 4096

typedef __attribute__((ext_vector_type(8))) short bf16x8;
typedef __attribute__((ext_vector_type(4))) short s16x4;
typedef __attribute__((ext_vector_type(4))) float f32x4;

__device__ __forceinline__ float b2f(short s) {
  unsigned u = ((unsigned)(unsigned short)s) << 16;
  return __builtin_bit_cast(float, u);
}
__device__ __forceinline__ short f2b(float f) {  // RNE bf16
  unsigned u = __builtin_bit_cast(unsigned, f);
  u = (u + 0x7fffu + ((u >> 16) & 1u)) >> 16;
  return (short)u;
}

// async global->LDS, 16B per lane; LDS base wave-uniform (HW adds lane*16)
__device__ __forceinline__ void gl2lds16(const void* g, void* l) {
  __builtin_amdgcn_global_load_lds((const __attribute__((address_space(1))) void*)g,
                                   (__attribute__((address_space(3))) void*)l, 16, 0, 0);
}

// ---------------- build / elementwise ----------------

__global__ void k_zero32(float* __restrict__ p, size_t n) {
  size_t i = (size_t)blockIdx.x * blockDim.x + threadIdx.x;
  size_t st = (size_t)gridDim.x * blockDim.x;
  for (; i < n; i += st) p[i] = 0.0f;
}

__global__ void k_widen_f32_f64(const float* __restrict__ in, double* __restrict__ out, int n) {
  int i = blockIdx.x * blockDim.x + threadIdx.x;
  int st = gridDim.x * blockDim.x;
  for (; i < n; i += st) out[i] = (double)in[i];
}

__global__ void k_build_adj(const int* __restrict__ ei, float* __restrict__ A, int E, int n) {
  int e = blockIdx.x * blockDim.x + threadIdx.x;
  if (e < E) atomicAdd(&A[(size_t)ei[E + e] * n + ei[e]], 1.0f);
}

// A0 f32 -> A0b bf16 + A0bt bf16 (transposed, +2 folded on diag)
__global__ __launch_bounds__(256) void k_transpose_split_f32(
    const float* __restrict__ A, short* __restrict__ B, short* __restrict__ BT) {
  __shared__ short sm[64][68];
  const int t = threadIdx.x;
  const int r0 = blockIdx.y * 64, c0 = blockIdx.x * 64;
  const int rr = t >> 2, cs = (t & 3) * 16;
  short tmp[16];
#pragma unroll
  for (int j = 0; j < 16; ++j) {
    short v = f2b(A[(size_t)(r0 + rr) * N0 + c0 + cs + j]);
    tmp[j] = v;
    sm[cs + j][rr] = v;
  }
#pragma unroll
  for (int j = 0; j < 16; j += 8)
    *(int4*)&B[(size_t)(r0 + rr) * N0 + c0 + cs + j] = *(int4*)&tmp[j];
  __syncthreads();
  const int cc = t >> 2, rs = (t & 3) * 16;
  const int orow = c0 + cc;
#pragma unroll
  for (int j = 0; j < 16; j += 8) {
    short o[8];
#pragma unroll
    for (int q = 0; q < 8; ++q) {
      short v = sm[cc][rs + j + q];
      if (r0 + rs + j + q == orow) v = f2b(b2f(v) + 2.0f);
      o[q] = v;
    }
    *(int4*)&BT[(size_t)orow * N0 + r0 + rs + j] = *(int4*)&o[0];
  }
}

// generalized bf16 square transpose (n mult of 64, pitch n) with diag fold
__global__ __launch_bounds__(256) void k_transpose_bf16s(
    const short* __restrict__ A, short* __restrict__ BT, int n, float fold) {
  __shared__ short sm[64][68];
  const int t = threadIdx.x;
  const int r0 = blockIdx.y * 64, c0 = blockIdx.x * 64;
  const int rr = t >> 2, cs = (t & 3) * 16;
#pragma unroll
  for (int j = 0; j < 16; ++j) sm[cs + j][rr] = A[(size_t)(r0 + rr) * n + c0 + cs + j];
  __syncthreads();
  const int cc = t >> 2, rs = (t & 3) * 16;
  const int orow = c0 + cc;
#pragma unroll
  for (int j = 0; j < 16; j += 8) {
    short o[8];
#pragma unroll
    for (int q = 0; q < 8; ++q) {
      short v = sm[cc][rs + j + q];
      if (r0 + rs + j + q == orow) v = f2b(b2f(v) + fold);
      o[q] = v;
    }
    *(int4*)&BT[(size_t)orow * n + r0 + rs + j] = *(int4*)&o[0];
  }
}

// ---------------- pipelined MFMA augment (aug1/aug2, verified round 6) ----------------
template <int MODE>
__global__ __launch_bounds__(256) void k_aug_pipe(
    const short* __restrict__ Asrc, const short* __restrict__ Btsrc,
    const int* __restrict__ perm, const short* __restrict__ zrow,
    int K, int ldk,
    float* __restrict__ Cf, short* __restrict__ Cb,
    int M, int N, int ldcp)
{
  __shared__ __align__(16) short Ls[2][2][4096];
  const int tid = threadIdx.x;
  const int wave = tid >> 6, lane = tid & 63;
  const int wr = wave >> 1, wc = wave & 1;
  const int brow = blockIdx.y * 128, bcol = blockIdx.x * 128;
  const int lr = lane & 15, ko = (lane >> 4) * 8;
  const int koff = (lane & 3) * 8;

  const short* pA[2];
  const short* pB[2];
#pragma unroll
  for (int c = 0; c < 2; ++c) {
    int r = (c * 4 + wave) * 16 + (lane >> 2);
    int ra = brow + r, rb = bcol + r;
    int ia, ib;
    if (MODE == 0) { ia = ra; ib = rb; }
    else {
      ia = (ra < M) ? perm[ra] : -1;
      ib = (rb < N) ? perm[rb] : -1;
    }
    pA[c] = (ia >= 0) ? Asrc + (size_t)ia * ldk : zrow;
    pB[c] = (ib >= 0) ? Btsrc + (size_t)ib * ldk : zrow;
  }

  f32x4 acc[4][4];
#pragma unroll
  for (int m = 0; m < 4; ++m)
#pragma unroll
    for (int n = 0; n < 4; ++n) acc[m][n] = (f32x4){0.f, 0.f, 0.f, 0.f};

  auto STAGE = [&](int buf, int kt) {
#pragma unroll
    for (int c = 0; c < 2; ++c) {
      int f = c * 4 + wave;
      gl2lds16(pA[c] + kt + koff, &Ls[buf][0][f * 512]);
      gl2lds16(pB[c] + kt + koff, &Ls[buf][1][f * 512]);
    }
  };

  STAGE(0, 0);
  __syncthreads();
  int cur = 0;
  for (int kt = 0; kt < K; kt += 32) {
    if (kt + 32 < K) STAGE(cur ^ 1, kt + 32);
    bf16x8 a0[4], b0[4];
#pragma unroll
    for (int m = 0; m < 4; ++m) a0[m] = *(const bf16x8*)&Ls[cur][0][(wr * 64 + m * 16 + lr) * 32 + ko];
#pragma unroll
    for (int n = 0; n < 4; ++n) b0[n] = *(const bf16x8*)&Ls[cur][1][(wc * 64 + n * 16 + lr) * 32 + ko];
#pragma unroll
    for (int m = 0; m < 4; ++m)
#pragma unroll
      for (int n = 0; n < 4; ++n)
        acc[m][n] = __builtin_amdgcn_mfma_f32_16x16x32_bf16(a0[m], b0[n], acc[m][n], 0, 0, 0);
    __syncthreads();
    cur ^= 1;
  }

#pragma unroll
  for (int m = 0; m < 4; ++m)
#pragma unroll
    for (int n = 0; n < 4; ++n)
#pragma unroll
      for (int q = 0; q < 4; ++q) {
        int grow = brow + wr * 64 + m * 16 + (lane >> 4) * 4 + q;
        int gcol = bcol + wc * 64 + n * 16 + lr;
        float v = acc[m][n][q];
        if (MODE == 0) {
          if (grow == gcol) v = 0.0f;
          Cb[(size_t)grow * N0 + gcol] = f2b(v);
        } else {
          if (grow < M && gcol < ldcp) {
            if (gcol >= N || grow == gcol) v = 0.0f;
            Cf[(size_t)grow * ldcp + gcol] = v;
          }
        }
      }
}

// aug3: C = rows(64h+l) @ (cols(64h+l)+2I), 3-term (drop l@l, rel ~4e-4, values-path).
__global__ __launch_bounds__(256) void k_aug3_pipe2(
    const short* __restrict__ Ast, const short* __restrict__ AstT,
    const int* __restrict__ perm, const short* __restrict__ zrow,
    int Kpad,
    float* __restrict__ Cf, int M, int N, int ldcp)
{
  __shared__ __align__(16) short Ls[2][4][4096];
  const int tid = threadIdx.x;
  const int wave = tid >> 6, lane = tid & 63;
  const int wr = wave >> 1, wc = wave & 1;
  const int brow = blockIdx.y * 128, bcol = blockIdx.x * 128;
  const int lr = lane & 15, ko = (lane >> 4) * 8;
  const int koff = (lane & 3) * 8;
  const size_t plane = (size_t)Kpad * Kpad;

  const short *pAh[2], *pAl[2], *pBh[2], *pBl[2];
#pragma unroll
  for (int c = 0; c < 2; ++c) {
    int r = (c * 4 + wave) * 16 + (lane >> 2);
    int ra = brow + r, rb = bcol + r;
    int ia = (ra < M) ? perm[ra] : -1;
    int ib = (rb < N) ? perm[rb] : -1;
    pAh[c] = (ia >= 0) ? Ast + (size_t)ia * Kpad : zrow;
    pAl[c] = (ia >= 0) ? Ast + plane + (size_t)ia * Kpad : zrow;
    pBh[c] = (ib >= 0) ? AstT + (size_t)ib * Kpad : zrow;
    pBl[c] = (ib >= 0) ? AstT + plane + (size_t)ib * Kpad : zrow;
  }

  f32x4 ahh[4][4], axx[4][4];
#pragma unroll
  for (int m = 0; m < 4; ++m)
#pragma unroll
    for (int n = 0; n < 4; ++n) {
      ahh[m][n] = (f32x4){0.f, 0.f, 0.f, 0.f};
      axx[m][n] = (f32x4){0.f, 0.f, 0.f, 0.f};
    }

  auto STAGE = [&](int buf, int kt) {
#pragma unroll
    for (int c = 0; c < 2; ++c) {
      int f = c * 4 + wave;
      gl2lds16(pAh[c] + kt + koff, &Ls[buf][0][f * 512]);
      gl2lds16(pBh[c] + kt + koff, &Ls[buf][1][f * 512]);
      gl2lds16(pAl[c] + kt + koff, &Ls[buf][2][f * 512]);
      gl2lds16(pBl[c] + kt + koff, &Ls[buf][3][f * 512]);
    }
  };

  STAGE(0, 0);
  __syncthreads();
  int cur = 0;
  for (int kt = 0; kt < Kpad; kt += 32) {
    if (kt + 32 < Kpad) STAGE(cur ^ 1, kt + 32);
    bf16x8 ah[4], al[4], bh[4], bl[4];
#pragma unroll
    for (int m = 0; m < 4; ++m) {
      ah[m] = *(const bf16x8*)&Ls[cur][0][(wr * 64 + m * 16 + lr) * 32 + ko];
      al[m] = *(const bf16x8*)&Ls[cur][2][(wr * 64 + m * 16 + lr) * 32 + ko];
    }
#pragma unroll
    for (int n = 0; n < 4; ++n) {
      bh[n] = *(const bf16x8*)&Ls[cur][1][(wc * 64 + n * 16 + lr) * 32 + ko];
      bl[n] = *(const bf16x8*)&Ls[cur][3][(wc * 64 + n * 16 + lr) * 32 + ko];
    }
#pragma unroll
    for (int m = 0; m < 4; ++m)
#pragma unroll
      for (int n = 0; n < 4; ++n) {
        ahh[m][n] = __builtin_amdgcn_mfma_f32_16x16x32_bf16(ah[m], bh[n], ahh[m][n], 0, 0, 0);
        axx[m][n] = __builtin_amdgcn_mfma_f32_16x16x32_bf16(ah[m], bl[n], axx[m][n], 0, 0, 0);
        axx[m][n] = __builtin_amdgcn_mfma_f32_16x16x32_bf16(al[m], bh[n], axx[m][n], 0, 0, 0);
      }
    __syncthreads();
    cur ^= 1;
  }

#pragma unroll
  for (int m = 0; m < 4; ++m)
#pragma unroll
    for (int n = 0; n < 4; ++n)
#pragma unroll
      for (int q = 0; q < 4; ++q) {
        int grow = brow + wr * 64 + m * 16 + (lane >> 4) * 4 + q;
        int gcol = bcol + wc * 64 + n * 16 + lr;
        if (grow < M && gcol < ldcp) {
          float v = 4096.0f * ahh[m][n][q] + 64.0f * axx[m][n][q];
          if (gcol >= N || grow == gcol) v = 0.0f;
          Cf[(size_t)grow * ldcp + gcol] = v;
        }
      }
}

// ---------------- f64 x@W ----------------

__global__ __launch_bounds__(256) void k_gemm_xw(
    const double* __restrict__ X, const float* __restrict__ W, double* __restrict__ C,
    int M, int N, int K) {
  __shared__ double As[16][64];
  __shared__ double Bs[16][64];
  const int tx = threadIdx.x, ty = threadIdx.y;
  const int tid = ty * 16 + tx;
  const int brow = blockIdx.y * 64, bcol = blockIdx.x * 64;
  double acc[4][4];
#pragma unroll
  for (int i = 0; i < 4; ++i)
#pragma unroll
    for (int j = 0; j < 4; ++j) acc[i][j] = 0.0;
  const int lac = tid & 15, lar = tid >> 4;
  const int lbc = tid & 63, lbr = tid >> 6;
  for (int kt = 0; kt < K; kt += 16) {
#pragma unroll
    for (int rr = 0; rr < 4; ++rr) {
      int r = lar + rr * 16;
      int gr = brow + r, gk = kt + lac;
      As[lac][r] = (gr < M && gk < K) ? X[(size_t)gr * K + gk] : 0.0;
    }
#pragma unroll
    for (int rr = 0; rr < 4; ++rr) {
      int br = lbr + rr * 4;
      int gk = kt + br, gc = bcol + lbc;
      Bs[br][lbc] = (gk < K && gc < N) ? (double)W[(size_t)gk * N + gc] : 0.0;
    }
    __syncthreads();
#pragma unroll
    for (int kk = 0; kk < 16; ++kk) {
      double a[4], b[4];
#pragma unroll
      for (int i = 0; i < 4; ++i) a[i] = As[kk][ty * 4 + i];
#pragma unroll
      for (int j = 0; j < 4; ++j) b[j] = Bs[kk][tx * 4 + j];
#pragma unroll
      for (int i = 0; i < 4; ++i)
#pragma unroll
        for (int j = 0; j < 4; ++j) acc[i][j] = fma(a[i], b[j], acc[i][j]);
    }
    __syncthreads();
  }
#pragma unroll
  for (int i = 0; i < 4; ++i) {
    int gr = brow + ty * 4 + i;
    if (gr >= M) continue;
#pragma unroll
    for (int j = 0; j < 4; ++j) {
      int gc = bcol + tx * 4 + j;
      if (gc >= N) continue;
      C[(size_t)gr * N + gc] = acc[i][j];
    }
  }
}

// ---------------- digit machinery ----------------

__global__ void k_reset_u32(unsigned* p) { if (threadIdx.x == 0 && blockIdx.x == 0) *p = 0u; }

__global__ void k_wmax(const double* __restrict__ t, const double* __restrict__ dinv,
                       unsigned* __restrict__ wmax, int K, int N) {
  __shared__ float red[256];
  float mx = 0.0f;
  int tot = K * N;
  for (int i = blockIdx.x * 256 + threadIdx.x; i < tot; i += gridDim.x * 256) {
    double w = dinv[i / N] * t[i];
    float a = (float)fabs(w);
    mx = fmaxf(mx, a);
  }
  red[threadIdx.x] = mx;
  __syncthreads();
  for (int st = 128; st > 0; st >>= 1) {
    if (threadIdx.x < st) red[threadIdx.x] = fmaxf(red[threadIdx.x], red[threadIdx.x + st]);
    __syncthreads();
  }
  if (threadIdx.x == 0) atomicMax(wmax, __builtin_bit_cast(unsigned, red[0]));
}

// w[k][n] = dinv[k]*t[k][n] -> D bf16 digit planes wdT[d][n][Kpad], base-32 balanced.
template <int D>
__global__ __launch_bounds__(256) void k_digitize(
    const double* __restrict__ t, const double* __restrict__ dinv,
    const unsigned* __restrict__ wmax, short* __restrict__ wdT,
    int K, int Kpad, int N) {
  __shared__ char sm[D][64][66];
  const int tid = threadIdx.x;
  const int k0 = blockIdx.x * 64, n0 = blockIdx.y * 64;
  float wm = __builtin_bit_cast(float, *wmax);
  double sc = (wm > 0.0f) ? scalbn(1.0, -(ilogbf(wm) + 1)) : 0.0;
  const int kk = tid >> 2, ns = (tid & 3) * 16;
  int k = k0 + kk;
  double dv = (k < K) ? dinv[k] : 0.0;
#pragma unroll
  for (int j = 0; j < 16; ++j) {
    int n = n0 + ns + j;
    double w = (k < K) ? dv * t[(size_t)k * N + n] : 0.0;
    double r = w * sc;
#pragma unroll
    for (int d = 0; d < D; ++d) {
      double rm = r * 32.0;
      double m = rint(rm);
      sm[d][kk][ns + j] = (char)(int)m;
      r = rm - m;
    }
  }
  __syncthreads();
  const int nn = tid >> 2, ks = (tid & 3) * 16;
  const size_t PS = (size_t)N * Kpad;
#pragma unroll
  for (int d = 0; d < D; ++d) {
    short o[16];
#pragma unroll
    for (int j = 0; j < 16; ++j) o[j] = f2b((float)sm[d][ks + j][nn]);
    short* dst = wdT + d * PS + (size_t)(n0 + nn) * Kpad + k0 + ks;
    *(int4*)&dst[0] = *(int4*)&o[0];
    *(int4*)&dst[8] = *(int4*)&o[8];
  }
}

// A f32 [M][ldsrc] -> 2 stacked bf16 planes [Kpad][Kpad] each.
// MODE 0: hi=floor(v/64), lo=v-64hi (exact, weights 64/1). MODE 1: b/r (approx, weights 1/1).
template <int MODE>
__global__ void k_splitA(const float* __restrict__ A, int M, int ldsrc,
                         short* __restrict__ S, int Kpad) {
  int r = blockIdx.x;
  const size_t plane = (size_t)Kpad * Kpad;
  for (int c4 = threadIdx.x * 4; c4 < Kpad; c4 += blockDim.x * 4) {
    float v[4] = {0.f, 0.f, 0.f, 0.f};
    if (r < M && c4 < ldsrc) *(float4*)v = *(const float4*)(A + (size_t)r * ldsrc + c4);
    short h[4], l[4];
#pragma unroll
    for (int q = 0; q < 4; ++q) {
      if (MODE == 0) {
        float hi = floorf(v[q] * (1.0f / 64.0f));
        h[q] = f2b(hi);
        l[q] = f2b(v[q] - 64.0f * hi);
      } else {
        h[q] = f2b(v[q]);
        l[q] = f2b(v[q] - b2f(h[q]));
      }
    }
    *(s16x4*)&S[(size_t)r * Kpad + c4] = *(s16x4*)&h[0];
    *(s16x4*)&S[plane + (size_t)r * Kpad + c4] = *(s16x4*)&l[0];
  }
}

// P[Mp][Neff] f32 = A[Mp][Kpad] bf16 @ wdT[Neff][Kpad]^T — m97-style DMA-pipelined GEMM.
// All dims multiples of 128 (rows) / 32 (K); all rows valid memory. Exact for integer inputs
// with per-column sums < 2^24.
__global__ __launch_bounds__(256) void k_axw_pipe(
    const short* __restrict__ Asrc, const short* __restrict__ Bsrc,
    int Kpad, float* __restrict__ P, int Neff)
{
  __shared__ __align__(16) short Ls[2][2][4096];
  const int tid = threadIdx.x;
  const int wave = tid >> 6, lane = tid & 63;
  const int wr = wave >> 1, wc = wave & 1;
  const int brow = blockIdx.y * 128, bcol = blockIdx.x * 128;
  const int lr = lane & 15, ko = (lane >> 4) * 8;
  const int koff = (lane & 3) * 8;

  const short* pA[2];
  const short* pB[2];
#pragma unroll
  for (int c = 0; c < 2; ++c) {
    int r = (c * 4 + wave) * 16 + (lane >> 2);
    pA[c] = Asrc + (size_t)(brow + r) * Kpad;
    pB[c] = Bsrc + (size_t)(bcol + r) * Kpad;
  }

  f32x4 acc[4][4];
#pragma unroll
  for (int m = 0; m < 4; ++m)
#pragma unroll
    for (int n = 0; n < 4; ++n) acc[m][n] = (f32x4){0.f, 0.f, 0.f, 0.f};

  auto STAGE = [&](int buf, int kt) {
#pragma unroll
    for (int c = 0; c < 2; ++c) {
      int f = c * 4 + wave;
      gl2lds16(pA[c] + kt + koff, &Ls[buf][0][f * 512]);
      gl2lds16(pB[c] + kt + koff, &Ls[buf][1][f * 512]);
    }
  };

  STAGE(0, 0);
  __syncthreads();
  int cur = 0;
  for (int kt = 0; kt < Kpad; kt += 32) {
    if (kt + 32 < Kpad) STAGE(cur ^ 1, kt + 32);
    bf16x8 a0[4], b0[4];
#pragma unroll
    for (int m = 0; m < 4; ++m) a0[m] = *(const bf16x8*)&Ls[cur][0][(wr * 64 + m * 16 + lr) * 32 + ko];
#pragma unroll
    for (int n = 0; n < 4; ++n) b0[n] = *(const bf16x8*)&Ls[cur][1][(wc * 64 + n * 16 + lr) * 32 + ko];
#pragma unroll
    for (int m = 0; m < 4; ++m)
#pragma unroll
      for (int n = 0; n < 4; ++n)
        acc[m][n] = __builtin_amdgcn_mfma_f32_16x16x32_bf16(a0[m], b0[n], acc[m][n], 0, 0, 0);
    __syncthreads();
    cur ^= 1;
  }

#pragma unroll
  for (int m = 0; m < 4; ++m)
#pragma unroll
    for (int n = 0; n < 4; ++n)
#pragma unroll
      for (int q = 0; q < 4; ++q) {
        int grow = brow + wr * 64 + m * 16 + (lane >> 4) * 4 + q;
        int gcol = bcol + wc * 64 + n * 16 + lr;
        P[(size_t)grow * Neff + gcol] = acc[m][n][q];
      }
}

// y[m][n] f64 = sum_d 2^(E-5(d+1)) * (w0*P[m][dN+n] + w1*P[M0pad+m][dN+n])
__global__ void k_reduce_y(const float* __restrict__ P, const unsigned* __restrict__ wmax,
                           double* __restrict__ y, int Neff, int N, int D,
                           int M0pad, int nplane, double w0, double w1) {
  int m = blockIdx.x;
  float wm = __builtin_bit_cast(float, *wmax);
  if (wm <= 0.0f) {
    for (int n = threadIdx.x; n < N; n += blockDim.x) y[(size_t)m * N + n] = 0.0;
    return;
  }
  int E = ilogbf(wm) + 1;
  for (int n = threadIdx.x; n < N; n += blockDim.x) {
    double acc = 0.0;
    for (int d = 0; d < D; ++d) {
      double v = w0 * (double)P[(size_t)m * Neff + d * N + n];
      if (nplane == 2) v += w1 * (double)P[(size_t)(M0pad + m) * Neff + d * N + n];
      acc += scalbn(v, E - 5 * (d + 1));
    }
    y[(size_t)m * N + n] = acc;
  }
}

// ---------------- GCN tail / pooling ----------------

template <typename TA>
__device__ __forceinline__ float a_as_f32(TA v);
template <> __device__ __forceinline__ float a_as_f32<short>(short v) { return b2f(v); }
template <> __device__ __forceinline__ float a_as_f32<float>(float v) { return v; }

template <typename TA>
__global__ void k_degdinv(const TA* __restrict__ A, int lda, double* __restrict__ dinv, int n) {
  __shared__ double red[256];
  int row = blockIdx.x;
  double s = 0.0;
  for (int j = threadIdx.x; j < n; j += 256) s += (double)a_as_f32<TA>(A[(size_t)row * lda + j]);
  red[threadIdx.x] = s;
  __syncthreads();
  for (int st = 128; st > 0; st >>= 1) {
    if (threadIdx.x < st) red[threadIdx.x] += red[threadIdx.x + st];
    __syncthreads();
  }
  if (threadIdx.x == 0) {
    double deg = red[0] + 2.0;
    dinv[row] = (deg > 0.0) ? 1.0 / sqrt(deg) : 0.0;
  }
}

__global__ void k_gcn_fin(const double* __restrict__ y, const double* __restrict__ t,
                          const double* __restrict__ dinv, const float* __restrict__ b,
                          double* __restrict__ out, int C, int relu) {
  int row = blockIdx.x;
  double d = dinv[row];
  for (int c = threadIdx.x; c < C; c += blockDim.x) {
    double v = d * (y[(size_t)row * C + c] + 2.0 * d * t[(size_t)row * C + c]) + (double)b[c];
    if (relu) v = v > 0.0 ? v : 0.0;
    out[(size_t)row * C + c] = v;
  }
}

__global__ void k_pnorm(const float* __restrict__ p, double* __restrict__ pn, int C) {
  __shared__ double red[256];
  double s = 0.0;
  for (int j = threadIdx.x; j < C; j += 256) { double v = (double)p[j]; s += v * v; }
  red[threadIdx.x] = s;
  __syncthreads();
  for (int st = 128; st > 0; st >>= 1) {
    if (threadIdx.x < st) red[threadIdx.x] += red[threadIdx.x + st];
    __syncthreads();
  }
  if (threadIdx.x == 0) pn[0] = sqrt(red[0]);
}

__global__ void k_scores(const double* __restrict__ x, const float* __restrict__ p,
                         const double* __restrict__ pn, double* __restrict__ sc, int C) {
  __shared__ double red[256];
  int row = blockIdx.x;
  double s = 0.0;
  for (int j = threadIdx.x; j < C; j += 256) s += x[(size_t)row * C + j] * (double)p[j];
  red[threadIdx.x] = s;
  __syncthreads();
  for (int st = 128; st > 0; st >>= 1) {
    if (threadIdx.x < st) red[threadIdx.x] += red[threadIdx.x + st];
    __syncthreads();
  }
  if (threadIdx.x == 0) sc[row] = tanh(red[0] / pn[0]);
}

__global__ __launch_bounds__(1024) void k_topk(const double* __restrict__ sc, int n,
                                               int* __restrict__ perm, double* __restrict__ vals) {
  __shared__ double s[SORT_N];
  __shared__ int id[SORT_N];
  const int t = threadIdx.x;
  for (int i = t; i < SORT_N; i += 1024) {
    s[i] = (i < n) ? sc[i] : -INFINITY;
    id[i] = i;
  }
  __syncthreads();
  for (int size = 2; size <= SORT_N; size <<= 1) {
    for (int stride = size >> 1; stride > 0; stride >>= 1) {
      for (int i = t; i < SORT_N; i += 1024) {
        int l = i ^ stride;
        if (l > i) {
          double si = s[i], sl = s[l];
          int ii = id[i], il = id[l];
          bool iAfterL = (sl > si) || (sl == si && il < ii);
          bool up = ((i & size) == 0);
          if (iAfterL == up) { s[i] = sl; s[l] = si; id[i] = il; id[l] = ii; }
        }
      }
      __syncthreads();
    }
  }
  for (int i = t; i < n; i += 1024) { perm[i] = id[i]; vals[i] = s[i]; }
}

__global__ void k_gather_x(const double* __restrict__ x, const int* __restrict__ perm,
                           const double* __restrict__ vals, double* __restrict__ xo, int C) {
  int row = blockIdx.x;
  int src = perm[row];
  double v = vals[row];
  for (int c = threadIdx.x; c < C; c += blockDim.x)
    xo[(size_t)row * C + c] = x[(size_t)src * C + c] * v;
}

__global__ void k_write_out(const double* __restrict__ x, float* __restrict__ out,
                            int nvals, int total) {
  int i = blockIdx.x * blockDim.x + threadIdx.x;
  int st = gridDim.x * blockDim.x;
  for (; i < total; i += st) out[i] = (i < nvals) ? (float)x[i] : 0.0f;
}

__global__ void k_sentinel(float* __restrict__ out, int total) {
  int i = blockIdx.x * blockDim.x + threadIdx.x;
  int st = gridDim.x * blockDim.x;
  for (; i < total; i += st) out[i] = 1e30f;
}

// ---------------- driver ----------------

extern "C" void kernel_launch(void* const* d_in, const int* in_sizes, int n_in,
                              void* d_out, int out_size, void* d_ws, size_t ws_size,
                              hipStream_t stream) {
  const float* x0f  = (const float*)d_in[0];
  const int*   ei   = (const int*)d_in[1];
  const float* W0   = (const float*)d_in[2];
  const float* b0   = (const float*)d_in[3];
  const float* W1   = (const float*)d_in[4];
  const float* b1   = (const float*)d_in[5];
  const float* W2   = (const float*)d_in[6];
  const float* b2   = (const float*)d_in[7];
  const float* p1   = (const float*)d_in[8];
  const float* p2   = (const float*)d_in[9];
  const float* Wout = (const float*)d_in[10];
  const float* bout = (const float*)d_in[11];
  const int E = in_sizes[1] / 2;

  const size_t MiB = 1ull << 20;
  if (ws_size < 160 * MiB) {
    k_sentinel<<<dim3(256), dim3(256), 0, stream>>>((float*)d_out, out_size);
    return;
  }
  char* W = (char*)d_ws;
  // epoch A (build/aug1)
  float*  A0      = (float*)(W + 0);            // 64 MiB
  short*  A0b     = (short*)(W + 64 * MiB);     // 32
  short*  A0bt    = (short*)(W + 96 * MiB);     // 32 (+2I folded)
  // epoch A2 (gcn1)
  short*  A1      = (short*)(W + 0);            // 32
  short*  A1T     = (short*)(W + 32 * MiB);     // 32 (+2I folded)
  short*  wdT1    = (short*)(W + 64 * MiB);     // 20
  float*  P1      = (float*)(W + 85 * MiB);     // 40
  // epoch B (aug2/gcn2)
  float*  A2p     = (float*)(W + 64 * MiB);     // 41.0 (over wdT1/P1 after gcn1)
  short*  A2stack = (short*)(W + 0);            // 42.3 (over A1/A1T after aug2)
  short*  wdT2    = (short*)(W + 43 * MiB);     // 16.25
  float*  P2      = (float*)(W + 60 * MiB);     // 65.0 (over A2p after splits)
  // epoch C (aug3/gcn3/out)
  short*  A2stackT= (short*)(W + 43 * MiB);     // 42.3 (over wdT2/P2 after gcn2)
  float*  A3p     = (float*)(W + 86 * MiB);     // 14.8
  short*  A3stack = (short*)(W + 0);            // 15.0 (over A2stack after aug3)
  short*  wdT3    = (short*)(W + 16 * MiB);     // 2.9
  float*  P3      = (float*)(W + 19 * MiB);     // 11.7
  // features
  double* tb   = (double*)(W + 128 * MiB);
  double* yb   = (double*)(W + 136 * MiB);
  double* xA   = (double*)(W + 144 * MiB);
  double* xB   = (double*)(W + 152 * MiB);
  char* SM = W + (159 * MiB + 256 * 1024);
  double* dinv = (double*)(SM);
  double* sc   = (double*)(SM + 32768);
  double* vals = (double*)(SM + 65536);
  double* pn   = (double*)(SM + 98304);
  unsigned* wmax = (unsigned*)(SM + 98304 + 128);
  int* perm    = (int*)(SM + 98304 + 256);
  int* permB   = (int*)(SM + 98304 + 256 + 16384);
  float* zpage = (float*)(W + 159 * MiB + 512 * 1024);  // 32 KiB zeros

  // ---- build A0, split+transpose ----
  k_zero32<<<dim3(8), dim3(256), 0, stream>>>(zpage, 8192);
  k_zero32<<<dim3(2048), dim3(256), 0, stream>>>(A0, (size_t)N0 * N0);
  k_build_adj<<<dim3((E + 255) / 256), dim3(256), 0, stream>>>(ei, A0, E, N0);
  k_transpose_split_f32<<<dim3(64, 64), dim3(256), 0, stream>>>(A0, A0b, A0bt);

  // ---- aug1 ----
  k_aug_pipe<0><<<dim3(32, 32), dim3(256), 0, stream>>>(
      A0b, A0bt, nullptr, (const short*)zpage, N0, N0, nullptr, A1, N0, N0, N0);
  k_transpose_bf16s<<<dim3(64, 64), dim3(256), 0, stream>>>(A1, A1T, N0, 2.0f);

  // ---- gcn1 ----
  k_widen_f32_f64<<<dim3(512), dim3(256), 0, stream>>>(x0f, xB, N0 * CIN);
  {
    dim3 b(16, 16), g((HID + 63) / 64, (N0 + 63) / 64);
    k_gemm_xw<<<g, b, 0, stream>>>(xB, W0, tb, N0, HID, CIN);
    k_degdinv<short><<<dim3(N0), dim3(256), 0, stream>>>(A1, N0, dinv, N0);
    k_reset_u32<<<dim3(1), dim3(64), 0, stream>>>(wmax);
    k_wmax<<<dim3(256), dim3(256), 0, stream>>>(tb, dinv, wmax, N0, HID);
    k_digitize<10><<<dim3(N0 / 64, HID / 64), dim3(256), 0, stream>>>(tb, dinv, wmax, wdT1, N0, N0, HID);
    k_axw_pipe<<<dim3(2560 / 128, N0 / 128), dim3(256), 0, stream>>>(A1, wdT1, N0, P1, 2560);
    k_reduce_y<<<dim3(N0), dim3(256), 0, stream>>>(P1, wmax, yb, 2560, HID, 10, 0, 1, 1.0, 0.0);
    k_gcn_fin<<<dim3(N0), dim3(256), 0, stream>>>(yb, tb, dinv, b0, xA, HID, 1);
  }

  // ---- pool1 ----
  k_pnorm<<<dim3(1), dim3(256), 0, stream>>>(p1, pn, HID);
  k_scores<<<dim3(N0), dim3(256), 0, stream>>>(xA, p1, pn, sc, HID);
  k_topk<<<dim3(1), dim3(1024), 0, stream>>>(sc, N0, perm, vals);
  k_gather_x<<<dim3(K1P), dim3(256), 0, stream>>>(xA, perm, vals, xB, HID);

  // ---- aug2 ----
  k_aug_pipe<1><<<dim3(26, 26), dim3(256), 0, stream>>>(
      A1, A1T, perm, (const short*)zpage, N0, N0, A2p, nullptr, K1P, K1P, LD2);

  // ---- gcn2 ----
  {
    dim3 b(16, 16), g((HID + 63) / 64, (K1P + 63) / 64);
    k_gemm_xw<<<g, b, 0, stream>>>(xB, W1, tb, K1P, HID, HID);
    k_degdinv<float><<<dim3(K1P), dim3(256), 0, stream>>>(A2p, LD2, dinv, K1P);
    k_splitA<0><<<dim3(KI2), dim3(256), 0, stream>>>(A2p, K1P, LD2, A2stack, KI2);
    k_reset_u32<<<dim3(1), dim3(64), 0, stream>>>(wmax);
    k_wmax<<<dim3(256), dim3(256), 0, stream>>>(tb, dinv, wmax, K1P, HID);
    k_digitize<10><<<dim3(KI2 / 64, HID / 64), dim3(256), 0, stream>>>(tb, dinv, wmax, wdT2, K1P, KI2, HID);
    k_axw_pipe<<<dim3(2560 / 128, 2 * KI2 / 128), dim3(256), 0, stream>>>(A2stack, wdT2, KI2, P2, 2560);
    k_reduce_y<<<dim3(K1P), dim3(256), 0, stream>>>(P2, wmax, yb, 2560, HID, 10, KI2, 2, 64.0, 1.0);
    k_gcn_fin<<<dim3(K1P), dim3(256), 0, stream>>>(yb, tb, dinv, b1, xA, HID, 1);
  }

  // ---- pool2 ----
  k_pnorm<<<dim3(1), dim3(256), 0, stream>>>(p2, pn, HID);
  k_scores<<<dim3(K1P), dim3(256), 0, stream>>>(xA, p2, pn, sc, HID);
  k_topk<<<dim3(1), dim3(1024), 0, stream>>>(sc, K1P, permB, vals);
  k_gather_x<<<dim3(K2P), dim3(256), 0, stream>>>(xA, permB, vals, xB, HID);

  // ---- aug3 (DMA 3-term from hi/lo planes; +2I folded into lo-transpose diag) ----
  {
    const size_t plane = (size_t)KI2 * KI2;
    k_transpose_bf16s<<<dim3(KI2 / 64, KI2 / 64), dim3(256), 0, stream>>>(A2stack, A2stackT, KI2, 0.0f);
    k_transpose_bf16s<<<dim3(KI2 / 64, KI2 / 64), dim3(256), 0, stream>>>(A2stack + plane, A2stackT + plane, KI2, 2.0f);
    k_aug3_pipe2<<<dim3(16, 16), dim3(256), 0, stream>>>(
        A2stack, A2stackT, permB, (const short*)zpage, KI2, A3p, K2P, K2P, LD3);
  }

  // ---- gcn3 ----
  {
    dim3 b(16, 16), g((HID + 63) / 64, (K2P + 63) / 64);
    k_gemm_xw<<<g, b, 0, stream>>>(xB, W2, tb, K2P, HID, HID);
    k_degdinv<float><<<dim3(K2P), dim3(256), 0, stream>>>(A3p, LD3, dinv, K2P);
    k_splitA<1><<<dim3(KI3), dim3(256), 0, stream>>>(A3p, K2P, LD3, A3stack, KI3);
    k_reset_u32<<<dim3(1), dim3(64), 0, stream>>>(wmax);
    k_wmax<<<dim3(256), dim3(256), 0, stream>>>(tb, dinv, wmax, K2P, HID);
    k_digitize<3><<<dim3(KI3 / 64, HID / 64), dim3(256), 0, stream>>>(tb, dinv, wmax, wdT3, K2P, KI3, HID);
    k_axw_pipe<<<dim3(768 / 128, 2 * KI3 / 128), dim3(256), 0, stream>>>(A3stack, wdT3, KI3, P3, 768);
    k_reduce_y<<<dim3(K2P), dim3(256), 0, stream>>>(P3, wmax, yb, 768, HID, 3, KI3, 2, 1.0, 1.0);
    k_gcn_fin<<<dim3(K2P), dim3(256), 0, stream>>>(yb, tb, dinv, b2, xA, HID, 1);
  }

  // ---- gcn_out (reuse dinv, A3stack) ----
  {
    dim3 b(16, 16), g((COUTC + 63) / 64, (K2P + 63) / 64);
    k_gemm_xw<<<g, b, 0, stream>>>(xA, Wout, tb, K2P, COUTC, HID);
    k_reset_u32<<<dim3(1), dim3(64), 0, stream>>>(wmax);
    k_wmax<<<dim3(256), dim3(256), 0, stream>>>(tb, dinv, wmax, K2P, COUTC);
    k_digitize<3><<<dim3(KI3 / 64, COUTC / 64), dim3(256), 0, stream>>>(tb, dinv, wmax, wdT3, K2P, KI3, COUTC);
    k_axw_pipe<<<dim3(384 / 128, 2 * KI3 / 128), dim3(256), 0, stream>>>(A3stack, wdT3, KI3, P3, 384);
    k_reduce_y<<<dim3(K2P), dim3(256), 0, stream>>>(P3, wmax, yb, 384, COUTC, 3, KI3, 2, 1.0, 1.0);
    k_gcn_fin<<<dim3(K2P), dim3(256), 0, stream>>>(yb, tb, dinv, bout, xB, COUTC, 0);
  }

  k_write_out<<<dim3(1024), dim3(256), 0, stream>>>(xB, (float*)d_out, K2P * COUTC, out_size);
}

// Round 8
// 1023.859 us; speedup vs baseline: 8.1739x; 1.3158x over previous
//
#include <hip/hip_runtime.h>
#include <math.h>

#define N0    4096
#define CIN   128
#define HID   256
#define COUTC 128
#define K1P   3277   // ceil(0.8*4096)
#define K2P   1967   // ceil(0.6*3277)
#define LD2   3280   // K1P padded to mult of 4 floats (16B rows)
#define LD3   1968   // K2P padded likewise
#define KI2   3328   // K1P padded to mult of 64
#define KI3   1984   // K2P padded to mult of 64
#define SORT_N 4096
#define DNUM  8      // digit planes, base-128 -> 56 bits

typedef __attribute__((ext_vector_type(8))) short bf16x8;
typedef __attribute__((ext_vector_type(4))) short s16x4;
typedef __attribute__((ext_vector_type(4))) float f32x4;
typedef __attribute__((ext_vector_type(4))) int   i32x4;

__device__ __forceinline__ float b2f(short s) {
  unsigned u = ((unsigned)(unsigned short)s) << 16;
  return __builtin_bit_cast(float, u);
}
__device__ __forceinline__ short f2b(float f) {  // RNE bf16
  unsigned u = __builtin_bit_cast(unsigned, f);
  u = (u + 0x7fffu + ((u >> 16) & 1u)) >> 16;
  return (short)u;
}

// async global->LDS, 16B per lane; LDS base wave-uniform (HW adds lane*16)
__device__ __forceinline__ void gl2lds16(const void* g, void* l) {
  __builtin_amdgcn_global_load_lds((const __attribute__((address_space(1))) void*)g,
                                   (__attribute__((address_space(3))) void*)l, 16, 0, 0);
}

// ---------------- build / elementwise ----------------

__global__ void k_zero32(float* __restrict__ p, size_t n) {
  size_t i = (size_t)blockIdx.x * blockDim.x + threadIdx.x;
  size_t st = (size_t)gridDim.x * blockDim.x;
  for (; i < n; i += st) p[i] = 0.0f;
}

__global__ void k_widen_f32_f64(const float* __restrict__ in, double* __restrict__ out, int n) {
  int i = blockIdx.x * blockDim.x + threadIdx.x;
  int st = gridDim.x * blockDim.x;
  for (; i < n; i += st) out[i] = (double)in[i];
}

__global__ void k_build_adj(const int* __restrict__ ei, float* __restrict__ A, int E, int n) {
  int e = blockIdx.x * blockDim.x + threadIdx.x;
  if (e < E) atomicAdd(&A[(size_t)ei[E + e] * n + ei[e]], 1.0f);
}

// A0 f32 -> A0s8 i8 + A0s8T i8 (transposed, +2 folded on diag). Small ints, exact.
__global__ __launch_bounds__(256) void k_transpose_split_i8(
    const float* __restrict__ A, char* __restrict__ B, char* __restrict__ BT) {
  __shared__ char sm[64][68];
  const int t = threadIdx.x;
  const int r0 = blockIdx.y * 64, c0 = blockIdx.x * 64;
  const int rr = t >> 2, cs = (t & 3) * 16;
  char tmp[16];
#pragma unroll
  for (int j = 0; j < 16; ++j) {
    char v = (char)(int)A[(size_t)(r0 + rr) * N0 + c0 + cs + j];
    tmp[j] = v;
    sm[cs + j][rr] = v;
  }
  *(int4*)&B[(size_t)(r0 + rr) * N0 + c0 + cs] = *(int4*)&tmp[0];
  __syncthreads();
  const int cc = t >> 2, rs = (t & 3) * 16;
  const int orow = c0 + cc;
  char o[16];
#pragma unroll
  for (int q = 0; q < 16; ++q) {
    char v = sm[cc][rs + q];
    if (r0 + rs + q == orow) v = (char)(v + 2);  // fold +2I
    o[q] = v;
  }
  *(int4*)&BT[(size_t)orow * N0 + r0 + rs] = *(int4*)&o[0];
}

// i8 square transpose (n mult of 64) with integer diag fold
__global__ __launch_bounds__(256) void k_transpose_i8s(
    const char* __restrict__ A, char* __restrict__ BT, int n, int fold) {
  __shared__ char sm[64][68];
  const int t = threadIdx.x;
  const int r0 = blockIdx.y * 64, c0 = blockIdx.x * 64;
  const int rr = t >> 2, cs = (t & 3) * 16;
  *(int4*)&sm[0][0];  // no-op
  {
    int4 v = *(const int4*)&A[(size_t)(r0 + rr) * n + c0 + cs];
    char* vb = (char*)&v;
#pragma unroll
    for (int j = 0; j < 16; ++j) sm[cs + j][rr] = vb[j];
  }
  __syncthreads();
  const int cc = t >> 2, rs = (t & 3) * 16;
  const int orow = c0 + cc;
  char o[16];
#pragma unroll
  for (int q = 0; q < 16; ++q) {
    char v = sm[cc][rs + q];
    if (r0 + rs + q == orow) v = (char)(v + fold);
    o[q] = v;
  }
  *(int4*)&BT[(size_t)orow * n + r0 + rs] = *(int4*)&o[0];
}

// bf16 square transpose (n mult of 64) with diag fold (aug3 path)
__global__ __launch_bounds__(256) void k_transpose_bf16s(
    const short* __restrict__ A, short* __restrict__ BT, int n, float fold) {
  __shared__ short sm[64][68];
  const int t = threadIdx.x;
  const int r0 = blockIdx.y * 64, c0 = blockIdx.x * 64;
  const int rr = t >> 2, cs = (t & 3) * 16;
#pragma unroll
  for (int j = 0; j < 16; ++j) sm[cs + j][rr] = A[(size_t)(r0 + rr) * n + c0 + cs + j];
  __syncthreads();
  const int cc = t >> 2, rs = (t & 3) * 16;
  const int orow = c0 + cc;
#pragma unroll
  for (int j = 0; j < 16; j += 8) {
    short o[8];
#pragma unroll
    for (int q = 0; q < 8; ++q) {
      short v = sm[cc][rs + j + q];
      if (r0 + rs + j + q == orow) v = f2b(b2f(v) + fold);
      o[q] = v;
    }
    *(int4*)&BT[(size_t)orow * n + r0 + rs + j] = *(int4*)&o[0];
  }
}

// ---------------- i8 pipelined MFMA augment (aug1: i8-out; aug2: f32-out) ----------------
// C = rows(A) @ rows(Bt)^T, +2I pre-folded in Bt diag; diag(C)->0. K-step 64 bytes, DMA dbuf.
template <int MODE>
__global__ __launch_bounds__(256) void k_aug_pipe8(
    const char* __restrict__ Asrc, const char* __restrict__ Btsrc,
    const int* __restrict__ perm, const char* __restrict__ zrow,
    int K, int ldk,
    float* __restrict__ Cf, char* __restrict__ Cb,
    int M, int N, int ldcp)
{
  __shared__ __align__(16) char Ls[2][2][8192];  // [buf][A/B][128 rows * 64 B]
  const int tid = threadIdx.x;
  const int wave = tid >> 6, lane = tid & 63;
  const int wr = wave >> 1, wc = wave & 1;
  const int brow = blockIdx.y * 128, bcol = blockIdx.x * 128;
  const int lr = lane & 15, ko = (lane >> 4) * 16;
  const int koff = (lane & 3) * 16;

  const char* pA[2];
  const char* pB[2];
#pragma unroll
  for (int c = 0; c < 2; ++c) {
    int r = (c * 4 + wave) * 16 + (lane >> 2);
    int ra = brow + r, rb = bcol + r;
    int ia, ib;
    if (MODE == 0) { ia = ra; ib = rb; }
    else {
      ia = (ra < M) ? perm[ra] : -1;
      ib = (rb < N) ? perm[rb] : -1;
    }
    pA[c] = (ia >= 0) ? Asrc + (size_t)ia * ldk : zrow;
    pB[c] = (ib >= 0) ? Btsrc + (size_t)ib * ldk : zrow;
  }

  i32x4 acc[4][4];
#pragma unroll
  for (int m = 0; m < 4; ++m)
#pragma unroll
    for (int n = 0; n < 4; ++n) acc[m][n] = (i32x4){0, 0, 0, 0};

  auto STAGE = [&](int buf, int kt) {
#pragma unroll
    for (int c = 0; c < 2; ++c) {
      int f = c * 4 + wave;
      gl2lds16(pA[c] + kt + koff, &Ls[buf][0][f * 1024]);
      gl2lds16(pB[c] + kt + koff, &Ls[buf][1][f * 1024]);
    }
  };

  STAGE(0, 0);
  __syncthreads();
  int cur = 0;
  for (int kt = 0; kt < K; kt += 64) {
    if (kt + 64 < K) STAGE(cur ^ 1, kt + 64);
    i32x4 a0[4], b0[4];
#pragma unroll
    for (int m = 0; m < 4; ++m) a0[m] = *(const i32x4*)&Ls[cur][0][(wr * 64 + m * 16 + lr) * 64 + ko];
#pragma unroll
    for (int n = 0; n < 4; ++n) b0[n] = *(const i32x4*)&Ls[cur][1][(wc * 64 + n * 16 + lr) * 64 + ko];
#pragma unroll
    for (int m = 0; m < 4; ++m)
#pragma unroll
      for (int n = 0; n < 4; ++n)
        acc[m][n] = __builtin_amdgcn_mfma_i32_16x16x64_i8(a0[m], b0[n], acc[m][n], 0, 0, 0);
    __syncthreads();
    cur ^= 1;
  }

#pragma unroll
  for (int m = 0; m < 4; ++m)
#pragma unroll
    for (int n = 0; n < 4; ++n)
#pragma unroll
      for (int q = 0; q < 4; ++q) {
        int grow = brow + wr * 64 + m * 16 + (lane >> 4) * 4 + q;
        int gcol = bcol + wc * 64 + n * 16 + lr;
        int v = acc[m][n][q];
        if (MODE == 0) {
          if (grow == gcol) v = 0;
          Cb[(size_t)grow * N0 + gcol] = (char)v;
        } else {
          if (grow < M && gcol < ldcp) {
            float fv = (float)v;
            if (gcol >= N || grow == gcol) fv = 0.0f;
            Cf[(size_t)grow * ldcp + gcol] = fv;
          }
        }
      }
}

// aug3 (bf16, unchanged-verified): C = rows(64h+l) @ (cols(64h+l)+2I), 3-term.
__global__ __launch_bounds__(256) void k_aug3_pipe2(
    const short* __restrict__ Ast, const short* __restrict__ AstT,
    const int* __restrict__ perm, const short* __restrict__ zrow,
    int Kpad,
    float* __restrict__ Cf, int M, int N, int ldcp)
{
  __shared__ __align__(16) short Ls[2][4][4096];
  const int tid = threadIdx.x;
  const int wave = tid >> 6, lane = tid & 63;
  const int wr = wave >> 1, wc = wave & 1;
  const int brow = blockIdx.y * 128, bcol = blockIdx.x * 128;
  const int lr = lane & 15, ko = (lane >> 4) * 8;
  const int koff = (lane & 3) * 8;
  const size_t plane = (size_t)Kpad * Kpad;

  const short *pAh[2], *pAl[2], *pBh[2], *pBl[2];
#pragma unroll
  for (int c = 0; c < 2; ++c) {
    int r = (c * 4 + wave) * 16 + (lane >> 2);
    int ra = brow + r, rb = bcol + r;
    int ia = (ra < M) ? perm[ra] : -1;
    int ib = (rb < N) ? perm[rb] : -1;
    pAh[c] = (ia >= 0) ? Ast + (size_t)ia * Kpad : zrow;
    pAl[c] = (ia >= 0) ? Ast + plane + (size_t)ia * Kpad : zrow;
    pBh[c] = (ib >= 0) ? AstT + (size_t)ib * Kpad : zrow;
    pBl[c] = (ib >= 0) ? AstT + plane + (size_t)ib * Kpad : zrow;
  }

  f32x4 ahh[4][4], axx[4][4];
#pragma unroll
  for (int m = 0; m < 4; ++m)
#pragma unroll
    for (int n = 0; n < 4; ++n) {
      ahh[m][n] = (f32x4){0.f, 0.f, 0.f, 0.f};
      axx[m][n] = (f32x4){0.f, 0.f, 0.f, 0.f};
    }

  auto STAGE = [&](int buf, int kt) {
#pragma unroll
    for (int c = 0; c < 2; ++c) {
      int f = c * 4 + wave;
      gl2lds16(pAh[c] + kt + koff, &Ls[buf][0][f * 512]);
      gl2lds16(pBh[c] + kt + koff, &Ls[buf][1][f * 512]);
      gl2lds16(pAl[c] + kt + koff, &Ls[buf][2][f * 512]);
      gl2lds16(pBl[c] + kt + koff, &Ls[buf][3][f * 512]);
    }
  };

  STAGE(0, 0);
  __syncthreads();
  int cur = 0;
  for (int kt = 0; kt < Kpad; kt += 32) {
    if (kt + 32 < Kpad) STAGE(cur ^ 1, kt + 32);
    bf16x8 ah[4], al[4], bh[4], bl[4];
#pragma unroll
    for (int m = 0; m < 4; ++m) {
      ah[m] = *(const bf16x8*)&Ls[cur][0][(wr * 64 + m * 16 + lr) * 32 + ko];
      al[m] = *(const bf16x8*)&Ls[cur][2][(wr * 64 + m * 16 + lr) * 32 + ko];
    }
#pragma unroll
    for (int n = 0; n < 4; ++n) {
      bh[n] = *(const bf16x8*)&Ls[cur][1][(wc * 64 + n * 16 + lr) * 32 + ko];
      bl[n] = *(const bf16x8*)&Ls[cur][3][(wc * 64 + n * 16 + lr) * 32 + ko];
    }
#pragma unroll
    for (int m = 0; m < 4; ++m)
#pragma unroll
      for (int n = 0; n < 4; ++n) {
        ahh[m][n] = __builtin_amdgcn_mfma_f32_16x16x32_bf16(ah[m], bh[n], ahh[m][n], 0, 0, 0);
        axx[m][n] = __builtin_amdgcn_mfma_f32_16x16x32_bf16(ah[m], bl[n], axx[m][n], 0, 0, 0);
        axx[m][n] = __builtin_amdgcn_mfma_f32_16x16x32_bf16(al[m], bh[n], axx[m][n], 0, 0, 0);
      }
    __syncthreads();
    cur ^= 1;
  }

#pragma unroll
  for (int m = 0; m < 4; ++m)
#pragma unroll
    for (int n = 0; n < 4; ++n)
#pragma unroll
      for (int q = 0; q < 4; ++q) {
        int grow = brow + wr * 64 + m * 16 + (lane >> 4) * 4 + q;
        int gcol = bcol + wc * 64 + n * 16 + lr;
        if (grow < M && gcol < ldcp) {
          float v = 4096.0f * ahh[m][n][q] + 64.0f * axx[m][n][q];
          if (gcol >= N || grow == gcol) v = 0.0f;
          Cf[(size_t)grow * ldcp + gcol] = v;
        }
      }
}

// ---------------- f64 x@W ----------------

__global__ __launch_bounds__(256) void k_gemm_xw(
    const double* __restrict__ X, const float* __restrict__ W, double* __restrict__ C,
    int M, int N, int K) {
  __shared__ double As[16][64];
  __shared__ double Bs[16][64];
  const int tx = threadIdx.x, ty = threadIdx.y;
  const int tid = ty * 16 + tx;
  const int brow = blockIdx.y * 64, bcol = blockIdx.x * 64;
  double acc[4][4];
#pragma unroll
  for (int i = 0; i < 4; ++i)
#pragma unroll
    for (int j = 0; j < 4; ++j) acc[i][j] = 0.0;
  const int lac = tid & 15, lar = tid >> 4;
  const int lbc = tid & 63, lbr = tid >> 6;
  for (int kt = 0; kt < K; kt += 16) {
#pragma unroll
    for (int rr = 0; rr < 4; ++rr) {
      int r = lar + rr * 16;
      int gr = brow + r, gk = kt + lac;
      As[lac][r] = (gr < M && gk < K) ? X[(size_t)gr * K + gk] : 0.0;
    }
#pragma unroll
    for (int rr = 0; rr < 4; ++rr) {
      int br = lbr + rr * 4;
      int gk = kt + br, gc = bcol + lbc;
      Bs[br][lbc] = (gk < K && gc < N) ? (double)W[(size_t)gk * N + gc] : 0.0;
    }
    __syncthreads();
#pragma unroll
    for (int kk = 0; kk < 16; ++kk) {
      double a[4], b[4];
#pragma unroll
      for (int i = 0; i < 4; ++i) a[i] = As[kk][ty * 4 + i];
#pragma unroll
      for (int j = 0; j < 4; ++j) b[j] = Bs[kk][tx * 4 + j];
#pragma unroll
      for (int i = 0; i < 4; ++i)
#pragma unroll
        for (int j = 0; j < 4; ++j) acc[i][j] = fma(a[i], b[j], acc[i][j]);
    }
    __syncthreads();
  }
#pragma unroll
  for (int i = 0; i < 4; ++i) {
    int gr = brow + ty * 4 + i;
    if (gr >= M) continue;
#pragma unroll
    for (int j = 0; j < 4; ++j) {
      int gc = bcol + tx * 4 + j;
      if (gc >= N) continue;
      C[(size_t)gr * N + gc] = acc[i][j];
    }
  }
}

// ---------------- digit machinery (i8, base-128) ----------------

__global__ void k_reset_u32(unsigned* p) { if (threadIdx.x == 0 && blockIdx.x == 0) *p = 0u; }

__global__ void k_wmax(const double* __restrict__ t, const double* __restrict__ dinv,
                       unsigned* __restrict__ wmax, int K, int N) {
  __shared__ float red[256];
  float mx = 0.0f;
  int tot = K * N;
  for (int i = blockIdx.x * 256 + threadIdx.x; i < tot; i += gridDim.x * 256) {
    double w = dinv[i / N] * t[i];
    mx = fmaxf(mx, (float)fabs(w));
  }
  red[threadIdx.x] = mx;
  __syncthreads();
  for (int st = 128; st > 0; st >>= 1) {
    if (threadIdx.x < st) red[threadIdx.x] = fmaxf(red[threadIdx.x], red[threadIdx.x + st]);
    __syncthreads();
  }
  if (threadIdx.x == 0) atomicMax(wmax, __builtin_bit_cast(unsigned, red[0]));
}

__global__ void k_wmaxf(const float* __restrict__ A, size_t n, unsigned* __restrict__ out) {
  __shared__ float red[256];
  float mx = 0.0f;
  for (size_t i = (size_t)blockIdx.x * 256 + threadIdx.x; i < n; i += (size_t)gridDim.x * 256)
    mx = fmaxf(mx, fabsf(A[i]));
  red[threadIdx.x] = mx;
  __syncthreads();
  for (int st = 128; st > 0; st >>= 1) {
    if (threadIdx.x < st) red[threadIdx.x] = fmaxf(red[threadIdx.x], red[threadIdx.x + st]);
    __syncthreads();
  }
  if (threadIdx.x == 0) atomicMax(out, __builtin_bit_cast(unsigned, red[0]));
}

// w[k][n]=dinv[k]*t[k][n] -> D i8 digit planes wdT[d][n][Kpad], base-128 balanced.
// sc = 2^-(ilogb(wm)+2) so |r|<=1/2 -> digits in [-64,64].
template <int D>
__global__ __launch_bounds__(256) void k_digitize8(
    const double* __restrict__ t, const double* __restrict__ dinv,
    const unsigned* __restrict__ wmax, char* __restrict__ wdT,
    int K, int Kpad, int N) {
  __shared__ char sm[D][64][68];
  const int tid = threadIdx.x;
  const int k0 = blockIdx.x * 64, n0 = blockIdx.y * 64;
  float wm = __builtin_bit_cast(float, *wmax);
  double sc = (wm > 0.0f) ? scalbn(1.0, -(ilogbf(wm) + 2)) : 0.0;
  const int kk = tid >> 2, ns = (tid & 3) * 16;
  int k = k0 + kk;
  double dv = (k < K) ? dinv[k] : 0.0;
#pragma unroll
  for (int j = 0; j < 16; ++j) {
    int n = n0 + ns + j;
    double w = (k < K) ? dv * t[(size_t)k * N + n] : 0.0;
    double r = w * sc;
#pragma unroll
    for (int d = 0; d < D; ++d) {
      double rm = r * 128.0;
      double m = rint(rm);
      sm[d][kk][ns + j] = (char)(int)m;
      r = rm - m;
    }
  }
  __syncthreads();
  const int nn = tid >> 2, ks = (tid & 3) * 16;
  const size_t PS = (size_t)N * Kpad;
#pragma unroll
  for (int d = 0; d < D; ++d) {
    char o[16];
#pragma unroll
    for (int j = 0; j < 16; ++j) o[j] = sm[d][ks + j][nn];
    *(int4*)&wdT[d * PS + (size_t)(n0 + nn) * Kpad + k0 + ks] = *(int4*)&o[0];
  }
}

// A2p f32 (exact nonneg ints < 2^14) -> 2 i8 planes base-128 (exact; weights 128/1)
__global__ void k_splitA8(const float* __restrict__ A, int M, int ldsrc,
                          char* __restrict__ S, int Kpad) {
  int r = blockIdx.x;
  const size_t plane = (size_t)Kpad * Kpad;
  for (int c4 = threadIdx.x * 4; c4 < Kpad; c4 += blockDim.x * 4) {
    float v[4] = {0.f, 0.f, 0.f, 0.f};
    if (r < M && c4 < ldsrc) *(float4*)v = *(const float4*)(A + (size_t)r * ldsrc + c4);
    unsigned hw = 0, lw = 0;
#pragma unroll
    for (int q = 0; q < 4; ++q) {
      int iv = (int)v[q];
      int h = iv >> 7, l = iv - (h << 7);
      hw |= ((unsigned)(unsigned char)(char)h) << (8 * q);
      lw |= ((unsigned)(unsigned char)(char)l) << (8 * q);
    }
    *(unsigned*)(S + (size_t)r * Kpad + c4) = hw;
    *(unsigned*)(S + plane + (size_t)r * Kpad + c4) = lw;
  }
}

// A3p f32 (nonneg, values-path) -> scaled 14-bit base-128 i8 planes.
// q = rint(v * 2^(13-EA)) in [0,8192]; h=q>>7, l=q&127; weights (128,1)*2^(EA-13).
__global__ void k_splitA8s(const float* __restrict__ A, int M, int ldsrc,
                           const unsigned* __restrict__ amax,
                           char* __restrict__ S, int Kpad) {
  int r = blockIdx.x;
  const size_t plane = (size_t)Kpad * Kpad;
  float am = __builtin_bit_cast(float, *amax);
  float s13 = (am > 0.0f) ? scalbnf(1.0f, 13 - (ilogbf(am) + 1)) : 0.0f;
  for (int c4 = threadIdx.x * 4; c4 < Kpad; c4 += blockDim.x * 4) {
    float v[4] = {0.f, 0.f, 0.f, 0.f};
    if (r < M && c4 < ldsrc) *(float4*)v = *(const float4*)(A + (size_t)r * ldsrc + c4);
    unsigned hw = 0, lw = 0;
#pragma unroll
    for (int q = 0; q < 4; ++q) {
      int iv = (int)rintf(v[q] * s13);
      int h = iv >> 7, l = iv - (h << 7);
      hw |= ((unsigned)(unsigned char)(char)h) << (8 * q);
      lw |= ((unsigned)(unsigned char)(char)l) << (8 * q);
    }
    *(unsigned*)(S + (size_t)r * Kpad + c4) = hw;
    *(unsigned*)(S + plane + (size_t)r * Kpad + c4) = lw;
  }
}

// P[Mp][Neff] i32 = A[Mp][Kpad] i8 @ wdT[Neff][Kpad]^T — DMA-pipelined i8 GEMM, exact.
__global__ __launch_bounds__(256) void k_axw_pipe8(
    const char* __restrict__ Asrc, const char* __restrict__ Bsrc,
    int Kpad, int* __restrict__ P, int Neff)
{
  __shared__ __align__(16) char Ls[2][2][8192];
  const int tid = threadIdx.x;
  const int wave = tid >> 6, lane = tid & 63;
  const int wr = wave >> 1, wc = wave & 1;
  const int brow = blockIdx.y * 128, bcol = blockIdx.x * 128;
  const int lr = lane & 15, ko = (lane >> 4) * 16;
  const int koff = (lane & 3) * 16;

  const char* pA[2];
  const char* pB[2];
#pragma unroll
  for (int c = 0; c < 2; ++c) {
    int r = (c * 4 + wave) * 16 + (lane >> 2);
    pA[c] = Asrc + (size_t)(brow + r) * Kpad;
    pB[c] = Bsrc + (size_t)(bcol + r) * Kpad;
  }

  i32x4 acc[4][4];
#pragma unroll
  for (int m = 0; m < 4; ++m)
#pragma unroll
    for (int n = 0; n < 4; ++n) acc[m][n] = (i32x4){0, 0, 0, 0};

  auto STAGE = [&](int buf, int kt) {
#pragma unroll
    for (int c = 0; c < 2; ++c) {
      int f = c * 4 + wave;
      gl2lds16(pA[c] + kt + koff, &Ls[buf][0][f * 1024]);
      gl2lds16(pB[c] + kt + koff, &Ls[buf][1][f * 1024]);
    }
  };

  STAGE(0, 0);
  __syncthreads();
  int cur = 0;
  for (int kt = 0; kt < Kpad; kt += 64) {
    if (kt + 64 < Kpad) STAGE(cur ^ 1, kt + 64);
    i32x4 a0[4], b0[4];
#pragma unroll
    for (int m = 0; m < 4; ++m) a0[m] = *(const i32x4*)&Ls[cur][0][(wr * 64 + m * 16 + lr) * 64 + ko];
#pragma unroll
    for (int n = 0; n < 4; ++n) b0[n] = *(const i32x4*)&Ls[cur][1][(wc * 64 + n * 16 + lr) * 64 + ko];
#pragma unroll
    for (int m = 0; m < 4; ++m)
#pragma unroll
      for (int n = 0; n < 4; ++n)
        acc[m][n] = __builtin_amdgcn_mfma_i32_16x16x64_i8(a0[m], b0[n], acc[m][n], 0, 0, 0);
    __syncthreads();
    cur ^= 1;
  }

#pragma unroll
  for (int m = 0; m < 4; ++m)
#pragma unroll
    for (int n = 0; n < 4; ++n)
#pragma unroll
      for (int q = 0; q < 4; ++q) {
        int grow = brow + wr * 64 + m * 16 + (lane >> 4) * 4 + q;
        int gcol = bcol + wc * 64 + n * 16 + lr;
        P[(size_t)grow * Neff + gcol] = acc[m][n][q];
      }
}

// y[m][n] f64 = sum_d 2^(Ep-7(d+1)) * (s0*P[m][dN+n] + s1*P[M0pad+m][dN+n]); P i32 exact.
__global__ void k_reduce_y(const int* __restrict__ P, const unsigned* __restrict__ wmax,
                           const unsigned* __restrict__ amax,
                           double* __restrict__ y, int Neff, int N, int D,
                           int M0pad, int nplane, double w0, double w1) {
  int m = blockIdx.x;
  float wm = __builtin_bit_cast(float, *wmax);
  double s0 = w0, s1 = w1;
  bool zero = (wm <= 0.0f);
  if (amax) {
    float am = __builtin_bit_cast(float, *amax);
    if (am > 0.0f) {
      int EA = ilogbf(am) + 1;
      s0 = scalbn(w0, EA - 13);
      s1 = scalbn(w1, EA - 13);
    } else zero = true;
  }
  if (zero) {
    for (int n = threadIdx.x; n < N; n += blockDim.x) y[(size_t)m * N + n] = 0.0;
    return;
  }
  int Ep = ilogbf(wm) + 2;
  for (int n = threadIdx.x; n < N; n += blockDim.x) {
    double acc = 0.0;
    for (int d = 0; d < D; ++d) {
      double v = s0 * (double)P[(size_t)m * Neff + d * N + n];
      if (nplane == 2) v += s1 * (double)P[(size_t)(M0pad + m) * Neff + d * N + n];
      acc += scalbn(v, Ep - 7 * (d + 1));
    }
    y[(size_t)m * N + n] = acc;
  }
}

// A2p f32 -> 2 bf16 planes base-64 (exact; weights 64/1) for aug3 (verified path)
__global__ void k_splitA_bf16(const float* __restrict__ A, int M, int ldsrc,
                              short* __restrict__ S, int Kpad) {
  int r = blockIdx.x;
  const size_t plane = (size_t)Kpad * Kpad;
  for (int c4 = threadIdx.x * 4; c4 < Kpad; c4 += blockDim.x * 4) {
    float v[4] = {0.f, 0.f, 0.f, 0.f};
    if (r < M && c4 < ldsrc) *(float4*)v = *(const float4*)(A + (size_t)r * ldsrc + c4);
    short h[4], l[4];
#pragma unroll
    for (int q = 0; q < 4; ++q) {
      float hi = floorf(v[q] * (1.0f / 64.0f));
      h[q] = f2b(hi);
      l[q] = f2b(v[q] - 64.0f * hi);
    }
    *(s16x4*)&S[(size_t)r * Kpad + c4] = *(s16x4*)&h[0];
    *(s16x4*)&S[plane + (size_t)r * Kpad + c4] = *(s16x4*)&l[0];
  }
}

// ---------------- GCN tail / pooling ----------------

template <typename TA>
__device__ __forceinline__ float a_as_f32(TA v);
template <> __device__ __forceinline__ float a_as_f32<char>(char v) { return (float)v; }
template <> __device__ __forceinline__ float a_as_f32<float>(float v) { return v; }

template <typename TA>
__global__ void k_degdinv(const TA* __restrict__ A, int lda, double* __restrict__ dinv, int n) {
  __shared__ double red[256];
  int row = blockIdx.x;
  double s = 0.0;
  for (int j = threadIdx.x; j < n; j += 256) s += (double)a_as_f32<TA>(A[(size_t)row * lda + j]);
  red[threadIdx.x] = s;
  __syncthreads();
  for (int st = 128; st > 0; st >>= 1) {
    if (threadIdx.x < st) red[threadIdx.x] += red[threadIdx.x + st];
    __syncthreads();
  }
  if (threadIdx.x == 0) {
    double deg = red[0] + 2.0;
    dinv[row] = (deg > 0.0) ? 1.0 / sqrt(deg) : 0.0;
  }
}

__global__ void k_gcn_fin(const double* __restrict__ y, const double* __restrict__ t,
                          const double* __restrict__ dinv, const float* __restrict__ b,
                          double* __restrict__ out, int C, int relu) {
  int row = blockIdx.x;
  double d = dinv[row];
  for (int c = threadIdx.x; c < C; c += blockDim.x) {
    double v = d * (y[(size_t)row * C + c] + 2.0 * d * t[(size_t)row * C + c]) + (double)b[c];
    if (relu) v = v > 0.0 ? v : 0.0;
    out[(size_t)row * C + c] = v;
  }
}

__global__ void k_pnorm(const float* __restrict__ p, double* __restrict__ pn, int C) {
  __shared__ double red[256];
  double s = 0.0;
  for (int j = threadIdx.x; j < C; j += 256) { double v = (double)p[j]; s += v * v; }
  red[threadIdx.x] = s;
  __syncthreads();
  for (int st = 128; st > 0; st >>= 1) {
    if (threadIdx.x < st) red[threadIdx.x] += red[threadIdx.x + st];
    __syncthreads();
  }
  if (threadIdx.x == 0) pn[0] = sqrt(red[0]);
}

__global__ void k_scores(const double* __restrict__ x, const float* __restrict__ p,
                         const double* __restrict__ pn, double* __restrict__ sc, int C) {
  __shared__ double red[256];
  int row = blockIdx.x;
  double s = 0.0;
  for (int j = threadIdx.x; j < C; j += 256) s += x[(size_t)row * C + j] * (double)p[j];
  red[threadIdx.x] = s;
  __syncthreads();
  for (int st = 128; st > 0; st >>= 1) {
    if (threadIdx.x < st) red[threadIdx.x] += red[threadIdx.x + st];
    __syncthreads();
  }
  if (threadIdx.x == 0) sc[row] = tanh(red[0] / pn[0]);
}

__global__ __launch_bounds__(1024) void k_topk(const double* __restrict__ sc, int n,
                                               int* __restrict__ perm, double* __restrict__ vals) {
  __shared__ double s[SORT_N];
  __shared__ int id[SORT_N];
  const int t = threadIdx.x;
  for (int i = t; i < SORT_N; i += 1024) {
    s[i] = (i < n) ? sc[i] : -INFINITY;
    id[i] = i;
  }
  __syncthreads();
  for (int size = 2; size <= SORT_N; size <<= 1) {
    for (int stride = size >> 1; stride > 0; stride >>= 1) {
      for (int i = t; i < SORT_N; i += 1024) {
        int l = i ^ stride;
        if (l > i) {
          double si = s[i], sl = s[l];
          int ii = id[i], il = id[l];
          bool iAfterL = (sl > si) || (sl == si && il < ii);
          bool up = ((i & size) == 0);
          if (iAfterL == up) { s[i] = sl; s[l] = si; id[i] = il; id[l] = ii; }
        }
      }
      __syncthreads();
    }
  }
  for (int i = t; i < n; i += 1024) { perm[i] = id[i]; vals[i] = s[i]; }
}

__global__ void k_gather_x(const double* __restrict__ x, const int* __restrict__ perm,
                           const double* __restrict__ vals, double* __restrict__ xo, int C) {
  int row = blockIdx.x;
  int src = perm[row];
  double v = vals[row];
  for (int c = threadIdx.x; c < C; c += blockDim.x)
    xo[(size_t)row * C + c] = x[(size_t)src * C + c] * v;
}

__global__ void k_write_out(const double* __restrict__ x, float* __restrict__ out,
                            int nvals, int total) {
  int i = blockIdx.x * blockDim.x + threadIdx.x;
  int st = gridDim.x * blockDim.x;
  for (; i < total; i += st) out[i] = (i < nvals) ? (float)x[i] : 0.0f;
}

__global__ void k_sentinel(float* __restrict__ out, int total) {
  int i = blockIdx.x * blockDim.x + threadIdx.x;
  int st = gridDim.x * blockDim.x;
  for (; i < total; i += st) out[i] = 1e30f;
}

// ---------------- driver ----------------

extern "C" void kernel_launch(void* const* d_in, const int* in_sizes, int n_in,
                              void* d_out, int out_size, void* d_ws, size_t ws_size,
                              hipStream_t stream) {
  const float* x0f  = (const float*)d_in[0];
  const int*   ei   = (const int*)d_in[1];
  const float* W0   = (const float*)d_in[2];
  const float* b0   = (const float*)d_in[3];
  const float* W1   = (const float*)d_in[4];
  const float* b1   = (const float*)d_in[5];
  const float* W2   = (const float*)d_in[6];
  const float* b2   = (const float*)d_in[7];
  const float* p1   = (const float*)d_in[8];
  const float* p2   = (const float*)d_in[9];
  const float* Wout = (const float*)d_in[10];
  const float* bout = (const float*)d_in[11];
  const int E = in_sizes[1] / 2;

  const size_t MiB = 1ull << 20;
  if (ws_size < 160 * MiB) {
    k_sentinel<<<dim3(256), dim3(256), 0, stream>>>((float*)d_out, out_size);
    return;
  }
  char* W = (char*)d_ws;
  // epoch A: build + aug1
  float* A0    = (float*)(W + 0);            // 64 MiB
  char*  A0s8  = (char*)(W + 64 * MiB);      // 16
  char*  A0s8T = (char*)(W + 80 * MiB);      // 16 (+2I folded)
  // epoch A2: gcn1
  char*  A1    = (char*)(W + 0);             // 16
  char*  A1T   = (char*)(W + 16 * MiB);      // 16 (+2I folded)
  char*  wdT1  = (char*)(W + 32 * MiB);      // 8   (8*256*4096)
  int*   P1    = (int*)(W + 40 * MiB);       // 32  (4096*2048*4)
  // epoch B: aug2 + gcn2
  float* A2p      = (float*)(W + 34 * MiB);  // 41.1 (over wdT1/P1 after gcn1)
  char*  A2s8     = (char*)(W + 0);          // 21.2 (over A1/A1T after aug2)
  char*  wdT2     = (char*)(W + 22 * MiB);   // 6.5  (8*256*3328)
  int*   P2       = (int*)(W + 29 * MiB);    // 52.0 (over A2p after splits)
  short* A2stack  = (short*)(W + 82 * MiB);  // 42.3 (bf16 hi/lo for aug3)
  // epoch C: aug3 + gcn3/out
  short* A2stackT = (short*)(W + 29 * MiB);  // 42.3 (over wdT2/P2 after gcn2)
  float* A3p      = (float*)(W + 0);         // 14.8 (over A2s8)
  char*  A3stack  = (char*)(W + 15 * MiB);   // 7.6
  char*  wdT3     = (char*)(W + 23 * MiB);   // 1.0
  int*   P3       = (int*)(W + 24 * MiB);    // 7.8
  // features
  double* tb   = (double*)(W + 128 * MiB);
  double* yb   = (double*)(W + 136 * MiB);
  double* xA   = (double*)(W + 144 * MiB);
  double* xB   = (double*)(W + 152 * MiB);
  char* SM = W + (159 * MiB + 256 * 1024);
  double* dinv = (double*)(SM);
  double* sc   = (double*)(SM + 32768);
  double* vals = (double*)(SM + 65536);
  double* pn   = (double*)(SM + 98304);
  unsigned* wmax  = (unsigned*)(SM + 98304 + 128);
  unsigned* a3max = (unsigned*)(SM + 98304 + 192);
  int* perm    = (int*)(SM + 98304 + 256);
  int* permB   = (int*)(SM + 98304 + 256 + 16384);
  char* zpage  = (char*)(W + 159 * MiB + 512 * 1024);  // 32 KiB zeros

  // ---- build A0, i8 split+transpose ----
  k_zero32<<<dim3(8), dim3(256), 0, stream>>>((float*)zpage, 8192);
  k_zero32<<<dim3(2048), dim3(256), 0, stream>>>(A0, (size_t)N0 * N0);
  k_build_adj<<<dim3((E + 255) / 256), dim3(256), 0, stream>>>(ei, A0, E, N0);
  k_transpose_split_i8<<<dim3(64, 64), dim3(256), 0, stream>>>(A0, A0s8, A0s8T);

  // ---- aug1: A1 = offdiag(A0 @ (A0+2I)), i8 exact ----
  k_aug_pipe8<0><<<dim3(32, 32), dim3(256), 0, stream>>>(
      A0s8, A0s8T, nullptr, zpage, N0, N0, nullptr, A1, N0, N0, N0);
  k_transpose_i8s<<<dim3(64, 64), dim3(256), 0, stream>>>(A1, A1T, N0, 2);

  // ---- gcn1 ----
  k_widen_f32_f64<<<dim3(512), dim3(256), 0, stream>>>(x0f, xB, N0 * CIN);
  {
    dim3 b(16, 16), g((HID + 63) / 64, (N0 + 63) / 64);
    k_gemm_xw<<<g, b, 0, stream>>>(xB, W0, tb, N0, HID, CIN);
    k_degdinv<char><<<dim3(N0), dim3(256), 0, stream>>>(A1, N0, dinv, N0);
    k_reset_u32<<<dim3(1), dim3(64), 0, stream>>>(wmax);
    k_wmax<<<dim3(256), dim3(256), 0, stream>>>(tb, dinv, wmax, N0, HID);
    k_digitize8<DNUM><<<dim3(N0 / 64, HID / 64), dim3(256), 0, stream>>>(tb, dinv, wmax, wdT1, N0, N0, HID);
    k_axw_pipe8<<<dim3(DNUM * HID / 128, N0 / 128), dim3(256), 0, stream>>>(A1, wdT1, N0, P1, DNUM * HID);
    k_reduce_y<<<dim3(N0), dim3(256), 0, stream>>>(P1, wmax, nullptr, yb, DNUM * HID, HID, DNUM, 0, 1, 1.0, 0.0);
    k_gcn_fin<<<dim3(N0), dim3(256), 0, stream>>>(yb, tb, dinv, b0, xA, HID, 1);
  }

  // ---- pool1 ----
  k_pnorm<<<dim3(1), dim3(256), 0, stream>>>(p1, pn, HID);
  k_scores<<<dim3(N0), dim3(256), 0, stream>>>(xA, p1, pn, sc, HID);
  k_topk<<<dim3(1), dim3(1024), 0, stream>>>(sc, N0, perm, vals);
  k_gather_x<<<dim3(K1P), dim3(256), 0, stream>>>(xA, perm, vals, xB, HID);

  // ---- aug2: A2p = offdiag(A1 @ (A1+2I))[perm x perm], i8 exact ----
  k_aug_pipe8<1><<<dim3(26, 26), dim3(256), 0, stream>>>(
      A1, A1T, perm, zpage, N0, N0, A2p, nullptr, K1P, K1P, LD2);

  // ---- gcn2 (exact base-128 i8 A-split + i8 digits) ----
  {
    dim3 b(16, 16), g((HID + 63) / 64, (K1P + 63) / 64);
    k_gemm_xw<<<g, b, 0, stream>>>(xB, W1, tb, K1P, HID, HID);
    k_degdinv<float><<<dim3(K1P), dim3(256), 0, stream>>>(A2p, LD2, dinv, K1P);
    k_splitA_bf16<<<dim3(KI2), dim3(256), 0, stream>>>(A2p, K1P, LD2, A2stack, KI2);
    k_splitA8<<<dim3(KI2), dim3(256), 0, stream>>>(A2p, K1P, LD2, A2s8, KI2);
    k_reset_u32<<<dim3(1), dim3(64), 0, stream>>>(wmax);
    k_wmax<<<dim3(256), dim3(256), 0, stream>>>(tb, dinv, wmax, K1P, HID);
    k_digitize8<DNUM><<<dim3(KI2 / 64, HID / 64), dim3(256), 0, stream>>>(tb, dinv, wmax, wdT2, K1P, KI2, HID);
    k_axw_pipe8<<<dim3(DNUM * HID / 128, 2 * KI2 / 128), dim3(256), 0, stream>>>(A2s8, wdT2, KI2, P2, DNUM * HID);
    k_reduce_y<<<dim3(K1P), dim3(256), 0, stream>>>(P2, wmax, nullptr, yb, DNUM * HID, HID, DNUM, KI2, 2, 128.0, 1.0);
    k_gcn_fin<<<dim3(K1P), dim3(256), 0, stream>>>(yb, tb, dinv, b1, xA, HID, 1);
  }

  // ---- pool2 ----
  k_pnorm<<<dim3(1), dim3(256), 0, stream>>>(p2, pn, HID);
  k_scores<<<dim3(K1P), dim3(256), 0, stream>>>(xA, p2, pn, sc, HID);
  k_topk<<<dim3(1), dim3(1024), 0, stream>>>(sc, K1P, permB, vals);
  k_gather_x<<<dim3(K2P), dim3(256), 0, stream>>>(xA, permB, vals, xB, HID);

  // ---- aug3 (bf16 3-term, verified) ----
  {
    const size_t plane = (size_t)KI2 * KI2;
    k_transpose_bf16s<<<dim3(KI2 / 64, KI2 / 64), dim3(256), 0, stream>>>(A2stack, A2stackT, KI2, 0.0f);
    k_transpose_bf16s<<<dim3(KI2 / 64, KI2 / 64), dim3(256), 0, stream>>>(A2stack + plane, A2stackT + plane, KI2, 2.0f);
    k_aug3_pipe2<<<dim3(16, 16), dim3(256), 0, stream>>>(
        A2stack, A2stackT, permB, (const short*)zpage, KI2, A3p, K2P, K2P, LD3);
  }

  // ---- gcn3 (scaled 14-bit i8 A-split; values-path) ----
  {
    dim3 b(16, 16), g((HID + 63) / 64, (K2P + 63) / 64);
    k_gemm_xw<<<g, b, 0, stream>>>(xB, W2, tb, K2P, HID, HID);
    k_degdinv<float><<<dim3(K2P), dim3(256), 0, stream>>>(A3p, LD3, dinv, K2P);
    k_reset_u32<<<dim3(1), dim3(64), 0, stream>>>(a3max);
    k_wmaxf<<<dim3(256), dim3(256), 0, stream>>>(A3p, (size_t)K2P * LD3, a3max);
    k_splitA8s<<<dim3(KI3), dim3(256), 0, stream>>>(A3p, K2P, LD3, a3max, A3stack, KI3);
    k_reset_u32<<<dim3(1), dim3(64), 0, stream>>>(wmax);
    k_wmax<<<dim3(256), dim3(256), 0, stream>>>(tb, dinv, wmax, K2P, HID);
    k_digitize8<2><<<dim3(KI3 / 64, HID / 64), dim3(256), 0, stream>>>(tb, dinv, wmax, wdT3, K2P, KI3, HID);
    k_axw_pipe8<<<dim3(2 * HID / 128, 2 * KI3 / 128), dim3(256), 0, stream>>>(A3stack, wdT3, KI3, P3, 2 * HID);
    k_reduce_y<<<dim3(K2P), dim3(256), 0, stream>>>(P3, wmax, a3max, yb, 2 * HID, HID, 2, KI3, 2, 128.0, 1.0);
    k_gcn_fin<<<dim3(K2P), dim3(256), 0, stream>>>(yb, tb, dinv, b2, xA, HID, 1);
  }

  // ---- gcn_out (reuse dinv, a3max, A3stack) ----
  {
    dim3 b(16, 16), g((COUTC + 63) / 64, (K2P + 63) / 64);
    k_gemm_xw<<<g, b, 0, stream>>>(xA, Wout, tb, K2P, COUTC, HID);
    k_reset_u32<<<dim3(1), dim3(64), 0, stream>>>(wmax);
    k_wmax<<<dim3(256), dim3(256), 0, stream>>>(tb, dinv, wmax, K2P, COUTC);
    k_digitize8<2><<<dim3(KI3 / 64, COUTC / 64), dim3(256), 0, stream>>>(tb, dinv, wmax, wdT3, K2P, KI3, COUTC);
    k_axw_pipe8<<<dim3(2 * COUTC / 128, 2 * KI3 / 128), dim3(256), 0, stream>>>(A3stack, wdT3, KI3, P3, 2 * COUTC);
    k_reduce_y<<<dim3(K2P), dim3(256), 0, stream>>>(P3, wmax, a3max, yb, 2 * COUTC, COUTC, 2, KI3, 2, 128.0, 1.0);
    k_gcn_fin<<<dim3(K2P), dim3(256), 0, stream>>>(yb, tb, dinv, bout, xB, COUTC, 0);
  }

  k_write_out<<<dim3(1024), dim3(256), 0, stream>>>(xB, (float*)d_out, K2P * COUTC, out_size);
}

// Round 9
// 955.021 us; speedup vs baseline: 8.7631x; 1.0721x over previous
//
#include <hip/hip_runtime.h>
#include <math.h>

#define N0    4096
#define CIN   128
#define HID   256
#define COUTC 128
#define K1P   3277   // ceil(0.8*4096)
#define K2P   1967   // ceil(0.6*3277)
#define LD2   3280   // K1P padded to mult of 4 floats (16B rows)
#define LD3   1968   // K2P padded likewise
#define KI2   3328   // K1P padded to mult of 64
#define KI3   1984   // K2P padded to mult of 64
#define SORT_N 4096
#define DNUM  8      // digit planes, base-128 -> 56 bits

typedef __attribute__((ext_vector_type(8))) short bf16x8;
typedef __attribute__((ext_vector_type(4))) short s16x4;
typedef __attribute__((ext_vector_type(4))) float f32x4;
typedef __attribute__((ext_vector_type(4))) int   i32x4;

__device__ __forceinline__ float b2f(short s) {
  unsigned u = ((unsigned)(unsigned short)s) << 16;
  return __builtin_bit_cast(float, u);
}
__device__ __forceinline__ short f2b(float f) {  // RNE bf16
  unsigned u = __builtin_bit_cast(unsigned, f);
  u = (u + 0x7fffu + ((u >> 16) & 1u)) >> 16;
  return (short)u;
}

// async global->LDS, 16B per lane; LDS base wave-uniform (HW adds lane*16)
__device__ __forceinline__ void gl2lds16(const void* g, void* l) {
  __builtin_amdgcn_global_load_lds((const __attribute__((address_space(1))) void*)g,
                                   (__attribute__((address_space(3))) void*)l, 16, 0, 0);
}

// ---------------- build / elementwise ----------------

__global__ void k_zero32(float* __restrict__ p, size_t n) {
  size_t i = (size_t)blockIdx.x * blockDim.x + threadIdx.x;
  size_t st = (size_t)gridDim.x * blockDim.x;
  for (; i < n; i += st) p[i] = 0.0f;
}

__global__ void k_widen_f32_f64(const float* __restrict__ in, double* __restrict__ out, int n) {
  int i = blockIdx.x * blockDim.x + threadIdx.x;
  int st = gridDim.x * blockDim.x;
  for (; i < n; i += st) out[i] = (double)in[i];
}

__global__ void k_build_adj(const int* __restrict__ ei, float* __restrict__ A, int E, int n) {
  int e = blockIdx.x * blockDim.x + threadIdx.x;
  if (e < E) atomicAdd(&A[(size_t)ei[E + e] * n + ei[e]], 1.0f);
}

// A0 f32 -> A0s8 i8 + A0s8T i8 (transposed, +2 folded on diag). Small ints, exact.
__global__ __launch_bounds__(256) void k_transpose_split_i8(
    const float* __restrict__ A, char* __restrict__ B, char* __restrict__ BT) {
  __shared__ char sm[64][68];
  const int t = threadIdx.x;
  const int r0 = blockIdx.y * 64, c0 = blockIdx.x * 64;
  const int rr = t >> 2, cs = (t & 3) * 16;
  char tmp[16];
#pragma unroll
  for (int j = 0; j < 16; ++j) {
    char v = (char)(int)A[(size_t)(r0 + rr) * N0 + c0 + cs + j];
    tmp[j] = v;
    sm[cs + j][rr] = v;
  }
  *(int4*)&B[(size_t)(r0 + rr) * N0 + c0 + cs] = *(int4*)&tmp[0];
  __syncthreads();
  const int cc = t >> 2, rs = (t & 3) * 16;
  const int orow = c0 + cc;
  char o[16];
#pragma unroll
  for (int q = 0; q < 16; ++q) {
    char v = sm[cc][rs + q];
    if (r0 + rs + q == orow) v = (char)(v + 2);  // fold +2I
    o[q] = v;
  }
  *(int4*)&BT[(size_t)orow * N0 + r0 + rs] = *(int4*)&o[0];
}

// i8 square transpose (n mult of 64) with integer diag fold
__global__ __launch_bounds__(256) void k_transpose_i8s(
    const char* __restrict__ A, char* __restrict__ BT, int n, int fold) {
  __shared__ char sm[64][68];
  const int t = threadIdx.x;
  const int r0 = blockIdx.y * 64, c0 = blockIdx.x * 64;
  const int rr = t >> 2, cs = (t & 3) * 16;
  {
    int4 v = *(const int4*)&A[(size_t)(r0 + rr) * n + c0 + cs];
    char* vb = (char*)&v;
#pragma unroll
    for (int j = 0; j < 16; ++j) sm[cs + j][rr] = vb[j];
  }
  __syncthreads();
  const int cc = t >> 2, rs = (t & 3) * 16;
  const int orow = c0 + cc;
  char o[16];
#pragma unroll
  for (int q = 0; q < 16; ++q) {
    char v = sm[cc][rs + q];
    if (r0 + rs + q == orow) v = (char)(v + fold);
    o[q] = v;
  }
  *(int4*)&BT[(size_t)orow * n + r0 + rs] = *(int4*)&o[0];
}

// bf16 square transpose (n mult of 64) with diag fold (aug3 path)
__global__ __launch_bounds__(256) void k_transpose_bf16s(
    const short* __restrict__ A, short* __restrict__ BT, int n, float fold) {
  __shared__ short sm[64][68];
  const int t = threadIdx.x;
  const int r0 = blockIdx.y * 64, c0 = blockIdx.x * 64;
  const int rr = t >> 2, cs = (t & 3) * 16;
#pragma unroll
  for (int j = 0; j < 16; ++j) sm[cs + j][rr] = A[(size_t)(r0 + rr) * n + c0 + cs + j];
  __syncthreads();
  const int cc = t >> 2, rs = (t & 3) * 16;
  const int orow = c0 + cc;
#pragma unroll
  for (int j = 0; j < 16; j += 8) {
    short o[8];
#pragma unroll
    for (int q = 0; q < 8; ++q) {
      short v = sm[cc][rs + j + q];
      if (r0 + rs + j + q == orow) v = f2b(b2f(v) + fold);
      o[q] = v;
    }
    *(int4*)&BT[(size_t)orow * n + r0 + rs + j] = *(int4*)&o[0];
  }
}

// ---------------- i8 pipelined MFMA augment (aug1: i8-out; aug2: f32-out) ----------------
template <int MODE>
__global__ __launch_bounds__(256) void k_aug_pipe8(
    const char* __restrict__ Asrc, const char* __restrict__ Btsrc,
    const int* __restrict__ perm, const char* __restrict__ zrow,
    int K, int ldk,
    float* __restrict__ Cf, char* __restrict__ Cb,
    int M, int N, int ldcp)
{
  __shared__ __align__(16) char Ls[2][2][8192];
  const int tid = threadIdx.x;
  const int wave = tid >> 6, lane = tid & 63;
  const int wr = wave >> 1, wc = wave & 1;
  const int brow = blockIdx.y * 128, bcol = blockIdx.x * 128;
  const int lr = lane & 15, ko = (lane >> 4) * 16;
  const int koff = (lane & 3) * 16;

  const char* pA[2];
  const char* pB[2];
#pragma unroll
  for (int c = 0; c < 2; ++c) {
    int r = (c * 4 + wave) * 16 + (lane >> 2);
    int ra = brow + r, rb = bcol + r;
    int ia, ib;
    if (MODE == 0) { ia = ra; ib = rb; }
    else {
      ia = (ra < M) ? perm[ra] : -1;
      ib = (rb < N) ? perm[rb] : -1;
    }
    pA[c] = (ia >= 0) ? Asrc + (size_t)ia * ldk : zrow;
    pB[c] = (ib >= 0) ? Btsrc + (size_t)ib * ldk : zrow;
  }

  i32x4 acc[4][4];
#pragma unroll
  for (int m = 0; m < 4; ++m)
#pragma unroll
    for (int n = 0; n < 4; ++n) acc[m][n] = (i32x4){0, 0, 0, 0};

  auto STAGE = [&](int buf, int kt) {
#pragma unroll
    for (int c = 0; c < 2; ++c) {
      int f = c * 4 + wave;
      gl2lds16(pA[c] + kt + koff, &Ls[buf][0][f * 1024]);
      gl2lds16(pB[c] + kt + koff, &Ls[buf][1][f * 1024]);
    }
  };

  STAGE(0, 0);
  __syncthreads();
  int cur = 0;
  for (int kt = 0; kt < K; kt += 64) {
    if (kt + 64 < K) STAGE(cur ^ 1, kt + 64);
    i32x4 a0[4], b0[4];
#pragma unroll
    for (int m = 0; m < 4; ++m) a0[m] = *(const i32x4*)&Ls[cur][0][(wr * 64 + m * 16 + lr) * 64 + ko];
#pragma unroll
    for (int n = 0; n < 4; ++n) b0[n] = *(const i32x4*)&Ls[cur][1][(wc * 64 + n * 16 + lr) * 64 + ko];
#pragma unroll
    for (int m = 0; m < 4; ++m)
#pragma unroll
      for (int n = 0; n < 4; ++n)
        acc[m][n] = __builtin_amdgcn_mfma_i32_16x16x64_i8(a0[m], b0[n], acc[m][n], 0, 0, 0);
    __syncthreads();
    cur ^= 1;
  }

#pragma unroll
  for (int m = 0; m < 4; ++m)
#pragma unroll
    for (int n = 0; n < 4; ++n)
#pragma unroll
      for (int q = 0; q < 4; ++q) {
        int grow = brow + wr * 64 + m * 16 + (lane >> 4) * 4 + q;
        int gcol = bcol + wc * 64 + n * 16 + lr;
        int v = acc[m][n][q];
        if (MODE == 0) {
          if (grow == gcol) v = 0;
          Cb[(size_t)grow * N0 + gcol] = (char)v;
        } else {
          if (grow < M && gcol < ldcp) {
            float fv = (float)v;
            if (gcol >= N || grow == gcol) fv = 0.0f;
            Cf[(size_t)grow * ldcp + gcol] = fv;
          }
        }
      }
}

// aug3: C = rows(64h+l) @ (cols(64h+l)+2I), 3-term (drop l@l). 512 threads / 8 waves
// for 2x occupancy; per-output K-order identical to 256-thread version -> bitwise same.
__global__ __launch_bounds__(512) void k_aug3_pipe2(
    const short* __restrict__ Ast, const short* __restrict__ AstT,
    const int* __restrict__ perm, const short* __restrict__ zrow,
    int Kpad,
    float* __restrict__ Cf, int M, int N, int ldcp)
{
  __shared__ __align__(16) short Ls[2][4][4096];
  const int tid = threadIdx.x;
  const int wave = tid >> 6, lane = tid & 63;
  const int wr = wave >> 1, wc = wave & 1;  // 4x2 wave grid
  const int brow = blockIdx.y * 128, bcol = blockIdx.x * 128;
  const int lr = lane & 15, ko = (lane >> 4) * 8;
  const int koff = (lane & 3) * 8;          // shorts
  const size_t plane = (size_t)Kpad * Kpad;

  // one staged row per thread: wave w covers rows [w*16, w*16+16)
  const short *pAh, *pAl, *pBh, *pBl;
  {
    int r = (wave << 4) + (lane >> 2);
    int ra = brow + r, rb = bcol + r;
    int ia = (ra < M) ? perm[ra] : -1;
    int ib = (rb < N) ? perm[rb] : -1;
    pAh = (ia >= 0) ? Ast + (size_t)ia * Kpad : zrow;
    pAl = (ia >= 0) ? Ast + plane + (size_t)ia * Kpad : zrow;
    pBh = (ib >= 0) ? AstT + (size_t)ib * Kpad : zrow;
    pBl = (ib >= 0) ? AstT + plane + (size_t)ib * Kpad : zrow;
  }

  f32x4 ahh[2][4], axx[2][4];
#pragma unroll
  for (int m = 0; m < 2; ++m)
#pragma unroll
    for (int n = 0; n < 4; ++n) {
      ahh[m][n] = (f32x4){0.f, 0.f, 0.f, 0.f};
      axx[m][n] = (f32x4){0.f, 0.f, 0.f, 0.f};
    }

  auto STAGE = [&](int buf, int kt) {
    int f = wave * 512;  // shorts offset for this wave's 16 rows
    gl2lds16(pAh + kt + koff, &Ls[buf][0][f]);
    gl2lds16(pBh + kt + koff, &Ls[buf][1][f]);
    gl2lds16(pAl + kt + koff, &Ls[buf][2][f]);
    gl2lds16(pBl + kt + koff, &Ls[buf][3][f]);
  };

  STAGE(0, 0);
  __syncthreads();
  int cur = 0;
  for (int kt = 0; kt < Kpad; kt += 32) {
    if (kt + 32 < Kpad) STAGE(cur ^ 1, kt + 32);
    bf16x8 ah[2], al[2], bh[4], bl[4];
#pragma unroll
    for (int m = 0; m < 2; ++m) {
      ah[m] = *(const bf16x8*)&Ls[cur][0][(wr * 32 + m * 16 + lr) * 32 + ko];
      al[m] = *(const bf16x8*)&Ls[cur][2][(wr * 32 + m * 16 + lr) * 32 + ko];
    }
#pragma unroll
    for (int n = 0; n < 4; ++n) {
      bh[n] = *(const bf16x8*)&Ls[cur][1][(wc * 64 + n * 16 + lr) * 32 + ko];
      bl[n] = *(const bf16x8*)&Ls[cur][3][(wc * 64 + n * 16 + lr) * 32 + ko];
    }
#pragma unroll
    for (int m = 0; m < 2; ++m)
#pragma unroll
      for (int n = 0; n < 4; ++n) {
        ahh[m][n] = __builtin_amdgcn_mfma_f32_16x16x32_bf16(ah[m], bh[n], ahh[m][n], 0, 0, 0);
        axx[m][n] = __builtin_amdgcn_mfma_f32_16x16x32_bf16(ah[m], bl[n], axx[m][n], 0, 0, 0);
        axx[m][n] = __builtin_amdgcn_mfma_f32_16x16x32_bf16(al[m], bh[n], axx[m][n], 0, 0, 0);
      }
    __syncthreads();
    cur ^= 1;
  }

#pragma unroll
  for (int m = 0; m < 2; ++m)
#pragma unroll
    for (int n = 0; n < 4; ++n)
#pragma unroll
      for (int q = 0; q < 4; ++q) {
        int grow = brow + wr * 32 + m * 16 + (lane >> 4) * 4 + q;
        int gcol = bcol + wc * 64 + n * 16 + lr;
        if (grow < M && gcol < ldcp) {
          float v = 4096.0f * ahh[m][n][q] + 64.0f * axx[m][n][q];
          if (gcol >= N || grow == gcol) v = 0.0f;
          Cf[(size_t)grow * ldcp + gcol] = v;
        }
      }
}

// ---------------- f64 x@W (32x64 tiles for occupancy; K-order identical) ----------------

__global__ __launch_bounds__(256) void k_gemm_xw32(
    const double* __restrict__ X, const float* __restrict__ W, double* __restrict__ C,
    int M, int N, int K) {
  __shared__ double As[16][32];
  __shared__ double Bs[16][64];
  const int tx = threadIdx.x, ty = threadIdx.y;
  const int tid = ty * 16 + tx;
  const int brow = blockIdx.y * 32, bcol = blockIdx.x * 64;
  double acc[2][4];
#pragma unroll
  for (int i = 0; i < 2; ++i)
#pragma unroll
    for (int j = 0; j < 4; ++j) acc[i][j] = 0.0;
  const int lac = tid & 15, lar = tid >> 4;
  const int lbc = tid & 63, lbr = tid >> 6;
  for (int kt = 0; kt < K; kt += 16) {
#pragma unroll
    for (int rr = 0; rr < 2; ++rr) {
      int r = lar + rr * 16;
      int gr = brow + r, gk = kt + lac;
      As[lac][r] = (gr < M && gk < K) ? X[(size_t)gr * K + gk] : 0.0;
    }
#pragma unroll
    for (int rr = 0; rr < 4; ++rr) {
      int br = lbr + rr * 4;
      int gk = kt + br, gc = bcol + lbc;
      Bs[br][lbc] = (gk < K && gc < N) ? (double)W[(size_t)gk * N + gc] : 0.0;
    }
    __syncthreads();
#pragma unroll
    for (int kk = 0; kk < 16; ++kk) {
      double a[2], b[4];
#pragma unroll
      for (int i = 0; i < 2; ++i) a[i] = As[kk][ty * 2 + i];
#pragma unroll
      for (int j = 0; j < 4; ++j) b[j] = Bs[kk][tx * 4 + j];
#pragma unroll
      for (int i = 0; i < 2; ++i)
#pragma unroll
        for (int j = 0; j < 4; ++j) acc[i][j] = fma(a[i], b[j], acc[i][j]);
    }
    __syncthreads();
  }
#pragma unroll
  for (int i = 0; i < 2; ++i) {
    int gr = brow + ty * 2 + i;
    if (gr >= M) continue;
#pragma unroll
    for (int j = 0; j < 4; ++j) {
      int gc = bcol + tx * 4 + j;
      if (gc >= N) continue;
      C[(size_t)gr * N + gc] = acc[i][j];
    }
  }
}

// ---------------- digit machinery (i8, base-128) ----------------

__global__ void k_reset_u32(unsigned* p) { if (threadIdx.x == 0 && blockIdx.x == 0) *p = 0u; }

__global__ void k_wmax(const double* __restrict__ t, const double* __restrict__ dinv,
                       unsigned* __restrict__ wmax, int K, int N) {
  __shared__ float red[256];
  float mx = 0.0f;
  int tot = K * N;
  for (int i = blockIdx.x * 256 + threadIdx.x; i < tot; i += gridDim.x * 256) {
    double w = dinv[i / N] * t[i];
    mx = fmaxf(mx, (float)fabs(w));
  }
  red[threadIdx.x] = mx;
  __syncthreads();
  for (int st = 128; st > 0; st >>= 1) {
    if (threadIdx.x < st) red[threadIdx.x] = fmaxf(red[threadIdx.x], red[threadIdx.x + st]);
    __syncthreads();
  }
  if (threadIdx.x == 0) atomicMax(wmax, __builtin_bit_cast(unsigned, red[0]));
}

__global__ void k_wmaxf(const float* __restrict__ A, size_t n, unsigned* __restrict__ out) {
  __shared__ float red[256];
  float mx = 0.0f;
  for (size_t i = (size_t)blockIdx.x * 256 + threadIdx.x; i < n; i += (size_t)gridDim.x * 256)
    mx = fmaxf(mx, fabsf(A[i]));
  red[threadIdx.x] = mx;
  __syncthreads();
  for (int st = 128; st > 0; st >>= 1) {
    if (threadIdx.x < st) red[threadIdx.x] = fmaxf(red[threadIdx.x], red[threadIdx.x + st]);
    __syncthreads();
  }
  if (threadIdx.x == 0) atomicMax(out, __builtin_bit_cast(unsigned, red[0]));
}

template <int D>
__global__ __launch_bounds__(256) void k_digitize8(
    const double* __restrict__ t, const double* __restrict__ dinv,
    const unsigned* __restrict__ wmax, char* __restrict__ wdT,
    int K, int Kpad, int N) {
  __shared__ char sm[D][64][68];
  const int tid = threadIdx.x;
  const int k0 = blockIdx.x * 64, n0 = blockIdx.y * 64;
  float wm = __builtin_bit_cast(float, *wmax);
  double sc = (wm > 0.0f) ? scalbn(1.0, -(ilogbf(wm) + 2)) : 0.0;
  const int kk = tid >> 2, ns = (tid & 3) * 16;
  int k = k0 + kk;
  double dv = (k < K) ? dinv[k] : 0.0;
#pragma unroll
  for (int j = 0; j < 16; ++j) {
    int n = n0 + ns + j;
    double w = (k < K) ? dv * t[(size_t)k * N + n] : 0.0;
    double r = w * sc;
#pragma unroll
    for (int d = 0; d < D; ++d) {
      double rm = r * 128.0;
      double m = rint(rm);
      sm[d][kk][ns + j] = (char)(int)m;
      r = rm - m;
    }
  }
  __syncthreads();
  const int nn = tid >> 2, ks = (tid & 3) * 16;
  const size_t PS = (size_t)N * Kpad;
#pragma unroll
  for (int d = 0; d < D; ++d) {
    char o[16];
#pragma unroll
    for (int j = 0; j < 16; ++j) o[j] = sm[d][ks + j][nn];
    *(int4*)&wdT[d * PS + (size_t)(n0 + nn) * Kpad + k0 + ks] = *(int4*)&o[0];
  }
}

// A2p f32 (exact nonneg ints < 2^14) -> 2 i8 planes base-128 (exact; weights 128/1)
__global__ void k_splitA8(const float* __restrict__ A, int M, int ldsrc,
                          char* __restrict__ S, int Kpad) {
  int r = blockIdx.x;
  const size_t plane = (size_t)Kpad * Kpad;
  for (int c4 = threadIdx.x * 4; c4 < Kpad; c4 += blockDim.x * 4) {
    float v[4] = {0.f, 0.f, 0.f, 0.f};
    if (r < M && c4 < ldsrc) *(float4*)v = *(const float4*)(A + (size_t)r * ldsrc + c4);
    unsigned hw = 0, lw = 0;
#pragma unroll
    for (int q = 0; q < 4; ++q) {
      int iv = (int)v[q];
      int h = iv >> 7, l = iv - (h << 7);
      hw |= ((unsigned)(unsigned char)(char)h) << (8 * q);
      lw |= ((unsigned)(unsigned char)(char)l) << (8 * q);
    }
    *(unsigned*)(S + (size_t)r * Kpad + c4) = hw;
    *(unsigned*)(S + plane + (size_t)r * Kpad + c4) = lw;
  }
}

// A3p f32 (nonneg, values-path) -> scaled 14-bit base-128 i8 planes.
__global__ void k_splitA8s(const float* __restrict__ A, int M, int ldsrc,
                           const unsigned* __restrict__ amax,
                           char* __restrict__ S, int Kpad) {
  int r = blockIdx.x;
  const size_t plane = (size_t)Kpad * Kpad;
  float am = __builtin_bit_cast(float, *amax);
  float s13 = (am > 0.0f) ? scalbnf(1.0f, 13 - (ilogbf(am) + 1)) : 0.0f;
  for (int c4 = threadIdx.x * 4; c4 < Kpad; c4 += blockDim.x * 4) {
    float v[4] = {0.f, 0.f, 0.f, 0.f};
    if (r < M && c4 < ldsrc) *(float4*)v = *(const float4*)(A + (size_t)r * ldsrc + c4);
    unsigned hw = 0, lw = 0;
#pragma unroll
    for (int q = 0; q < 4; ++q) {
      int iv = (int)rintf(v[q] * s13);
      int h = iv >> 7, l = iv - (h << 7);
      hw |= ((unsigned)(unsigned char)(char)h) << (8 * q);
      lw |= ((unsigned)(unsigned char)(char)l) << (8 * q);
    }
    *(unsigned*)(S + (size_t)r * Kpad + c4) = hw;
    *(unsigned*)(S + plane + (size_t)r * Kpad + c4) = lw;
  }
}

// P[Mp][Neff] i32 = A[Mp][Kpad] i8 @ wdT[Neff][Kpad]^T — DMA-pipelined i8 GEMM, exact.
__global__ __launch_bounds__(256) void k_axw_pipe8(
    const char* __restrict__ Asrc, const char* __restrict__ Bsrc,
    int Kpad, int* __restrict__ P, int Neff)
{
  __shared__ __align__(16) char Ls[2][2][8192];
  const int tid = threadIdx.x;
  const int wave = tid >> 6, lane = tid & 63;
  const int wr = wave >> 1, wc = wave & 1;
  const int brow = blockIdx.y * 128, bcol = blockIdx.x * 128;
  const int lr = lane & 15, ko = (lane >> 4) * 16;
  const int koff = (lane & 3) * 16;

  const char* pA[2];
  const char* pB[2];
#pragma unroll
  for (int c = 0; c < 2; ++c) {
    int r = (c * 4 + wave) * 16 + (lane >> 2);
    pA[c] = Asrc + (size_t)(brow + r) * Kpad;
    pB[c] = Bsrc + (size_t)(bcol + r) * Kpad;
  }

  i32x4 acc[4][4];
#pragma unroll
  for (int m = 0; m < 4; ++m)
#pragma unroll
    for (int n = 0; n < 4; ++n) acc[m][n] = (i32x4){0, 0, 0, 0};

  auto STAGE = [&](int buf, int kt) {
#pragma unroll
    for (int c = 0; c < 2; ++c) {
      int f = c * 4 + wave;
      gl2lds16(pA[c] + kt + koff, &Ls[buf][0][f * 1024]);
      gl2lds16(pB[c] + kt + koff, &Ls[buf][1][f * 1024]);
    }
  };

  STAGE(0, 0);
  __syncthreads();
  int cur = 0;
  for (int kt = 0; kt < Kpad; kt += 64) {
    if (kt + 64 < Kpad) STAGE(cur ^ 1, kt + 64);
    i32x4 a0[4], b0[4];
#pragma unroll
    for (int m = 0; m < 4; ++m) a0[m] = *(const i32x4*)&Ls[cur][0][(wr * 64 + m * 16 + lr) * 64 + ko];
#pragma unroll
    for (int n = 0; n < 4; ++n) b0[n] = *(const i32x4*)&Ls[cur][1][(wc * 64 + n * 16 + lr) * 64 + ko];
#pragma unroll
    for (int m = 0; m < 4; ++m)
#pragma unroll
      for (int n = 0; n < 4; ++n)
        acc[m][n] = __builtin_amdgcn_mfma_i32_16x16x64_i8(a0[m], b0[n], acc[m][n], 0, 0, 0);
    __syncthreads();
    cur ^= 1;
  }

#pragma unroll
  for (int m = 0; m < 4; ++m)
#pragma unroll
    for (int n = 0; n < 4; ++n)
#pragma unroll
      for (int q = 0; q < 4; ++q) {
        int grow = brow + wr * 64 + m * 16 + (lane >> 4) * 4 + q;
        int gcol = bcol + wc * 64 + n * 16 + lr;
        P[(size_t)grow * Neff + gcol] = acc[m][n][q];
      }
}

// y[m][n] f64 = sum_d 2^(Ep-7(d+1)) * (s0*P[m][dN+n] + s1*P[M0pad+m][dN+n]); P i32 exact.
__global__ void k_reduce_y(const int* __restrict__ P, const unsigned* __restrict__ wmax,
                           const unsigned* __restrict__ amax,
                           double* __restrict__ y, int Neff, int N, int D,
                           int M0pad, int nplane, double w0, double w1) {
  int m = blockIdx.x;
  float wm = __builtin_bit_cast(float, *wmax);
  double s0 = w0, s1 = w1;
  bool zero = (wm <= 0.0f);
  if (amax) {
    float am = __builtin_bit_cast(float, *amax);
    if (am > 0.0f) {
      int EA = ilogbf(am) + 1;
      s0 = scalbn(w0, EA - 13);
      s1 = scalbn(w1, EA - 13);
    } else zero = true;
  }
  if (zero) {
    for (int n = threadIdx.x; n < N; n += blockDim.x) y[(size_t)m * N + n] = 0.0;
    return;
  }
  int Ep = ilogbf(wm) + 2;
  for (int n = threadIdx.x; n < N; n += blockDim.x) {
    double acc = 0.0;
    for (int d = 0; d < D; ++d) {
      double v = s0 * (double)P[(size_t)m * Neff + d * N + n];
      if (nplane == 2) v += s1 * (double)P[(size_t)(M0pad + m) * Neff + d * N + n];
      acc += scalbn(v, Ep - 7 * (d + 1));
    }
    y[(size_t)m * N + n] = acc;
  }
}

// A2p f32 -> 2 bf16 planes base-64 (exact; weights 64/1) for aug3 (verified path)
__global__ void k_splitA_bf16(const float* __restrict__ A, int M, int ldsrc,
                              short* __restrict__ S, int Kpad) {
  int r = blockIdx.x;
  const size_t plane = (size_t)Kpad * Kpad;
  for (int c4 = threadIdx.x * 4; c4 < Kpad; c4 += blockDim.x * 4) {
    float v[4] = {0.f, 0.f, 0.f, 0.f};
    if (r < M && c4 < ldsrc) *(float4*)v = *(const float4*)(A + (size_t)r * ldsrc + c4);
    short h[4], l[4];
#pragma unroll
    for (int q = 0; q < 4; ++q) {
      float hi = floorf(v[q] * (1.0f / 64.0f));
      h[q] = f2b(hi);
      l[q] = f2b(v[q] - 64.0f * hi);
    }
    *(s16x4*)&S[(size_t)r * Kpad + c4] = *(s16x4*)&h[0];
    *(s16x4*)&S[plane + (size_t)r * Kpad + c4] = *(s16x4*)&l[0];
  }
}

// ---------------- GCN tail / pooling ----------------

template <typename TA>
__device__ __forceinline__ float a_as_f32(TA v);
template <> __device__ __forceinline__ float a_as_f32<char>(char v) { return (float)v; }
template <> __device__ __forceinline__ float a_as_f32<float>(float v) { return v; }

// degdinv; block 0 also resets up to two max-accumulators (visible to following kernels)
template <typename TA>
__global__ void k_degdinv(const TA* __restrict__ A, int lda, double* __restrict__ dinv, int n,
                          unsigned* __restrict__ rst0, unsigned* __restrict__ rst1) {
  if (blockIdx.x == 0 && threadIdx.x == 0) {
    if (rst0) *rst0 = 0u;
    if (rst1) *rst1 = 0u;
  }
  __shared__ double red[256];
  int row = blockIdx.x;
  double s = 0.0;
  for (int j = threadIdx.x; j < n; j += 256) s += (double)a_as_f32<TA>(A[(size_t)row * lda + j]);
  red[threadIdx.x] = s;
  __syncthreads();
  for (int st = 128; st > 0; st >>= 1) {
    if (threadIdx.x < st) red[threadIdx.x] += red[threadIdx.x + st];
    __syncthreads();
  }
  if (threadIdx.x == 0) {
    double deg = red[0] + 2.0;
    dinv[row] = (deg > 0.0) ? 1.0 / sqrt(deg) : 0.0;
  }
}

__global__ void k_gcn_fin(const double* __restrict__ y, const double* __restrict__ t,
                          const double* __restrict__ dinv, const float* __restrict__ b,
                          double* __restrict__ out, int C, int relu) {
  int row = blockIdx.x;
  double d = dinv[row];
  for (int c = threadIdx.x; c < C; c += blockDim.x) {
    double v = d * (y[(size_t)row * C + c] + 2.0 * d * t[(size_t)row * C + c]) + (double)b[c];
    if (relu) v = v > 0.0 ? v : 0.0;
    out[(size_t)row * C + c] = v;
  }
}

// scores with fused ||p|| (identical reduction order per block -> deterministic)
__global__ void k_scores(const double* __restrict__ x, const float* __restrict__ p,
                         double* __restrict__ sc, int C) {
  __shared__ double red[256], red2[256];
  int row = blockIdx.x;
  double s = 0.0, s2 = 0.0;
  for (int j = threadIdx.x; j < C; j += 256) {
    double pv = (double)p[j];
    s += x[(size_t)row * C + j] * pv;
    s2 += pv * pv;
  }
  red[threadIdx.x] = s;
  red2[threadIdx.x] = s2;
  __syncthreads();
  for (int st = 128; st > 0; st >>= 1) {
    if (threadIdx.x < st) {
      red[threadIdx.x] += red[threadIdx.x + st];
      red2[threadIdx.x] += red2[threadIdx.x + st];
    }
    __syncthreads();
  }
  if (threadIdx.x == 0) sc[row] = tanh(red[0] / sqrt(red2[0]));
}

__global__ __launch_bounds__(1024) void k_topk(const double* __restrict__ sc, int n,
                                               int* __restrict__ perm, double* __restrict__ vals) {
  __shared__ double s[SORT_N];
  __shared__ int id[SORT_N];
  const int t = threadIdx.x;
  for (int i = t; i < SORT_N; i += 1024) {
    s[i] = (i < n) ? sc[i] : -INFINITY;
    id[i] = i;
  }
  __syncthreads();
  for (int size = 2; size <= SORT_N; size <<= 1) {
    for (int stride = size >> 1; stride > 0; stride >>= 1) {
      for (int i = t; i < SORT_N; i += 1024) {
        int l = i ^ stride;
        if (l > i) {
          double si = s[i], sl = s[l];
          int ii = id[i], il = id[l];
          bool iAfterL = (sl > si) || (sl == si && il < ii);
          bool up = ((i & size) == 0);
          if (iAfterL == up) { s[i] = sl; s[l] = si; id[i] = il; id[l] = ii; }
        }
      }
      __syncthreads();
    }
  }
  for (int i = t; i < n; i += 1024) { perm[i] = id[i]; vals[i] = s[i]; }
}

__global__ void k_gather_x(const double* __restrict__ x, const int* __restrict__ perm,
                           const double* __restrict__ vals, double* __restrict__ xo, int C) {
  int row = blockIdx.x;
  int src = perm[row];
  double v = vals[row];
  for (int c = threadIdx.x; c < C; c += blockDim.x)
    xo[(size_t)row * C + c] = x[(size_t)src * C + c] * v;
}

__global__ void k_write_out(const double* __restrict__ x, float* __restrict__ out,
                            int nvals, int total) {
  int i = blockIdx.x * blockDim.x + threadIdx.x;
  int st = gridDim.x * blockDim.x;
  for (; i < total; i += st) out[i] = (i < nvals) ? (float)x[i] : 0.0f;
}

__global__ void k_sentinel(float* __restrict__ out, int total) {
  int i = blockIdx.x * blockDim.x + threadIdx.x;
  int st = gridDim.x * blockDim.x;
  for (; i < total; i += st) out[i] = 1e30f;
}

// ---------------- driver ----------------

extern "C" void kernel_launch(void* const* d_in, const int* in_sizes, int n_in,
                              void* d_out, int out_size, void* d_ws, size_t ws_size,
                              hipStream_t stream) {
  const float* x0f  = (const float*)d_in[0];
  const int*   ei   = (const int*)d_in[1];
  const float* W0   = (const float*)d_in[2];
  const float* b0   = (const float*)d_in[3];
  const float* W1   = (const float*)d_in[4];
  const float* b1   = (const float*)d_in[5];
  const float* W2   = (const float*)d_in[6];
  const float* b2   = (const float*)d_in[7];
  const float* p1   = (const float*)d_in[8];
  const float* p2   = (const float*)d_in[9];
  const float* Wout = (const float*)d_in[10];
  const float* bout = (const float*)d_in[11];
  const int E = in_sizes[1] / 2;

  const size_t MiB = 1ull << 20;
  if (ws_size < 160 * MiB) {
    k_sentinel<<<dim3(256), dim3(256), 0, stream>>>((float*)d_out, out_size);
    return;
  }
  char* W = (char*)d_ws;
  // epoch A: build + aug1
  float* A0    = (float*)(W + 0);            // 64 MiB
  char*  A0s8  = (char*)(W + 64 * MiB);      // 16
  char*  A0s8T = (char*)(W + 80 * MiB);      // 16 (+2I folded)
  // epoch A2: gcn1
  char*  A1    = (char*)(W + 0);             // 16
  char*  A1T   = (char*)(W + 16 * MiB);      // 16 (+2I folded)
  char*  wdT1  = (char*)(W + 32 * MiB);      // 8
  int*   P1    = (int*)(W + 40 * MiB);       // 32
  // epoch B: aug2 + gcn2
  float* A2p      = (float*)(W + 34 * MiB);  // 41.1
  char*  A2s8     = (char*)(W + 0);          // 21.2
  char*  wdT2     = (char*)(W + 22 * MiB);   // 6.5
  int*   P2       = (int*)(W + 29 * MiB);    // 52.0
  short* A2stack  = (short*)(W + 82 * MiB);  // 42.3 (bf16 hi/lo for aug3)
  // epoch C: aug3 + gcn3/out
  short* A2stackT = (short*)(W + 29 * MiB);  // 42.3
  float* A3p      = (float*)(W + 0);         // 14.8
  char*  A3stack  = (char*)(W + 15 * MiB);   // 7.6
  char*  wdT3     = (char*)(W + 23 * MiB);   // 1.0
  int*   P3       = (int*)(W + 24 * MiB);    // 7.8
  // features
  double* tb   = (double*)(W + 128 * MiB);
  double* yb   = (double*)(W + 136 * MiB);
  double* xA   = (double*)(W + 144 * MiB);
  double* xB   = (double*)(W + 152 * MiB);
  char* SM = W + (159 * MiB + 256 * 1024);
  double* dinv = (double*)(SM);
  double* sc   = (double*)(SM + 32768);
  double* vals = (double*)(SM + 65536);
  unsigned* wmax  = (unsigned*)(SM + 98304 + 128);
  unsigned* a3max = (unsigned*)(SM + 98304 + 192);
  int* perm    = (int*)(SM + 98304 + 256);
  int* permB   = (int*)(SM + 98304 + 256 + 16384);
  char* zpage  = (char*)(W + 159 * MiB + 512 * 1024);  // 32 KiB zeros

  // ---- build A0, i8 split+transpose ----
  k_zero32<<<dim3(8), dim3(256), 0, stream>>>((float*)zpage, 8192);
  k_zero32<<<dim3(2048), dim3(256), 0, stream>>>(A0, (size_t)N0 * N0);
  k_build_adj<<<dim3((E + 255) / 256), dim3(256), 0, stream>>>(ei, A0, E, N0);
  k_transpose_split_i8<<<dim3(64, 64), dim3(256), 0, stream>>>(A0, A0s8, A0s8T);

  // ---- aug1: A1 = offdiag(A0 @ (A0+2I)), i8 exact ----
  k_aug_pipe8<0><<<dim3(32, 32), dim3(256), 0, stream>>>(
      A0s8, A0s8T, nullptr, zpage, N0, N0, nullptr, A1, N0, N0, N0);
  k_transpose_i8s<<<dim3(64, 64), dim3(256), 0, stream>>>(A1, A1T, N0, 2);

  // ---- gcn1 ----
  k_widen_f32_f64<<<dim3(512), dim3(256), 0, stream>>>(x0f, xB, N0 * CIN);
  {
    dim3 b(16, 16);
    k_gemm_xw32<<<dim3(HID / 64, (N0 + 31) / 32), b, 0, stream>>>(xB, W0, tb, N0, HID, CIN);
    k_degdinv<char><<<dim3(N0), dim3(256), 0, stream>>>(A1, N0, dinv, N0, wmax, nullptr);
    k_wmax<<<dim3(256), dim3(256), 0, stream>>>(tb, dinv, wmax, N0, HID);
    k_digitize8<DNUM><<<dim3(N0 / 64, HID / 64), dim3(256), 0, stream>>>(tb, dinv, wmax, wdT1, N0, N0, HID);
    k_axw_pipe8<<<dim3(DNUM * HID / 128, N0 / 128), dim3(256), 0, stream>>>(A1, wdT1, N0, P1, DNUM * HID);
    k_reduce_y<<<dim3(N0), dim3(256), 0, stream>>>(P1, wmax, nullptr, yb, DNUM * HID, HID, DNUM, 0, 1, 1.0, 0.0);
    k_gcn_fin<<<dim3(N0), dim3(256), 0, stream>>>(yb, tb, dinv, b0, xA, HID, 1);
  }

  // ---- pool1 ----
  k_scores<<<dim3(N0), dim3(256), 0, stream>>>(xA, p1, sc, HID);
  k_topk<<<dim3(1), dim3(1024), 0, stream>>>(sc, N0, perm, vals);
  k_gather_x<<<dim3(K1P), dim3(256), 0, stream>>>(xA, perm, vals, xB, HID);

  // ---- aug2: A2p = offdiag(A1 @ (A1+2I))[perm x perm], i8 exact ----
  k_aug_pipe8<1><<<dim3(26, 26), dim3(256), 0, stream>>>(
      A1, A1T, perm, zpage, N0, N0, A2p, nullptr, K1P, K1P, LD2);

  // ---- gcn2 (exact base-128 i8 A-split + i8 digits) ----
  {
    dim3 b(16, 16);
    k_gemm_xw32<<<dim3(HID / 64, (K1P + 31) / 32), b, 0, stream>>>(xB, W1, tb, K1P, HID, HID);
    k_degdinv<float><<<dim3(K1P), dim3(256), 0, stream>>>(A2p, LD2, dinv, K1P, wmax, nullptr);
    k_splitA_bf16<<<dim3(KI2), dim3(256), 0, stream>>>(A2p, K1P, LD2, A2stack, KI2);
    k_splitA8<<<dim3(KI2), dim3(256), 0, stream>>>(A2p, K1P, LD2, A2s8, KI2);
    k_wmax<<<dim3(256), dim3(256), 0, stream>>>(tb, dinv, wmax, K1P, HID);
    k_digitize8<DNUM><<<dim3(KI2 / 64, HID / 64), dim3(256), 0, stream>>>(tb, dinv, wmax, wdT2, K1P, KI2, HID);
    k_axw_pipe8<<<dim3(DNUM * HID / 128, 2 * KI2 / 128), dim3(256), 0, stream>>>(A2s8, wdT2, KI2, P2, DNUM * HID);
    k_reduce_y<<<dim3(K1P), dim3(256), 0, stream>>>(P2, wmax, nullptr, yb, DNUM * HID, HID, DNUM, KI2, 2, 128.0, 1.0);
    k_gcn_fin<<<dim3(K1P), dim3(256), 0, stream>>>(yb, tb, dinv, b1, xA, HID, 1);
  }

  // ---- pool2 ----
  k_scores<<<dim3(K1P), dim3(256), 0, stream>>>(xA, p2, sc, HID);
  k_topk<<<dim3(1), dim3(1024), 0, stream>>>(sc, K1P, permB, vals);
  k_gather_x<<<dim3(K2P), dim3(256), 0, stream>>>(xA, permB, vals, xB, HID);

  // ---- aug3 (bf16 3-term, 8-wave blocks) ----
  {
    const size_t plane = (size_t)KI2 * KI2;
    k_transpose_bf16s<<<dim3(KI2 / 64, KI2 / 64), dim3(256), 0, stream>>>(A2stack, A2stackT, KI2, 0.0f);
    k_transpose_bf16s<<<dim3(KI2 / 64, KI2 / 64), dim3(256), 0, stream>>>(A2stack + plane, A2stackT + plane, KI2, 2.0f);
    k_aug3_pipe2<<<dim3(16, 16), dim3(512), 0, stream>>>(
        A2stack, A2stackT, permB, (const short*)zpage, KI2, A3p, K2P, K2P, LD3);
  }

  // ---- gcn3 (scaled 14-bit i8 A-split; values-path) ----
  {
    dim3 b(16, 16);
    k_gemm_xw32<<<dim3(HID / 64, (K2P + 31) / 32), b, 0, stream>>>(xB, W2, tb, K2P, HID, HID);
    k_degdinv<float><<<dim3(K2P), dim3(256), 0, stream>>>(A3p, LD3, dinv, K2P, wmax, a3max);
    k_wmaxf<<<dim3(256), dim3(256), 0, stream>>>(A3p, (size_t)K2P * LD3, a3max);
    k_splitA8s<<<dim3(KI3), dim3(256), 0, stream>>>(A3p, K2P, LD3, a3max, A3stack, KI3);
    k_wmax<<<dim3(256), dim3(256), 0, stream>>>(tb, dinv, wmax, K2P, HID);
    k_digitize8<2><<<dim3(KI3 / 64, HID / 64), dim3(256), 0, stream>>>(tb, dinv, wmax, wdT3, K2P, KI3, HID);
    k_axw_pipe8<<<dim3(2 * HID / 128, 2 * KI3 / 128), dim3(256), 0, stream>>>(A3stack, wdT3, KI3, P3, 2 * HID);
    k_reduce_y<<<dim3(K2P), dim3(256), 0, stream>>>(P3, wmax, a3max, yb, 2 * HID, HID, 2, KI3, 2, 128.0, 1.0);
    k_gcn_fin<<<dim3(K2P), dim3(256), 0, stream>>>(yb, tb, dinv, b2, xA, HID, 1);
  }

  // ---- gcn_out (reuse dinv, a3max, A3stack) ----
  {
    dim3 b(16, 16);
    k_gemm_xw32<<<dim3(COUTC / 64, (K2P + 31) / 32), b, 0, stream>>>(xA, Wout, tb, K2P, COUTC, HID);
    k_reset_u32<<<dim3(1), dim3(64), 0, stream>>>(wmax);
    k_wmax<<<dim3(256), dim3(256), 0, stream>>>(tb, dinv, wmax, K2P, COUTC);
    k_digitize8<2><<<dim3(KI3 / 64, COUTC / 64), dim3(256), 0, stream>>>(tb, dinv, wmax, wdT3, K2P, KI3, COUTC);
    k_axw_pipe8<<<dim3(2 * COUTC / 128, 2 * KI3 / 128), dim3(256), 0, stream>>>(A3stack, wdT3, KI3, P3, 2 * COUTC);
    k_reduce_y<<<dim3(K2P), dim3(256), 0, stream>>>(P3, wmax, a3max, yb, 2 * COUTC, COUTC, 2, KI3, 2, 128.0, 1.0);
    k_gcn_fin<<<dim3(K2P), dim3(256), 0, stream>>>(yb, tb, dinv, bout, xB, COUTC, 0);
  }

  k_write_out<<<dim3(1024), dim3(256), 0, stream>>>(xB, (float*)d_out, K2P * COUTC, out_size);
}

// Round 10
// 921.154 us; speedup vs baseline: 9.0853x; 1.0368x over previous
//
#include <hip/hip_runtime.h>
#include <math.h>

#define N0    4096
#define CIN   128
#define HID   256
#define COUTC 128
#define K1P   3277   // ceil(0.8*4096)
#define K2P   1967   // ceil(0.6*3277)
#define LD3   1968   // K2P padded to 4-float rows
#define KI2   3328   // K1P padded to mult of 64
#define KI3   1984   // K2P padded to mult of 64
#define SORT_N 4096
#define DNUM  8      // digit planes, base-128 -> 56 bits

typedef __attribute__((ext_vector_type(4))) int i32x4;

__device__ __forceinline__ void gl2lds16(const void* g, void* l) {
  __builtin_amdgcn_global_load_lds((const __attribute__((address_space(1))) void*)g,
                                   (__attribute__((address_space(3))) void*)l, 16, 0, 0);
}

// ---------------- build / elementwise ----------------

__global__ void k_zero32(float* __restrict__ p, size_t n) {
  size_t i = (size_t)blockIdx.x * blockDim.x + threadIdx.x;
  size_t st = (size_t)gridDim.x * blockDim.x;
  for (; i < n; i += st) p[i] = 0.0f;
}

__global__ void k_widen_f32_f64(const float* __restrict__ in, double* __restrict__ out, int n) {
  int i = blockIdx.x * blockDim.x + threadIdx.x;
  int st = gridDim.x * blockDim.x;
  for (; i < n; i += st) out[i] = (double)in[i];
}

__global__ void k_build_adj(const int* __restrict__ ei, float* __restrict__ A, int E, int n) {
  int e = blockIdx.x * blockDim.x + threadIdx.x;
  if (e < E) atomicAdd(&A[(size_t)ei[E + e] * n + ei[e]], 1.0f);
}

// A0 f32 -> A0s8 i8 + A0s8T i8 (transposed, +2 folded on diag). Small ints, exact.
__global__ __launch_bounds__(256) void k_transpose_split_i8(
    const float* __restrict__ A, char* __restrict__ B, char* __restrict__ BT) {
  __shared__ char sm[64][68];
  const int t = threadIdx.x;
  const int r0 = blockIdx.y * 64, c0 = blockIdx.x * 64;
  const int rr = t >> 2, cs = (t & 3) * 16;
  char tmp[16];
#pragma unroll
  for (int j = 0; j < 16; ++j) {
    char v = (char)(int)A[(size_t)(r0 + rr) * N0 + c0 + cs + j];
    tmp[j] = v;
    sm[cs + j][rr] = v;
  }
  *(int4*)&B[(size_t)(r0 + rr) * N0 + c0 + cs] = *(int4*)&tmp[0];
  __syncthreads();
  const int cc = t >> 2, rs = (t & 3) * 16;
  const int orow = c0 + cc;
  char o[16];
#pragma unroll
  for (int q = 0; q < 16; ++q) {
    char v = sm[cc][rs + q];
    if (r0 + rs + q == orow) v = (char)(v + 2);
    o[q] = v;
  }
  *(int4*)&BT[(size_t)orow * N0 + r0 + rs] = *(int4*)&o[0];
}

// -------- i8 pipelined augment with fused transposed output --------
// C = rows(A) @ rows(Bt)^T (Bt diag pre-folded +2I); diag(C)->0.
// MODE 0 (aug1): O=A1 (1 i8 plane), OT=A1T with +2 diag fold. M=N=4096.
// MODE 1 (aug2): O=A2s8 hi/lo planes (stride `plane`), OT=A2s8T hi/lo, lo-diag=2.
template <int MODE>
__global__ __launch_bounds__(256) void k_aug_pipe8(
    const char* __restrict__ Asrc, const char* __restrict__ Btsrc,
    const int* __restrict__ perm, const char* __restrict__ zrow,
    int K, int ldk,
    char* __restrict__ O, char* __restrict__ OT, size_t plane, int ldo,
    int M, int N)
{
  __shared__ __align__(16) char Ls[2][2][8192];  // 32 KB
  const int tid = threadIdx.x;
  const int wave = tid >> 6, lane = tid & 63;
  const int wr = wave >> 1, wc = wave & 1;
  const int brow = blockIdx.y * 128, bcol = blockIdx.x * 128;
  const int lr = lane & 15, ko = (lane >> 4) * 16;
  const int koff = (lane & 3) * 16;

  const char* pA[2];
  const char* pB[2];
#pragma unroll
  for (int c = 0; c < 2; ++c) {
    int r = (c * 4 + wave) * 16 + (lane >> 2);
    int ra = brow + r, rb = bcol + r;
    int ia, ib;
    if (MODE == 0) { ia = ra; ib = rb; }
    else {
      ia = (ra < M) ? perm[ra] : -1;
      ib = (rb < N) ? perm[rb] : -1;
    }
    pA[c] = (ia >= 0) ? Asrc + (size_t)ia * ldk : zrow;
    pB[c] = (ib >= 0) ? Btsrc + (size_t)ib * ldk : zrow;
  }

  i32x4 acc[4][4];
#pragma unroll
  for (int m = 0; m < 4; ++m)
#pragma unroll
    for (int n = 0; n < 4; ++n) acc[m][n] = (i32x4){0, 0, 0, 0};

  auto STAGE = [&](int buf, int kt) {
#pragma unroll
    for (int c = 0; c < 2; ++c) {
      int f = c * 4 + wave;
      gl2lds16(pA[c] + kt + koff, &Ls[buf][0][f * 1024]);
      gl2lds16(pB[c] + kt + koff, &Ls[buf][1][f * 1024]);
    }
  };

  STAGE(0, 0);
  __syncthreads();
  int cur = 0;
  for (int kt = 0; kt < K; kt += 64) {
    if (kt + 64 < K) STAGE(cur ^ 1, kt + 64);
    i32x4 a0[4], b0[4];
#pragma unroll
    for (int m = 0; m < 4; ++m) a0[m] = *(const i32x4*)&Ls[cur][0][(wr * 64 + m * 16 + lr) * 64 + ko];
#pragma unroll
    for (int n = 0; n < 4; ++n) b0[n] = *(const i32x4*)&Ls[cur][1][(wc * 64 + n * 16 + lr) * 64 + ko];
#pragma unroll
    for (int m = 0; m < 4; ++m)
#pragma unroll
      for (int n = 0; n < 4; ++n)
        acc[m][n] = __builtin_amdgcn_mfma_i32_16x16x64_i8(a0[m], b0[n], acc[m][n], 0, 0, 0);
    __syncthreads();
    cur ^= 1;
  }

  // ---- epilogue: bounce tile through LDS, write straight + transposed ----
  char* Lh = &Ls[0][0][0];          // 16 KB
  char* Ll = &Ls[0][0][0] + 16384;  // 16 KB (MODE 1 only)
#pragma unroll
  for (int m = 0; m < 4; ++m)
#pragma unroll
    for (int n = 0; n < 4; ++n)
#pragma unroll
      for (int q = 0; q < 4; ++q) {
        int r = wr * 64 + m * 16 + (lane >> 4) * 4 + q;
        int c = wc * 64 + n * 16 + lr;
        int v = acc[m][n][q];
        if (MODE == 0) {
          if (brow + r == bcol + c) v = 0;
          Lh[r * 128 + (c ^ ((r & 7) << 4))] = (char)v;
        } else {
          if (brow + r >= M || bcol + c >= N || brow + r == bcol + c) v = 0;
          int idx = r * 128 + (c ^ ((r & 7) << 4));
          Lh[idx] = (char)(v >> 7);
          Ll[idx] = (char)(v & 127);
        }
      }
  __syncthreads();
  {
    const int r = tid >> 1, hf = tid & 1;
    // straight rows
    char oh[64], ol[64];
#pragma unroll
    for (int j = 0; j < 64; ++j) {
      int c = hf * 64 + j;
      int idx = r * 128 + (c ^ ((r & 7) << 4));
      oh[j] = Lh[idx];
      if (MODE == 1) ol[j] = Ll[idx];
    }
    char* dst = O + (size_t)(brow + r) * ldo + bcol + hf * 64;
#pragma unroll
    for (int j = 0; j < 4; ++j) *(int4*)(dst + j * 16) = *(int4*)&oh[j * 16];
    if (MODE == 1) {
      char* dst2 = O + plane + (size_t)(brow + r) * ldo + bcol + hf * 64;
#pragma unroll
      for (int j = 0; j < 4; ++j) *(int4*)(dst2 + j * 16) = *(int4*)&ol[j * 16];
    }
    // transposed rows (diag fold +2: MODE0 -> A1T, MODE1 -> lo plane)
    const int c2 = r;  // reuse tid>>1 as column index
#pragma unroll
    for (int j = 0; j < 64; ++j) {
      int r2 = hf * 64 + j;
      int idx = r2 * 128 + (c2 ^ ((r2 & 7) << 4));
      char vh = Lh[idx];
      if (MODE == 0) {
        if (brow + r2 == bcol + c2) vh = (char)(vh + 2);
        oh[j] = vh;
      } else {
        char vl = Ll[idx];
        if (brow + r2 == bcol + c2) vl = (char)(vl + 2);  // v==0 at diag
        oh[j] = vh;
        ol[j] = vl;
      }
    }
    char* dstT = OT + (size_t)(bcol + c2) * ldo + brow + hf * 64;
#pragma unroll
    for (int j = 0; j < 4; ++j) *(int4*)(dstT + j * 16) = *(int4*)&oh[j * 16];
    if (MODE == 1) {
      char* dstT2 = OT + plane + (size_t)(bcol + c2) * ldo + brow + hf * 64;
#pragma unroll
      for (int j = 0; j < 4; ++j) *(int4*)(dstT2 + j * 16) = *(int4*)&ol[j * 16];
    }
  }
}

// aug3 (i8, exact): A3 = (128H+L) @ (128H'+(L'+2I)) = 16384 HH' + 128 (HL'+LH') + LL'.
// 512 threads / 8 waves; fused block-max -> amax (order-independent atomicMax).
__global__ __launch_bounds__(512) void k_aug3_pipe8(
    const char* __restrict__ S, const char* __restrict__ ST,
    const int* __restrict__ perm, const char* __restrict__ zrow,
    int Kpad, float* __restrict__ Cf, unsigned* __restrict__ amax,
    int M, int N, int ldcp)
{
  __shared__ __align__(16) char Ls[2][4][8192];  // 64 KB
  const int tid = threadIdx.x;
  const int wave = tid >> 6, lane = tid & 63;
  const int wr = wave >> 1, wc = wave & 1;  // 4x2 wave grid
  const int brow = blockIdx.y * 128, bcol = blockIdx.x * 128;
  const int lr = lane & 15, ko = (lane >> 4) * 16;
  const int koff = (lane & 3) * 16;
  const size_t plane = (size_t)Kpad * Kpad;

  const char *pAh, *pAl, *pBh, *pBl;
  {
    int r = (wave << 4) + (lane >> 2);
    int ra = brow + r, rb = bcol + r;
    int ia = (ra < M) ? perm[ra] : -1;
    int ib = (rb < N) ? perm[rb] : -1;
    pAh = (ia >= 0) ? S + (size_t)ia * Kpad : zrow;
    pAl = (ia >= 0) ? S + plane + (size_t)ia * Kpad : zrow;
    pBh = (ib >= 0) ? ST + (size_t)ib * Kpad : zrow;
    pBl = (ib >= 0) ? ST + plane + (size_t)ib * Kpad : zrow;
  }

  i32x4 hh[2][4], mid[2][4], ll[2][4];
#pragma unroll
  for (int m = 0; m < 2; ++m)
#pragma unroll
    for (int n = 0; n < 4; ++n) {
      hh[m][n] = (i32x4){0, 0, 0, 0};
      mid[m][n] = (i32x4){0, 0, 0, 0};
      ll[m][n] = (i32x4){0, 0, 0, 0};
    }

  auto STAGE = [&](int buf, int kt) {
    int f = wave * 1024;
    gl2lds16(pAh + kt + koff, &Ls[buf][0][f]);
    gl2lds16(pBh + kt + koff, &Ls[buf][1][f]);
    gl2lds16(pAl + kt + koff, &Ls[buf][2][f]);
    gl2lds16(pBl + kt + koff, &Ls[buf][3][f]);
  };

  STAGE(0, 0);
  __syncthreads();
  int cur = 0;
  for (int kt = 0; kt < Kpad; kt += 64) {
    if (kt + 64 < Kpad) STAGE(cur ^ 1, kt + 64);
    i32x4 ah[2], al[2], bh[4], bl[4];
#pragma unroll
    for (int m = 0; m < 2; ++m) {
      ah[m] = *(const i32x4*)&Ls[cur][0][(wr * 32 + m * 16 + lr) * 64 + ko];
      al[m] = *(const i32x4*)&Ls[cur][2][(wr * 32 + m * 16 + lr) * 64 + ko];
    }
#pragma unroll
    for (int n = 0; n < 4; ++n) {
      bh[n] = *(const i32x4*)&Ls[cur][1][(wc * 64 + n * 16 + lr) * 64 + ko];
      bl[n] = *(const i32x4*)&Ls[cur][3][(wc * 64 + n * 16 + lr) * 64 + ko];
    }
#pragma unroll
    for (int m = 0; m < 2; ++m)
#pragma unroll
      for (int n = 0; n < 4; ++n) {
        hh[m][n]  = __builtin_amdgcn_mfma_i32_16x16x64_i8(ah[m], bh[n], hh[m][n], 0, 0, 0);
        mid[m][n] = __builtin_amdgcn_mfma_i32_16x16x64_i8(ah[m], bl[n], mid[m][n], 0, 0, 0);
        mid[m][n] = __builtin_amdgcn_mfma_i32_16x16x64_i8(al[m], bh[n], mid[m][n], 0, 0, 0);
        ll[m][n]  = __builtin_amdgcn_mfma_i32_16x16x64_i8(al[m], bl[n], ll[m][n], 0, 0, 0);
      }
    __syncthreads();
    cur ^= 1;
  }

  float mloc = 0.0f;
#pragma unroll
  for (int m = 0; m < 2; ++m)
#pragma unroll
    for (int n = 0; n < 4; ++n)
#pragma unroll
      for (int q = 0; q < 4; ++q) {
        int grow = brow + wr * 32 + m * 16 + (lane >> 4) * 4 + q;
        int gcol = bcol + wc * 64 + n * 16 + lr;
        if (grow < M && gcol < ldcp) {
          float v = 16384.0f * (float)hh[m][n][q] + 128.0f * (float)mid[m][n][q] + (float)ll[m][n][q];
          if (gcol >= N || grow == gcol) v = 0.0f;
          Cf[(size_t)grow * ldcp + gcol] = v;
          mloc = fmaxf(mloc, v);
        }
      }
  __syncthreads();
  float* red = (float*)&Ls[0][0][0];
  red[tid] = mloc;
  __syncthreads();
  for (int st = 256; st > 0; st >>= 1) {
    if (tid < st) red[tid] = fmaxf(red[tid], red[tid + st]);
    __syncthreads();
  }
  if (tid == 0) atomicMax(amax, __builtin_bit_cast(unsigned, red[0]));
}

// ---------------- f64 x@W (32x64 tiles) ----------------

__global__ __launch_bounds__(256) void k_gemm_xw32(
    const double* __restrict__ X, const float* __restrict__ W, double* __restrict__ C,
    int M, int N, int K) {
  __shared__ double As[16][32];
  __shared__ double Bs[16][64];
  const int tx = threadIdx.x, ty = threadIdx.y;
  const int tid = ty * 16 + tx;
  const int brow = blockIdx.y * 32, bcol = blockIdx.x * 64;
  double acc[2][4];
#pragma unroll
  for (int i = 0; i < 2; ++i)
#pragma unroll
    for (int j = 0; j < 4; ++j) acc[i][j] = 0.0;
  const int lac = tid & 15, lar = tid >> 4;
  const int lbc = tid & 63, lbr = tid >> 6;
  for (int kt = 0; kt < K; kt += 16) {
#pragma unroll
    for (int rr = 0; rr < 2; ++rr) {
      int r = lar + rr * 16;
      int gr = brow + r, gk = kt + lac;
      As[lac][r] = (gr < M && gk < K) ? X[(size_t)gr * K + gk] : 0.0;
    }
#pragma unroll
    for (int rr = 0; rr < 4; ++rr) {
      int br = lbr + rr * 4;
      int gk = kt + br, gc = bcol + lbc;
      Bs[br][lbc] = (gk < K && gc < N) ? (double)W[(size_t)gk * N + gc] : 0.0;
    }
    __syncthreads();
#pragma unroll
    for (int kk = 0; kk < 16; ++kk) {
      double a[2], b[4];
#pragma unroll
      for (int i = 0; i < 2; ++i) a[i] = As[kk][ty * 2 + i];
#pragma unroll
      for (int j = 0; j < 4; ++j) b[j] = Bs[kk][tx * 4 + j];
#pragma unroll
      for (int i = 0; i < 2; ++i)
#pragma unroll
        for (int j = 0; j < 4; ++j) acc[i][j] = fma(a[i], b[j], acc[i][j]);
    }
    __syncthreads();
  }
#pragma unroll
  for (int i = 0; i < 2; ++i) {
    int gr = brow + ty * 2 + i;
    if (gr >= M) continue;
#pragma unroll
    for (int j = 0; j < 4; ++j) {
      int gc = bcol + tx * 4 + j;
      if (gc >= N) continue;
      C[(size_t)gr * N + gc] = acc[i][j];
    }
  }
}

// ---------------- digit machinery (i8, base-128) ----------------

__global__ void k_reset_u32(unsigned* p) { if (threadIdx.x == 0 && blockIdx.x == 0) *p = 0u; }

__global__ void k_wmax(const double* __restrict__ t, const double* __restrict__ dinv,
                       unsigned* __restrict__ wmax, int K, int N) {
  __shared__ float red[256];
  float mx = 0.0f;
  int tot = K * N;
  for (int i = blockIdx.x * 256 + threadIdx.x; i < tot; i += gridDim.x * 256) {
    double w = dinv[i / N] * t[i];
    mx = fmaxf(mx, (float)fabs(w));
  }
  red[threadIdx.x] = mx;
  __syncthreads();
  for (int st = 128; st > 0; st >>= 1) {
    if (threadIdx.x < st) red[threadIdx.x] = fmaxf(red[threadIdx.x], red[threadIdx.x + st]);
    __syncthreads();
  }
  if (threadIdx.x == 0) atomicMax(wmax, __builtin_bit_cast(unsigned, red[0]));
}

template <int D>
__global__ __launch_bounds__(256) void k_digitize8(
    const double* __restrict__ t, const double* __restrict__ dinv,
    const unsigned* __restrict__ wmax, char* __restrict__ wdT,
    int K, int Kpad, int N) {
  __shared__ char sm[D][64][68];
  const int tid = threadIdx.x;
  const int k0 = blockIdx.x * 64, n0 = blockIdx.y * 64;
  float wm = __builtin_bit_cast(float, *wmax);
  double sc = (wm > 0.0f) ? scalbn(1.0, -(ilogbf(wm) + 2)) : 0.0;
  const int kk = tid >> 2, ns = (tid & 3) * 16;
  int k = k0 + kk;
  double dv = (k < K) ? dinv[k] : 0.0;
#pragma unroll
  for (int j = 0; j < 16; ++j) {
    int n = n0 + ns + j;
    double w = (k < K) ? dv * t[(size_t)k * N + n] : 0.0;
    double r = w * sc;
#pragma unroll
    for (int d = 0; d < D; ++d) {
      double rm = r * 128.0;
      double m = rint(rm);
      sm[d][kk][ns + j] = (char)(int)m;
      r = rm - m;
    }
  }
  __syncthreads();
  const int nn = tid >> 2, ks = (tid & 3) * 16;
  const size_t PS = (size_t)N * Kpad;
#pragma unroll
  for (int d = 0; d < D; ++d) {
    char o[16];
#pragma unroll
    for (int j = 0; j < 16; ++j) o[j] = sm[d][ks + j][nn];
    *(int4*)&wdT[d * PS + (size_t)(n0 + nn) * Kpad + k0 + ks] = *(int4*)&o[0];
  }
}

// A3p f32 (nonneg, values-path) -> scaled 14-bit base-128 i8 planes.
__global__ void k_splitA8s(const float* __restrict__ A, int M, int ldsrc,
                           const unsigned* __restrict__ amax,
                           char* __restrict__ S, int Kpad) {
  int r = blockIdx.x;
  const size_t plane = (size_t)Kpad * Kpad;
  float am = __builtin_bit_cast(float, *amax);
  float s13 = (am > 0.0f) ? scalbnf(1.0f, 13 - (ilogbf(am) + 1)) : 0.0f;
  for (int c4 = threadIdx.x * 4; c4 < Kpad; c4 += blockDim.x * 4) {
    float v[4] = {0.f, 0.f, 0.f, 0.f};
    if (r < M && c4 < ldsrc) *(float4*)v = *(const float4*)(A + (size_t)r * ldsrc + c4);
    unsigned hw = 0, lw = 0;
#pragma unroll
    for (int q = 0; q < 4; ++q) {
      int iv = (int)rintf(v[q] * s13);
      int h = iv >> 7, l = iv - (h << 7);
      hw |= ((unsigned)(unsigned char)(char)h) << (8 * q);
      lw |= ((unsigned)(unsigned char)(char)l) << (8 * q);
    }
    *(unsigned*)(S + (size_t)r * Kpad + c4) = hw;
    *(unsigned*)(S + plane + (size_t)r * Kpad + c4) = lw;
  }
}

// P[Mp][Neff] i32 = A[Mp][Kpad] i8 @ wdT[Neff][Kpad]^T — DMA-pipelined i8 GEMM, exact.
__global__ __launch_bounds__(256) void k_axw_pipe8(
    const char* __restrict__ Asrc, const char* __restrict__ Bsrc,
    int Kpad, int* __restrict__ P, int Neff)
{
  __shared__ __align__(16) char Ls[2][2][8192];
  const int tid = threadIdx.x;
  const int wave = tid >> 6, lane = tid & 63;
  const int wr = wave >> 1, wc = wave & 1;
  const int brow = blockIdx.y * 128, bcol = blockIdx.x * 128;
  const int lr = lane & 15, ko = (lane >> 4) * 16;
  const int koff = (lane & 3) * 16;

  const char* pA[2];
  const char* pB[2];
#pragma unroll
  for (int c = 0; c < 2; ++c) {
    int r = (c * 4 + wave) * 16 + (lane >> 2);
    pA[c] = Asrc + (size_t)(brow + r) * Kpad;
    pB[c] = Bsrc + (size_t)(bcol + r) * Kpad;
  }

  i32x4 acc[4][4];
#pragma unroll
  for (int m = 0; m < 4; ++m)
#pragma unroll
    for (int n = 0; n < 4; ++n) acc[m][n] = (i32x4){0, 0, 0, 0};

  auto STAGE = [&](int buf, int kt) {
#pragma unroll
    for (int c = 0; c < 2; ++c) {
      int f = c * 4 + wave;
      gl2lds16(pA[c] + kt + koff, &Ls[buf][0][f * 1024]);
      gl2lds16(pB[c] + kt + koff, &Ls[buf][1][f * 1024]);
    }
  };

  STAGE(0, 0);
  __syncthreads();
  int cur = 0;
  for (int kt = 0; kt < Kpad; kt += 64) {
    if (kt + 64 < Kpad) STAGE(cur ^ 1, kt + 64);
    i32x4 a0[4], b0[4];
#pragma unroll
    for (int m = 0; m < 4; ++m) a0[m] = *(const i32x4*)&Ls[cur][0][(wr * 64 + m * 16 + lr) * 64 + ko];
#pragma unroll
    for (int n = 0; n < 4; ++n) b0[n] = *(const i32x4*)&Ls[cur][1][(wc * 64 + n * 16 + lr) * 64 + ko];
#pragma unroll
    for (int m = 0; m < 4; ++m)
#pragma unroll
      for (int n = 0; n < 4; ++n)
        acc[m][n] = __builtin_amdgcn_mfma_i32_16x16x64_i8(a0[m], b0[n], acc[m][n], 0, 0, 0);
    __syncthreads();
    cur ^= 1;
  }

#pragma unroll
  for (int m = 0; m < 4; ++m)
#pragma unroll
    for (int n = 0; n < 4; ++n)
#pragma unroll
      for (int q = 0; q < 4; ++q) {
        int grow = brow + wr * 64 + m * 16 + (lane >> 4) * 4 + q;
        int gcol = bcol + wc * 64 + n * 16 + lr;
        P[(size_t)grow * Neff + gcol] = acc[m][n][q];
      }
}

// fused reduce_y + gcn_fin: out = relu?( d*(y + 2*d*t) + b ), y from digit planes.
__global__ void k_reduce_fin(const int* __restrict__ P, const unsigned* __restrict__ wmax,
                             const unsigned* __restrict__ amax,
                             const double* __restrict__ t, const double* __restrict__ dinv,
                             const float* __restrict__ bias, double* __restrict__ out,
                             int Neff, int N, int D, int M0pad, int nplane,
                             double w0, double w1, int relu) {
  int m = blockIdx.x;
  float wm = __builtin_bit_cast(float, *wmax);
  double s0 = w0, s1 = w1;
  bool zero = (wm <= 0.0f);
  if (amax) {
    float am = __builtin_bit_cast(float, *amax);
    if (am > 0.0f) {
      int EA = ilogbf(am) + 1;
      s0 = scalbn(w0, EA - 13);
      s1 = scalbn(w1, EA - 13);
    } else zero = true;
  }
  int Ep = zero ? 0 : (ilogbf(wm) + 2);
  double d = dinv[m];
  for (int n = threadIdx.x; n < N; n += blockDim.x) {
    double acc = 0.0;
    if (!zero) {
      for (int dd = 0; dd < D; ++dd) {
        double v = s0 * (double)P[(size_t)m * Neff + dd * N + n];
        if (nplane == 2) v += s1 * (double)P[(size_t)(M0pad + m) * Neff + dd * N + n];
        acc += scalbn(v, Ep - 7 * (dd + 1));
      }
    }
    double v = d * (acc + 2.0 * d * t[(size_t)m * N + n]) + (double)bias[n];
    if (relu) v = v > 0.0 ? v : 0.0;
    out[(size_t)m * N + n] = v;
  }
}

// ---------------- GCN tail / pooling ----------------

template <typename TA>
__device__ __forceinline__ float a_as_f32(TA v);
template <> __device__ __forceinline__ float a_as_f32<char>(char v) { return (float)v; }
template <> __device__ __forceinline__ float a_as_f32<float>(float v) { return v; }

template <typename TA>
__global__ void k_degdinv(const TA* __restrict__ A, int lda, double* __restrict__ dinv, int n,
                          unsigned* __restrict__ rst0, unsigned* __restrict__ rst1) {
  if (blockIdx.x == 0 && threadIdx.x == 0) {
    if (rst0) *rst0 = 0u;
    if (rst1) *rst1 = 0u;
  }
  __shared__ double red[256];
  int row = blockIdx.x;
  double s = 0.0;
  for (int j = threadIdx.x; j < n; j += 256) s += (double)a_as_f32<TA>(A[(size_t)row * lda + j]);
  red[threadIdx.x] = s;
  __syncthreads();
  for (int st = 128; st > 0; st >>= 1) {
    if (threadIdx.x < st) red[threadIdx.x] += red[threadIdx.x + st];
    __syncthreads();
  }
  if (threadIdx.x == 0) {
    double deg = red[0] + 2.0;
    dinv[row] = (deg > 0.0) ? 1.0 / sqrt(deg) : 0.0;
  }
}

// dinv from 2-plane i8 (128*h + l): exact integer row sums, identical to f32 path.
__global__ void k_degdinv2p(const char* __restrict__ S, int Kpad, double* __restrict__ dinv,
                            int n, unsigned* __restrict__ rst0) {
  if (blockIdx.x == 0 && threadIdx.x == 0 && rst0) *rst0 = 0u;
  __shared__ double red[256];
  const size_t plane = (size_t)Kpad * Kpad;
  int row = blockIdx.x;
  const char* h = S + (size_t)row * Kpad;
  const char* l = S + plane + (size_t)row * Kpad;
  long s = 0;
  for (int j = threadIdx.x; j < n; j += 256) s += 128 * (long)h[j] + (long)l[j];
  red[threadIdx.x] = (double)s;
  __syncthreads();
  for (int st = 128; st > 0; st >>= 1) {
    if (threadIdx.x < st) red[threadIdx.x] += red[threadIdx.x + st];
    __syncthreads();
  }
  if (threadIdx.x == 0) {
    double deg = red[0] + 2.0;
    dinv[row] = (deg > 0.0) ? 1.0 / sqrt(deg) : 0.0;
  }
}

// scores with fused ||p||; optional reset of a max accumulator for a LATER kernel
__global__ void k_scores(const double* __restrict__ x, const float* __restrict__ p,
                         double* __restrict__ sc, int C, unsigned* __restrict__ rst) {
  if (blockIdx.x == 0 && threadIdx.x == 0 && rst) *rst = 0u;
  __shared__ double red[256], red2[256];
  int row = blockIdx.x;
  double s = 0.0, s2 = 0.0;
  for (int j = threadIdx.x; j < C; j += 256) {
    double pv = (double)p[j];
    s += x[(size_t)row * C + j] * pv;
    s2 += pv * pv;
  }
  red[threadIdx.x] = s;
  red2[threadIdx.x] = s2;
  __syncthreads();
  for (int st = 128; st > 0; st >>= 1) {
    if (threadIdx.x < st) {
      red[threadIdx.x] += red[threadIdx.x + st];
      red2[threadIdx.x] += red2[threadIdx.x + st];
    }
    __syncthreads();
  }
  if (threadIdx.x == 0) sc[row] = tanh(red[0] / sqrt(red2[0]));
}

__global__ __launch_bounds__(1024) void k_topk(const double* __restrict__ sc, int n,
                                               int* __restrict__ perm, double* __restrict__ vals) {
  __shared__ double s[SORT_N];
  __shared__ int id[SORT_N];
  const int t = threadIdx.x;
  for (int i = t; i < SORT_N; i += 1024) {
    s[i] = (i < n) ? sc[i] : -INFINITY;
    id[i] = i;
  }
  __syncthreads();
  for (int size = 2; size <= SORT_N; size <<= 1) {
    for (int stride = size >> 1; stride > 0; stride >>= 1) {
      for (int i = t; i < SORT_N; i += 1024) {
        int l = i ^ stride;
        if (l > i) {
          double si = s[i], sl = s[l];
          int ii = id[i], il = id[l];
          bool iAfterL = (sl > si) || (sl == si && il < ii);
          bool up = ((i & size) == 0);
          if (iAfterL == up) { s[i] = sl; s[l] = si; id[i] = il; id[l] = ii; }
        }
      }
      __syncthreads();
    }
  }
  for (int i = t; i < n; i += 1024) { perm[i] = id[i]; vals[i] = s[i]; }
}

__global__ void k_gather_x(const double* __restrict__ x, const int* __restrict__ perm,
                           const double* __restrict__ vals, double* __restrict__ xo, int C) {
  int row = blockIdx.x;
  int src = perm[row];
  double v = vals[row];
  for (int c = threadIdx.x; c < C; c += blockDim.x)
    xo[(size_t)row * C + c] = x[(size_t)src * C + c] * v;
}

__global__ void k_write_out(const double* __restrict__ x, float* __restrict__ out,
                            int nvals, int total) {
  int i = blockIdx.x * blockDim.x + threadIdx.x;
  int st = gridDim.x * blockDim.x;
  for (; i < total; i += st) out[i] = (i < nvals) ? (float)x[i] : 0.0f;
}

__global__ void k_sentinel(float* __restrict__ out, int total) {
  int i = blockIdx.x * blockDim.x + threadIdx.x;
  int st = gridDim.x * blockDim.x;
  for (; i < total; i += st) out[i] = 1e30f;
}

// ---------------- driver ----------------

extern "C" void kernel_launch(void* const* d_in, const int* in_sizes, int n_in,
                              void* d_out, int out_size, void* d_ws, size_t ws_size,
                              hipStream_t stream) {
  const float* x0f  = (const float*)d_in[0];
  const int*   ei   = (const int*)d_in[1];
  const float* W0   = (const float*)d_in[2];
  const float* b0   = (const float*)d_in[3];
  const float* W1   = (const float*)d_in[4];
  const float* b1   = (const float*)d_in[5];
  const float* W2   = (const float*)d_in[6];
  const float* b2   = (const float*)d_in[7];
  const float* p1   = (const float*)d_in[8];
  const float* p2   = (const float*)d_in[9];
  const float* Wout = (const float*)d_in[10];
  const float* bout = (const float*)d_in[11];
  const int E = in_sizes[1] / 2;

  const size_t MiB = 1ull << 20;
  if (ws_size < 160 * MiB) {
    k_sentinel<<<dim3(256), dim3(256), 0, stream>>>((float*)d_out, out_size);
    return;
  }
  char* W = (char*)d_ws;
  const size_t PL2 = (size_t)KI2 * KI2;  // 10.56 MiB per i8 plane
  // epoch A: build + aug1
  float* A0    = (float*)(W + 0);            // 0..64
  char*  A0s8  = (char*)(W + 64 * MiB);      // 64..80
  char*  A0s8T = (char*)(W + 80 * MiB);      // 80..96 (+2I folded)
  // epoch A2: gcn1
  char*  A1    = (char*)(W + 0);             // 0..16
  char*  A1T   = (char*)(W + 16 * MiB);      // 16..32 (+2I folded)
  char*  wdT1  = (char*)(W + 32 * MiB);      // 32..40
  int*   P1    = (int*)(W + 40 * MiB);       // 40..72
  // epoch B: aug2 + gcn2
  char*  A2s8  = (char*)(W + 64 * MiB);      // 64..85.2 (hi/lo planes)
  char*  A2s8T = (char*)(W + 86 * MiB);      // 86..107.2 (hi/lo, lo diag=+2)
  char*  wdT2  = (char*)(W + 0);             // 0..6.6
  int*   P2    = (int*)(W + 7 * MiB);        // 7..61.5
  // epoch C: aug3 + gcn3/out
  float* A3p     = (float*)(W + 108 * MiB);  // 108..122.8
  char*  A3stack = (char*)(W + 0);           // 0..7.9
  char*  wdT3    = (char*)(W + 8 * MiB);     // 8..9.1
  int*   P3      = (int*)(W + 10 * MiB);     // 10..18.2
  // features
  double* tb   = (double*)(W + 128 * MiB);
  double* xA   = (double*)(W + 144 * MiB);
  double* xB   = (double*)(W + 152 * MiB);
  char* SM = W + (159 * MiB + 256 * 1024);
  double* dinv = (double*)(SM);
  double* sc   = (double*)(SM + 32768);
  double* vals = (double*)(SM + 65536);
  unsigned* wmax  = (unsigned*)(SM + 98304 + 128);
  unsigned* a3max = (unsigned*)(SM + 98304 + 192);
  int* perm    = (int*)(SM + 98304 + 256);
  int* permB   = (int*)(SM + 98304 + 256 + 16384);
  char* zpage  = (char*)(W + 159 * MiB + 512 * 1024);  // 32 KiB zeros

  // ---- build A0, i8 split+transpose ----
  k_zero32<<<dim3(8), dim3(256), 0, stream>>>((float*)zpage, 8192);
  k_zero32<<<dim3(2048), dim3(256), 0, stream>>>(A0, (size_t)N0 * N0);
  k_build_adj<<<dim3((E + 255) / 256), dim3(256), 0, stream>>>(ei, A0, E, N0);
  k_transpose_split_i8<<<dim3(64, 64), dim3(256), 0, stream>>>(A0, A0s8, A0s8T);

  // ---- aug1: A1 = offdiag(A0 @ (A0+2I)), i8 exact; A1T fused (+2I) ----
  k_aug_pipe8<0><<<dim3(32, 32), dim3(256), 0, stream>>>(
      A0s8, A0s8T, nullptr, zpage, N0, N0, A1, A1T, 0, N0, N0, N0);

  // ---- gcn1 ----
  k_widen_f32_f64<<<dim3(512), dim3(256), 0, stream>>>(x0f, xB, N0 * CIN);
  {
    dim3 b(16, 16);
    k_gemm_xw32<<<dim3(HID / 64, (N0 + 31) / 32), b, 0, stream>>>(xB, W0, tb, N0, HID, CIN);
    k_degdinv<char><<<dim3(N0), dim3(256), 0, stream>>>(A1, N0, dinv, N0, wmax, nullptr);
    k_wmax<<<dim3(256), dim3(256), 0, stream>>>(tb, dinv, wmax, N0, HID);
    k_digitize8<DNUM><<<dim3(N0 / 64, HID / 64), dim3(256), 0, stream>>>(tb, dinv, wmax, wdT1, N0, N0, HID);
    k_axw_pipe8<<<dim3(DNUM * HID / 128, N0 / 128), dim3(256), 0, stream>>>(A1, wdT1, N0, P1, DNUM * HID);
    k_reduce_fin<<<dim3(N0), dim3(256), 0, stream>>>(P1, wmax, nullptr, tb, dinv, b0, xA,
                                                     DNUM * HID, HID, DNUM, 0, 1, 1.0, 0.0, 1);
  }

  // ---- pool1 ----
  k_scores<<<dim3(N0), dim3(256), 0, stream>>>(xA, p1, sc, HID, nullptr);
  k_topk<<<dim3(1), dim3(1024), 0, stream>>>(sc, N0, perm, vals);
  k_gather_x<<<dim3(K1P), dim3(256), 0, stream>>>(xA, perm, vals, xB, HID);

  // ---- aug2: A2s8 hi/lo = base-128 split of offdiag(A1@(A1+2I))[perm x perm]; T fused ----
  k_aug_pipe8<1><<<dim3(26, 26), dim3(256), 0, stream>>>(
      A1, A1T, perm, zpage, N0, N0, A2s8, A2s8T, PL2, KI2, K1P, K1P);

  // ---- gcn2 ----
  {
    dim3 b(16, 16);
    k_gemm_xw32<<<dim3(HID / 64, (K1P + 31) / 32), b, 0, stream>>>(xB, W1, tb, K1P, HID, HID);
    k_degdinv2p<<<dim3(K1P), dim3(256), 0, stream>>>(A2s8, KI2, dinv, K1P, wmax);
    k_wmax<<<dim3(256), dim3(256), 0, stream>>>(tb, dinv, wmax, K1P, HID);
    k_digitize8<DNUM><<<dim3(KI2 / 64, HID / 64), dim3(256), 0, stream>>>(tb, dinv, wmax, wdT2, K1P, KI2, HID);
    k_axw_pipe8<<<dim3(DNUM * HID / 128, 2 * KI2 / 128), dim3(256), 0, stream>>>(A2s8, wdT2, KI2, P2, DNUM * HID);
    k_reduce_fin<<<dim3(K1P), dim3(256), 0, stream>>>(P2, wmax, nullptr, tb, dinv, b1, xA,
                                                      DNUM * HID, HID, DNUM, KI2, 2, 128.0, 1.0, 1);
  }

  // ---- pool2 (scores also resets a3max for aug3) ----
  k_scores<<<dim3(K1P), dim3(256), 0, stream>>>(xA, p2, sc, HID, a3max);
  k_topk<<<dim3(1), dim3(1024), 0, stream>>>(sc, K1P, permB, vals);
  k_gather_x<<<dim3(K2P), dim3(256), 0, stream>>>(xA, permB, vals, xB, HID);

  // ---- aug3: exact i8 4-plane, fused a3max ----
  k_aug3_pipe8<<<dim3(16, 16), dim3(512), 0, stream>>>(
      A2s8, A2s8T, permB, zpage, KI2, A3p, a3max, K2P, K2P, LD3);

  // ---- gcn3 ----
  {
    dim3 b(16, 16);
    k_gemm_xw32<<<dim3(HID / 64, (K2P + 31) / 32), b, 0, stream>>>(xB, W2, tb, K2P, HID, HID);
    k_degdinv<float><<<dim3(K2P), dim3(256), 0, stream>>>(A3p, LD3, dinv, K2P, wmax, nullptr);
    k_splitA8s<<<dim3(KI3), dim3(256), 0, stream>>>(A3p, K2P, LD3, a3max, A3stack, KI3);
    k_wmax<<<dim3(256), dim3(256), 0, stream>>>(tb, dinv, wmax, K2P, HID);
    k_digitize8<2><<<dim3(KI3 / 64, HID / 64), dim3(256), 0, stream>>>(tb, dinv, wmax, wdT3, K2P, KI3, HID);
    k_axw_pipe8<<<dim3(2 * HID / 128, 2 * KI3 / 128), dim3(256), 0, stream>>>(A3stack, wdT3, KI3, P3, 2 * HID);
    k_reduce_fin<<<dim3(K2P), dim3(256), 0, stream>>>(P3, wmax, a3max, tb, dinv, b2, xA,
                                                      2 * HID, HID, 2, KI3, 2, 128.0, 1.0, 1);
  }

  // ---- gcn_out (reuse dinv, a3max, A3stack) ----
  {
    dim3 b(16, 16);
    k_gemm_xw32<<<dim3(COUTC / 64, (K2P + 31) / 32), b, 0, stream>>>(xA, Wout, tb, K2P, COUTC, HID);
    k_reset_u32<<<dim3(1), dim3(64), 0, stream>>>(wmax);
    k_wmax<<<dim3(256), dim3(256), 0, stream>>>(tb, dinv, wmax, K2P, COUTC);
    k_digitize8<2><<<dim3(KI3 / 64, COUTC / 64), dim3(256), 0, stream>>>(tb, dinv, wmax, wdT3, K2P, KI3, COUTC);
    k_axw_pipe8<<<dim3(2 * COUTC / 128, 2 * KI3 / 128), dim3(256), 0, stream>>>(A3stack, wdT3, KI3, P3, 2 * COUTC);
    k_reduce_fin<<<dim3(K2P), dim3(256), 0, stream>>>(P3, wmax, a3max, tb, dinv, bout, xB,
                                                      2 * COUTC, COUTC, 2, KI3, 2, 128.0, 1.0, 0);
  }

  k_write_out<<<dim3(1024), dim3(256), 0, stream>>>(xB, (float*)d_out, K2P * COUTC, out_size);
}

// Round 11
// 857.269 us; speedup vs baseline: 9.7624x; 1.0745x over previous
//
#include <hip/hip_runtime.h>
#include <math.h>

#define N0    4096
#define CIN   128
#define HID   256
#define COUTC 128
#define K1P   3277   // ceil(0.8*4096)
#define K2P   1967   // ceil(0.6*3277)
#define LD3   1968   // K2P padded to 4-float rows
#define KI2   3328   // K1P padded to mult of 64
#define KI3   1984   // K2P padded to mult of 64
#define SORT_N 4096
#define DNUM  8      // digit planes, base-128 -> 56 bits

typedef __attribute__((ext_vector_type(4))) int i32x4;

__device__ __forceinline__ void gl2lds16(const void* g, void* l) {
  __builtin_amdgcn_global_load_lds((const __attribute__((address_space(1))) void*)g,
                                   (__attribute__((address_space(3))) void*)l, 16, 0, 0);
}

// ---------------- build / elementwise ----------------

__global__ void k_zero32(float* __restrict__ p, size_t n) {
  size_t i = (size_t)blockIdx.x * blockDim.x + threadIdx.x;
  size_t st = (size_t)gridDim.x * blockDim.x;
  for (; i < n; i += st) p[i] = 0.0f;
}

__global__ void k_widen_f32_f64(const float* __restrict__ in, double* __restrict__ out, int n) {
  int i = blockIdx.x * blockDim.x + threadIdx.x;
  int st = gridDim.x * blockDim.x;
  for (; i < n; i += st) out[i] = (double)in[i];
}

__global__ void k_build_adj(const int* __restrict__ ei, float* __restrict__ A, int E, int n) {
  int e = blockIdx.x * blockDim.x + threadIdx.x;
  if (e < E) atomicAdd(&A[(size_t)ei[E + e] * n + ei[e]], 1.0f);
}

// A0 f32 -> A0s8 i8 + A0s8T i8 (transposed, +2 folded on diag). Small ints, exact.
__global__ __launch_bounds__(256) void k_transpose_split_i8(
    const float* __restrict__ A, char* __restrict__ B, char* __restrict__ BT) {
  __shared__ char sm[64][68];
  const int t = threadIdx.x;
  const int r0 = blockIdx.y * 64, c0 = blockIdx.x * 64;
  const int rr = t >> 2, cs = (t & 3) * 16;
  char tmp[16];
#pragma unroll
  for (int j = 0; j < 16; ++j) {
    char v = (char)(int)A[(size_t)(r0 + rr) * N0 + c0 + cs + j];
    tmp[j] = v;
    sm[cs + j][rr] = v;
  }
  *(int4*)&B[(size_t)(r0 + rr) * N0 + c0 + cs] = *(int4*)&tmp[0];
  __syncthreads();
  const int cc = t >> 2, rs = (t & 3) * 16;
  const int orow = c0 + cc;
  char o[16];
#pragma unroll
  for (int q = 0; q < 16; ++q) {
    char v = sm[cc][rs + q];
    if (r0 + rs + q == orow) v = (char)(v + 2);
    o[q] = v;
  }
  *(int4*)&BT[(size_t)orow * N0 + r0 + rs] = *(int4*)&o[0];
}

// i8 square transpose (n mult of 64) with integer diag fold (proven round-9 kernel)
__global__ __launch_bounds__(256) void k_transpose_i8s(
    const char* __restrict__ A, char* __restrict__ BT, int n, int fold) {
  __shared__ char sm[64][68];
  const int t = threadIdx.x;
  const int r0 = blockIdx.y * 64, c0 = blockIdx.x * 64;
  const int rr = t >> 2, cs = (t & 3) * 16;
  {
    int4 v = *(const int4*)&A[(size_t)(r0 + rr) * n + c0 + cs];
    char* vb = (char*)&v;
#pragma unroll
    for (int j = 0; j < 16; ++j) sm[cs + j][rr] = vb[j];
  }
  __syncthreads();
  const int cc = t >> 2, rs = (t & 3) * 16;
  const int orow = c0 + cc;
  char o[16];
#pragma unroll
  for (int q = 0; q < 16; ++q) {
    char v = sm[cc][rs + q];
    if (r0 + rs + q == orow) v = (char)(v + fold);
    o[q] = v;
  }
  *(int4*)&BT[(size_t)orow * n + r0 + rs] = *(int4*)&o[0];
}

// -------- i8 pipelined augment, direct register epilogue (straight planes only) --------
// C = rows(A) @ rows(Bt)^T (Bt diag pre-folded +2I); diag(C)->0.
// MODE 0 (aug1): O = A1, 1 i8 plane [N0][N0].
// MODE 1 (aug2): O = A2s8 hi/lo planes (stride `plane`, pitch ldo); pads -> 0.
template <int MODE>
__global__ __launch_bounds__(256) void k_aug_pipe8(
    const char* __restrict__ Asrc, const char* __restrict__ Btsrc,
    const int* __restrict__ perm, const char* __restrict__ zrow,
    int K, int ldk,
    char* __restrict__ O, size_t plane, int ldo,
    int M, int N)
{
  __shared__ __align__(16) char Ls[2][2][8192];  // 32 KB
  const int tid = threadIdx.x;
  const int wave = tid >> 6, lane = tid & 63;
  const int wr = wave >> 1, wc = wave & 1;
  const int brow = blockIdx.y * 128, bcol = blockIdx.x * 128;
  const int lr = lane & 15, ko = (lane >> 4) * 16;
  const int koff = (lane & 3) * 16;

  const char* pA[2];
  const char* pB[2];
#pragma unroll
  for (int c = 0; c < 2; ++c) {
    int r = (c * 4 + wave) * 16 + (lane >> 2);
    int ra = brow + r, rb = bcol + r;
    int ia, ib;
    if (MODE == 0) { ia = ra; ib = rb; }
    else {
      ia = (ra < M) ? perm[ra] : -1;
      ib = (rb < N) ? perm[rb] : -1;
    }
    pA[c] = (ia >= 0) ? Asrc + (size_t)ia * ldk : zrow;
    pB[c] = (ib >= 0) ? Btsrc + (size_t)ib * ldk : zrow;
  }

  i32x4 acc[4][4];
#pragma unroll
  for (int m = 0; m < 4; ++m)
#pragma unroll
    for (int n = 0; n < 4; ++n) acc[m][n] = (i32x4){0, 0, 0, 0};

  auto STAGE = [&](int buf, int kt) {
#pragma unroll
    for (int c = 0; c < 2; ++c) {
      int f = c * 4 + wave;
      gl2lds16(pA[c] + kt + koff, &Ls[buf][0][f * 1024]);
      gl2lds16(pB[c] + kt + koff, &Ls[buf][1][f * 1024]);
    }
  };

  STAGE(0, 0);
  __syncthreads();
  int cur = 0;
  for (int kt = 0; kt < K; kt += 64) {
    if (kt + 64 < K) STAGE(cur ^ 1, kt + 64);
    i32x4 a0[4], b0[4];
#pragma unroll
    for (int m = 0; m < 4; ++m) a0[m] = *(const i32x4*)&Ls[cur][0][(wr * 64 + m * 16 + lr) * 64 + ko];
#pragma unroll
    for (int n = 0; n < 4; ++n) b0[n] = *(const i32x4*)&Ls[cur][1][(wc * 64 + n * 16 + lr) * 64 + ko];
#pragma unroll
    for (int m = 0; m < 4; ++m)
#pragma unroll
      for (int n = 0; n < 4; ++n)
        acc[m][n] = __builtin_amdgcn_mfma_i32_16x16x64_i8(a0[m], b0[n], acc[m][n], 0, 0, 0);
    __syncthreads();
    cur ^= 1;
  }

  // direct register epilogue (no LDS bounce, minimal VGPR)
#pragma unroll
  for (int m = 0; m < 4; ++m)
#pragma unroll
    for (int n = 0; n < 4; ++n)
#pragma unroll
      for (int q = 0; q < 4; ++q) {
        int grow = brow + wr * 64 + m * 16 + (lane >> 4) * 4 + q;
        int gcol = bcol + wc * 64 + n * 16 + lr;
        int v = acc[m][n][q];
        if (MODE == 0) {
          if (grow == gcol) v = 0;
          O[(size_t)grow * ldo + gcol] = (char)v;
        } else {
          if (grow >= M || gcol >= N || grow == gcol) v = 0;
          O[(size_t)grow * ldo + gcol] = (char)(v >> 7);
          O[plane + (size_t)grow * ldo + gcol] = (char)(v & 127);
        }
      }
}

// aug3 (i8, exact): A3 = (128H+L) @ (128H'+(L'+2I)) = 16384 HH' + 128 (HL'+LH') + LL'.
// 512 threads / 8 waves; fused block-max -> amax (order-independent atomicMax).
__global__ __launch_bounds__(512) void k_aug3_pipe8(
    const char* __restrict__ S, const char* __restrict__ ST,
    const int* __restrict__ perm, const char* __restrict__ zrow,
    int Kpad, float* __restrict__ Cf, unsigned* __restrict__ amax,
    int M, int N, int ldcp)
{
  __shared__ __align__(16) char Ls[2][4][8192];  // 64 KB
  const int tid = threadIdx.x;
  const int wave = tid >> 6, lane = tid & 63;
  const int wr = wave >> 1, wc = wave & 1;
  const int brow = blockIdx.y * 128, bcol = blockIdx.x * 128;
  const int lr = lane & 15, ko = (lane >> 4) * 16;
  const int koff = (lane & 3) * 16;
  const size_t plane = (size_t)Kpad * Kpad;

  const char *pAh, *pAl, *pBh, *pBl;
  {
    int r = (wave << 4) + (lane >> 2);
    int ra = brow + r, rb = bcol + r;
    int ia = (ra < M) ? perm[ra] : -1;
    int ib = (rb < N) ? perm[rb] : -1;
    pAh = (ia >= 0) ? S + (size_t)ia * Kpad : zrow;
    pAl = (ia >= 0) ? S + plane + (size_t)ia * Kpad : zrow;
    pBh = (ib >= 0) ? ST + (size_t)ib * Kpad : zrow;
    pBl = (ib >= 0) ? ST + plane + (size_t)ib * Kpad : zrow;
  }

  i32x4 hh[2][4], mid[2][4], ll[2][4];
#pragma unroll
  for (int m = 0; m < 2; ++m)
#pragma unroll
    for (int n = 0; n < 4; ++n) {
      hh[m][n] = (i32x4){0, 0, 0, 0};
      mid[m][n] = (i32x4){0, 0, 0, 0};
      ll[m][n] = (i32x4){0, 0, 0, 0};
    }

  auto STAGE = [&](int buf, int kt) {
    int f = wave * 1024;
    gl2lds16(pAh + kt + koff, &Ls[buf][0][f]);
    gl2lds16(pBh + kt + koff, &Ls[buf][1][f]);
    gl2lds16(pAl + kt + koff, &Ls[buf][2][f]);
    gl2lds16(pBl + kt + koff, &Ls[buf][3][f]);
  };

  STAGE(0, 0);
  __syncthreads();
  int cur = 0;
  for (int kt = 0; kt < Kpad; kt += 64) {
    if (kt + 64 < Kpad) STAGE(cur ^ 1, kt + 64);
    i32x4 ah[2], al[2], bh[4], bl[4];
#pragma unroll
    for (int m = 0; m < 2; ++m) {
      ah[m] = *(const i32x4*)&Ls[cur][0][(wr * 32 + m * 16 + lr) * 64 + ko];
      al[m] = *(const i32x4*)&Ls[cur][2][(wr * 32 + m * 16 + lr) * 64 + ko];
    }
#pragma unroll
    for (int n = 0; n < 4; ++n) {
      bh[n] = *(const i32x4*)&Ls[cur][1][(wc * 64 + n * 16 + lr) * 64 + ko];
      bl[n] = *(const i32x4*)&Ls[cur][3][(wc * 64 + n * 16 + lr) * 64 + ko];
    }
#pragma unroll
    for (int m = 0; m < 2; ++m)
#pragma unroll
      for (int n = 0; n < 4; ++n) {
        hh[m][n]  = __builtin_amdgcn_mfma_i32_16x16x64_i8(ah[m], bh[n], hh[m][n], 0, 0, 0);
        mid[m][n] = __builtin_amdgcn_mfma_i32_16x16x64_i8(ah[m], bl[n], mid[m][n], 0, 0, 0);
        mid[m][n] = __builtin_amdgcn_mfma_i32_16x16x64_i8(al[m], bh[n], mid[m][n], 0, 0, 0);
        ll[m][n]  = __builtin_amdgcn_mfma_i32_16x16x64_i8(al[m], bl[n], ll[m][n], 0, 0, 0);
      }
    __syncthreads();
    cur ^= 1;
  }

  float mloc = 0.0f;
#pragma unroll
  for (int m = 0; m < 2; ++m)
#pragma unroll
    for (int n = 0; n < 4; ++n)
#pragma unroll
      for (int q = 0; q < 4; ++q) {
        int grow = brow + wr * 32 + m * 16 + (lane >> 4) * 4 + q;
        int gcol = bcol + wc * 64 + n * 16 + lr;
        if (grow < M && gcol < ldcp) {
          float v = 16384.0f * (float)hh[m][n][q] + 128.0f * (float)mid[m][n][q] + (float)ll[m][n][q];
          if (gcol >= N || grow == gcol) v = 0.0f;
          Cf[(size_t)grow * ldcp + gcol] = v;
          mloc = fmaxf(mloc, v);
        }
      }
  __syncthreads();
  float* red = (float*)&Ls[0][0][0];
  red[tid] = mloc;
  __syncthreads();
  for (int st = 256; st > 0; st >>= 1) {
    if (tid < st) red[tid] = fmaxf(red[tid], red[tid + st]);
    __syncthreads();
  }
  if (tid == 0) atomicMax(amax, __builtin_bit_cast(unsigned, red[0]));
}

// ---------------- f64 x@W (32x64 tiles) ----------------

__global__ __launch_bounds__(256) void k_gemm_xw32(
    const double* __restrict__ X, const float* __restrict__ W, double* __restrict__ C,
    int M, int N, int K) {
  __shared__ double As[16][32];
  __shared__ double Bs[16][64];
  const int tx = threadIdx.x, ty = threadIdx.y;
  const int tid = ty * 16 + tx;
  const int brow = blockIdx.y * 32, bcol = blockIdx.x * 64;
  double acc[2][4];
#pragma unroll
  for (int i = 0; i < 2; ++i)
#pragma unroll
    for (int j = 0; j < 4; ++j) acc[i][j] = 0.0;
  const int lac = tid & 15, lar = tid >> 4;
  const int lbc = tid & 63, lbr = tid >> 6;
  for (int kt = 0; kt < K; kt += 16) {
#pragma unroll
    for (int rr = 0; rr < 2; ++rr) {
      int r = lar + rr * 16;
      int gr = brow + r, gk = kt + lac;
      As[lac][r] = (gr < M && gk < K) ? X[(size_t)gr * K + gk] : 0.0;
    }
#pragma unroll
    for (int rr = 0; rr < 4; ++rr) {
      int br = lbr + rr * 4;
      int gk = kt + br, gc = bcol + lbc;
      Bs[br][lbc] = (gk < K && gc < N) ? (double)W[(size_t)gk * N + gc] : 0.0;
    }
    __syncthreads();
#pragma unroll
    for (int kk = 0; kk < 16; ++kk) {
      double a[2], b[4];
#pragma unroll
      for (int i = 0; i < 2; ++i) a[i] = As[kk][ty * 2 + i];
#pragma unroll
      for (int j = 0; j < 4; ++j) b[j] = Bs[kk][tx * 4 + j];
#pragma unroll
      for (int i = 0; i < 2; ++i)
#pragma unroll
        for (int j = 0; j < 4; ++j) acc[i][j] = fma(a[i], b[j], acc[i][j]);
    }
    __syncthreads();
  }
#pragma unroll
  for (int i = 0; i < 2; ++i) {
    int gr = brow + ty * 2 + i;
    if (gr >= M) continue;
#pragma unroll
    for (int j = 0; j < 4; ++j) {
      int gc = bcol + tx * 4 + j;
      if (gc >= N) continue;
      C[(size_t)gr * N + gc] = acc[i][j];
    }
  }
}

// ---------------- digit machinery (i8, base-128) ----------------

__global__ void k_reset_u32(unsigned* p) { if (threadIdx.x == 0 && blockIdx.x == 0) *p = 0u; }

__global__ void k_wmax(const double* __restrict__ t, const double* __restrict__ dinv,
                       unsigned* __restrict__ wmax, int K, int N) {
  __shared__ float red[256];
  float mx = 0.0f;
  int tot = K * N;
  for (int i = blockIdx.x * 256 + threadIdx.x; i < tot; i += gridDim.x * 256) {
    double w = dinv[i / N] * t[i];
    mx = fmaxf(mx, (float)fabs(w));
  }
  red[threadIdx.x] = mx;
  __syncthreads();
  for (int st = 128; st > 0; st >>= 1) {
    if (threadIdx.x < st) red[threadIdx.x] = fmaxf(red[threadIdx.x], red[threadIdx.x + st]);
    __syncthreads();
  }
  if (threadIdx.x == 0) atomicMax(wmax, __builtin_bit_cast(unsigned, red[0]));
}

template <int D>
__global__ __launch_bounds__(256) void k_digitize8(
    const double* __restrict__ t, const double* __restrict__ dinv,
    const unsigned* __restrict__ wmax, char* __restrict__ wdT,
    int K, int Kpad, int N) {
  __shared__ char sm[D][64][68];
  const int tid = threadIdx.x;
  const int k0 = blockIdx.x * 64, n0 = blockIdx.y * 64;
  float wm = __builtin_bit_cast(float, *wmax);
  double sc = (wm > 0.0f) ? scalbn(1.0, -(ilogbf(wm) + 2)) : 0.0;
  const int kk = tid >> 2, ns = (tid & 3) * 16;
  int k = k0 + kk;
  double dv = (k < K) ? dinv[k] : 0.0;
#pragma unroll
  for (int j = 0; j < 16; ++j) {
    int n = n0 + ns + j;
    double w = (k < K) ? dv * t[(size_t)k * N + n] : 0.0;
    double r = w * sc;
#pragma unroll
    for (int d = 0; d < D; ++d) {
      double rm = r * 128.0;
      double m = rint(rm);
      sm[d][kk][ns + j] = (char)(int)m;
      r = rm - m;
    }
  }
  __syncthreads();
  const int nn = tid >> 2, ks = (tid & 3) * 16;
  const size_t PS = (size_t)N * Kpad;
#pragma unroll
  for (int d = 0; d < D; ++d) {
    char o[16];
#pragma unroll
    for (int j = 0; j < 16; ++j) o[j] = sm[d][ks + j][nn];
    *(int4*)&wdT[d * PS + (size_t)(n0 + nn) * Kpad + k0 + ks] = *(int4*)&o[0];
  }
}

// A3p f32 (nonneg, values-path) -> scaled 14-bit base-128 i8 planes.
__global__ void k_splitA8s(const float* __restrict__ A, int M, int ldsrc,
                           const unsigned* __restrict__ amax,
                           char* __restrict__ S, int Kpad) {
  int r = blockIdx.x;
  const size_t plane = (size_t)Kpad * Kpad;
  float am = __builtin_bit_cast(float, *amax);
  float s13 = (am > 0.0f) ? scalbnf(1.0f, 13 - (ilogbf(am) + 1)) : 0.0f;
  for (int c4 = threadIdx.x * 4; c4 < Kpad; c4 += blockDim.x * 4) {
    float v[4] = {0.f, 0.f, 0.f, 0.f};
    if (r < M && c4 < ldsrc) *(float4*)v = *(const float4*)(A + (size_t)r * ldsrc + c4);
    unsigned hw = 0, lw = 0;
#pragma unroll
    for (int q = 0; q < 4; ++q) {
      int iv = (int)rintf(v[q] * s13);
      int h = iv >> 7, l = iv - (h << 7);
      hw |= ((unsigned)(unsigned char)(char)h) << (8 * q);
      lw |= ((unsigned)(unsigned char)(char)l) << (8 * q);
    }
    *(unsigned*)(S + (size_t)r * Kpad + c4) = hw;
    *(unsigned*)(S + plane + (size_t)r * Kpad + c4) = lw;
  }
}

// P[Mp][Neff] i32 = A[Mp][Kpad] i8 @ wdT[Neff][Kpad]^T — DMA-pipelined i8 GEMM, exact.
__global__ __launch_bounds__(256) void k_axw_pipe8(
    const char* __restrict__ Asrc, const char* __restrict__ Bsrc,
    int Kpad, int* __restrict__ P, int Neff)
{
  __shared__ __align__(16) char Ls[2][2][8192];
  const int tid = threadIdx.x;
  const int wave = tid >> 6, lane = tid & 63;
  const int wr = wave >> 1, wc = wave & 1;
  const int brow = blockIdx.y * 128, bcol = blockIdx.x * 128;
  const int lr = lane & 15, ko = (lane >> 4) * 16;
  const int koff = (lane & 3) * 16;

  const char* pA[2];
  const char* pB[2];
#pragma unroll
  for (int c = 0; c < 2; ++c) {
    int r = (c * 4 + wave) * 16 + (lane >> 2);
    pA[c] = Asrc + (size_t)(brow + r) * Kpad;
    pB[c] = Bsrc + (size_t)(bcol + r) * Kpad;
  }

  i32x4 acc[4][4];
#pragma unroll
  for (int m = 0; m < 4; ++m)
#pragma unroll
    for (int n = 0; n < 4; ++n) acc[m][n] = (i32x4){0, 0, 0, 0};

  auto STAGE = [&](int buf, int kt) {
#pragma unroll
    for (int c = 0; c < 2; ++c) {
      int f = c * 4 + wave;
      gl2lds16(pA[c] + kt + koff, &Ls[buf][0][f * 1024]);
      gl2lds16(pB[c] + kt + koff, &Ls[buf][1][f * 1024]);
    }
  };

  STAGE(0, 0);
  __syncthreads();
  int cur = 0;
  for (int kt = 0; kt < Kpad; kt += 64) {
    if (kt + 64 < Kpad) STAGE(cur ^ 1, kt + 64);
    i32x4 a0[4], b0[4];
#pragma unroll
    for (int m = 0; m < 4; ++m) a0[m] = *(const i32x4*)&Ls[cur][0][(wr * 64 + m * 16 + lr) * 64 + ko];
#pragma unroll
    for (int n = 0; n < 4; ++n) b0[n] = *(const i32x4*)&Ls[cur][1][(wc * 64 + n * 16 + lr) * 64 + ko];
#pragma unroll
    for (int m = 0; m < 4; ++m)
#pragma unroll
      for (int n = 0; n < 4; ++n)
        acc[m][n] = __builtin_amdgcn_mfma_i32_16x16x64_i8(a0[m], b0[n], acc[m][n], 0, 0, 0);
    __syncthreads();
    cur ^= 1;
  }

#pragma unroll
  for (int m = 0; m < 4; ++m)
#pragma unroll
    for (int n = 0; n < 4; ++n)
#pragma unroll
      for (int q = 0; q < 4; ++q) {
        int grow = brow + wr * 64 + m * 16 + (lane >> 4) * 4 + q;
        int gcol = bcol + wc * 64 + n * 16 + lr;
        P[(size_t)grow * Neff + gcol] = acc[m][n][q];
      }
}

// fused reduce_y + gcn_fin: out = relu?( d*(y + 2*d*t) + b ), y from digit planes.
__global__ void k_reduce_fin(const int* __restrict__ P, const unsigned* __restrict__ wmax,
                             const unsigned* __restrict__ amax,
                             const double* __restrict__ t, const double* __restrict__ dinv,
                             const float* __restrict__ bias, double* __restrict__ out,
                             int Neff, int N, int D, int M0pad, int nplane,
                             double w0, double w1, int relu) {
  int m = blockIdx.x;
  float wm = __builtin_bit_cast(float, *wmax);
  double s0 = w0, s1 = w1;
  bool zero = (wm <= 0.0f);
  if (amax) {
    float am = __builtin_bit_cast(float, *amax);
    if (am > 0.0f) {
      int EA = ilogbf(am) + 1;
      s0 = scalbn(w0, EA - 13);
      s1 = scalbn(w1, EA - 13);
    } else zero = true;
  }
  int Ep = zero ? 0 : (ilogbf(wm) + 2);
  double d = dinv[m];
  for (int n = threadIdx.x; n < N; n += blockDim.x) {
    double acc = 0.0;
    if (!zero) {
      for (int dd = 0; dd < D; ++dd) {
        double v = s0 * (double)P[(size_t)m * Neff + dd * N + n];
        if (nplane == 2) v += s1 * (double)P[(size_t)(M0pad + m) * Neff + dd * N + n];
        acc += scalbn(v, Ep - 7 * (dd + 1));
      }
    }
    double v = d * (acc + 2.0 * d * t[(size_t)m * N + n]) + (double)bias[n];
    if (relu) v = v > 0.0 ? v : 0.0;
    out[(size_t)m * N + n] = v;
  }
}

// ---------------- GCN tail / pooling ----------------

template <typename TA>
__device__ __forceinline__ float a_as_f32(TA v);
template <> __device__ __forceinline__ float a_as_f32<char>(char v) { return (float)v; }
template <> __device__ __forceinline__ float a_as_f32<float>(float v) { return v; }

template <typename TA>
__global__ void k_degdinv(const TA* __restrict__ A, int lda, double* __restrict__ dinv, int n,
                          unsigned* __restrict__ rst0, unsigned* __restrict__ rst1) {
  if (blockIdx.x == 0 && threadIdx.x == 0) {
    if (rst0) *rst0 = 0u;
    if (rst1) *rst1 = 0u;
  }
  __shared__ double red[256];
  int row = blockIdx.x;
  double s = 0.0;
  for (int j = threadIdx.x; j < n; j += 256) s += (double)a_as_f32<TA>(A[(size_t)row * lda + j]);
  red[threadIdx.x] = s;
  __syncthreads();
  for (int st = 128; st > 0; st >>= 1) {
    if (threadIdx.x < st) red[threadIdx.x] += red[threadIdx.x + st];
    __syncthreads();
  }
  if (threadIdx.x == 0) {
    double deg = red[0] + 2.0;
    dinv[row] = (deg > 0.0) ? 1.0 / sqrt(deg) : 0.0;
  }
}

// dinv from 2-plane i8 (128*h + l): exact integer row sums, identical to f32 path.
__global__ void k_degdinv2p(const char* __restrict__ S, int Kpad, double* __restrict__ dinv,
                            int n, unsigned* __restrict__ rst0) {
  if (blockIdx.x == 0 && threadIdx.x == 0 && rst0) *rst0 = 0u;
  __shared__ double red[256];
  const size_t plane = (size_t)Kpad * Kpad;
  int row = blockIdx.x;
  const char* h = S + (size_t)row * Kpad;
  const char* l = S + plane + (size_t)row * Kpad;
  long s = 0;
  for (int j = threadIdx.x; j < n; j += 256) s += 128 * (long)h[j] + (long)l[j];
  red[threadIdx.x] = (double)s;
  __syncthreads();
  for (int st = 128; st > 0; st >>= 1) {
    if (threadIdx.x < st) red[threadIdx.x] += red[threadIdx.x + st];
    __syncthreads();
  }
  if (threadIdx.x == 0) {
    double deg = red[0] + 2.0;
    dinv[row] = (deg > 0.0) ? 1.0 / sqrt(deg) : 0.0;
  }
}

// scores with fused ||p||; optional reset of a max accumulator for a LATER kernel
__global__ void k_scores(const double* __restrict__ x, const float* __restrict__ p,
                         double* __restrict__ sc, int C, unsigned* __restrict__ rst) {
  if (blockIdx.x == 0 && threadIdx.x == 0 && rst) *rst = 0u;
  __shared__ double red[256], red2[256];
  int row = blockIdx.x;
  double s = 0.0, s2 = 0.0;
  for (int j = threadIdx.x; j < C; j += 256) {
    double pv = (double)p[j];
    s += x[(size_t)row * C + j] * pv;
    s2 += pv * pv;
  }
  red[threadIdx.x] = s;
  red2[threadIdx.x] = s2;
  __syncthreads();
  for (int st = 128; st > 0; st >>= 1) {
    if (threadIdx.x < st) {
      red[threadIdx.x] += red[threadIdx.x + st];
      red2[threadIdx.x] += red2[threadIdx.x + st];
    }
    __syncthreads();
  }
  if (threadIdx.x == 0) sc[row] = tanh(red[0] / sqrt(red2[0]));
}

__global__ __launch_bounds__(1024) void k_topk(const double* __restrict__ sc, int n,
                                               int* __restrict__ perm, double* __restrict__ vals) {
  __shared__ double s[SORT_N];
  __shared__ int id[SORT_N];
  const int t = threadIdx.x;
  for (int i = t; i < SORT_N; i += 1024) {
    s[i] = (i < n) ? sc[i] : -INFINITY;
    id[i] = i;
  }
  __syncthreads();
  for (int size = 2; size <= SORT_N; size <<= 1) {
    for (int stride = size >> 1; stride > 0; stride >>= 1) {
      for (int i = t; i < SORT_N; i += 1024) {
        int l = i ^ stride;
        if (l > i) {
          double si = s[i], sl = s[l];
          int ii = id[i], il = id[l];
          bool iAfterL = (sl > si) || (sl == si && il < ii);
          bool up = ((i & size) == 0);
          if (iAfterL == up) { s[i] = sl; s[l] = si; id[i] = il; id[l] = ii; }
        }
      }
      __syncthreads();
    }
  }
  for (int i = t; i < n; i += 1024) { perm[i] = id[i]; vals[i] = s[i]; }
}

__global__ void k_gather_x(const double* __restrict__ x, const int* __restrict__ perm,
                           const double* __restrict__ vals, double* __restrict__ xo, int C) {
  int row = blockIdx.x;
  int src = perm[row];
  double v = vals[row];
  for (int c = threadIdx.x; c < C; c += blockDim.x)
    xo[(size_t)row * C + c] = x[(size_t)src * C + c] * v;
}

__global__ void k_write_out(const double* __restrict__ x, float* __restrict__ out,
                            int nvals, int total) {
  int i = blockIdx.x * blockDim.x + threadIdx.x;
  int st = gridDim.x * blockDim.x;
  for (; i < total; i += st) out[i] = (i < nvals) ? (float)x[i] : 0.0f;
}

__global__ void k_sentinel(float* __restrict__ out, int total) {
  int i = blockIdx.x * blockDim.x + threadIdx.x;
  int st = gridDim.x * blockDim.x;
  for (; i < total; i += st) out[i] = 1e30f;
}

// ---------------- driver ----------------

extern "C" void kernel_launch(void* const* d_in, const int* in_sizes, int n_in,
                              void* d_out, int out_size, void* d_ws, size_t ws_size,
                              hipStream_t stream) {
  const float* x0f  = (const float*)d_in[0];
  const int*   ei   = (const int*)d_in[1];
  const float* W0   = (const float*)d_in[2];
  const float* b0   = (const float*)d_in[3];
  const float* W1   = (const float*)d_in[4];
  const float* b1   = (const float*)d_in[5];
  const float* W2   = (const float*)d_in[6];
  const float* b2   = (const float*)d_in[7];
  const float* p1   = (const float*)d_in[8];
  const float* p2   = (const float*)d_in[9];
  const float* Wout = (const float*)d_in[10];
  const float* bout = (const float*)d_in[11];
  const int E = in_sizes[1] / 2;

  const size_t MiB = 1ull << 20;
  if (ws_size < 160 * MiB) {
    k_sentinel<<<dim3(256), dim3(256), 0, stream>>>((float*)d_out, out_size);
    return;
  }
  char* W = (char*)d_ws;
  const size_t PL2 = (size_t)KI2 * KI2;  // 10.56 MiB per i8 plane
  // epoch A: build + aug1
  float* A0    = (float*)(W + 0);            // 0..64
  char*  A0s8  = (char*)(W + 64 * MiB);      // 64..80
  char*  A0s8T = (char*)(W + 80 * MiB);      // 80..96 (+2I folded)
  // epoch A2: gcn1
  char*  A1    = (char*)(W + 0);             // 0..16
  char*  A1T   = (char*)(W + 16 * MiB);      // 16..32 (+2I folded)
  char*  wdT1  = (char*)(W + 32 * MiB);      // 32..40
  int*   P1    = (int*)(W + 40 * MiB);       // 40..72
  // epoch B: aug2 + gcn2
  char*  A2s8  = (char*)(W + 64 * MiB);      // 64..85.2 (hi/lo planes)
  char*  A2s8T = (char*)(W + 86 * MiB);      // 86..107.2 (hi/lo, lo diag=+2)
  char*  wdT2  = (char*)(W + 0);             // 0..6.6
  int*   P2    = (int*)(W + 7 * MiB);        // 7..61.5
  // epoch C: aug3 + gcn3/out
  float* A3p     = (float*)(W + 108 * MiB);  // 108..122.8
  char*  A3stack = (char*)(W + 0);           // 0..7.9
  char*  wdT3    = (char*)(W + 8 * MiB);     // 8..9.1
  int*   P3      = (int*)(W + 10 * MiB);     // 10..18.2
  // features
  double* tb   = (double*)(W + 128 * MiB);
  double* xA   = (double*)(W + 144 * MiB);
  double* xB   = (double*)(W + 152 * MiB);
  char* SM = W + (159 * MiB + 256 * 1024);
  double* dinv = (double*)(SM);
  double* sc   = (double*)(SM + 32768);
  double* vals = (double*)(SM + 65536);
  unsigned* wmax  = (unsigned*)(SM + 98304 + 128);
  unsigned* a3max = (unsigned*)(SM + 98304 + 192);
  int* perm    = (int*)(SM + 98304 + 256);
  int* permB   = (int*)(SM + 98304 + 256 + 16384);
  char* zpage  = (char*)(W + 159 * MiB + 512 * 1024);  // 32 KiB zeros

  // ---- build A0, i8 split+transpose ----
  k_zero32<<<dim3(8), dim3(256), 0, stream>>>((float*)zpage, 8192);
  k_zero32<<<dim3(2048), dim3(256), 0, stream>>>(A0, (size_t)N0 * N0);
  k_build_adj<<<dim3((E + 255) / 256), dim3(256), 0, stream>>>(ei, A0, E, N0);
  k_transpose_split_i8<<<dim3(64, 64), dim3(256), 0, stream>>>(A0, A0s8, A0s8T);

  // ---- aug1: A1 = offdiag(A0 @ (A0+2I)), i8 exact; A1T via transpose kernel ----
  k_aug_pipe8<0><<<dim3(32, 32), dim3(256), 0, stream>>>(
      A0s8, A0s8T, nullptr, zpage, N0, N0, A1, 0, N0, N0, N0);
  k_transpose_i8s<<<dim3(64, 64), dim3(256), 0, stream>>>(A1, A1T, N0, 2);

  // ---- gcn1 ----
  k_widen_f32_f64<<<dim3(512), dim3(256), 0, stream>>>(x0f, xB, N0 * CIN);
  {
    dim3 b(16, 16);
    k_gemm_xw32<<<dim3(HID / 64, (N0 + 31) / 32), b, 0, stream>>>(xB, W0, tb, N0, HID, CIN);
    k_degdinv<char><<<dim3(N0), dim3(256), 0, stream>>>(A1, N0, dinv, N0, wmax, nullptr);
    k_wmax<<<dim3(256), dim3(256), 0, stream>>>(tb, dinv, wmax, N0, HID);
    k_digitize8<DNUM><<<dim3(N0 / 64, HID / 64), dim3(256), 0, stream>>>(tb, dinv, wmax, wdT1, N0, N0, HID);
    k_axw_pipe8<<<dim3(DNUM * HID / 128, N0 / 128), dim3(256), 0, stream>>>(A1, wdT1, N0, P1, DNUM * HID);
    k_reduce_fin<<<dim3(N0), dim3(256), 0, stream>>>(P1, wmax, nullptr, tb, dinv, b0, xA,
                                                     DNUM * HID, HID, DNUM, 0, 1, 1.0, 0.0, 1);
  }

  // ---- pool1 ----
  k_scores<<<dim3(N0), dim3(256), 0, stream>>>(xA, p1, sc, HID, nullptr);
  k_topk<<<dim3(1), dim3(1024), 0, stream>>>(sc, N0, perm, vals);
  k_gather_x<<<dim3(K1P), dim3(256), 0, stream>>>(xA, perm, vals, xB, HID);

  // ---- aug2: A2s8 hi/lo = base-128 split of offdiag(A1@(A1+2I))[perm x perm] ----
  k_aug_pipe8<1><<<dim3(26, 26), dim3(256), 0, stream>>>(
      A1, A1T, perm, zpage, N0, N0, A2s8, PL2, KI2, K1P, K1P);
  k_transpose_i8s<<<dim3(52, 52), dim3(256), 0, stream>>>(A2s8, A2s8T, KI2, 0);
  k_transpose_i8s<<<dim3(52, 52), dim3(256), 0, stream>>>(A2s8 + PL2, A2s8T + PL2, KI2, 2);

  // ---- gcn2 ----
  {
    dim3 b(16, 16);
    k_gemm_xw32<<<dim3(HID / 64, (K1P + 31) / 32), b, 0, stream>>>(xB, W1, tb, K1P, HID, HID);
    k_degdinv2p<<<dim3(K1P), dim3(256), 0, stream>>>(A2s8, KI2, dinv, K1P, wmax);
    k_wmax<<<dim3(256), dim3(256), 0, stream>>>(tb, dinv, wmax, K1P, HID);
    k_digitize8<DNUM><<<dim3(KI2 / 64, HID / 64), dim3(256), 0, stream>>>(tb, dinv, wmax, wdT2, K1P, KI2, HID);
    k_axw_pipe8<<<dim3(DNUM * HID / 128, 2 * KI2 / 128), dim3(256), 0, stream>>>(A2s8, wdT2, KI2, P2, DNUM * HID);
    k_reduce_fin<<<dim3(K1P), dim3(256), 0, stream>>>(P2, wmax, nullptr, tb, dinv, b1, xA,
                                                      DNUM * HID, HID, DNUM, KI2, 2, 128.0, 1.0, 1);
  }

  // ---- pool2 (scores also resets a3max for aug3) ----
  k_scores<<<dim3(K1P), dim3(256), 0, stream>>>(xA, p2, sc, HID, a3max);
  k_topk<<<dim3(1), dim3(1024), 0, stream>>>(sc, K1P, permB, vals);
  k_gather_x<<<dim3(K2P), dim3(256), 0, stream>>>(xA, permB, vals, xB, HID);

  // ---- aug3: exact i8 4-plane, fused a3max ----
  k_aug3_pipe8<<<dim3(16, 16), dim3(512), 0, stream>>>(
      A2s8, A2s8T, permB, zpage, KI2, A3p, a3max, K2P, K2P, LD3);

  // ---- gcn3 ----
  {
    dim3 b(16, 16);
    k_gemm_xw32<<<dim3(HID / 64, (K2P + 31) / 32), b, 0, stream>>>(xB, W2, tb, K2P, HID, HID);
    k_degdinv<float><<<dim3(K2P), dim3(256), 0, stream>>>(A3p, LD3, dinv, K2P, wmax, nullptr);
    k_splitA8s<<<dim3(KI3), dim3(256), 0, stream>>>(A3p, K2P, LD3, a3max, A3stack, KI3);
    k_wmax<<<dim3(256), dim3(256), 0, stream>>>(tb, dinv, wmax, K2P, HID);
    k_digitize8<2><<<dim3(KI3 / 64, HID / 64), dim3(256), 0, stream>>>(tb, dinv, wmax, wdT3, K2P, KI3, HID);
    k_axw_pipe8<<<dim3(2 * HID / 128, 2 * KI3 / 128), dim3(256), 0, stream>>>(A3stack, wdT3, KI3, P3, 2 * HID);
    k_reduce_fin<<<dim3(K2P), dim3(256), 0, stream>>>(P3, wmax, a3max, tb, dinv, b2, xA,
                                                      2 * HID, HID, 2, KI3, 2, 128.0, 1.0, 1);
  }

  // ---- gcn_out (reuse dinv, a3max, A3stack) ----
  {
    dim3 b(16, 16);
    k_gemm_xw32<<<dim3(COUTC / 64, (K2P + 31) / 32), b, 0, stream>>>(xA, Wout, tb, K2P, COUTC, HID);
    k_reset_u32<<<dim3(1), dim3(64), 0, stream>>>(wmax);
    k_wmax<<<dim3(256), dim3(256), 0, stream>>>(tb, dinv, wmax, K2P, COUTC);
    k_digitize8<2><<<dim3(KI3 / 64, COUTC / 64), dim3(256), 0, stream>>>(tb, dinv, wmax, wdT3, K2P, KI3, COUTC);
    k_axw_pipe8<<<dim3(2 * COUTC / 128, 2 * KI3 / 128), dim3(256), 0, stream>>>(A3stack, wdT3, KI3, P3, 2 * COUTC);
    k_reduce_fin<<<dim3(K2P), dim3(256), 0, stream>>>(P3, wmax, a3max, tb, dinv, bout, xB,
                                                      2 * COUTC, COUTC, 2, KI3, 2, 128.0, 1.0, 0);
  }

  k_write_out<<<dim3(1024), dim3(256), 0, stream>>>(xB, (float*)d_out, K2P * COUTC, out_size);
}

// Round 12
// 717.141 us; speedup vs baseline: 11.6699x; 1.1954x over previous
//
#include <hip/hip_runtime.h>
#include <math.h>

#define N0    4096
#define CIN   128
#define HID   256
#define COUTC 128
#define K1P   3277   // ceil(0.8*4096)
#define K2P   1967   // ceil(0.6*3277)
#define LD3   1968   // K2P padded to 4-float rows
#define KI2   3328   // K1P padded to mult of 64
#define KI3   1984   // K2P padded to mult of 64
#define DNUM  8      // digit planes, base-128 -> 56 bits

typedef __attribute__((ext_vector_type(4))) int i32x4;

__device__ __forceinline__ void gl2lds16(const void* g, void* l) {
  __builtin_amdgcn_global_load_lds((const __attribute__((address_space(1))) void*)g,
                                   (__attribute__((address_space(3))) void*)l, 16, 0, 0);
}

// ---------------- build / elementwise ----------------

__global__ void k_zero32(float* __restrict__ p, size_t n) {
  size_t i = (size_t)blockIdx.x * blockDim.x + threadIdx.x;
  size_t st = (size_t)gridDim.x * blockDim.x;
  for (; i < n; i += st) p[i] = 0.0f;
}

__global__ void k_widen_f32_f64(const float* __restrict__ in, double* __restrict__ out, int n) {
  int i = blockIdx.x * blockDim.x + threadIdx.x;
  int st = gridDim.x * blockDim.x;
  for (; i < n; i += st) out[i] = (double)in[i];
}

__global__ void k_build_adj(const int* __restrict__ ei, float* __restrict__ A, int E, int n) {
  int e = blockIdx.x * blockDim.x + threadIdx.x;
  if (e < E) atomicAdd(&A[(size_t)ei[E + e] * n + ei[e]], 1.0f);
}

// A0 f32 -> A0s8 i8 + A0s8T i8 (transposed, +2 folded on diag). Small ints, exact.
__global__ __launch_bounds__(256) void k_transpose_split_i8(
    const float* __restrict__ A, char* __restrict__ B, char* __restrict__ BT) {
  __shared__ char sm[64][68];
  const int t = threadIdx.x;
  const int r0 = blockIdx.y * 64, c0 = blockIdx.x * 64;
  const int rr = t >> 2, cs = (t & 3) * 16;
  char tmp[16];
#pragma unroll
  for (int j = 0; j < 16; ++j) {
    char v = (char)(int)A[(size_t)(r0 + rr) * N0 + c0 + cs + j];
    tmp[j] = v;
    sm[cs + j][rr] = v;
  }
  *(int4*)&B[(size_t)(r0 + rr) * N0 + c0 + cs] = *(int4*)&tmp[0];
  __syncthreads();
  const int cc = t >> 2, rs = (t & 3) * 16;
  const int orow = c0 + cc;
  char o[16];
#pragma unroll
  for (int q = 0; q < 16; ++q) {
    char v = sm[cc][rs + q];
    if (r0 + rs + q == orow) v = (char)(v + 2);
    o[q] = v;
  }
  *(int4*)&BT[(size_t)orow * N0 + r0 + rs] = *(int4*)&o[0];
}

// i8 square transpose (n mult of 64) with integer diag fold
__global__ __launch_bounds__(256) void k_transpose_i8s(
    const char* __restrict__ A, char* __restrict__ BT, int n, int fold) {
  __shared__ char sm[64][68];
  const int t = threadIdx.x;
  const int r0 = blockIdx.y * 64, c0 = blockIdx.x * 64;
  const int rr = t >> 2, cs = (t & 3) * 16;
  {
    int4 v = *(const int4*)&A[(size_t)(r0 + rr) * n + c0 + cs];
    char* vb = (char*)&v;
#pragma unroll
    for (int j = 0; j < 16; ++j) sm[cs + j][rr] = vb[j];
  }
  __syncthreads();
  const int cc = t >> 2, rs = (t & 3) * 16;
  const int orow = c0 + cc;
  char o[16];
#pragma unroll
  for (int q = 0; q < 16; ++q) {
    char v = sm[cc][rs + q];
    if (r0 + rs + q == orow) v = (char)(v + fold);
    o[q] = v;
  }
  *(int4*)&BT[(size_t)orow * n + r0 + rs] = *(int4*)&o[0];
}

// -------- i8 pipelined augment, direct register epilogue (straight planes only) --------
template <int MODE>
__global__ __launch_bounds__(256) void k_aug_pipe8(
    const char* __restrict__ Asrc, const char* __restrict__ Btsrc,
    const int* __restrict__ perm, const char* __restrict__ zrow,
    int K, int ldk,
    char* __restrict__ O, size_t plane, int ldo,
    int M, int N)
{
  __shared__ __align__(16) char Ls[2][2][8192];
  const int tid = threadIdx.x;
  const int wave = tid >> 6, lane = tid & 63;
  const int wr = wave >> 1, wc = wave & 1;
  const int brow = blockIdx.y * 128, bcol = blockIdx.x * 128;
  const int lr = lane & 15, ko = (lane >> 4) * 16;
  const int koff = (lane & 3) * 16;

  const char* pA[2];
  const char* pB[2];
#pragma unroll
  for (int c = 0; c < 2; ++c) {
    int r = (c * 4 + wave) * 16 + (lane >> 2);
    int ra = brow + r, rb = bcol + r;
    int ia, ib;
    if (MODE == 0) { ia = ra; ib = rb; }
    else {
      ia = (ra < M) ? perm[ra] : -1;
      ib = (rb < N) ? perm[rb] : -1;
    }
    pA[c] = (ia >= 0) ? Asrc + (size_t)ia * ldk : zrow;
    pB[c] = (ib >= 0) ? Btsrc + (size_t)ib * ldk : zrow;
  }

  i32x4 acc[4][4];
#pragma unroll
  for (int m = 0; m < 4; ++m)
#pragma unroll
    for (int n = 0; n < 4; ++n) acc[m][n] = (i32x4){0, 0, 0, 0};

  auto STAGE = [&](int buf, int kt) {
#pragma unroll
    for (int c = 0; c < 2; ++c) {
      int f = c * 4 + wave;
      gl2lds16(pA[c] + kt + koff, &Ls[buf][0][f * 1024]);
      gl2lds16(pB[c] + kt + koff, &Ls[buf][1][f * 1024]);
    }
  };

  STAGE(0, 0);
  __syncthreads();
  int cur = 0;
  for (int kt = 0; kt < K; kt += 64) {
    if (kt + 64 < K) STAGE(cur ^ 1, kt + 64);
    i32x4 a0[4], b0[4];
#pragma unroll
    for (int m = 0; m < 4; ++m) a0[m] = *(const i32x4*)&Ls[cur][0][(wr * 64 + m * 16 + lr) * 64 + ko];
#pragma unroll
    for (int n = 0; n < 4; ++n) b0[n] = *(const i32x4*)&Ls[cur][1][(wc * 64 + n * 16 + lr) * 64 + ko];
#pragma unroll
    for (int m = 0; m < 4; ++m)
#pragma unroll
      for (int n = 0; n < 4; ++n)
        acc[m][n] = __builtin_amdgcn_mfma_i32_16x16x64_i8(a0[m], b0[n], acc[m][n], 0, 0, 0);
    __syncthreads();
    cur ^= 1;
  }

#pragma unroll
  for (int m = 0; m < 4; ++m)
#pragma unroll
    for (int n = 0; n < 4; ++n)
#pragma unroll
      for (int q = 0; q < 4; ++q) {
        int grow = brow + wr * 64 + m * 16 + (lane >> 4) * 4 + q;
        int gcol = bcol + wc * 64 + n * 16 + lr;
        int v = acc[m][n][q];
        if (MODE == 0) {
          if (grow == gcol) v = 0;
          O[(size_t)grow * ldo + gcol] = (char)v;
        } else {
          if (grow >= M || gcol >= N || grow == gcol) v = 0;
          O[(size_t)grow * ldo + gcol] = (char)(v >> 7);
          O[plane + (size_t)grow * ldo + gcol] = (char)(v & 127);
        }
      }
}

// aug3 (i8, exact): A3 = (128H+L) @ (128H'+(L'+2I)) = 16384 HH' + 128 (HL'+LH') + LL'.
__global__ __launch_bounds__(512) void k_aug3_pipe8(
    const char* __restrict__ S, const char* __restrict__ ST,
    const int* __restrict__ perm, const char* __restrict__ zrow,
    int Kpad, float* __restrict__ Cf, unsigned* __restrict__ amax,
    int M, int N, int ldcp)
{
  __shared__ __align__(16) char Ls[2][4][8192];
  const int tid = threadIdx.x;
  const int wave = tid >> 6, lane = tid & 63;
  const int wr = wave >> 1, wc = wave & 1;
  const int brow = blockIdx.y * 128, bcol = blockIdx.x * 128;
  const int lr = lane & 15, ko = (lane >> 4) * 16;
  const int koff = (lane & 3) * 16;
  const size_t plane = (size_t)Kpad * Kpad;

  const char *pAh, *pAl, *pBh, *pBl;
  {
    int r = (wave << 4) + (lane >> 2);
    int ra = brow + r, rb = bcol + r;
    int ia = (ra < M) ? perm[ra] : -1;
    int ib = (rb < N) ? perm[rb] : -1;
    pAh = (ia >= 0) ? S + (size_t)ia * Kpad : zrow;
    pAl = (ia >= 0) ? S + plane + (size_t)ia * Kpad : zrow;
    pBh = (ib >= 0) ? ST + (size_t)ib * Kpad : zrow;
    pBl = (ib >= 0) ? ST + plane + (size_t)ib * Kpad : zrow;
  }

  i32x4 hh[2][4], mid[2][4], ll[2][4];
#pragma unroll
  for (int m = 0; m < 2; ++m)
#pragma unroll
    for (int n = 0; n < 4; ++n) {
      hh[m][n] = (i32x4){0, 0, 0, 0};
      mid[m][n] = (i32x4){0, 0, 0, 0};
      ll[m][n] = (i32x4){0, 0, 0, 0};
    }

  auto STAGE = [&](int buf, int kt) {
    int f = wave * 1024;
    gl2lds16(pAh + kt + koff, &Ls[buf][0][f]);
    gl2lds16(pBh + kt + koff, &Ls[buf][1][f]);
    gl2lds16(pAl + kt + koff, &Ls[buf][2][f]);
    gl2lds16(pBl + kt + koff, &Ls[buf][3][f]);
  };

  STAGE(0, 0);
  __syncthreads();
  int cur = 0;
  for (int kt = 0; kt < Kpad; kt += 64) {
    if (kt + 64 < Kpad) STAGE(cur ^ 1, kt + 64);
    i32x4 ah[2], al[2], bh[4], bl[4];
#pragma unroll
    for (int m = 0; m < 2; ++m) {
      ah[m] = *(const i32x4*)&Ls[cur][0][(wr * 32 + m * 16 + lr) * 64 + ko];
      al[m] = *(const i32x4*)&Ls[cur][2][(wr * 32 + m * 16 + lr) * 64 + ko];
    }
#pragma unroll
    for (int n = 0; n < 4; ++n) {
      bh[n] = *(const i32x4*)&Ls[cur][1][(wc * 64 + n * 16 + lr) * 64 + ko];
      bl[n] = *(const i32x4*)&Ls[cur][3][(wc * 64 + n * 16 + lr) * 64 + ko];
    }
#pragma unroll
    for (int m = 0; m < 2; ++m)
#pragma unroll
      for (int n = 0; n < 4; ++n) {
        hh[m][n]  = __builtin_amdgcn_mfma_i32_16x16x64_i8(ah[m], bh[n], hh[m][n], 0, 0, 0);
        mid[m][n] = __builtin_amdgcn_mfma_i32_16x16x64_i8(ah[m], bl[n], mid[m][n], 0, 0, 0);
        mid[m][n] = __builtin_amdgcn_mfma_i32_16x16x64_i8(al[m], bh[n], mid[m][n], 0, 0, 0);
        ll[m][n]  = __builtin_amdgcn_mfma_i32_16x16x64_i8(al[m], bl[n], ll[m][n], 0, 0, 0);
      }
    __syncthreads();
    cur ^= 1;
  }

  float mloc = 0.0f;
#pragma unroll
  for (int m = 0; m < 2; ++m)
#pragma unroll
    for (int n = 0; n < 4; ++n)
#pragma unroll
      for (int q = 0; q < 4; ++q) {
        int grow = brow + wr * 32 + m * 16 + (lane >> 4) * 4 + q;
        int gcol = bcol + wc * 64 + n * 16 + lr;
        if (grow < M && gcol < ldcp) {
          float v = 16384.0f * (float)hh[m][n][q] + 128.0f * (float)mid[m][n][q] + (float)ll[m][n][q];
          if (gcol >= N || grow == gcol) v = 0.0f;
          Cf[(size_t)grow * ldcp + gcol] = v;
          mloc = fmaxf(mloc, v);
        }
      }
  __syncthreads();
  float* red = (float*)&Ls[0][0][0];
  red[tid] = mloc;
  __syncthreads();
  for (int st = 256; st > 0; st >>= 1) {
    if (tid < st) red[tid] = fmaxf(red[tid], red[tid + st]);
    __syncthreads();
  }
  if (tid == 0) atomicMax(amax, __builtin_bit_cast(unsigned, red[0]));
}

// ---------------- f64 x@W (32x64 tiles) ----------------

__global__ __launch_bounds__(256) void k_gemm_xw32(
    const double* __restrict__ X, const float* __restrict__ W, double* __restrict__ C,
    int M, int N, int K) {
  __shared__ double As[16][32];
  __shared__ double Bs[16][64];
  const int tx = threadIdx.x, ty = threadIdx.y;
  const int tid = ty * 16 + tx;
  const int brow = blockIdx.y * 32, bcol = blockIdx.x * 64;
  double acc[2][4];
#pragma unroll
  for (int i = 0; i < 2; ++i)
#pragma unroll
    for (int j = 0; j < 4; ++j) acc[i][j] = 0.0;
  const int lac = tid & 15, lar = tid >> 4;
  const int lbc = tid & 63, lbr = tid >> 6;
  for (int kt = 0; kt < K; kt += 16) {
#pragma unroll
    for (int rr = 0; rr < 2; ++rr) {
      int r = lar + rr * 16;
      int gr = brow + r, gk = kt + lac;
      As[lac][r] = (gr < M && gk < K) ? X[(size_t)gr * K + gk] : 0.0;
    }
#pragma unroll
    for (int rr = 0; rr < 4; ++rr) {
      int br = lbr + rr * 4;
      int gk = kt + br, gc = bcol + lbc;
      Bs[br][lbc] = (gk < K && gc < N) ? (double)W[(size_t)gk * N + gc] : 0.0;
    }
    __syncthreads();
#pragma unroll
    for (int kk = 0; kk < 16; ++kk) {
      double a[2], b[4];
#pragma unroll
      for (int i = 0; i < 2; ++i) a[i] = As[kk][ty * 2 + i];
#pragma unroll
      for (int j = 0; j < 4; ++j) b[j] = Bs[kk][tx * 4 + j];
#pragma unroll
      for (int i = 0; i < 2; ++i)
#pragma unroll
        for (int j = 0; j < 4; ++j) acc[i][j] = fma(a[i], b[j], acc[i][j]);
    }
    __syncthreads();
  }
#pragma unroll
  for (int i = 0; i < 2; ++i) {
    int gr = brow + ty * 2 + i;
    if (gr >= M) continue;
#pragma unroll
    for (int j = 0; j < 4; ++j) {
      int gc = bcol + tx * 4 + j;
      if (gc >= N) continue;
      C[(size_t)gr * N + gc] = acc[i][j];
    }
  }
}

// ---------------- digit machinery (i8, base-128) ----------------

__global__ void k_reset_u32(unsigned* p) { if (threadIdx.x == 0 && blockIdx.x == 0) *p = 0u; }

__global__ void k_wmax(const double* __restrict__ t, const double* __restrict__ dinv,
                       unsigned* __restrict__ wmax, int K, int N) {
  __shared__ float red[256];
  float mx = 0.0f;
  int tot = K * N;
  for (int i = blockIdx.x * 256 + threadIdx.x; i < tot; i += gridDim.x * 256) {
    double w = dinv[i / N] * t[i];
    mx = fmaxf(mx, (float)fabs(w));
  }
  red[threadIdx.x] = mx;
  __syncthreads();
  for (int st = 128; st > 0; st >>= 1) {
    if (threadIdx.x < st) red[threadIdx.x] = fmaxf(red[threadIdx.x], red[threadIdx.x + st]);
    __syncthreads();
  }
  if (threadIdx.x == 0) atomicMax(wmax, __builtin_bit_cast(unsigned, red[0]));
}

template <int D>
__global__ __launch_bounds__(256) void k_digitize8(
    const double* __restrict__ t, const double* __restrict__ dinv,
    const unsigned* __restrict__ wmax, char* __restrict__ wdT,
    int K, int Kpad, int N) {
  __shared__ char sm[D][64][68];
  const int tid = threadIdx.x;
  const int k0 = blockIdx.x * 64, n0 = blockIdx.y * 64;
  float wm = __builtin_bit_cast(float, *wmax);
  double sc = (wm > 0.0f) ? scalbn(1.0, -(ilogbf(wm) + 2)) : 0.0;
  const int kk = tid >> 2, ns = (tid & 3) * 16;
  int k = k0 + kk;
  double dv = (k < K) ? dinv[k] : 0.0;
#pragma unroll
  for (int j = 0; j < 16; ++j) {
    int n = n0 + ns + j;
    double w = (k < K) ? dv * t[(size_t)k * N + n] : 0.0;
    double r = w * sc;
#pragma unroll
    for (int d = 0; d < D; ++d) {
      double rm = r * 128.0;
      double m = rint(rm);
      sm[d][kk][ns + j] = (char)(int)m;
      r = rm - m;
    }
  }
  __syncthreads();
  const int nn = tid >> 2, ks = (tid & 3) * 16;
  const size_t PS = (size_t)N * Kpad;
#pragma unroll
  for (int d = 0; d < D; ++d) {
    char o[16];
#pragma unroll
    for (int j = 0; j < 16; ++j) o[j] = sm[d][ks + j][nn];
    *(int4*)&wdT[d * PS + (size_t)(n0 + nn) * Kpad + k0 + ks] = *(int4*)&o[0];
  }
}

// A3p f32 (nonneg, values-path) -> scaled 14-bit base-128 i8 planes.
__global__ void k_splitA8s(const float* __restrict__ A, int M, int ldsrc,
                           const unsigned* __restrict__ amax,
                           char* __restrict__ S, int Kpad) {
  int r = blockIdx.x;
  const size_t plane = (size_t)Kpad * Kpad;
  float am = __builtin_bit_cast(float, *amax);
  float s13 = (am > 0.0f) ? scalbnf(1.0f, 13 - (ilogbf(am) + 1)) : 0.0f;
  for (int c4 = threadIdx.x * 4; c4 < Kpad; c4 += blockDim.x * 4) {
    float v[4] = {0.f, 0.f, 0.f, 0.f};
    if (r < M && c4 < ldsrc) *(float4*)v = *(const float4*)(A + (size_t)r * ldsrc + c4);
    unsigned hw = 0, lw = 0;
#pragma unroll
    for (int q = 0; q < 4; ++q) {
      int iv = (int)rintf(v[q] * s13);
      int h = iv >> 7, l = iv - (h << 7);
      hw |= ((unsigned)(unsigned char)(char)h) << (8 * q);
      lw |= ((unsigned)(unsigned char)(char)l) << (8 * q);
    }
    *(unsigned*)(S + (size_t)r * Kpad + c4) = hw;
    *(unsigned*)(S + plane + (size_t)r * Kpad + c4) = lw;
  }
}

// P[Mp][Neff] i32 = A[Mp][Kpad] i8 @ wdT[Neff][Kpad]^T — DMA-pipelined i8 GEMM, exact.
__global__ __launch_bounds__(256) void k_axw_pipe8(
    const char* __restrict__ Asrc, const char* __restrict__ Bsrc,
    int Kpad, int* __restrict__ P, int Neff)
{
  __shared__ __align__(16) char Ls[2][2][8192];
  const int tid = threadIdx.x;
  const int wave = tid >> 6, lane = tid & 63;
  const int wr = wave >> 1, wc = wave & 1;
  const int brow = blockIdx.y * 128, bcol = blockIdx.x * 128;
  const int lr = lane & 15, ko = (lane >> 4) * 16;
  const int koff = (lane & 3) * 16;

  const char* pA[2];
  const char* pB[2];
#pragma unroll
  for (int c = 0; c < 2; ++c) {
    int r = (c * 4 + wave) * 16 + (lane >> 2);
    pA[c] = Asrc + (size_t)(brow + r) * Kpad;
    pB[c] = Bsrc + (size_t)(bcol + r) * Kpad;
  }

  i32x4 acc[4][4];
#pragma unroll
  for (int m = 0; m < 4; ++m)
#pragma unroll
    for (int n = 0; n < 4; ++n) acc[m][n] = (i32x4){0, 0, 0, 0};

  auto STAGE = [&](int buf, int kt) {
#pragma unroll
    for (int c = 0; c < 2; ++c) {
      int f = c * 4 + wave;
      gl2lds16(pA[c] + kt + koff, &Ls[buf][0][f * 1024]);
      gl2lds16(pB[c] + kt + koff, &Ls[buf][1][f * 1024]);
    }
  };

  STAGE(0, 0);
  __syncthreads();
  int cur = 0;
  for (int kt = 0; kt < Kpad; kt += 64) {
    if (kt + 64 < Kpad) STAGE(cur ^ 1, kt + 64);
    i32x4 a0[4], b0[4];
#pragma unroll
    for (int m = 0; m < 4; ++m) a0[m] = *(const i32x4*)&Ls[cur][0][(wr * 64 + m * 16 + lr) * 64 + ko];
#pragma unroll
    for (int n = 0; n < 4; ++n) b0[n] = *(const i32x4*)&Ls[cur][1][(wc * 64 + n * 16 + lr) * 64 + ko];
#pragma unroll
    for (int m = 0; m < 4; ++m)
#pragma unroll
      for (int n = 0; n < 4; ++n)
        acc[m][n] = __builtin_amdgcn_mfma_i32_16x16x64_i8(a0[m], b0[n], acc[m][n], 0, 0, 0);
    __syncthreads();
    cur ^= 1;
  }

#pragma unroll
  for (int m = 0; m < 4; ++m)
#pragma unroll
    for (int n = 0; n < 4; ++n)
#pragma unroll
      for (int q = 0; q < 4; ++q) {
        int grow = brow + wr * 64 + m * 16 + (lane >> 4) * 4 + q;
        int gcol = bcol + wc * 64 + n * 16 + lr;
        P[(size_t)grow * Neff + gcol] = acc[m][n][q];
      }
}

// fused reduce_y + gcn_fin: out = relu?( d*(y + 2*d*t) + b ), y from digit planes.
__global__ void k_reduce_fin(const int* __restrict__ P, const unsigned* __restrict__ wmax,
                             const unsigned* __restrict__ amax,
                             const double* __restrict__ t, const double* __restrict__ dinv,
                             const float* __restrict__ bias, double* __restrict__ out,
                             int Neff, int N, int D, int M0pad, int nplane,
                             double w0, double w1, int relu) {
  int m = blockIdx.x;
  float wm = __builtin_bit_cast(float, *wmax);
  double s0 = w0, s1 = w1;
  bool zero = (wm <= 0.0f);
  if (amax) {
    float am = __builtin_bit_cast(float, *amax);
    if (am > 0.0f) {
      int EA = ilogbf(am) + 1;
      s0 = scalbn(w0, EA - 13);
      s1 = scalbn(w1, EA - 13);
    } else zero = true;
  }
  int Ep = zero ? 0 : (ilogbf(wm) + 2);
  double d = dinv[m];
  for (int n = threadIdx.x; n < N; n += blockDim.x) {
    double acc = 0.0;
    if (!zero) {
      for (int dd = 0; dd < D; ++dd) {
        double v = s0 * (double)P[(size_t)m * Neff + dd * N + n];
        if (nplane == 2) v += s1 * (double)P[(size_t)(M0pad + m) * Neff + dd * N + n];
        acc += scalbn(v, Ep - 7 * (dd + 1));
      }
    }
    double v = d * (acc + 2.0 * d * t[(size_t)m * N + n]) + (double)bias[n];
    if (relu) v = v > 0.0 ? v : 0.0;
    out[(size_t)m * N + n] = v;
  }
}

// ---------------- GCN tail / pooling ----------------

template <typename TA>
__device__ __forceinline__ float a_as_f32(TA v);
template <> __device__ __forceinline__ float a_as_f32<char>(char v) { return (float)v; }
template <> __device__ __forceinline__ float a_as_f32<float>(float v) { return v; }

template <typename TA>
__global__ void k_degdinv(const TA* __restrict__ A, int lda, double* __restrict__ dinv, int n,
                          unsigned* __restrict__ rst0, unsigned* __restrict__ rst1) {
  if (blockIdx.x == 0 && threadIdx.x == 0) {
    if (rst0) *rst0 = 0u;
    if (rst1) *rst1 = 0u;
  }
  __shared__ double red[256];
  int row = blockIdx.x;
  double s = 0.0;
  for (int j = threadIdx.x; j < n; j += 256) s += (double)a_as_f32<TA>(A[(size_t)row * lda + j]);
  red[threadIdx.x] = s;
  __syncthreads();
  for (int st = 128; st > 0; st >>= 1) {
    if (threadIdx.x < st) red[threadIdx.x] += red[threadIdx.x + st];
    __syncthreads();
  }
  if (threadIdx.x == 0) {
    double deg = red[0] + 2.0;
    dinv[row] = (deg > 0.0) ? 1.0 / sqrt(deg) : 0.0;
  }
}

// dinv from 2-plane i8 (128*h + l): exact integer row sums, identical to f32 path.
__global__ void k_degdinv2p(const char* __restrict__ S, int Kpad, double* __restrict__ dinv,
                            int n, unsigned* __restrict__ rst0) {
  if (blockIdx.x == 0 && threadIdx.x == 0 && rst0) *rst0 = 0u;
  __shared__ double red[256];
  const size_t plane = (size_t)Kpad * Kpad;
  int row = blockIdx.x;
  const char* h = S + (size_t)row * Kpad;
  const char* l = S + plane + (size_t)row * Kpad;
  long s = 0;
  for (int j = threadIdx.x; j < n; j += 256) s += 128 * (long)h[j] + (long)l[j];
  red[threadIdx.x] = (double)s;
  __syncthreads();
  for (int st = 128; st > 0; st >>= 1) {
    if (threadIdx.x < st) red[threadIdx.x] += red[threadIdx.x + st];
    __syncthreads();
  }
  if (threadIdx.x == 0) {
    double deg = red[0] + 2.0;
    dinv[row] = (deg > 0.0) ? 1.0 / sqrt(deg) : 0.0;
  }
}

// scores with fused ||p||; optional reset of a max accumulator for a LATER kernel
__global__ void k_scores(const double* __restrict__ x, const float* __restrict__ p,
                         double* __restrict__ sc, int C, unsigned* __restrict__ rst) {
  if (blockIdx.x == 0 && threadIdx.x == 0 && rst) *rst = 0u;
  __shared__ double red[256], red2[256];
  int row = blockIdx.x;
  double s = 0.0, s2 = 0.0;
  for (int j = threadIdx.x; j < C; j += 256) {
    double pv = (double)p[j];
    s += x[(size_t)row * C + j] * pv;
    s2 += pv * pv;
  }
  red[threadIdx.x] = s;
  red2[threadIdx.x] = s2;
  __syncthreads();
  for (int st = 128; st > 0; st >>= 1) {
    if (threadIdx.x < st) {
      red[threadIdx.x] += red[threadIdx.x + st];
      red2[threadIdx.x] += red2[threadIdx.x + st];
    }
    __syncthreads();
  }
  if (threadIdx.x == 0) sc[row] = tanh(red[0] / sqrt(red2[0]));
}

// rank-count top-k: rank(i) = #{j : s_j > s_i or (s_j == s_i and j < i)}.
// Bijection onto [0,n) under total order (score desc, idx asc) -> identical
// output to the bitonic full sort, but fully parallel (one block per element).
__global__ __launch_bounds__(256) void k_topk_rank(
    const double* __restrict__ sc, int n, int k,
    int* __restrict__ perm, double* __restrict__ vals) {
  __shared__ int red[256];
  const int i = blockIdx.x;
  const double si = sc[i];
  int cnt = 0;
  for (int j = threadIdx.x; j < n; j += 256) {
    double sj = sc[j];
    if (sj > si || (sj == si && j < i)) ++cnt;
  }
  red[threadIdx.x] = cnt;
  __syncthreads();
  for (int st = 128; st > 0; st >>= 1) {
    if (threadIdx.x < st) red[threadIdx.x] += red[threadIdx.x + st];
    __syncthreads();
  }
  if (threadIdx.x == 0) {
    int rank = red[0];
    if (rank < k) { perm[rank] = i; vals[rank] = si; }
  }
}

__global__ void k_gather_x(const double* __restrict__ x, const int* __restrict__ perm,
                           const double* __restrict__ vals, double* __restrict__ xo, int C) {
  int row = blockIdx.x;
  int src = perm[row];
  double v = vals[row];
  for (int c = threadIdx.x; c < C; c += blockDim.x)
    xo[(size_t)row * C + c] = x[(size_t)src * C + c] * v;
}

__global__ void k_write_out(const double* __restrict__ x, float* __restrict__ out,
                            int nvals, int total) {
  int i = blockIdx.x * blockDim.x + threadIdx.x;
  int st = gridDim.x * blockDim.x;
  for (; i < total; i += st) out[i] = (i < nvals) ? (float)x[i] : 0.0f;
}

__global__ void k_sentinel(float* __restrict__ out, int total) {
  int i = blockIdx.x * blockDim.x + threadIdx.x;
  int st = gridDim.x * blockDim.x;
  for (; i < total; i += st) out[i] = 1e30f;
}

// ---------------- driver ----------------

extern "C" void kernel_launch(void* const* d_in, const int* in_sizes, int n_in,
                              void* d_out, int out_size, void* d_ws, size_t ws_size,
                              hipStream_t stream) {
  const float* x0f  = (const float*)d_in[0];
  const int*   ei   = (const int*)d_in[1];
  const float* W0   = (const float*)d_in[2];
  const float* b0   = (const float*)d_in[3];
  const float* W1   = (const float*)d_in[4];
  const float* b1   = (const float*)d_in[5];
  const float* W2   = (const float*)d_in[6];
  const float* b2   = (const float*)d_in[7];
  const float* p1   = (const float*)d_in[8];
  const float* p2   = (const float*)d_in[9];
  const float* Wout = (const float*)d_in[10];
  const float* bout = (const float*)d_in[11];
  const int E = in_sizes[1] / 2;

  const size_t MiB = 1ull << 20;
  if (ws_size < 160 * MiB) {
    k_sentinel<<<dim3(256), dim3(256), 0, stream>>>((float*)d_out, out_size);
    return;
  }
  char* W = (char*)d_ws;
  const size_t PL2 = (size_t)KI2 * KI2;
  // epoch A: build + aug1
  float* A0    = (float*)(W + 0);
  char*  A0s8  = (char*)(W + 64 * MiB);
  char*  A0s8T = (char*)(W + 80 * MiB);
  // epoch A2: gcn1
  char*  A1    = (char*)(W + 0);
  char*  A1T   = (char*)(W + 16 * MiB);
  char*  wdT1  = (char*)(W + 32 * MiB);
  int*   P1    = (int*)(W + 40 * MiB);
  // epoch B: aug2 + gcn2
  char*  A2s8  = (char*)(W + 64 * MiB);
  char*  A2s8T = (char*)(W + 86 * MiB);
  char*  wdT2  = (char*)(W + 0);
  int*   P2    = (int*)(W + 7 * MiB);
  // epoch C: aug3 + gcn3/out
  float* A3p     = (float*)(W + 108 * MiB);
  char*  A3stack = (char*)(W + 0);
  char*  wdT3    = (char*)(W + 8 * MiB);
  int*   P3      = (int*)(W + 10 * MiB);
  // features
  double* tb   = (double*)(W + 128 * MiB);
  double* xA   = (double*)(W + 144 * MiB);
  double* xB   = (double*)(W + 152 * MiB);
  char* SM = W + (159 * MiB + 256 * 1024);
  double* dinv = (double*)(SM);
  double* sc   = (double*)(SM + 32768);
  double* vals = (double*)(SM + 65536);
  unsigned* wmax  = (unsigned*)(SM + 98304 + 128);
  unsigned* a3max = (unsigned*)(SM + 98304 + 192);
  int* perm    = (int*)(SM + 98304 + 256);
  int* permB   = (int*)(SM + 98304 + 256 + 16384);
  char* zpage  = (char*)(W + 159 * MiB + 512 * 1024);

  // ---- build A0, i8 split+transpose ----
  k_zero32<<<dim3(8), dim3(256), 0, stream>>>((float*)zpage, 8192);
  k_zero32<<<dim3(2048), dim3(256), 0, stream>>>(A0, (size_t)N0 * N0);
  k_build_adj<<<dim3((E + 255) / 256), dim3(256), 0, stream>>>(ei, A0, E, N0);
  k_transpose_split_i8<<<dim3(64, 64), dim3(256), 0, stream>>>(A0, A0s8, A0s8T);

  // ---- aug1 ----
  k_aug_pipe8<0><<<dim3(32, 32), dim3(256), 0, stream>>>(
      A0s8, A0s8T, nullptr, zpage, N0, N0, A1, 0, N0, N0, N0);
  k_transpose_i8s<<<dim3(64, 64), dim3(256), 0, stream>>>(A1, A1T, N0, 2);

  // ---- gcn1 ----
  k_widen_f32_f64<<<dim3(512), dim3(256), 0, stream>>>(x0f, xB, N0 * CIN);
  {
    dim3 b(16, 16);
    k_gemm_xw32<<<dim3(HID / 64, (N0 + 31) / 32), b, 0, stream>>>(xB, W0, tb, N0, HID, CIN);
    k_degdinv<char><<<dim3(N0), dim3(256), 0, stream>>>(A1, N0, dinv, N0, wmax, nullptr);
    k_wmax<<<dim3(256), dim3(256), 0, stream>>>(tb, dinv, wmax, N0, HID);
    k_digitize8<DNUM><<<dim3(N0 / 64, HID / 64), dim3(256), 0, stream>>>(tb, dinv, wmax, wdT1, N0, N0, HID);
    k_axw_pipe8<<<dim3(DNUM * HID / 128, N0 / 128), dim3(256), 0, stream>>>(A1, wdT1, N0, P1, DNUM * HID);
    k_reduce_fin<<<dim3(N0), dim3(256), 0, stream>>>(P1, wmax, nullptr, tb, dinv, b0, xA,
                                                     DNUM * HID, HID, DNUM, 0, 1, 1.0, 0.0, 1);
  }

  // ---- pool1 ----
  k_scores<<<dim3(N0), dim3(256), 0, stream>>>(xA, p1, sc, HID, nullptr);
  k_topk_rank<<<dim3(N0), dim3(256), 0, stream>>>(sc, N0, K1P, perm, vals);
  k_gather_x<<<dim3(K1P), dim3(256), 0, stream>>>(xA, perm, vals, xB, HID);

  // ---- aug2 ----
  k_aug_pipe8<1><<<dim3(26, 26), dim3(256), 0, stream>>>(
      A1, A1T, perm, zpage, N0, N0, A2s8, PL2, KI2, K1P, K1P);
  k_transpose_i8s<<<dim3(52, 52), dim3(256), 0, stream>>>(A2s8, A2s8T, KI2, 0);
  k_transpose_i8s<<<dim3(52, 52), dim3(256), 0, stream>>>(A2s8 + PL2, A2s8T + PL2, KI2, 2);

  // ---- gcn2 ----
  {
    dim3 b(16, 16);
    k_gemm_xw32<<<dim3(HID / 64, (K1P + 31) / 32), b, 0, stream>>>(xB, W1, tb, K1P, HID, HID);
    k_degdinv2p<<<dim3(K1P), dim3(256), 0, stream>>>(A2s8, KI2, dinv, K1P, wmax);
    k_wmax<<<dim3(256), dim3(256), 0, stream>>>(tb, dinv, wmax, K1P, HID);
    k_digitize8<DNUM><<<dim3(KI2 / 64, HID / 64), dim3(256), 0, stream>>>(tb, dinv, wmax, wdT2, K1P, KI2, HID);
    k_axw_pipe8<<<dim3(DNUM * HID / 128, 2 * KI2 / 128), dim3(256), 0, stream>>>(A2s8, wdT2, KI2, P2, DNUM * HID);
    k_reduce_fin<<<dim3(K1P), dim3(256), 0, stream>>>(P2, wmax, nullptr, tb, dinv, b1, xA,
                                                      DNUM * HID, HID, DNUM, KI2, 2, 128.0, 1.0, 1);
  }

  // ---- pool2 (scores also resets a3max for aug3) ----
  k_scores<<<dim3(K1P), dim3(256), 0, stream>>>(xA, p2, sc, HID, a3max);
  k_topk_rank<<<dim3(K1P), dim3(256), 0, stream>>>(sc, K1P, K2P, permB, vals);
  k_gather_x<<<dim3(K2P), dim3(256), 0, stream>>>(xA, permB, vals, xB, HID);

  // ---- aug3 ----
  k_aug3_pipe8<<<dim3(16, 16), dim3(512), 0, stream>>>(
      A2s8, A2s8T, permB, zpage, KI2, A3p, a3max, K2P, K2P, LD3);

  // ---- gcn3 ----
  {
    dim3 b(16, 16);
    k_gemm_xw32<<<dim3(HID / 64, (K2P + 31) / 32), b, 0, stream>>>(xB, W2, tb, K2P, HID, HID);
    k_degdinv<float><<<dim3(K2P), dim3(256), 0, stream>>>(A3p, LD3, dinv, K2P, wmax, nullptr);
    k_splitA8s<<<dim3(KI3), dim3(256), 0, stream>>>(A3p, K2P, LD3, a3max, A3stack, KI3);
    k_wmax<<<dim3(256), dim3(256), 0, stream>>>(tb, dinv, wmax, K2P, HID);
    k_digitize8<2><<<dim3(KI3 / 64, HID / 64), dim3(256), 0, stream>>>(tb, dinv, wmax, wdT3, K2P, KI3, HID);
    k_axw_pipe8<<<dim3(2 * HID / 128, 2 * KI3 / 128), dim3(256), 0, stream>>>(A3stack, wdT3, KI3, P3, 2 * HID);
    k_reduce_fin<<<dim3(K2P), dim3(256), 0, stream>>>(P3, wmax, a3max, tb, dinv, b2, xA,
                                                      2 * HID, HID, 2, KI3, 2, 128.0, 1.0, 1);
  }

  // ---- gcn_out ----
  {
    dim3 b(16, 16);
    k_gemm_xw32<<<dim3(COUTC / 64, (K2P + 31) / 32), b, 0, stream>>>(xA, Wout, tb, K2P, COUTC, HID);
    k_reset_u32<<<dim3(1), dim3(64), 0, stream>>>(wmax);
    k_wmax<<<dim3(256), dim3(256), 0, stream>>>(tb, dinv, wmax, K2P, COUTC);
    k_digitize8<2><<<dim3(KI3 / 64, COUTC / 64), dim3(256), 0, stream>>>(tb, dinv, wmax, wdT3, K2P, KI3, COUTC);
    k_axw_pipe8<<<dim3(2 * COUTC / 128, 2 * KI3 / 128), dim3(256), 0, stream>>>(A3stack, wdT3, KI3, P3, 2 * COUTC);
    k_reduce_fin<<<dim3(K2P), dim3(256), 0, stream>>>(P3, wmax, a3max, tb, dinv, bout, xB,
                                                      2 * COUTC, COUTC, 2, KI3, 2, 128.0, 1.0, 0);
  }

  k_write_out<<<dim3(1024), dim3(256), 0, stream>>>(xB, (float*)d_out, K2P * COUTC, out_size);
}

// Round 13
// 689.340 us; speedup vs baseline: 12.1405x; 1.0403x over previous
//
#include <hip/hip_runtime.h>
#include <math.h>

#define N0    4096
#define CIN   128
#define HID   256
#define COUTC 128
#define K1P   3277   // ceil(0.8*4096)
#define K2P   1967   // ceil(0.6*3277)
#define LD3   1968   // K2P padded to 4-float rows
#define KI2   3328   // K1P padded to mult of 64
#define KI3   1984   // K2P padded to mult of 64
#define DNUM  5      // digit planes, base-128 -> 35 bits (score-gap margin ~60x)

typedef __attribute__((ext_vector_type(4))) int i32x4;

__device__ __forceinline__ void gl2lds16(const void* g, void* l) {
  __builtin_amdgcn_global_load_lds((const __attribute__((address_space(1))) void*)g,
                                   (__attribute__((address_space(3))) void*)l, 16, 0, 0);
}

// ---------------- build / elementwise ----------------

__global__ void k_zero32(float* __restrict__ p, size_t n) {
  size_t i = (size_t)blockIdx.x * blockDim.x + threadIdx.x;
  size_t st = (size_t)gridDim.x * blockDim.x;
  for (; i < n; i += st) p[i] = 0.0f;
}

__global__ void k_widen_f32_f64(const float* __restrict__ in, double* __restrict__ out, int n) {
  int i = blockIdx.x * blockDim.x + threadIdx.x;
  int st = gridDim.x * blockDim.x;
  for (; i < n; i += st) out[i] = (double)in[i];
}

__global__ void k_build_adj(const int* __restrict__ ei, float* __restrict__ A, int E, int n) {
  int e = blockIdx.x * blockDim.x + threadIdx.x;
  if (e < E) atomicAdd(&A[(size_t)ei[E + e] * n + ei[e]], 1.0f);
}

// A0 f32 -> A0s8 i8 + A0s8T i8 (transposed, +2 folded on diag). Small ints, exact.
__global__ __launch_bounds__(256) void k_transpose_split_i8(
    const float* __restrict__ A, char* __restrict__ B, char* __restrict__ BT) {
  __shared__ char sm[64][68];
  const int t = threadIdx.x;
  const int r0 = blockIdx.y * 64, c0 = blockIdx.x * 64;
  const int rr = t >> 2, cs = (t & 3) * 16;
  char tmp[16];
#pragma unroll
  for (int j = 0; j < 16; ++j) {
    char v = (char)(int)A[(size_t)(r0 + rr) * N0 + c0 + cs + j];
    tmp[j] = v;
    sm[cs + j][rr] = v;
  }
  *(int4*)&B[(size_t)(r0 + rr) * N0 + c0 + cs] = *(int4*)&tmp[0];
  __syncthreads();
  const int cc = t >> 2, rs = (t & 3) * 16;
  const int orow = c0 + cc;
  char o[16];
#pragma unroll
  for (int q = 0; q < 16; ++q) {
    char v = sm[cc][rs + q];
    if (r0 + rs + q == orow) v = (char)(v + 2);
    o[q] = v;
  }
  *(int4*)&BT[(size_t)orow * N0 + r0 + rs] = *(int4*)&o[0];
}

// i8 square transpose (n mult of 64) with integer diag fold
__global__ __launch_bounds__(256) void k_transpose_i8s(
    const char* __restrict__ A, char* __restrict__ BT, int n, int fold) {
  __shared__ char sm[64][68];
  const int t = threadIdx.x;
  const int r0 = blockIdx.y * 64, c0 = blockIdx.x * 64;
  const int rr = t >> 2, cs = (t & 3) * 16;
  {
    int4 v = *(const int4*)&A[(size_t)(r0 + rr) * n + c0 + cs];
    char* vb = (char*)&v;
#pragma unroll
    for (int j = 0; j < 16; ++j) sm[cs + j][rr] = vb[j];
  }
  __syncthreads();
  const int cc = t >> 2, rs = (t & 3) * 16;
  const int orow = c0 + cc;
  char o[16];
#pragma unroll
  for (int q = 0; q < 16; ++q) {
    char v = sm[cc][rs + q];
    if (r0 + rs + q == orow) v = (char)(v + fold);
    o[q] = v;
  }
  *(int4*)&BT[(size_t)orow * n + r0 + rs] = *(int4*)&o[0];
}

// -------- i8 pipelined augment, direct register epilogue (straight planes only) --------
template <int MODE>
__global__ __launch_bounds__(256) void k_aug_pipe8(
    const char* __restrict__ Asrc, const char* __restrict__ Btsrc,
    const int* __restrict__ perm, const char* __restrict__ zrow,
    int K, int ldk,
    char* __restrict__ O, size_t plane, int ldo,
    int M, int N)
{
  __shared__ __align__(16) char Ls[2][2][8192];
  const int tid = threadIdx.x;
  const int wave = tid >> 6, lane = tid & 63;
  const int wr = wave >> 1, wc = wave & 1;
  const int brow = blockIdx.y * 128, bcol = blockIdx.x * 128;
  const int lr = lane & 15, ko = (lane >> 4) * 16;
  const int koff = (lane & 3) * 16;

  const char* pA[2];
  const char* pB[2];
#pragma unroll
  for (int c = 0; c < 2; ++c) {
    int r = (c * 4 + wave) * 16 + (lane >> 2);
    int ra = brow + r, rb = bcol + r;
    int ia, ib;
    if (MODE == 0) { ia = ra; ib = rb; }
    else {
      ia = (ra < M) ? perm[ra] : -1;
      ib = (rb < N) ? perm[rb] : -1;
    }
    pA[c] = (ia >= 0) ? Asrc + (size_t)ia * ldk : zrow;
    pB[c] = (ib >= 0) ? Btsrc + (size_t)ib * ldk : zrow;
  }

  i32x4 acc[4][4];
#pragma unroll
  for (int m = 0; m < 4; ++m)
#pragma unroll
    for (int n = 0; n < 4; ++n) acc[m][n] = (i32x4){0, 0, 0, 0};

  auto STAGE = [&](int buf, int kt) {
#pragma unroll
    for (int c = 0; c < 2; ++c) {
      int f = c * 4 + wave;
      gl2lds16(pA[c] + kt + koff, &Ls[buf][0][f * 1024]);
      gl2lds16(pB[c] + kt + koff, &Ls[buf][1][f * 1024]);
    }
  };

  STAGE(0, 0);
  __syncthreads();
  int cur = 0;
  for (int kt = 0; kt < K; kt += 64) {
    if (kt + 64 < K) STAGE(cur ^ 1, kt + 64);
    i32x4 a0[4], b0[4];
#pragma unroll
    for (int m = 0; m < 4; ++m) a0[m] = *(const i32x4*)&Ls[cur][0][(wr * 64 + m * 16 + lr) * 64 + ko];
#pragma unroll
    for (int n = 0; n < 4; ++n) b0[n] = *(const i32x4*)&Ls[cur][1][(wc * 64 + n * 16 + lr) * 64 + ko];
#pragma unroll
    for (int m = 0; m < 4; ++m)
#pragma unroll
      for (int n = 0; n < 4; ++n)
        acc[m][n] = __builtin_amdgcn_mfma_i32_16x16x64_i8(a0[m], b0[n], acc[m][n], 0, 0, 0);
    __syncthreads();
    cur ^= 1;
  }

#pragma unroll
  for (int m = 0; m < 4; ++m)
#pragma unroll
    for (int n = 0; n < 4; ++n)
#pragma unroll
      for (int q = 0; q < 4; ++q) {
        int grow = brow + wr * 64 + m * 16 + (lane >> 4) * 4 + q;
        int gcol = bcol + wc * 64 + n * 16 + lr;
        int v = acc[m][n][q];
        if (MODE == 0) {
          if (grow == gcol) v = 0;
          O[(size_t)grow * ldo + gcol] = (char)v;
        } else {
          if (grow >= M || gcol >= N || grow == gcol) v = 0;
          O[(size_t)grow * ldo + gcol] = (char)(v >> 7);
          O[plane + (size_t)grow * ldo + gcol] = (char)(v & 127);
        }
      }
}

// aug3 (i8): A3 ~= 16384 HH' + 128 (HL'+LH');  LL' dropped (~0.2% rel, values-path).
__global__ __launch_bounds__(512) void k_aug3_pipe8(
    const char* __restrict__ S, const char* __restrict__ ST,
    const int* __restrict__ perm, const char* __restrict__ zrow,
    int Kpad, float* __restrict__ Cf, unsigned* __restrict__ amax,
    int M, int N, int ldcp)
{
  __shared__ __align__(16) char Ls[2][4][8192];
  const int tid = threadIdx.x;
  const int wave = tid >> 6, lane = tid & 63;
  const int wr = wave >> 1, wc = wave & 1;
  const int brow = blockIdx.y * 128, bcol = blockIdx.x * 128;
  const int lr = lane & 15, ko = (lane >> 4) * 16;
  const int koff = (lane & 3) * 16;
  const size_t plane = (size_t)Kpad * Kpad;

  const char *pAh, *pAl, *pBh, *pBl;
  {
    int r = (wave << 4) + (lane >> 2);
    int ra = brow + r, rb = bcol + r;
    int ia = (ra < M) ? perm[ra] : -1;
    int ib = (rb < N) ? perm[rb] : -1;
    pAh = (ia >= 0) ? S + (size_t)ia * Kpad : zrow;
    pAl = (ia >= 0) ? S + plane + (size_t)ia * Kpad : zrow;
    pBh = (ib >= 0) ? ST + (size_t)ib * Kpad : zrow;
    pBl = (ib >= 0) ? ST + plane + (size_t)ib * Kpad : zrow;
  }

  i32x4 hh[2][4], mid[2][4];
#pragma unroll
  for (int m = 0; m < 2; ++m)
#pragma unroll
    for (int n = 0; n < 4; ++n) {
      hh[m][n] = (i32x4){0, 0, 0, 0};
      mid[m][n] = (i32x4){0, 0, 0, 0};
    }

  auto STAGE = [&](int buf, int kt) {
    int f = wave * 1024;
    gl2lds16(pAh + kt + koff, &Ls[buf][0][f]);
    gl2lds16(pBh + kt + koff, &Ls[buf][1][f]);
    gl2lds16(pAl + kt + koff, &Ls[buf][2][f]);
    gl2lds16(pBl + kt + koff, &Ls[buf][3][f]);
  };

  STAGE(0, 0);
  __syncthreads();
  int cur = 0;
  for (int kt = 0; kt < Kpad; kt += 64) {
    if (kt + 64 < Kpad) STAGE(cur ^ 1, kt + 64);
    i32x4 ah[2], al[2], bh[4], bl[4];
#pragma unroll
    for (int m = 0; m < 2; ++m) {
      ah[m] = *(const i32x4*)&Ls[cur][0][(wr * 32 + m * 16 + lr) * 64 + ko];
      al[m] = *(const i32x4*)&Ls[cur][2][(wr * 32 + m * 16 + lr) * 64 + ko];
    }
#pragma unroll
    for (int n = 0; n < 4; ++n) {
      bh[n] = *(const i32x4*)&Ls[cur][1][(wc * 64 + n * 16 + lr) * 64 + ko];
      bl[n] = *(const i32x4*)&Ls[cur][3][(wc * 64 + n * 16 + lr) * 64 + ko];
    }
#pragma unroll
    for (int m = 0; m < 2; ++m)
#pragma unroll
      for (int n = 0; n < 4; ++n) {
        hh[m][n]  = __builtin_amdgcn_mfma_i32_16x16x64_i8(ah[m], bh[n], hh[m][n], 0, 0, 0);
        mid[m][n] = __builtin_amdgcn_mfma_i32_16x16x64_i8(ah[m], bl[n], mid[m][n], 0, 0, 0);
        mid[m][n] = __builtin_amdgcn_mfma_i32_16x16x64_i8(al[m], bh[n], mid[m][n], 0, 0, 0);
      }
    __syncthreads();
    cur ^= 1;
  }

  float mloc = 0.0f;
#pragma unroll
  for (int m = 0; m < 2; ++m)
#pragma unroll
    for (int n = 0; n < 4; ++n)
#pragma unroll
      for (int q = 0; q < 4; ++q) {
        int grow = brow + wr * 32 + m * 16 + (lane >> 4) * 4 + q;
        int gcol = bcol + wc * 64 + n * 16 + lr;
        if (grow < M && gcol < ldcp) {
          float v = 16384.0f * (float)hh[m][n][q] + 128.0f * (float)mid[m][n][q];
          if (gcol >= N || grow == gcol) v = 0.0f;
          Cf[(size_t)grow * ldcp + gcol] = v;
          mloc = fmaxf(mloc, v);
        }
      }
  __syncthreads();
  float* red = (float*)&Ls[0][0][0];
  red[tid] = mloc;
  __syncthreads();
  for (int st = 256; st > 0; st >>= 1) {
    if (tid < st) red[tid] = fmaxf(red[tid], red[tid + st]);
    __syncthreads();
  }
  if (tid == 0) atomicMax(amax, __builtin_bit_cast(unsigned, red[0]));
}

// ---------------- f64 x@W (32x64 tiles); optional rst: block(0,0) resets a u32 ----------------

__global__ __launch_bounds__(256) void k_gemm_xw32(
    const double* __restrict__ X, const float* __restrict__ W, double* __restrict__ C,
    int M, int N, int K, unsigned* __restrict__ rst) {
  if (blockIdx.x == 0 && blockIdx.y == 0 && threadIdx.x == 0 && threadIdx.y == 0 && rst) *rst = 0u;
  __shared__ double As[16][32];
  __shared__ double Bs[16][64];
  const int tx = threadIdx.x, ty = threadIdx.y;
  const int tid = ty * 16 + tx;
  const int brow = blockIdx.y * 32, bcol = blockIdx.x * 64;
  double acc[2][4];
#pragma unroll
  for (int i = 0; i < 2; ++i)
#pragma unroll
    for (int j = 0; j < 4; ++j) acc[i][j] = 0.0;
  const int lac = tid & 15, lar = tid >> 4;
  const int lbc = tid & 63, lbr = tid >> 6;
  for (int kt = 0; kt < K; kt += 16) {
#pragma unroll
    for (int rr = 0; rr < 2; ++rr) {
      int r = lar + rr * 16;
      int gr = brow + r, gk = kt + lac;
      As[lac][r] = (gr < M && gk < K) ? X[(size_t)gr * K + gk] : 0.0;
    }
#pragma unroll
    for (int rr = 0; rr < 4; ++rr) {
      int br = lbr + rr * 4;
      int gk = kt + br, gc = bcol + lbc;
      Bs[br][lbc] = (gk < K && gc < N) ? (double)W[(size_t)gk * N + gc] : 0.0;
    }
    __syncthreads();
#pragma unroll
    for (int kk = 0; kk < 16; ++kk) {
      double a[2], b[4];
#pragma unroll
      for (int i = 0; i < 2; ++i) a[i] = As[kk][ty * 2 + i];
#pragma unroll
      for (int j = 0; j < 4; ++j) b[j] = Bs[kk][tx * 4 + j];
#pragma unroll
      for (int i = 0; i < 2; ++i)
#pragma unroll
        for (int j = 0; j < 4; ++j) acc[i][j] = fma(a[i], b[j], acc[i][j]);
    }
    __syncthreads();
  }
#pragma unroll
  for (int i = 0; i < 2; ++i) {
    int gr = brow + ty * 2 + i;
    if (gr >= M) continue;
#pragma unroll
    for (int j = 0; j < 4; ++j) {
      int gc = bcol + tx * 4 + j;
      if (gc >= N) continue;
      C[(size_t)gr * N + gc] = acc[i][j];
    }
  }
}

// ---------------- digit machinery (i8, base-128) ----------------

__global__ void k_wmax(const double* __restrict__ t, const double* __restrict__ dinv,
                       unsigned* __restrict__ wmax, int K, int N) {
  __shared__ float red[256];
  float mx = 0.0f;
  int tot = K * N;
  for (int i = blockIdx.x * 256 + threadIdx.x; i < tot; i += gridDim.x * 256) {
    double w = dinv[i / N] * t[i];
    mx = fmaxf(mx, (float)fabs(w));
  }
  red[threadIdx.x] = mx;
  __syncthreads();
  for (int st = 128; st > 0; st >>= 1) {
    if (threadIdx.x < st) red[threadIdx.x] = fmaxf(red[threadIdx.x], red[threadIdx.x + st]);
    __syncthreads();
  }
  if (threadIdx.x == 0) atomicMax(wmax, __builtin_bit_cast(unsigned, red[0]));
}

template <int D>
__global__ __launch_bounds__(256) void k_digitize8(
    const double* __restrict__ t, const double* __restrict__ dinv,
    const unsigned* __restrict__ wmax, char* __restrict__ wdT,
    int K, int Kpad, int N) {
  __shared__ char sm[D][64][68];
  const int tid = threadIdx.x;
  const int k0 = blockIdx.x * 64, n0 = blockIdx.y * 64;
  float wm = __builtin_bit_cast(float, *wmax);
  double sc = (wm > 0.0f) ? scalbn(1.0, -(ilogbf(wm) + 2)) : 0.0;
  const int kk = tid >> 2, ns = (tid & 3) * 16;
  int k = k0 + kk;
  double dv = (k < K) ? dinv[k] : 0.0;
#pragma unroll
  for (int j = 0; j < 16; ++j) {
    int n = n0 + ns + j;
    double w = (k < K) ? dv * t[(size_t)k * N + n] : 0.0;
    double r = w * sc;
#pragma unroll
    for (int d = 0; d < D; ++d) {
      double rm = r * 128.0;
      double m = rint(rm);
      sm[d][kk][ns + j] = (char)(int)m;
      r = rm - m;
    }
  }
  __syncthreads();
  const int nn = tid >> 2, ks = (tid & 3) * 16;
  const size_t PS = (size_t)N * Kpad;
#pragma unroll
  for (int d = 0; d < D; ++d) {
    char o[16];
#pragma unroll
    for (int j = 0; j < 16; ++j) o[j] = sm[d][ks + j][nn];
    *(int4*)&wdT[d * PS + (size_t)(n0 + nn) * Kpad + k0 + ks] = *(int4*)&o[0];
  }
}

// A3p f32 (nonneg, values-path) -> scaled 14-bit base-128 i8 planes.
__global__ void k_splitA8s(const float* __restrict__ A, int M, int ldsrc,
                           const unsigned* __restrict__ amax,
                           char* __restrict__ S, int Kpad) {
  int r = blockIdx.x;
  const size_t plane = (size_t)Kpad * Kpad;
  float am = __builtin_bit_cast(float, *amax);
  float s13 = (am > 0.0f) ? scalbnf(1.0f, 13 - (ilogbf(am) + 1)) : 0.0f;
  for (int c4 = threadIdx.x * 4; c4 < Kpad; c4 += blockDim.x * 4) {
    float v[4] = {0.f, 0.f, 0.f, 0.f};
    if (r < M && c4 < ldsrc) *(float4*)v = *(const float4*)(A + (size_t)r * ldsrc + c4);
    unsigned hw = 0, lw = 0;
#pragma unroll
    for (int q = 0; q < 4; ++q) {
      int iv = (int)rintf(v[q] * s13);
      int h = iv >> 7, l = iv - (h << 7);
      hw |= ((unsigned)(unsigned char)(char)h) << (8 * q);
      lw |= ((unsigned)(unsigned char)(char)l) << (8 * q);
    }
    *(unsigned*)(S + (size_t)r * Kpad + c4) = hw;
    *(unsigned*)(S + plane + (size_t)r * Kpad + c4) = lw;
  }
}

// P[Mp][Neff] i32 = A[Mp][Kpad] i8 @ wdT[Neff][Kpad]^T — DMA-pipelined i8 GEMM, exact.
__global__ __launch_bounds__(256) void k_axw_pipe8(
    const char* __restrict__ Asrc, const char* __restrict__ Bsrc,
    int Kpad, int* __restrict__ P, int Neff)
{
  __shared__ __align__(16) char Ls[2][2][8192];
  const int tid = threadIdx.x;
  const int wave = tid >> 6, lane = tid & 63;
  const int wr = wave >> 1, wc = wave & 1;
  const int brow = blockIdx.y * 128, bcol = blockIdx.x * 128;
  const int lr = lane & 15, ko = (lane >> 4) * 16;
  const int koff = (lane & 3) * 16;

  const char* pA[2];
  const char* pB[2];
#pragma unroll
  for (int c = 0; c < 2; ++c) {
    int r = (c * 4 + wave) * 16 + (lane >> 2);
    pA[c] = Asrc + (size_t)(brow + r) * Kpad;
    pB[c] = Bsrc + (size_t)(bcol + r) * Kpad;
  }

  i32x4 acc[4][4];
#pragma unroll
  for (int m = 0; m < 4; ++m)
#pragma unroll
    for (int n = 0; n < 4; ++n) acc[m][n] = (i32x4){0, 0, 0, 0};

  auto STAGE = [&](int buf, int kt) {
#pragma unroll
    for (int c = 0; c < 2; ++c) {
      int f = c * 4 + wave;
      gl2lds16(pA[c] + kt + koff, &Ls[buf][0][f * 1024]);
      gl2lds16(pB[c] + kt + koff, &Ls[buf][1][f * 1024]);
    }
  };

  STAGE(0, 0);
  __syncthreads();
  int cur = 0;
  for (int kt = 0; kt < Kpad; kt += 64) {
    if (kt + 64 < Kpad) STAGE(cur ^ 1, kt + 64);
    i32x4 a0[4], b0[4];
#pragma unroll
    for (int m = 0; m < 4; ++m) a0[m] = *(const i32x4*)&Ls[cur][0][(wr * 64 + m * 16 + lr) * 64 + ko];
#pragma unroll
    for (int n = 0; n < 4; ++n) b0[n] = *(const i32x4*)&Ls[cur][1][(wc * 64 + n * 16 + lr) * 64 + ko];
#pragma unroll
    for (int m = 0; m < 4; ++m)
#pragma unroll
      for (int n = 0; n < 4; ++n)
        acc[m][n] = __builtin_amdgcn_mfma_i32_16x16x64_i8(a0[m], b0[n], acc[m][n], 0, 0, 0);
    __syncthreads();
    cur ^= 1;
  }

#pragma unroll
  for (int m = 0; m < 4; ++m)
#pragma unroll
    for (int n = 0; n < 4; ++n)
#pragma unroll
      for (int q = 0; q < 4; ++q) {
        int grow = brow + wr * 64 + m * 16 + (lane >> 4) * 4 + q;
        int gcol = bcol + wc * 64 + n * 16 + lr;
        P[(size_t)grow * Neff + gcol] = acc[m][n][q];
      }
}

// fused reduce_y + gcn_fin: out = relu?( d*(y + 2*d*t) + b ), y from digit planes.
__global__ void k_reduce_fin(const int* __restrict__ P, const unsigned* __restrict__ wmax,
                             const unsigned* __restrict__ amax,
                             const double* __restrict__ t, const double* __restrict__ dinv,
                             const float* __restrict__ bias, double* __restrict__ out,
                             int Neff, int N, int D, int M0pad, int nplane,
                             double w0, double w1, int relu) {
  int m = blockIdx.x;
  float wm = __builtin_bit_cast(float, *wmax);
  double s0 = w0, s1 = w1;
  bool zero = (wm <= 0.0f);
  if (amax) {
    float am = __builtin_bit_cast(float, *amax);
    if (am > 0.0f) {
      int EA = ilogbf(am) + 1;
      s0 = scalbn(w0, EA - 13);
      s1 = scalbn(w1, EA - 13);
    } else zero = true;
  }
  int Ep = zero ? 0 : (ilogbf(wm) + 2);
  double d = dinv[m];
  for (int n = threadIdx.x; n < N; n += blockDim.x) {
    double acc = 0.0;
    if (!zero) {
      for (int dd = 0; dd < D; ++dd) {
        double v = s0 * (double)P[(size_t)m * Neff + dd * N + n];
        if (nplane == 2) v += s1 * (double)P[(size_t)(M0pad + m) * Neff + dd * N + n];
        acc += scalbn(v, Ep - 7 * (dd + 1));
      }
    }
    double v = d * (acc + 2.0 * d * t[(size_t)m * N + n]) + (double)bias[n];
    if (relu) v = v > 0.0 ? v : 0.0;
    out[(size_t)m * N + n] = v;
  }
}

// ---------------- GCN tail / pooling ----------------

template <typename TA>
__device__ __forceinline__ float a_as_f32(TA v);
template <> __device__ __forceinline__ float a_as_f32<char>(char v) { return (float)v; }
template <> __device__ __forceinline__ float a_as_f32<float>(float v) { return v; }

template <typename TA>
__global__ void k_degdinv(const TA* __restrict__ A, int lda, double* __restrict__ dinv, int n,
                          unsigned* __restrict__ rst0, unsigned* __restrict__ rst1) {
  if (blockIdx.x == 0 && threadIdx.x == 0) {
    if (rst0) *rst0 = 0u;
    if (rst1) *rst1 = 0u;
  }
  __shared__ double red[256];
  int row = blockIdx.x;
  double s = 0.0;
  for (int j = threadIdx.x; j < n; j += 256) s += (double)a_as_f32<TA>(A[(size_t)row * lda + j]);
  red[threadIdx.x] = s;
  __syncthreads();
  for (int st = 128; st > 0; st >>= 1) {
    if (threadIdx.x < st) red[threadIdx.x] += red[threadIdx.x + st];
    __syncthreads();
  }
  if (threadIdx.x == 0) {
    double deg = red[0] + 2.0;
    dinv[row] = (deg > 0.0) ? 1.0 / sqrt(deg) : 0.0;
  }
}

// dinv from 2-plane i8 (128*h + l): exact integer row sums.
__global__ void k_degdinv2p(const char* __restrict__ S, int Kpad, double* __restrict__ dinv,
                            int n, unsigned* __restrict__ rst0) {
  if (blockIdx.x == 0 && threadIdx.x == 0 && rst0) *rst0 = 0u;
  __shared__ double red[256];
  const size_t plane = (size_t)Kpad * Kpad;
  int row = blockIdx.x;
  const char* h = S + (size_t)row * Kpad;
  const char* l = S + plane + (size_t)row * Kpad;
  long s = 0;
  for (int j = threadIdx.x; j < n; j += 256) s += 128 * (long)h[j] + (long)l[j];
  red[threadIdx.x] = (double)s;
  __syncthreads();
  for (int st = 128; st > 0; st >>= 1) {
    if (threadIdx.x < st) red[threadIdx.x] += red[threadIdx.x + st];
    __syncthreads();
  }
  if (threadIdx.x == 0) {
    double deg = red[0] + 2.0;
    dinv[row] = (deg > 0.0) ? 1.0 / sqrt(deg) : 0.0;
  }
}

// scores with fused ||p||; optional reset of a max accumulator for a LATER kernel
__global__ void k_scores(const double* __restrict__ x, const float* __restrict__ p,
                         double* __restrict__ sc, int C, unsigned* __restrict__ rst) {
  if (blockIdx.x == 0 && threadIdx.x == 0 && rst) *rst = 0u;
  __shared__ double red[256], red2[256];
  int row = blockIdx.x;
  double s = 0.0, s2 = 0.0;
  for (int j = threadIdx.x; j < C; j += 256) {
    double pv = (double)p[j];
    s += x[(size_t)row * C + j] * pv;
    s2 += pv * pv;
  }
  red[threadIdx.x] = s;
  red2[threadIdx.x] = s2;
  __syncthreads();
  for (int st = 128; st > 0; st >>= 1) {
    if (threadIdx.x < st) {
      red[threadIdx.x] += red[threadIdx.x + st];
      red2[threadIdx.x] += red2[threadIdx.x + st];
    }
    __syncthreads();
  }
  if (threadIdx.x == 0) sc[row] = tanh(red[0] / sqrt(red2[0]));
}

// rank-count top-k (bitwise-identical to full sort under (score desc, idx asc))
__global__ __launch_bounds__(256) void k_topk_rank(
    const double* __restrict__ sc, int n, int k,
    int* __restrict__ perm, double* __restrict__ vals) {
  __shared__ int red[256];
  const int i = blockIdx.x;
  const double si = sc[i];
  int cnt = 0;
  for (int j = threadIdx.x; j < n; j += 256) {
    double sj = sc[j];
    if (sj > si || (sj == si && j < i)) ++cnt;
  }
  red[threadIdx.x] = cnt;
  __syncthreads();
  for (int st = 128; st > 0; st >>= 1) {
    if (threadIdx.x < st) red[threadIdx.x] += red[threadIdx.x + st];
    __syncthreads();
  }
  if (threadIdx.x == 0) {
    int rank = red[0];
    if (rank < k) { perm[rank] = i; vals[rank] = si; }
  }
}

__global__ void k_gather_x(const double* __restrict__ x, const int* __restrict__ perm,
                           const double* __restrict__ vals, double* __restrict__ xo, int C) {
  int row = blockIdx.x;
  int src = perm[row];
  double v = vals[row];
  for (int c = threadIdx.x; c < C; c += blockDim.x)
    xo[(size_t)row * C + c] = x[(size_t)src * C + c] * v;
}

__global__ void k_write_out(const double* __restrict__ x, float* __restrict__ out,
                            int nvals, int total) {
  int i = blockIdx.x * blockDim.x + threadIdx.x;
  int st = gridDim.x * blockDim.x;
  for (; i < total; i += st) out[i] = (i < nvals) ? (float)x[i] : 0.0f;
}

__global__ void k_sentinel(float* __restrict__ out, int total) {
  int i = blockIdx.x * blockDim.x + threadIdx.x;
  int st = gridDim.x * blockDim.x;
  for (; i < total; i += st) out[i] = 1e30f;
}

// ---------------- driver ----------------

extern "C" void kernel_launch(void* const* d_in, const int* in_sizes, int n_in,
                              void* d_out, int out_size, void* d_ws, size_t ws_size,
                              hipStream_t stream) {
  const float* x0f  = (const float*)d_in[0];
  const int*   ei   = (const int*)d_in[1];
  const float* W0   = (const float*)d_in[2];
  const float* b0   = (const float*)d_in[3];
  const float* W1   = (const float*)d_in[4];
  const float* b1   = (const float*)d_in[5];
  const float* W2   = (const float*)d_in[6];
  const float* b2   = (const float*)d_in[7];
  const float* p1   = (const float*)d_in[8];
  const float* p2   = (const float*)d_in[9];
  const float* Wout = (const float*)d_in[10];
  const float* bout = (const float*)d_in[11];
  const int E = in_sizes[1] / 2;

  const size_t MiB = 1ull << 20;
  if (ws_size < 160 * MiB) {
    k_sentinel<<<dim3(256), dim3(256), 0, stream>>>((float*)d_out, out_size);
    return;
  }
  char* W = (char*)d_ws;
  const size_t PL2 = (size_t)KI2 * KI2;
  // epoch A: build + aug1
  float* A0    = (float*)(W + 0);
  char*  A0s8  = (char*)(W + 64 * MiB);
  char*  A0s8T = (char*)(W + 80 * MiB);
  // epoch A2: gcn1
  char*  A1    = (char*)(W + 0);
  char*  A1T   = (char*)(W + 16 * MiB);
  char*  wdT1  = (char*)(W + 32 * MiB);   // 5*256*4096 = 5.25 MB
  int*   P1    = (int*)(W + 40 * MiB);    // 4096*1280*4 = 21 MB
  // epoch B: aug2 + gcn2
  char*  A2s8  = (char*)(W + 64 * MiB);
  char*  A2s8T = (char*)(W + 86 * MiB);
  char*  wdT2  = (char*)(W + 0);          // 5*256*3328 = 4.3 MB
  int*   P2    = (int*)(W + 7 * MiB);     // 6656*1280*4 = 34 MB
  // epoch C: aug3 + gcn3/out
  float* A3p     = (float*)(W + 108 * MiB);
  char*  A3stack = (char*)(W + 0);
  char*  wdT3    = (char*)(W + 8 * MiB);
  int*   P3      = (int*)(W + 10 * MiB);
  // features
  double* tb   = (double*)(W + 128 * MiB);
  double* xA   = (double*)(W + 144 * MiB);
  double* xB   = (double*)(W + 152 * MiB);
  char* SM = W + (159 * MiB + 256 * 1024);
  double* dinv = (double*)(SM);
  double* sc   = (double*)(SM + 32768);
  double* vals = (double*)(SM + 65536);
  unsigned* wmax  = (unsigned*)(SM + 98304 + 128);
  unsigned* a3max = (unsigned*)(SM + 98304 + 192);
  int* perm    = (int*)(SM + 98304 + 256);
  int* permB   = (int*)(SM + 98304 + 256 + 16384);
  char* zpage  = (char*)(W + 159 * MiB + 512 * 1024);

  // ---- build A0, i8 split+transpose ----
  k_zero32<<<dim3(8), dim3(256), 0, stream>>>((float*)zpage, 8192);
  k_zero32<<<dim3(2048), dim3(256), 0, stream>>>(A0, (size_t)N0 * N0);
  k_build_adj<<<dim3((E + 255) / 256), dim3(256), 0, stream>>>(ei, A0, E, N0);
  k_transpose_split_i8<<<dim3(64, 64), dim3(256), 0, stream>>>(A0, A0s8, A0s8T);

  // ---- aug1 ----
  k_aug_pipe8<0><<<dim3(32, 32), dim3(256), 0, stream>>>(
      A0s8, A0s8T, nullptr, zpage, N0, N0, A1, 0, N0, N0, N0);
  k_transpose_i8s<<<dim3(64, 64), dim3(256), 0, stream>>>(A1, A1T, N0, 2);

  // ---- gcn1 ----
  k_widen_f32_f64<<<dim3(512), dim3(256), 0, stream>>>(x0f, xB, N0 * CIN);
  {
    dim3 b(16, 16);
    k_gemm_xw32<<<dim3(HID / 64, (N0 + 31) / 32), b, 0, stream>>>(xB, W0, tb, N0, HID, CIN, nullptr);
    k_degdinv<char><<<dim3(N0), dim3(256), 0, stream>>>(A1, N0, dinv, N0, wmax, nullptr);
    k_wmax<<<dim3(256), dim3(256), 0, stream>>>(tb, dinv, wmax, N0, HID);
    k_digitize8<DNUM><<<dim3(N0 / 64, HID / 64), dim3(256), 0, stream>>>(tb, dinv, wmax, wdT1, N0, N0, HID);
    k_axw_pipe8<<<dim3(DNUM * HID / 128, N0 / 128), dim3(256), 0, stream>>>(A1, wdT1, N0, P1, DNUM * HID);
    k_reduce_fin<<<dim3(N0), dim3(256), 0, stream>>>(P1, wmax, nullptr, tb, dinv, b0, xA,
                                                     DNUM * HID, HID, DNUM, 0, 1, 1.0, 0.0, 1);
  }

  // ---- pool1 ----
  k_scores<<<dim3(N0), dim3(256), 0, stream>>>(xA, p1, sc, HID, nullptr);
  k_topk_rank<<<dim3(N0), dim3(256), 0, stream>>>(sc, N0, K1P, perm, vals);
  k_gather_x<<<dim3(K1P), dim3(256), 0, stream>>>(xA, perm, vals, xB, HID);

  // ---- aug2 ----
  k_aug_pipe8<1><<<dim3(26, 26), dim3(256), 0, stream>>>(
      A1, A1T, perm, zpage, N0, N0, A2s8, PL2, KI2, K1P, K1P);
  k_transpose_i8s<<<dim3(52, 52), dim3(256), 0, stream>>>(A2s8, A2s8T, KI2, 0);
  k_transpose_i8s<<<dim3(52, 52), dim3(256), 0, stream>>>(A2s8 + PL2, A2s8T + PL2, KI2, 2);

  // ---- gcn2 ----
  {
    dim3 b(16, 16);
    k_gemm_xw32<<<dim3(HID / 64, (K1P + 31) / 32), b, 0, stream>>>(xB, W1, tb, K1P, HID, HID, nullptr);
    k_degdinv2p<<<dim3(K1P), dim3(256), 0, stream>>>(A2s8, KI2, dinv, K1P, wmax);
    k_wmax<<<dim3(256), dim3(256), 0, stream>>>(tb, dinv, wmax, K1P, HID);
    k_digitize8<DNUM><<<dim3(KI2 / 64, HID / 64), dim3(256), 0, stream>>>(tb, dinv, wmax, wdT2, K1P, KI2, HID);
    k_axw_pipe8<<<dim3(DNUM * HID / 128, 2 * KI2 / 128), dim3(256), 0, stream>>>(A2s8, wdT2, KI2, P2, DNUM * HID);
    k_reduce_fin<<<dim3(K1P), dim3(256), 0, stream>>>(P2, wmax, nullptr, tb, dinv, b1, xA,
                                                      DNUM * HID, HID, DNUM, KI2, 2, 128.0, 1.0, 1);
  }

  // ---- pool2 (scores also resets a3max for aug3) ----
  k_scores<<<dim3(K1P), dim3(256), 0, stream>>>(xA, p2, sc, HID, a3max);
  k_topk_rank<<<dim3(K1P), dim3(256), 0, stream>>>(sc, K1P, K2P, permB, vals);
  k_gather_x<<<dim3(K2P), dim3(256), 0, stream>>>(xA, permB, vals, xB, HID);

  // ---- aug3 ----
  k_aug3_pipe8<<<dim3(16, 16), dim3(512), 0, stream>>>(
      A2s8, A2s8T, permB, zpage, KI2, A3p, a3max, K2P, K2P, LD3);

  // ---- gcn3 ----
  {
    dim3 b(16, 16);
    k_gemm_xw32<<<dim3(HID / 64, (K2P + 31) / 32), b, 0, stream>>>(xB, W2, tb, K2P, HID, HID, nullptr);
    k_degdinv<float><<<dim3(K2P), dim3(256), 0, stream>>>(A3p, LD3, dinv, K2P, wmax, nullptr);
    k_splitA8s<<<dim3(KI3), dim3(256), 0, stream>>>(A3p, K2P, LD3, a3max, A3stack, KI3);
    k_wmax<<<dim3(256), dim3(256), 0, stream>>>(tb, dinv, wmax, K2P, HID);
    k_digitize8<2><<<dim3(KI3 / 64, HID / 64), dim3(256), 0, stream>>>(tb, dinv, wmax, wdT3, K2P, KI3, HID);
    k_axw_pipe8<<<dim3(2 * HID / 128, 2 * KI3 / 128), dim3(256), 0, stream>>>(A3stack, wdT3, KI3, P3, 2 * HID);
    k_reduce_fin<<<dim3(K2P), dim3(256), 0, stream>>>(P3, wmax, a3max, tb, dinv, b2, xA,
                                                      2 * HID, HID, 2, KI3, 2, 128.0, 1.0, 1);
  }

  // ---- gcn_out (reuse dinv, a3max, A3stack; gemm resets wmax) ----
  {
    dim3 b(16, 16);
    k_gemm_xw32<<<dim3(COUTC / 64, (K2P + 31) / 32), b, 0, stream>>>(xA, Wout, tb, K2P, COUTC, HID, wmax);
    k_wmax<<<dim3(256), dim3(256), 0, stream>>>(tb, dinv, wmax, K2P, COUTC);
    k_digitize8<2><<<dim3(KI3 / 64, COUTC / 64), dim3(256), 0, stream>>>(tb, dinv, wmax, wdT3, K2P, KI3, COUTC);
    k_axw_pipe8<<<dim3(2 * COUTC / 128, 2 * KI3 / 128), dim3(256), 0, stream>>>(A3stack, wdT3, KI3, P3, 2 * COUTC);
    k_reduce_fin<<<dim3(K2P), dim3(256), 0, stream>>>(P3, wmax, a3max, tb, dinv, bout, xB,
                                                      2 * COUTC, COUTC, 2, KI3, 2, 128.0, 1.0, 0);
  }

  k_write_out<<<dim3(1024), dim3(256), 0, stream>>>(xB, (float*)d_out, K2P * COUTC, out_size);
}

// Round 14
// 653.936 us; speedup vs baseline: 12.7978x; 1.0541x over previous
//
#include <hip/hip_runtime.h>
#include <math.h>

#define N0    4096
#define CIN   128
#define HID   256
#define COUTC 128
#define K1P   3277   // ceil(0.8*4096)
#define K2P   1967   // ceil(0.6*3277)
#define LD3   1968   // K2P padded to 4-float rows
#define KI2   3328   // K1P padded to mult of 64
#define KI3   1984   // K2P padded to mult of 64
#define DNUM  5      // digit planes, base-128 -> 35 bits

typedef __attribute__((ext_vector_type(4))) int i32x4;

__device__ __forceinline__ void gl2lds16(const void* g, void* l) {
  __builtin_amdgcn_global_load_lds((const __attribute__((address_space(1))) void*)g,
                                   (__attribute__((address_space(3))) void*)l, 16, 0, 0);
}

// ---------------- build / elementwise ----------------

__global__ void k_zero32(float* __restrict__ p, size_t n) {
  size_t i = (size_t)blockIdx.x * blockDim.x + threadIdx.x;
  size_t st = (size_t)gridDim.x * blockDim.x;
  for (; i < n; i += st) p[i] = 0.0f;
}

// adjacency built directly as i8 counts via u32-word atomics (counts << 255: no carry)
__global__ void k_build_adj8(const int* __restrict__ ei, unsigned* __restrict__ A, int E, int n) {
  int e = blockIdx.x * blockDim.x + threadIdx.x;
  if (e < E) {
    size_t byte = (size_t)ei[E + e] * n + ei[e];
    atomicAdd(&A[byte >> 2], 1u << (8 * (byte & 3)));
  }
}

// i8 square transpose (n mult of 64), multi-plane via blockIdx.z, per-plane diag fold
__global__ __launch_bounds__(256) void k_transpose_i8s(
    const char* __restrict__ A, char* __restrict__ BT, int n, size_t splane,
    int fold0, int fold1) {
  __shared__ char sm[64][68];
  const char* src = A + blockIdx.z * splane;
  char* dst = BT + blockIdx.z * splane;
  const int fold = blockIdx.z ? fold1 : fold0;
  const int t = threadIdx.x;
  const int r0 = blockIdx.y * 64, c0 = blockIdx.x * 64;
  const int rr = t >> 2, cs = (t & 3) * 16;
  {
    int4 v = *(const int4*)&src[(size_t)(r0 + rr) * n + c0 + cs];
    char* vb = (char*)&v;
#pragma unroll
    for (int j = 0; j < 16; ++j) sm[cs + j][rr] = vb[j];
  }
  __syncthreads();
  const int cc = t >> 2, rs = (t & 3) * 16;
  const int orow = c0 + cc;
  char o[16];
#pragma unroll
  for (int q = 0; q < 16; ++q) {
    char v = sm[cc][rs + q];
    if (r0 + rs + q == orow) v = (char)(v + fold);
    o[q] = v;
  }
  *(int4*)&dst[(size_t)orow * n + r0 + rs] = *(int4*)&o[0];
}

// -------- i8 pipelined augment, direct register epilogue (straight planes only) --------
template <int MODE>
__global__ __launch_bounds__(256) void k_aug_pipe8(
    const char* __restrict__ Asrc, const char* __restrict__ Btsrc,
    const int* __restrict__ perm, const char* __restrict__ zrow,
    int K, int ldk,
    char* __restrict__ O, size_t plane, int ldo,
    int M, int N)
{
  __shared__ __align__(16) char Ls[2][2][8192];
  const int tid = threadIdx.x;
  const int wave = tid >> 6, lane = tid & 63;
  const int wr = wave >> 1, wc = wave & 1;
  const int brow = blockIdx.y * 128, bcol = blockIdx.x * 128;
  const int lr = lane & 15, ko = (lane >> 4) * 16;
  const int koff = (lane & 3) * 16;

  const char* pA[2];
  const char* pB[2];
#pragma unroll
  for (int c = 0; c < 2; ++c) {
    int r = (c * 4 + wave) * 16 + (lane >> 2);
    int ra = brow + r, rb = bcol + r;
    int ia, ib;
    if (MODE == 0) { ia = ra; ib = rb; }
    else {
      ia = (ra < M) ? perm[ra] : -1;
      ib = (rb < N) ? perm[rb] : -1;
    }
    pA[c] = (ia >= 0) ? Asrc + (size_t)ia * ldk : zrow;
    pB[c] = (ib >= 0) ? Btsrc + (size_t)ib * ldk : zrow;
  }

  i32x4 acc[4][4];
#pragma unroll
  for (int m = 0; m < 4; ++m)
#pragma unroll
    for (int n = 0; n < 4; ++n) acc[m][n] = (i32x4){0, 0, 0, 0};

  auto STAGE = [&](int buf, int kt) {
#pragma unroll
    for (int c = 0; c < 2; ++c) {
      int f = c * 4 + wave;
      gl2lds16(pA[c] + kt + koff, &Ls[buf][0][f * 1024]);
      gl2lds16(pB[c] + kt + koff, &Ls[buf][1][f * 1024]);
    }
  };

  STAGE(0, 0);
  __syncthreads();
  int cur = 0;
  for (int kt = 0; kt < K; kt += 64) {
    if (kt + 64 < K) STAGE(cur ^ 1, kt + 64);
    i32x4 a0[4], b0[4];
#pragma unroll
    for (int m = 0; m < 4; ++m) a0[m] = *(const i32x4*)&Ls[cur][0][(wr * 64 + m * 16 + lr) * 64 + ko];
#pragma unroll
    for (int n = 0; n < 4; ++n) b0[n] = *(const i32x4*)&Ls[cur][1][(wc * 64 + n * 16 + lr) * 64 + ko];
#pragma unroll
    for (int m = 0; m < 4; ++m)
#pragma unroll
      for (int n = 0; n < 4; ++n)
        acc[m][n] = __builtin_amdgcn_mfma_i32_16x16x64_i8(a0[m], b0[n], acc[m][n], 0, 0, 0);
    __syncthreads();
    cur ^= 1;
  }

#pragma unroll
  for (int m = 0; m < 4; ++m)
#pragma unroll
    for (int n = 0; n < 4; ++n)
#pragma unroll
      for (int q = 0; q < 4; ++q) {
        int grow = brow + wr * 64 + m * 16 + (lane >> 4) * 4 + q;
        int gcol = bcol + wc * 64 + n * 16 + lr;
        int v = acc[m][n][q];
        if (MODE == 0) {
          if (grow == gcol) v = 0;
          O[(size_t)grow * ldo + gcol] = (char)v;
        } else {
          if (grow >= M || gcol >= N || grow == gcol) v = 0;
          O[(size_t)grow * ldo + gcol] = (char)(v >> 7);
          O[plane + (size_t)grow * ldo + gcol] = (char)(v & 127);
        }
      }
}

// aug3 (i8): A3 ~= 16384 HH' + 128 (HL'+LH');  LL' dropped (~0.2% rel, values-path).
__global__ __launch_bounds__(512) void k_aug3_pipe8(
    const char* __restrict__ S, const char* __restrict__ ST,
    const int* __restrict__ perm, const char* __restrict__ zrow,
    int Kpad, float* __restrict__ Cf, unsigned* __restrict__ amax,
    int M, int N, int ldcp)
{
  __shared__ __align__(16) char Ls[2][4][8192];
  const int tid = threadIdx.x;
  const int wave = tid >> 6, lane = tid & 63;
  const int wr = wave >> 1, wc = wave & 1;
  const int brow = blockIdx.y * 128, bcol = blockIdx.x * 128;
  const int lr = lane & 15, ko = (lane >> 4) * 16;
  const int koff = (lane & 3) * 16;
  const size_t plane = (size_t)Kpad * Kpad;

  const char *pAh, *pAl, *pBh, *pBl;
  {
    int r = (wave << 4) + (lane >> 2);
    int ra = brow + r, rb = bcol + r;
    int ia = (ra < M) ? perm[ra] : -1;
    int ib = (rb < N) ? perm[rb] : -1;
    pAh = (ia >= 0) ? S + (size_t)ia * Kpad : zrow;
    pAl = (ia >= 0) ? S + plane + (size_t)ia * Kpad : zrow;
    pBh = (ib >= 0) ? ST + (size_t)ib * Kpad : zrow;
    pBl = (ib >= 0) ? ST + plane + (size_t)ib * Kpad : zrow;
  }

  i32x4 hh[2][4], mid[2][4];
#pragma unroll
  for (int m = 0; m < 2; ++m)
#pragma unroll
    for (int n = 0; n < 4; ++n) {
      hh[m][n] = (i32x4){0, 0, 0, 0};
      mid[m][n] = (i32x4){0, 0, 0, 0};
    }

  auto STAGE = [&](int buf, int kt) {
    int f = wave * 1024;
    gl2lds16(pAh + kt + koff, &Ls[buf][0][f]);
    gl2lds16(pBh + kt + koff, &Ls[buf][1][f]);
    gl2lds16(pAl + kt + koff, &Ls[buf][2][f]);
    gl2lds16(pBl + kt + koff, &Ls[buf][3][f]);
  };

  STAGE(0, 0);
  __syncthreads();
  int cur = 0;
  for (int kt = 0; kt < Kpad; kt += 64) {
    if (kt + 64 < Kpad) STAGE(cur ^ 1, kt + 64);
    i32x4 ah[2], al[2], bh[4], bl[4];
#pragma unroll
    for (int m = 0; m < 2; ++m) {
      ah[m] = *(const i32x4*)&Ls[cur][0][(wr * 32 + m * 16 + lr) * 64 + ko];
      al[m] = *(const i32x4*)&Ls[cur][2][(wr * 32 + m * 16 + lr) * 64 + ko];
    }
#pragma unroll
    for (int n = 0; n < 4; ++n) {
      bh[n] = *(const i32x4*)&Ls[cur][1][(wc * 64 + n * 16 + lr) * 64 + ko];
      bl[n] = *(const i32x4*)&Ls[cur][3][(wc * 64 + n * 16 + lr) * 64 + ko];
    }
#pragma unroll
    for (int m = 0; m < 2; ++m)
#pragma unroll
      for (int n = 0; n < 4; ++n) {
        hh[m][n]  = __builtin_amdgcn_mfma_i32_16x16x64_i8(ah[m], bh[n], hh[m][n], 0, 0, 0);
        mid[m][n] = __builtin_amdgcn_mfma_i32_16x16x64_i8(ah[m], bl[n], mid[m][n], 0, 0, 0);
        mid[m][n] = __builtin_amdgcn_mfma_i32_16x16x64_i8(al[m], bh[n], mid[m][n], 0, 0, 0);
      }
    __syncthreads();
    cur ^= 1;
  }

  float mloc = 0.0f;
#pragma unroll
  for (int m = 0; m < 2; ++m)
#pragma unroll
    for (int n = 0; n < 4; ++n)
#pragma unroll
      for (int q = 0; q < 4; ++q) {
        int grow = brow + wr * 32 + m * 16 + (lane >> 4) * 4 + q;
        int gcol = bcol + wc * 64 + n * 16 + lr;
        if (grow < M && gcol < ldcp) {
          float v = 16384.0f * (float)hh[m][n][q] + 128.0f * (float)mid[m][n][q];
          if (gcol >= N || grow == gcol) v = 0.0f;
          Cf[(size_t)grow * ldcp + gcol] = v;
          mloc = fmaxf(mloc, v);
        }
      }
  __syncthreads();
  float* red = (float*)&Ls[0][0][0];
  red[tid] = mloc;
  __syncthreads();
  for (int st = 256; st > 0; st >>= 1) {
    if (tid < st) red[tid] = fmaxf(red[tid], red[tid + st]);
    __syncthreads();
  }
  if (tid == 0) atomicMax(amax, __builtin_bit_cast(unsigned, red[0]));
}

// ---------------- f64 x@W (32x64 tiles); TX = float/double; optional row-gather*val ----------------

template <typename TX, int GATHER>
__global__ __launch_bounds__(256) void k_gemm_xw32(
    const TX* __restrict__ X, const int* __restrict__ perm, const double* __restrict__ vals,
    const float* __restrict__ W, double* __restrict__ C,
    int M, int N, int K, unsigned* __restrict__ rst) {
  if (blockIdx.x == 0 && blockIdx.y == 0 && threadIdx.x == 0 && threadIdx.y == 0 && rst) *rst = 0u;
  __shared__ double As[16][32];
  __shared__ double Bs[16][64];
  const int tx = threadIdx.x, ty = threadIdx.y;
  const int tid = ty * 16 + tx;
  const int brow = blockIdx.y * 32, bcol = blockIdx.x * 64;
  const int lac = tid & 15, lar = tid >> 4;
  const int lbc = tid & 63, lbr = tid >> 6;

  // per-thread source rows (constant over K loop)
  int srow[2];
  double sval[2];
#pragma unroll
  for (int rr = 0; rr < 2; ++rr) {
    int gr = brow + lar + rr * 16;
    if (GATHER) {
      srow[rr] = (gr < M) ? perm[gr] : 0;
      sval[rr] = (gr < M) ? vals[gr] : 0.0;
    } else {
      srow[rr] = gr;
      sval[rr] = 1.0;
    }
  }

  double acc[2][4];
#pragma unroll
  for (int i = 0; i < 2; ++i)
#pragma unroll
    for (int j = 0; j < 4; ++j) acc[i][j] = 0.0;

  for (int kt = 0; kt < K; kt += 16) {
#pragma unroll
    for (int rr = 0; rr < 2; ++rr) {
      int gr = brow + lar + rr * 16;
      int gk = kt + lac;
      double v = 0.0;
      if (gr < M && gk < K) {
        v = (double)X[(size_t)srow[rr] * K + gk];
        if (GATHER) v *= sval[rr];
      }
      As[lac][lar + rr * 16] = v;
    }
#pragma unroll
    for (int rr = 0; rr < 4; ++rr) {
      int br = lbr + rr * 4;
      int gk = kt + br, gc = bcol + lbc;
      Bs[br][lbc] = (gk < K && gc < N) ? (double)W[(size_t)gk * N + gc] : 0.0;
    }
    __syncthreads();
#pragma unroll
    for (int kk = 0; kk < 16; ++kk) {
      double a[2], b[4];
#pragma unroll
      for (int i = 0; i < 2; ++i) a[i] = As[kk][ty * 2 + i];
#pragma unroll
      for (int j = 0; j < 4; ++j) b[j] = Bs[kk][tx * 4 + j];
#pragma unroll
      for (int i = 0; i < 2; ++i)
#pragma unroll
        for (int j = 0; j < 4; ++j) acc[i][j] = fma(a[i], b[j], acc[i][j]);
    }
    __syncthreads();
  }
#pragma unroll
  for (int i = 0; i < 2; ++i) {
    int gr = brow + ty * 2 + i;
    if (gr >= M) continue;
#pragma unroll
    for (int j = 0; j < 4; ++j) {
      int gc = bcol + tx * 4 + j;
      if (gc >= N) continue;
      C[(size_t)gr * N + gc] = acc[i][j];
    }
  }
}

// ---------------- digit machinery (i8, base-128) ----------------

__global__ void k_wmax(const double* __restrict__ t, const double* __restrict__ dinv,
                       unsigned* __restrict__ wmax, int K, int N) {
  __shared__ float red[256];
  float mx = 0.0f;
  int tot = K * N;
  for (int i = blockIdx.x * 256 + threadIdx.x; i < tot; i += gridDim.x * 256) {
    double w = dinv[i / N] * t[i];
    mx = fmaxf(mx, (float)fabs(w));
  }
  red[threadIdx.x] = mx;
  __syncthreads();
  for (int st = 128; st > 0; st >>= 1) {
    if (threadIdx.x < st) red[threadIdx.x] = fmaxf(red[threadIdx.x], red[threadIdx.x + st]);
    __syncthreads();
  }
  if (threadIdx.x == 0) atomicMax(wmax, __builtin_bit_cast(unsigned, red[0]));
}

template <int D>
__global__ __launch_bounds__(256) void k_digitize8(
    const double* __restrict__ t, const double* __restrict__ dinv,
    const unsigned* __restrict__ wmax, char* __restrict__ wdT,
    int K, int Kpad, int N) {
  __shared__ char sm[D][64][68];
  const int tid = threadIdx.x;
  const int k0 = blockIdx.x * 64, n0 = blockIdx.y * 64;
  float wm = __builtin_bit_cast(float, *wmax);
  double sc = (wm > 0.0f) ? scalbn(1.0, -(ilogbf(wm) + 2)) : 0.0;
  const int kk = tid >> 2, ns = (tid & 3) * 16;
  int k = k0 + kk;
  double dv = (k < K) ? dinv[k] : 0.0;
#pragma unroll
  for (int j = 0; j < 16; ++j) {
    int n = n0 + ns + j;
    double w = (k < K) ? dv * t[(size_t)k * N + n] : 0.0;
    double r = w * sc;
#pragma unroll
    for (int d = 0; d < D; ++d) {
      double rm = r * 128.0;
      double m = rint(rm);
      sm[d][kk][ns + j] = (char)(int)m;
      r = rm - m;
    }
  }
  __syncthreads();
  const int nn = tid >> 2, ks = (tid & 3) * 16;
  const size_t PS = (size_t)N * Kpad;
#pragma unroll
  for (int d = 0; d < D; ++d) {
    char o[16];
#pragma unroll
    for (int j = 0; j < 16; ++j) o[j] = sm[d][ks + j][nn];
    *(int4*)&wdT[d * PS + (size_t)(n0 + nn) * Kpad + k0 + ks] = *(int4*)&o[0];
  }
}

// A3p f32 (nonneg, values-path) -> scaled 14-bit base-128 i8 planes.
__global__ void k_splitA8s(const float* __restrict__ A, int M, int ldsrc,
                           const unsigned* __restrict__ amax,
                           char* __restrict__ S, int Kpad) {
  int r = blockIdx.x;
  const size_t plane = (size_t)Kpad * Kpad;
  float am = __builtin_bit_cast(float, *amax);
  float s13 = (am > 0.0f) ? scalbnf(1.0f, 13 - (ilogbf(am) + 1)) : 0.0f;
  for (int c4 = threadIdx.x * 4; c4 < Kpad; c4 += blockDim.x * 4) {
    float v[4] = {0.f, 0.f, 0.f, 0.f};
    if (r < M && c4 < ldsrc) *(float4*)v = *(const float4*)(A + (size_t)r * ldsrc + c4);
    unsigned hw = 0, lw = 0;
#pragma unroll
    for (int q = 0; q < 4; ++q) {
      int iv = (int)rintf(v[q] * s13);
      int h = iv >> 7, l = iv - (h << 7);
      hw |= ((unsigned)(unsigned char)(char)h) << (8 * q);
      lw |= ((unsigned)(unsigned char)(char)l) << (8 * q);
    }
    *(unsigned*)(S + (size_t)r * Kpad + c4) = hw;
    *(unsigned*)(S + plane + (size_t)r * Kpad + c4) = lw;
  }
}

// P[Mp][Neff] i32 = A[Mp][Kpad] i8 @ wdT[Neff][Kpad]^T — DMA-pipelined i8 GEMM, exact.
__global__ __launch_bounds__(256) void k_axw_pipe8(
    const char* __restrict__ Asrc, const char* __restrict__ Bsrc,
    int Kpad, int* __restrict__ P, int Neff)
{
  __shared__ __align__(16) char Ls[2][2][8192];
  const int tid = threadIdx.x;
  const int wave = tid >> 6, lane = tid & 63;
  const int wr = wave >> 1, wc = wave & 1;
  const int brow = blockIdx.y * 128, bcol = blockIdx.x * 128;
  const int lr = lane & 15, ko = (lane >> 4) * 16;
  const int koff = (lane & 3) * 16;

  const char* pA[2];
  const char* pB[2];
#pragma unroll
  for (int c = 0; c < 2; ++c) {
    int r = (c * 4 + wave) * 16 + (lane >> 2);
    pA[c] = Asrc + (size_t)(brow + r) * Kpad;
    pB[c] = Bsrc + (size_t)(bcol + r) * Kpad;
  }

  i32x4 acc[4][4];
#pragma unroll
  for (int m = 0; m < 4; ++m)
#pragma unroll
    for (int n = 0; n < 4; ++n) acc[m][n] = (i32x4){0, 0, 0, 0};

  auto STAGE = [&](int buf, int kt) {
#pragma unroll
    for (int c = 0; c < 2; ++c) {
      int f = c * 4 + wave;
      gl2lds16(pA[c] + kt + koff, &Ls[buf][0][f * 1024]);
      gl2lds16(pB[c] + kt + koff, &Ls[buf][1][f * 1024]);
    }
  };

  STAGE(0, 0);
  __syncthreads();
  int cur = 0;
  for (int kt = 0; kt < Kpad; kt += 64) {
    if (kt + 64 < Kpad) STAGE(cur ^ 1, kt + 64);
    i32x4 a0[4], b0[4];
#pragma unroll
    for (int m = 0; m < 4; ++m) a0[m] = *(const i32x4*)&Ls[cur][0][(wr * 64 + m * 16 + lr) * 64 + ko];
#pragma unroll
    for (int n = 0; n < 4; ++n) b0[n] = *(const i32x4*)&Ls[cur][1][(wc * 64 + n * 16 + lr) * 64 + ko];
#pragma unroll
    for (int m = 0; m < 4; ++m)
#pragma unroll
      for (int n = 0; n < 4; ++n)
        acc[m][n] = __builtin_amdgcn_mfma_i32_16x16x64_i8(a0[m], b0[n], acc[m][n], 0, 0, 0);
    __syncthreads();
    cur ^= 1;
  }

#pragma unroll
  for (int m = 0; m < 4; ++m)
#pragma unroll
    for (int n = 0; n < 4; ++n)
#pragma unroll
      for (int q = 0; q < 4; ++q) {
        int grow = brow + wr * 64 + m * 16 + (lane >> 4) * 4 + q;
        int gcol = bcol + wc * 64 + n * 16 + lr;
        P[(size_t)grow * Neff + gcol] = acc[m][n][q];
      }
}

// fused reduce_y + gcn_fin (+ optional per-row scores, + optional f32 output with tail zero)
template <int SCORES, int OUT32>
__global__ void k_reduce_fin(const int* __restrict__ P, const unsigned* __restrict__ wmax,
                             const unsigned* __restrict__ amax,
                             const double* __restrict__ t, const double* __restrict__ dinv,
                             const float* __restrict__ bias, double* __restrict__ out,
                             float* __restrict__ fout, int nvals, int total,
                             const float* __restrict__ p, double* __restrict__ scv,
                             unsigned* __restrict__ rst,
                             int Neff, int N, int D, int M0pad, int nplane,
                             double w0, double w1, int relu) {
  int m = blockIdx.x;
  if (SCORES) { if (m == 0 && threadIdx.x == 0 && rst) *rst = 0u; }
  float wm = __builtin_bit_cast(float, *wmax);
  double s0 = w0, s1 = w1;
  bool zero = (wm <= 0.0f);
  if (amax) {
    float am = __builtin_bit_cast(float, *amax);
    if (am > 0.0f) {
      int EA = ilogbf(am) + 1;
      s0 = scalbn(w0, EA - 13);
      s1 = scalbn(w1, EA - 13);
    } else zero = true;
  }
  int Ep = zero ? 0 : (ilogbf(wm) + 2);
  double d = dinv[m];
  __shared__ double red[256], red2[256];
  double sdot = 0.0, sp2 = 0.0;
  for (int n = threadIdx.x; n < N; n += blockDim.x) {
    double acc = 0.0;
    if (!zero) {
      for (int dd = 0; dd < D; ++dd) {
        double v = s0 * (double)P[(size_t)m * Neff + dd * N + n];
        if (nplane == 2) v += s1 * (double)P[(size_t)(M0pad + m) * Neff + dd * N + n];
        acc += scalbn(v, Ep - 7 * (dd + 1));
      }
    }
    double v = d * (acc + 2.0 * d * t[(size_t)m * N + n]) + (double)bias[n];
    if (relu) v = v > 0.0 ? v : 0.0;
    if (OUT32) fout[(size_t)m * N + n] = (float)v;
    else out[(size_t)m * N + n] = v;
    if (SCORES) {
      double pv = (double)p[n];
      sdot += v * pv;
      sp2 += pv * pv;
    }
  }
  if (OUT32) {  // block 0 zeroes the batch tail
    if (m == 0)
      for (int i = nvals + threadIdx.x; i < total; i += blockDim.x) fout[i] = 0.0f;
  }
  if (SCORES) {
    red[threadIdx.x] = sdot;
    red2[threadIdx.x] = sp2;
    __syncthreads();
    for (int st = 128; st > 0; st >>= 1) {
      if (threadIdx.x < st) {
        red[threadIdx.x] += red[threadIdx.x + st];
        red2[threadIdx.x] += red2[threadIdx.x + st];
      }
      __syncthreads();
    }
    if (threadIdx.x == 0) scv[m] = tanh(red[0] / sqrt(red2[0]));
  }
}

// ---------------- GCN tail / pooling ----------------

template <typename TA>
__device__ __forceinline__ float a_as_f32(TA v);
template <> __device__ __forceinline__ float a_as_f32<char>(char v) { return (float)v; }
template <> __device__ __forceinline__ float a_as_f32<float>(float v) { return v; }

template <typename TA>
__global__ void k_degdinv(const TA* __restrict__ A, int lda, double* __restrict__ dinv, int n,
                          unsigned* __restrict__ rst0, unsigned* __restrict__ rst1) {
  if (blockIdx.x == 0 && threadIdx.x == 0) {
    if (rst0) *rst0 = 0u;
    if (rst1) *rst1 = 0u;
  }
  __shared__ double red[256];
  int row = blockIdx.x;
  double s = 0.0;
  for (int j = threadIdx.x; j < n; j += 256) s += (double)a_as_f32<TA>(A[(size_t)row * lda + j]);
  red[threadIdx.x] = s;
  __syncthreads();
  for (int st = 128; st > 0; st >>= 1) {
    if (threadIdx.x < st) red[threadIdx.x] += red[threadIdx.x + st];
    __syncthreads();
  }
  if (threadIdx.x == 0) {
    double deg = red[0] + 2.0;
    dinv[row] = (deg > 0.0) ? 1.0 / sqrt(deg) : 0.0;
  }
}

// dinv from 2-plane i8 (128*h + l): exact integer row sums.
__global__ void k_degdinv2p(const char* __restrict__ S, int Kpad, double* __restrict__ dinv,
                            int n, unsigned* __restrict__ rst0) {
  if (blockIdx.x == 0 && threadIdx.x == 0 && rst0) *rst0 = 0u;
  __shared__ double red[256];
  const size_t plane = (size_t)Kpad * Kpad;
  int row = blockIdx.x;
  const char* h = S + (size_t)row * Kpad;
  const char* l = S + plane + (size_t)row * Kpad;
  long s = 0;
  for (int j = threadIdx.x; j < n; j += 256) s += 128 * (long)h[j] + (long)l[j];
  red[threadIdx.x] = (double)s;
  __syncthreads();
  for (int st = 128; st > 0; st >>= 1) {
    if (threadIdx.x < st) red[threadIdx.x] += red[threadIdx.x + st];
    __syncthreads();
  }
  if (threadIdx.x == 0) {
    double deg = red[0] + 2.0;
    dinv[row] = (deg > 0.0) ? 1.0 / sqrt(deg) : 0.0;
  }
}

// rank-count top-k (bitwise-identical to full sort under (score desc, idx asc))
__global__ __launch_bounds__(256) void k_topk_rank(
    const double* __restrict__ sc, int n, int k,
    int* __restrict__ perm, double* __restrict__ vals) {
  __shared__ int red[256];
  const int i = blockIdx.x;
  const double si = sc[i];
  int cnt = 0;
  for (int j = threadIdx.x; j < n; j += 256) {
    double sj = sc[j];
    if (sj > si || (sj == si && j < i)) ++cnt;
  }
  red[threadIdx.x] = cnt;
  __syncthreads();
  for (int st = 128; st > 0; st >>= 1) {
    if (threadIdx.x < st) red[threadIdx.x] += red[threadIdx.x + st];
    __syncthreads();
  }
  if (threadIdx.x == 0) {
    int rank = red[0];
    if (rank < k) { perm[rank] = i; vals[rank] = si; }
  }
}

__global__ void k_sentinel(float* __restrict__ out, int total) {
  int i = blockIdx.x * blockDim.x + threadIdx.x;
  int st = gridDim.x * blockDim.x;
  for (; i < total; i += st) out[i] = 1e30f;
}

// ---------------- driver ----------------

extern "C" void kernel_launch(void* const* d_in, const int* in_sizes, int n_in,
                              void* d_out, int out_size, void* d_ws, size_t ws_size,
                              hipStream_t stream) {
  const float* x0f  = (const float*)d_in[0];
  const int*   ei   = (const int*)d_in[1];
  const float* W0   = (const float*)d_in[2];
  const float* b0   = (const float*)d_in[3];
  const float* W1   = (const float*)d_in[4];
  const float* b1   = (const float*)d_in[5];
  const float* W2   = (const float*)d_in[6];
  const float* b2   = (const float*)d_in[7];
  const float* p1   = (const float*)d_in[8];
  const float* p2   = (const float*)d_in[9];
  const float* Wout = (const float*)d_in[10];
  const float* bout = (const float*)d_in[11];
  const int E = in_sizes[1] / 2;

  const size_t MiB = 1ull << 20;
  if (ws_size < 160 * MiB) {
    k_sentinel<<<dim3(256), dim3(256), 0, stream>>>((float*)d_out, out_size);
    return;
  }
  char* W = (char*)d_ws;
  const size_t PL2 = (size_t)KI2 * KI2;
  // epoch A: build + aug1 (A0 built directly as i8)
  char*  A0s8  = (char*)(W + 64 * MiB);      // 16 MiB
  char*  A0s8T = (char*)(W + 80 * MiB);      // 16 MiB (+2I folded)
  // epoch A2: gcn1
  char*  A1    = (char*)(W + 0);
  char*  A1T   = (char*)(W + 16 * MiB);
  char*  wdT1  = (char*)(W + 32 * MiB);
  int*   P1    = (int*)(W + 40 * MiB);
  // epoch B: aug2 + gcn2
  char*  A2s8  = (char*)(W + 64 * MiB);
  char*  A2s8T = (char*)(W + 86 * MiB);
  char*  wdT2  = (char*)(W + 0);
  int*   P2    = (int*)(W + 7 * MiB);
  // epoch C: aug3 + gcn3/out
  float* A3p     = (float*)(W + 108 * MiB);
  char*  A3stack = (char*)(W + 0);
  char*  wdT3    = (char*)(W + 8 * MiB);
  int*   P3      = (int*)(W + 10 * MiB);
  // features
  double* tb   = (double*)(W + 128 * MiB);
  double* xA   = (double*)(W + 144 * MiB);
  char* SM = W + (159 * MiB + 256 * 1024);
  double* dinv = (double*)(SM);
  double* sc   = (double*)(SM + 32768);
  double* vals = (double*)(SM + 65536);
  unsigned* wmax  = (unsigned*)(SM + 98304 + 128);
  unsigned* a3max = (unsigned*)(SM + 98304 + 192);
  int* perm    = (int*)(SM + 98304 + 256);
  int* permB   = (int*)(SM + 98304 + 256 + 16384);
  char* zpage  = (char*)(W + 159 * MiB + 512 * 1024);

  // ---- build A0 as i8 + transpose (+2I) ----
  k_zero32<<<dim3(8), dim3(256), 0, stream>>>((float*)zpage, 8192);
  k_zero32<<<dim3(1024), dim3(256), 0, stream>>>((float*)A0s8, (size_t)N0 * N0 / 4);
  k_build_adj8<<<dim3((E + 255) / 256), dim3(256), 0, stream>>>(ei, (unsigned*)A0s8, E, N0);
  k_transpose_i8s<<<dim3(64, 64, 1), dim3(256), 0, stream>>>(A0s8, A0s8T, N0, 0, 2, 0);

  // ---- aug1 ----
  k_aug_pipe8<0><<<dim3(32, 32), dim3(256), 0, stream>>>(
      A0s8, A0s8T, nullptr, zpage, N0, N0, A1, 0, N0, N0, N0);
  k_transpose_i8s<<<dim3(64, 64, 1), dim3(256), 0, stream>>>(A1, A1T, N0, 0, 2, 0);

  // ---- gcn1 (x@W reads f32 x0 directly) ----
  {
    dim3 b(16, 16);
    k_gemm_xw32<float, 0><<<dim3(HID / 64, (N0 + 31) / 32), b, 0, stream>>>(
        x0f, nullptr, nullptr, W0, tb, N0, HID, CIN, nullptr);
    k_degdinv<char><<<dim3(N0), dim3(256), 0, stream>>>(A1, N0, dinv, N0, wmax, nullptr);
    k_wmax<<<dim3(256), dim3(256), 0, stream>>>(tb, dinv, wmax, N0, HID);
    k_digitize8<DNUM><<<dim3(N0 / 64, HID / 64), dim3(256), 0, stream>>>(tb, dinv, wmax, wdT1, N0, N0, HID);
    k_axw_pipe8<<<dim3(DNUM * HID / 128, N0 / 128), dim3(256), 0, stream>>>(A1, wdT1, N0, P1, DNUM * HID);
    k_reduce_fin<1, 0><<<dim3(N0), dim3(256), 0, stream>>>(
        P1, wmax, nullptr, tb, dinv, b0, xA, nullptr, 0, 0, p1, sc, nullptr,
        DNUM * HID, HID, DNUM, 0, 1, 1.0, 0.0, 1);
  }

  // ---- pool1 ----
  k_topk_rank<<<dim3(N0), dim3(256), 0, stream>>>(sc, N0, K1P, perm, vals);

  // ---- aug2 ----
  k_aug_pipe8<1><<<dim3(26, 26), dim3(256), 0, stream>>>(
      A1, A1T, perm, zpage, N0, N0, A2s8, PL2, KI2, K1P, K1P);
  k_transpose_i8s<<<dim3(52, 52, 2), dim3(256), 0, stream>>>(A2s8, A2s8T, KI2, PL2, 0, 2);

  // ---- gcn2 (x@W gathers xA[perm]*vals inline) ----
  {
    dim3 b(16, 16);
    k_gemm_xw32<double, 1><<<dim3(HID / 64, (K1P + 31) / 32), b, 0, stream>>>(
        xA, perm, vals, W1, tb, K1P, HID, HID, nullptr);
    k_degdinv2p<<<dim3(K1P), dim3(256), 0, stream>>>(A2s8, KI2, dinv, K1P, wmax);
    k_wmax<<<dim3(256), dim3(256), 0, stream>>>(tb, dinv, wmax, K1P, HID);
    k_digitize8<DNUM><<<dim3(KI2 / 64, HID / 64), dim3(256), 0, stream>>>(tb, dinv, wmax, wdT2, K1P, KI2, HID);
    k_axw_pipe8<<<dim3(DNUM * HID / 128, 2 * KI2 / 128), dim3(256), 0, stream>>>(A2s8, wdT2, KI2, P2, DNUM * HID);
    k_reduce_fin<1, 0><<<dim3(K1P), dim3(256), 0, stream>>>(
        P2, wmax, nullptr, tb, dinv, b1, xA, nullptr, 0, 0, p2, sc, a3max,
        DNUM * HID, HID, DNUM, KI2, 2, 128.0, 1.0, 1);
  }

  // ---- pool2 ----
  k_topk_rank<<<dim3(K1P), dim3(256), 0, stream>>>(sc, K1P, K2P, permB, vals);

  // ---- aug3 ----
  k_aug3_pipe8<<<dim3(16, 16), dim3(512), 0, stream>>>(
      A2s8, A2s8T, permB, zpage, KI2, A3p, a3max, K2P, K2P, LD3);

  // ---- gcn3 (x@W gathers xA[permB]*vals inline) ----
  {
    dim3 b(16, 16);
    k_gemm_xw32<double, 1><<<dim3(HID / 64, (K2P + 31) / 32), b, 0, stream>>>(
        xA, permB, vals, W2, tb, K2P, HID, HID, nullptr);
    k_degdinv<float><<<dim3(K2P), dim3(256), 0, stream>>>(A3p, LD3, dinv, K2P, wmax, nullptr);
    k_splitA8s<<<dim3(KI3), dim3(256), 0, stream>>>(A3p, K2P, LD3, a3max, A3stack, KI3);
    k_wmax<<<dim3(256), dim3(256), 0, stream>>>(tb, dinv, wmax, K2P, HID);
    k_digitize8<2><<<dim3(KI3 / 64, HID / 64), dim3(256), 0, stream>>>(tb, dinv, wmax, wdT3, K2P, KI3, HID);
    k_axw_pipe8<<<dim3(2 * HID / 128, 2 * KI3 / 128), dim3(256), 0, stream>>>(A3stack, wdT3, KI3, P3, 2 * HID);
    k_reduce_fin<0, 0><<<dim3(K2P), dim3(256), 0, stream>>>(
        P3, wmax, a3max, tb, dinv, b2, xA, nullptr, 0, 0, nullptr, nullptr, nullptr,
        2 * HID, HID, 2, KI3, 2, 128.0, 1.0, 1);
  }

  // ---- gcn_out (f32 output fused, tail zeroed) ----
  {
    dim3 b(16, 16);
    k_gemm_xw32<double, 0><<<dim3(COUTC / 64, (K2P + 31) / 32), b, 0, stream>>>(
        xA, nullptr, nullptr, Wout, tb, K2P, COUTC, HID, wmax);
    k_wmax<<<dim3(256), dim3(256), 0, stream>>>(tb, dinv, wmax, K2P, COUTC);
    k_digitize8<2><<<dim3(KI3 / 64, COUTC / 64), dim3(256), 0, stream>>>(tb, dinv, wmax, wdT3, K2P, KI3, COUTC);
    k_axw_pipe8<<<dim3(2 * COUTC / 128, 2 * KI3 / 128), dim3(256), 0, stream>>>(A3stack, wdT3, KI3, P3, 2 * COUTC);
    k_reduce_fin<0, 1><<<dim3(K2P), dim3(256), 0, stream>>>(
        P3, wmax, a3max, tb, dinv, bout, nullptr, (float*)d_out, K2P * COUTC, out_size,
        nullptr, nullptr, nullptr, 2 * COUTC, COUTC, 2, KI3, 2, 128.0, 1.0, 0);
  }
}